// Round 1
// baseline (1807.265 us; speedup 1.0000x reference)
//
#include <hip/hip_runtime.h>

#define BDIM 8
#define NDIM 1024
#define KNN 20

// ---------------- KNN: exact formula match with numpy reference ----------------
__global__ __launch_bounds__(256) void knn_kernel(const float* __restrict__ x,
                                                  int* __restrict__ nn) {
#pragma clang fp contract(off)
  __shared__ float xs0[NDIM], xs1[NDIM], xs2[NDIM], sq[NDIM];
  const int b = blockIdx.x >> 2;
  const int n = ((blockIdx.x & 3) << 8) + threadIdx.x;
  for (int i = threadIdx.x; i < NDIM; i += 256) {
    float a0 = x[(b * 3 + 0) * NDIM + i];
    float a1 = x[(b * 3 + 1) * NDIM + i];
    float a2 = x[(b * 3 + 2) * NDIM + i];
    xs0[i] = a0; xs1[i] = a1; xs2[i] = a2;
    sq[i] = (a0 * a0 + a1 * a1) + a2 * a2;
  }
  __syncthreads();
  const float xn0 = xs0[n], xn1 = xs1[n], xn2 = xs2[n], sqn = sq[n];
  float dist[KNN];
  int idx[KNN];
#pragma unroll
  for (int j = 0; j < KNN; ++j) { dist[j] = 3.4e38f; idx[j] = 0; }
  for (int m = 0; m < NDIM; ++m) {
    float dot = (xn0 * xs0[m] + xn1 * xs1[m]) + xn2 * xs2[m];
    float d = (sqn - 2.0f * dot) + sq[m];
    if (d < dist[KNN - 1]) {   // strict <: stable, lower index wins ties
      dist[KNN - 1] = d; idx[KNN - 1] = m;
#pragma unroll
      for (int j = KNN - 1; j > 0; --j) {
        if (dist[j] < dist[j - 1]) {
          float td = dist[j]; dist[j] = dist[j - 1]; dist[j - 1] = td;
          int ti = idx[j]; idx[j] = idx[j - 1]; idx[j - 1] = ti;
        }
      }
    }
  }
#pragma unroll
  for (int j = 0; j < KNN; ++j) nn[(b * NDIM + n) * KNN + j] = idx[j];
}

// ---------------- generic 4x4-microtile conv over LDS tiles ----------------
template <int CINC, int COUTC, int INP, int OUTP>
__device__ inline void tile_conv(const float* __restrict__ Xls,
                                 const float* __restrict__ w,
                                 const float* __restrict__ bias,
                                 float* __restrict__ Yls, int tid) {
  constexpr int PG = (2 * KNN) / 4;  // 10 position groups
  constexpr int NT = PG * (COUTC / 4);
  for (int t = tid; t < NT; t += 256) {
    int pg = t % PG, og = t / PG;
    float acc[4][4];
#pragma unroll
    for (int j = 0; j < 4; ++j) {
      float bj = bias[og * 4 + j];
#pragma unroll
      for (int i = 0; i < 4; ++i) acc[i][j] = bj;
    }
    for (int cin = 0; cin < CINC; cin += 4) {
      float4 xr[4], wr[4];
#pragma unroll
      for (int i = 0; i < 4; ++i)
        xr[i] = *(const float4*)&Xls[(pg * 4 + i) * INP + cin];
#pragma unroll
      for (int j = 0; j < 4; ++j)
        wr[j] = *(const float4*)&w[(og * 4 + j) * CINC + cin];
#pragma unroll
      for (int i = 0; i < 4; ++i)
#pragma unroll
        for (int j = 0; j < 4; ++j) {
          acc[i][j] += xr[i].x * wr[j].x;
          acc[i][j] += xr[i].y * wr[j].y;
          acc[i][j] += xr[i].z * wr[j].z;
          acc[i][j] += xr[i].w * wr[j].w;
        }
    }
#pragma unroll
    for (int i = 0; i < 4; ++i)
#pragma unroll
      for (int j = 0; j < 4; ++j)
        Yls[(pg * 4 + i) * OUTP + og * 4 + j] = fmaxf(acc[i][j], 0.0f);
  }
}

// ---------------- edge MP: 2 rows (40 positions) per block ----------------
template <int CE, int CH, int CMID, int COUT, bool FIRST, bool WRITE_E>
__global__ __launch_bounds__(256) void edge_mp(
    const float* __restrict__ eprev, const float* __restrict__ h,
    const float* __restrict__ inputs, const int* __restrict__ nnb,
    const float* __restrict__ w1, const float* __restrict__ b1v,
    const float* __restrict__ w2, const float* __restrict__ b2v,
    float* __restrict__ eout, float* __restrict__ mout) {
  constexpr int CIN = CE + 2 * CH;
  constexpr int TP = 2 * KNN;  // 40
  constexpr int XP = CIN + 4;
  constexpr int Y1P = CMID + 4;
  constexpr int Y2P = COUT + 4;
  __shared__ float Xs[TP * XP];
  __shared__ float Y1s[TP * Y1P];
  __shared__ float Y2s[TP * Y2P];
  __shared__ int nns[TP];
  const int tid = threadIdx.x;
  const int bn0 = blockIdx.x * 2;
  const int b = bn0 >> 10;
  if (tid < TP) nns[tid] = nnb[bn0 * KNN + tid];
  __syncthreads();
  // assemble X = [e_prev, h_i, h_j]
  for (int idx = tid; idx < TP * CIN; idx += 256) {
    int p = idx / CIN, c = idx - p * CIN;
    int bn = bn0 + (p >= KNN ? 1 : 0);
    int n = bn & (NDIM - 1);
    int j = nns[p];
    float v;
    if (FIRST) {
      int cc = c % 3;
      int seg = c / 3;  // 0: h_i  1: h_i-h_j  2: h_i  3: h_j
      float hi = inputs[(b * 3 + cc) * NDIM + n];
      float hj = inputs[(b * 3 + cc) * NDIM + j];
      v = (seg == 1) ? (hi - hj) : ((seg == 3) ? hj : hi);
    } else {
      if (c < CE) v = eprev[(bn0 * KNN + p) * CE + c];
      else if (c < CE + CH) v = h[bn * CH + (c - CE)];
      else v = h[((b << 10) + j) * CH + (c - CE - CH)];
    }
    Xs[p * XP + c] = v;
  }
  __syncthreads();
  tile_conv<CIN, CMID, XP, Y1P>(Xs, w1, b1v, Y1s, tid);
  __syncthreads();
  tile_conv<CMID, COUT, Y1P, Y2P>(Y1s, w2, b2v, Y2s, tid);
  __syncthreads();
  if constexpr (WRITE_E) {
    for (int idx = tid; idx < TP * COUT / 4; idx += 256) {
      int p = idx / (COUT / 4), c4 = idx - p * (COUT / 4);
      float4 v = *(const float4*)&Y2s[p * Y2P + c4 * 4];
      *(float4*)&eout[(bn0 * KNN + p) * COUT + c4 * 4] = v;
    }
  }
  // deterministic m = sum_k e (ascending k, matches numpy order)
  for (int idx = tid; idx < 2 * COUT; idx += 256) {
    int r = idx / COUT, c = idx - r * COUT;
    float s = 0.0f;
#pragma unroll
    for (int k = 0; k < KNN; ++k) s += Y2s[(r * KNN + k) * Y2P + c];
    mout[(bn0 + r) * COUT + c] = s;
  }
}

// ---------------- node MP: one wave per (b,n) row ----------------
template <int CH, int CM, int CMID, int COUT, bool FIRSTH>
__global__ __launch_bounds__(64) void node_mp(
    const float* __restrict__ h, const float* __restrict__ inputs,
    const float* __restrict__ mbuf, const float* __restrict__ w1,
    const float* __restrict__ b1v, const float* __restrict__ w2,
    const float* __restrict__ b2v, float* __restrict__ hout) {
  constexpr int CIN = CH + CM;
  __shared__ float xs[CIN];
  __shared__ float ys[CMID];
  const int bn = blockIdx.x;
  const int tid = threadIdx.x;
  if (FIRSTH) {
    int b = bn >> 10, n = bn & (NDIM - 1);
    if (tid < CH) xs[tid] = inputs[(b * 3 + tid) * NDIM + n];
  } else {
    for (int c = tid; c < CH; c += 64) xs[c] = h[bn * CH + c];
  }
  for (int c = tid; c < CM; c += 64) xs[CH + c] = mbuf[bn * CM + c];
  __syncthreads();
  for (int oc = tid; oc < CMID; oc += 64) {
    float acc = b1v[oc];
    for (int cin = 0; cin < CIN; ++cin) acc += xs[cin] * w1[oc * CIN + cin];
    ys[oc] = fmaxf(acc, 0.0f);
  }
  __syncthreads();
  for (int oc = tid; oc < COUT; oc += 64) {
    float acc = b2v[oc];
#pragma unroll 4
    for (int cin = 0; cin < CMID; ++cin) acc += ys[cin] * w2[oc * CMID + cin];
    hout[bn * COUT + oc] = fmaxf(acc, 0.0f);
  }
}

// ---------------- fusion conv (384->512) + relu + global max pool ----------------
__global__ __launch_bounds__(256) void fuse_pool(
    const float* __restrict__ h1, const float* __restrict__ h2,
    const float* __restrict__ h3, const float* __restrict__ fw,
    const float* __restrict__ fb, int* __restrict__ pooled) {
  constexpr int CIN = 384, COUT = 512, TP = 16, XP = CIN + 4;
  __shared__ float Xs[TP * XP];
  __shared__ int pmax[COUT];
  const int tid = threadIdx.x;
  const int bn0 = blockIdx.x * TP;
  const int b = bn0 >> 10;
  for (int i = tid; i < COUT; i += 256) pmax[i] = 0;
  for (int idx = tid; idx < TP * CIN; idx += 256) {
    int p = idx / CIN, c = idx - p * CIN;
    int bn = bn0 + p;
    float v;
    if (c < 64) v = h1[bn * 64 + c];
    else if (c < 192) v = h2[bn * 128 + (c - 64)];
    else v = h3[bn * 192 + (c - 192)];
    Xs[p * XP + c] = v;
  }
  __syncthreads();
  constexpr int PG = TP / 4;           // 4
  constexpr int NT = PG * (COUT / 4);  // 512
  for (int t = tid; t < NT; t += 256) {
    int pg = t % PG, og = t / PG;
    float acc[4][4];
#pragma unroll
    for (int j = 0; j < 4; ++j) {
      float bj = fb[og * 4 + j];
#pragma unroll
      for (int i = 0; i < 4; ++i) acc[i][j] = bj;
    }
    for (int cin = 0; cin < CIN; cin += 4) {
      float4 xr[4], wr[4];
#pragma unroll
      for (int i = 0; i < 4; ++i)
        xr[i] = *(const float4*)&Xs[(pg * 4 + i) * XP + cin];
#pragma unroll
      for (int j = 0; j < 4; ++j)
        wr[j] = *(const float4*)&fw[(og * 4 + j) * CIN + cin];
#pragma unroll
      for (int i = 0; i < 4; ++i)
#pragma unroll
        for (int j = 0; j < 4; ++j) {
          acc[i][j] += xr[i].x * wr[j].x;
          acc[i][j] += xr[i].y * wr[j].y;
          acc[i][j] += xr[i].z * wr[j].z;
          acc[i][j] += xr[i].w * wr[j].w;
        }
    }
#pragma unroll
    for (int j = 0; j < 4; ++j) {
      float v = fmaxf(fmaxf(acc[0][j], acc[1][j]), fmaxf(acc[2][j], acc[3][j]));
      v = fmaxf(v, 0.0f);
      atomicMax(&pmax[og * 4 + j], __float_as_int(v));
    }
  }
  __syncthreads();
  for (int i = tid; i < COUT; i += 256)
    atomicMax(&pooled[b * COUT + i], pmax[i]);
}

// ---------------- prediction head ----------------
__global__ __launch_bounds__(256) void head_kernel(
    const int* __restrict__ pooledi, const float* __restrict__ p1w,
    const float* __restrict__ p1b, const float* __restrict__ p2w,
    const float* __restrict__ p2b, const float* __restrict__ p3w,
    const float* __restrict__ p3b, float* __restrict__ out) {
  __shared__ float xs[512], y1[256], y2[128];
  const int b = blockIdx.x, tid = threadIdx.x;
  for (int i = tid; i < 512; i += 256) xs[i] = __int_as_float(pooledi[b * 512 + i]);
  __syncthreads();
  {
    float acc = p1b[tid];
    for (int c = 0; c < 512; ++c) acc += xs[c] * p1w[tid * 512 + c];
    y1[tid] = fmaxf(acc, 0.0f);
  }
  __syncthreads();
  if (tid < 128) {
    float acc = p2b[tid];
    for (int c = 0; c < 256; ++c) acc += y1[c] * p2w[tid * 256 + c];
    y2[tid] = fmaxf(acc, 0.0f);
  }
  __syncthreads();
  if (tid < 40) {
    float acc = p3b[tid];
    for (int c = 0; c < 128; ++c) acc += y2[c] * p3w[tid * 128 + c];
    out[b * 40 + tid] = acc;
  }
}

__global__ void zero_kernel(int* __restrict__ p, int nel) {
  int i = blockIdx.x * 256 + threadIdx.x;
  if (i < nel) p[i] = 0;
}

extern "C" void kernel_launch(void* const* d_in, const int* in_sizes, int n_in,
                              void* d_out, int out_size, void* d_ws,
                              size_t ws_size, hipStream_t stream) {
  const float* inputs = (const float*)d_in[0];
  const float* he_w1 = (const float*)d_in[1];
  const float* he_b1 = (const float*)d_in[2];
  const float* he_w2 = (const float*)d_in[3];
  const float* he_b2 = (const float*)d_in[4];
  const float* hn_w1 = (const float*)d_in[5];
  const float* hn_b1 = (const float*)d_in[6];
  const float* hn_w2 = (const float*)d_in[7];
  const float* hn_b2 = (const float*)d_in[8];
  const float* b1e_w1 = (const float*)d_in[9];
  const float* b1e_b1 = (const float*)d_in[10];
  const float* b1e_w2 = (const float*)d_in[11];
  const float* b1e_b2 = (const float*)d_in[12];
  const float* b1n_w1 = (const float*)d_in[13];
  const float* b1n_b1 = (const float*)d_in[14];
  const float* b1n_w2 = (const float*)d_in[15];
  const float* b1n_b2 = (const float*)d_in[16];
  const float* b2e_w1 = (const float*)d_in[17];
  const float* b2e_b1 = (const float*)d_in[18];
  const float* b2e_w2 = (const float*)d_in[19];
  const float* b2e_b2 = (const float*)d_in[20];
  const float* b2n_w1 = (const float*)d_in[21];
  const float* b2n_b1 = (const float*)d_in[22];
  const float* b2n_w2 = (const float*)d_in[23];
  const float* b2n_b2 = (const float*)d_in[24];
  const float* f_w = (const float*)d_in[25];
  const float* f_b = (const float*)d_in[26];
  const float* p1_w = (const float*)d_in[27];
  const float* p1_b = (const float*)d_in[28];
  const float* p2_w = (const float*)d_in[29];
  const float* p2_b = (const float*)d_in[30];
  const float* p3_w = (const float*)d_in[31];
  const float* p3_b = (const float*)d_in[32];
  float* out = (float*)d_out;

  char* ws = (char*)d_ws;
  size_t off = 0;
  int* nn = (int*)(ws + off); off += (size_t)BDIM * NDIM * KNN * 4;
  float* m1 = (float*)(ws + off); off += (size_t)BDIM * NDIM * 64 * 4;
  float* h1 = (float*)(ws + off); off += (size_t)BDIM * NDIM * 64 * 4;
  float* e1 = (float*)(ws + off); off += (size_t)BDIM * NDIM * KNN * 64 * 4;
  float* m2 = (float*)(ws + off); off += (size_t)BDIM * NDIM * 128 * 4;
  float* h2 = (float*)(ws + off); off += (size_t)BDIM * NDIM * 128 * 4;
  float* e2 = (float*)(ws + off); off += (size_t)BDIM * NDIM * KNN * 128 * 4;
  float* m3 = (float*)(ws + off); off += (size_t)BDIM * NDIM * 192 * 4;
  float* h3 = (float*)(ws + off); off += (size_t)BDIM * NDIM * 192 * 4;
  int* pooled = (int*)(ws + off); off += (size_t)BDIM * 512 * 4;

  knn_kernel<<<BDIM * 4, 256, 0, stream>>>(inputs, nn);

  edge_mp<6, 3, 32, 64, true, true><<<BDIM * NDIM / 2, 256, 0, stream>>>(
      nullptr, nullptr, inputs, nn, he_w1, he_b1, he_w2, he_b2, e1, m1);
  node_mp<3, 64, 32, 64, true><<<BDIM * NDIM, 64, 0, stream>>>(
      nullptr, inputs, m1, hn_w1, hn_b1, hn_w2, hn_b2, h1);

  edge_mp<64, 64, 48, 128, false, true><<<BDIM * NDIM / 2, 256, 0, stream>>>(
      e1, h1, nullptr, nn, b1e_w1, b1e_b1, b1e_w2, b1e_b2, e2, m2);
  node_mp<64, 128, 48, 128, false><<<BDIM * NDIM, 64, 0, stream>>>(
      h1, nullptr, m2, b1n_w1, b1n_b1, b1n_w2, b1n_b2, h2);

  edge_mp<128, 128, 96, 192, false, false><<<BDIM * NDIM / 2, 256, 0, stream>>>(
      e2, h2, nullptr, nn, b2e_w1, b2e_b1, b2e_w2, b2e_b2, nullptr, m3);
  node_mp<128, 192, 96, 192, false><<<BDIM * NDIM, 64, 0, stream>>>(
      h2, nullptr, m3, b2n_w1, b2n_b1, b2n_w2, b2n_b2, h3);

  zero_kernel<<<(BDIM * 512 + 255) / 256, 256, 0, stream>>>(pooled, BDIM * 512);
  fuse_pool<<<BDIM * NDIM / 16, 256, 0, stream>>>(h1, h2, h3, f_w, f_b, pooled);
  head_kernel<<<BDIM, 256, 0, stream>>>(pooled, p1_w, p1_b, p2_w, p2_b, p3_w,
                                        p3_b, out);

  hipMemcpyAsync(out + BDIM * 40, d_in[0], (size_t)BDIM * 3 * NDIM * 4,
                 hipMemcpyDeviceToDevice, stream);
}

// Round 2
// 1067.341 us; speedup vs baseline: 1.6932x; 1.6932x over previous
//
#include <hip/hip_runtime.h>

#define BDIM 8
#define NDIM 1024
#define KNN 20

// ---------------- KNN v2: one wave per point, wave-parallel top-20 ----------------
// Distance formula and association kept bit-identical to the R1 version that
// matched the numpy reference exactly: d = (sqn - 2*dot) + sq[m],
// dot = (x0*x0 + x1*x1) + x2*x2, fp contract OFF.
// Selection: 20 rounds of lexicographic (dist, idx) wave-argmin == stable top_k.
__global__ __launch_bounds__(256) void knn_kernel(const float* __restrict__ x,
                                                  int* __restrict__ nn) {
#pragma clang fp contract(off)
  __shared__ float xs0[NDIM], xs1[NDIM], xs2[NDIM], sq[NDIM];
  const int tid = threadIdx.x;
  const int lane = tid & 63;
  const int w = tid >> 6;  // wave id 0..3
  const int b = blockIdx.x >> 8;              // 256 blocks per batch
  const int n = ((blockIdx.x & 255) << 2) + w;  // 4 points per block
  for (int i = tid; i < NDIM; i += 256) {
    float a0 = x[(b * 3 + 0) * NDIM + i];
    float a1 = x[(b * 3 + 1) * NDIM + i];
    float a2 = x[(b * 3 + 2) * NDIM + i];
    xs0[i] = a0; xs1[i] = a1; xs2[i] = a2;
    sq[i] = (a0 * a0 + a1 * a1) + a2 * a2;
  }
  __syncthreads();
  const float xn0 = xs0[n], xn1 = xs1[n], xn2 = xs2[n], sqn = sq[n];
  // each lane: 16 candidates m = t*64 + lane
  float dl[16];
#pragma unroll
  for (int t = 0; t < 16; ++t) {
    int m = t * 64 + lane;
    float dot = (xn0 * xs0[m] + xn1 * xs1[m]) + xn2 * xs2[m];
    dl[t] = (sqn - 2.0f * dot) + sq[m];
  }
  int* nnrow = &nn[(b * NDIM + n) * KNN];
  for (int r = 0; r < KNN; ++r) {
    // lane-local min (strict < keeps lowest t on ties -> lowest index)
    float bd = dl[0];
    int bt = 0;
#pragma unroll
    for (int t = 1; t < 16; ++t) {
      if (dl[t] < bd) { bd = dl[t]; bt = t; }
    }
    int bi = bt * 64 + lane;
    // wave butterfly argmin, lexicographic (dist, idx)
#pragma unroll
    for (int off = 1; off < 64; off <<= 1) {
      float pd = __shfl_xor(bd, off);
      int pi = __shfl_xor(bi, off);
      if (pd < bd || (pd == bd && pi < bi)) { bd = pd; bi = pi; }
    }
    if (lane == 0) nnrow[r] = bi;
    // mask the winner out of its owner's slot
    if ((bi & 63) == lane) {
      int wt = bi >> 6;
#pragma unroll
      for (int t = 0; t < 16; ++t) {
        if (t == wt) dl[t] = 3.4e38f;
      }
    }
  }
}

// ---------------- generic 4x4-microtile conv over LDS tiles ----------------
template <int CINC, int COUTC, int INP, int OUTP>
__device__ inline void tile_conv(const float* __restrict__ Xls,
                                 const float* __restrict__ w,
                                 const float* __restrict__ bias,
                                 float* __restrict__ Yls, int tid) {
  constexpr int PG = (2 * KNN) / 4;  // 10 position groups
  constexpr int NT = PG * (COUTC / 4);
  for (int t = tid; t < NT; t += 256) {
    int pg = t % PG, og = t / PG;
    float acc[4][4];
#pragma unroll
    for (int j = 0; j < 4; ++j) {
      float bj = bias[og * 4 + j];
#pragma unroll
      for (int i = 0; i < 4; ++i) acc[i][j] = bj;
    }
    for (int cin = 0; cin < CINC; cin += 4) {
      float4 xr[4], wr[4];
#pragma unroll
      for (int i = 0; i < 4; ++i)
        xr[i] = *(const float4*)&Xls[(pg * 4 + i) * INP + cin];
#pragma unroll
      for (int j = 0; j < 4; ++j)
        wr[j] = *(const float4*)&w[(og * 4 + j) * CINC + cin];
#pragma unroll
      for (int i = 0; i < 4; ++i)
#pragma unroll
        for (int j = 0; j < 4; ++j) {
          acc[i][j] += xr[i].x * wr[j].x;
          acc[i][j] += xr[i].y * wr[j].y;
          acc[i][j] += xr[i].z * wr[j].z;
          acc[i][j] += xr[i].w * wr[j].w;
        }
    }
#pragma unroll
    for (int i = 0; i < 4; ++i)
#pragma unroll
      for (int j = 0; j < 4; ++j)
        Yls[(pg * 4 + i) * OUTP + og * 4 + j] = fmaxf(acc[i][j], 0.0f);
  }
}

// ---------------- edge MP: 2 rows (40 positions) per block ----------------
template <int CE, int CH, int CMID, int COUT, bool FIRST, bool WRITE_E>
__global__ __launch_bounds__(256) void edge_mp(
    const float* __restrict__ eprev, const float* __restrict__ h,
    const float* __restrict__ inputs, const int* __restrict__ nnb,
    const float* __restrict__ w1, const float* __restrict__ b1v,
    const float* __restrict__ w2, const float* __restrict__ b2v,
    float* __restrict__ eout, float* __restrict__ mout) {
  constexpr int CIN = CE + 2 * CH;
  constexpr int TP = 2 * KNN;  // 40
  constexpr int XP = CIN + 4;
  constexpr int Y1P = CMID + 4;
  constexpr int Y2P = COUT + 4;
  __shared__ float Xs[TP * XP];
  __shared__ float Y1s[TP * Y1P];
  __shared__ float Y2s[TP * Y2P];
  __shared__ int nns[TP];
  const int tid = threadIdx.x;
  const int bn0 = blockIdx.x * 2;
  const int b = bn0 >> 10;
  if (tid < TP) nns[tid] = nnb[bn0 * KNN + tid];
  __syncthreads();
  // assemble X = [e_prev, h_i, h_j]
  for (int idx = tid; idx < TP * CIN; idx += 256) {
    int p = idx / CIN, c = idx - p * CIN;
    int bn = bn0 + (p >= KNN ? 1 : 0);
    int n = bn & (NDIM - 1);
    int j = nns[p];
    float v;
    if (FIRST) {
      int cc = c % 3;
      int seg = c / 3;  // 0: h_i  1: h_i-h_j  2: h_i  3: h_j
      float hi = inputs[(b * 3 + cc) * NDIM + n];
      float hj = inputs[(b * 3 + cc) * NDIM + j];
      v = (seg == 1) ? (hi - hj) : ((seg == 3) ? hj : hi);
    } else {
      if (c < CE) v = eprev[(bn0 * KNN + p) * CE + c];
      else if (c < CE + CH) v = h[bn * CH + (c - CE)];
      else v = h[((b << 10) + j) * CH + (c - CE - CH)];
    }
    Xs[p * XP + c] = v;
  }
  __syncthreads();
  tile_conv<CIN, CMID, XP, Y1P>(Xs, w1, b1v, Y1s, tid);
  __syncthreads();
  tile_conv<CMID, COUT, Y1P, Y2P>(Y1s, w2, b2v, Y2s, tid);
  __syncthreads();
  if constexpr (WRITE_E) {
    for (int idx = tid; idx < TP * COUT / 4; idx += 256) {
      int p = idx / (COUT / 4), c4 = idx - p * (COUT / 4);
      float4 v = *(const float4*)&Y2s[p * Y2P + c4 * 4];
      *(float4*)&eout[(bn0 * KNN + p) * COUT + c4 * 4] = v;
    }
  }
  // deterministic m = sum_k e (ascending k, matches numpy order)
  for (int idx = tid; idx < 2 * COUT; idx += 256) {
    int r = idx / COUT, c = idx - r * COUT;
    float s = 0.0f;
#pragma unroll
    for (int k = 0; k < KNN; ++k) s += Y2s[(r * KNN + k) * Y2P + c];
    mout[(bn0 + r) * COUT + c] = s;
  }
}

// ---------------- node MP: one wave per (b,n) row ----------------
template <int CH, int CM, int CMID, int COUT, bool FIRSTH>
__global__ __launch_bounds__(64) void node_mp(
    const float* __restrict__ h, const float* __restrict__ inputs,
    const float* __restrict__ mbuf, const float* __restrict__ w1,
    const float* __restrict__ b1v, const float* __restrict__ w2,
    const float* __restrict__ b2v, float* __restrict__ hout) {
  constexpr int CIN = CH + CM;
  __shared__ float xs[CIN];
  __shared__ float ys[CMID];
  const int bn = blockIdx.x;
  const int tid = threadIdx.x;
  if (FIRSTH) {
    int b = bn >> 10, n = bn & (NDIM - 1);
    if (tid < CH) xs[tid] = inputs[(b * 3 + tid) * NDIM + n];
  } else {
    for (int c = tid; c < CH; c += 64) xs[c] = h[bn * CH + c];
  }
  for (int c = tid; c < CM; c += 64) xs[CH + c] = mbuf[bn * CM + c];
  __syncthreads();
  for (int oc = tid; oc < CMID; oc += 64) {
    float acc = b1v[oc];
    for (int cin = 0; cin < CIN; ++cin) acc += xs[cin] * w1[oc * CIN + cin];
    ys[oc] = fmaxf(acc, 0.0f);
  }
  __syncthreads();
  for (int oc = tid; oc < COUT; oc += 64) {
    float acc = b2v[oc];
#pragma unroll 4
    for (int cin = 0; cin < CMID; ++cin) acc += ys[cin] * w2[oc * CMID + cin];
    hout[bn * COUT + oc] = fmaxf(acc, 0.0f);
  }
}

// ---------------- fusion conv (384->512) + relu + global max pool ----------------
__global__ __launch_bounds__(256) void fuse_pool(
    const float* __restrict__ h1, const float* __restrict__ h2,
    const float* __restrict__ h3, const float* __restrict__ fw,
    const float* __restrict__ fb, int* __restrict__ pooled) {
  constexpr int CIN = 384, COUT = 512, TP = 16, XP = CIN + 4;
  __shared__ float Xs[TP * XP];
  __shared__ int pmax[COUT];
  const int tid = threadIdx.x;
  const int bn0 = blockIdx.x * TP;
  const int b = bn0 >> 10;
  for (int i = tid; i < COUT; i += 256) pmax[i] = 0;
  for (int idx = tid; idx < TP * CIN; idx += 256) {
    int p = idx / CIN, c = idx - p * CIN;
    int bn = bn0 + p;
    float v;
    if (c < 64) v = h1[bn * 64 + c];
    else if (c < 192) v = h2[bn * 128 + (c - 64)];
    else v = h3[bn * 192 + (c - 192)];
    Xs[p * XP + c] = v;
  }
  __syncthreads();
  constexpr int PG = TP / 4;           // 4
  constexpr int NT = PG * (COUT / 4);  // 512
  for (int t = tid; t < NT; t += 256) {
    int pg = t % PG, og = t / PG;
    float acc[4][4];
#pragma unroll
    for (int j = 0; j < 4; ++j) {
      float bj = fb[og * 4 + j];
#pragma unroll
      for (int i = 0; i < 4; ++i) acc[i][j] = bj;
    }
    for (int cin = 0; cin < CIN; cin += 4) {
      float4 xr[4], wr[4];
#pragma unroll
      for (int i = 0; i < 4; ++i)
        xr[i] = *(const float4*)&Xs[(pg * 4 + i) * XP + cin];
#pragma unroll
      for (int j = 0; j < 4; ++j)
        wr[j] = *(const float4*)&fw[(og * 4 + j) * CIN + cin];
#pragma unroll
      for (int i = 0; i < 4; ++i)
#pragma unroll
        for (int j = 0; j < 4; ++j) {
          acc[i][j] += xr[i].x * wr[j].x;
          acc[i][j] += xr[i].y * wr[j].y;
          acc[i][j] += xr[i].z * wr[j].z;
          acc[i][j] += xr[i].w * wr[j].w;
        }
    }
#pragma unroll
    for (int j = 0; j < 4; ++j) {
      float v = fmaxf(fmaxf(acc[0][j], acc[1][j]), fmaxf(acc[2][j], acc[3][j]));
      v = fmaxf(v, 0.0f);
      atomicMax(&pmax[og * 4 + j], __float_as_int(v));
    }
  }
  __syncthreads();
  for (int i = tid; i < COUT; i += 256)
    atomicMax(&pooled[b * COUT + i], pmax[i]);
}

// ---------------- prediction head ----------------
__global__ __launch_bounds__(256) void head_kernel(
    const int* __restrict__ pooledi, const float* __restrict__ p1w,
    const float* __restrict__ p1b, const float* __restrict__ p2w,
    const float* __restrict__ p2b, const float* __restrict__ p3w,
    const float* __restrict__ p3b, float* __restrict__ out) {
  __shared__ float xs[512], y1[256], y2[128];
  const int b = blockIdx.x, tid = threadIdx.x;
  for (int i = tid; i < 512; i += 256) xs[i] = __int_as_float(pooledi[b * 512 + i]);
  __syncthreads();
  {
    float acc = p1b[tid];
    for (int c = 0; c < 512; ++c) acc += xs[c] * p1w[tid * 512 + c];
    y1[tid] = fmaxf(acc, 0.0f);
  }
  __syncthreads();
  if (tid < 128) {
    float acc = p2b[tid];
    for (int c = 0; c < 256; ++c) acc += y1[c] * p2w[tid * 256 + c];
    y2[tid] = fmaxf(acc, 0.0f);
  }
  __syncthreads();
  if (tid < 40) {
    float acc = p3b[tid];
    for (int c = 0; c < 128; ++c) acc += y2[c] * p3w[tid * 128 + c];
    out[b * 40 + tid] = acc;
  }
}

__global__ void zero_kernel(int* __restrict__ p, int nel) {
  int i = blockIdx.x * 256 + threadIdx.x;
  if (i < nel) p[i] = 0;
}

extern "C" void kernel_launch(void* const* d_in, const int* in_sizes, int n_in,
                              void* d_out, int out_size, void* d_ws,
                              size_t ws_size, hipStream_t stream) {
  const float* inputs = (const float*)d_in[0];
  const float* he_w1 = (const float*)d_in[1];
  const float* he_b1 = (const float*)d_in[2];
  const float* he_w2 = (const float*)d_in[3];
  const float* he_b2 = (const float*)d_in[4];
  const float* hn_w1 = (const float*)d_in[5];
  const float* hn_b1 = (const float*)d_in[6];
  const float* hn_w2 = (const float*)d_in[7];
  const float* hn_b2 = (const float*)d_in[8];
  const float* b1e_w1 = (const float*)d_in[9];
  const float* b1e_b1 = (const float*)d_in[10];
  const float* b1e_w2 = (const float*)d_in[11];
  const float* b1e_b2 = (const float*)d_in[12];
  const float* b1n_w1 = (const float*)d_in[13];
  const float* b1n_b1 = (const float*)d_in[14];
  const float* b1n_w2 = (const float*)d_in[15];
  const float* b1n_b2 = (const float*)d_in[16];
  const float* b2e_w1 = (const float*)d_in[17];
  const float* b2e_b1 = (const float*)d_in[18];
  const float* b2e_w2 = (const float*)d_in[19];
  const float* b2e_b2 = (const float*)d_in[20];
  const float* b2n_w1 = (const float*)d_in[21];
  const float* b2n_b1 = (const float*)d_in[22];
  const float* b2n_w2 = (const float*)d_in[23];
  const float* b2n_b2 = (const float*)d_in[24];
  const float* f_w = (const float*)d_in[25];
  const float* f_b = (const float*)d_in[26];
  const float* p1_w = (const float*)d_in[27];
  const float* p1_b = (const float*)d_in[28];
  const float* p2_w = (const float*)d_in[29];
  const float* p2_b = (const float*)d_in[30];
  const float* p3_w = (const float*)d_in[31];
  const float* p3_b = (const float*)d_in[32];
  float* out = (float*)d_out;

  char* ws = (char*)d_ws;
  size_t off = 0;
  int* nn = (int*)(ws + off); off += (size_t)BDIM * NDIM * KNN * 4;
  float* m1 = (float*)(ws + off); off += (size_t)BDIM * NDIM * 64 * 4;
  float* h1 = (float*)(ws + off); off += (size_t)BDIM * NDIM * 64 * 4;
  float* e1 = (float*)(ws + off); off += (size_t)BDIM * NDIM * KNN * 64 * 4;
  float* m2 = (float*)(ws + off); off += (size_t)BDIM * NDIM * 128 * 4;
  float* h2 = (float*)(ws + off); off += (size_t)BDIM * NDIM * 128 * 4;
  float* e2 = (float*)(ws + off); off += (size_t)BDIM * NDIM * KNN * 128 * 4;
  float* m3 = (float*)(ws + off); off += (size_t)BDIM * NDIM * 192 * 4;
  float* h3 = (float*)(ws + off); off += (size_t)BDIM * NDIM * 192 * 4;
  int* pooled = (int*)(ws + off); off += (size_t)BDIM * 512 * 4;

  knn_kernel<<<BDIM * 256, 256, 0, stream>>>(inputs, nn);

  edge_mp<6, 3, 32, 64, true, true><<<BDIM * NDIM / 2, 256, 0, stream>>>(
      nullptr, nullptr, inputs, nn, he_w1, he_b1, he_w2, he_b2, e1, m1);
  node_mp<3, 64, 32, 64, true><<<BDIM * NDIM, 64, 0, stream>>>(
      nullptr, inputs, m1, hn_w1, hn_b1, hn_w2, hn_b2, h1);

  edge_mp<64, 64, 48, 128, false, true><<<BDIM * NDIM / 2, 256, 0, stream>>>(
      e1, h1, nullptr, nn, b1e_w1, b1e_b1, b1e_w2, b1e_b2, e2, m2);
  node_mp<64, 128, 48, 128, false><<<BDIM * NDIM, 64, 0, stream>>>(
      h1, nullptr, m2, b1n_w1, b1n_b1, b1n_w2, b1n_b2, h2);

  edge_mp<128, 128, 96, 192, false, false><<<BDIM * NDIM / 2, 256, 0, stream>>>(
      e2, h2, nullptr, nn, b2e_w1, b2e_b1, b2e_w2, b2e_b2, nullptr, m3);
  node_mp<128, 192, 96, 192, false><<<BDIM * NDIM, 64, 0, stream>>>(
      h2, nullptr, m3, b2n_w1, b2n_b1, b2n_w2, b2n_b2, h3);

  zero_kernel<<<(BDIM * 512 + 255) / 256, 256, 0, stream>>>(pooled, BDIM * 512);
  fuse_pool<<<BDIM * NDIM / 16, 256, 0, stream>>>(h1, h2, h3, f_w, f_b, pooled);
  head_kernel<<<BDIM, 256, 0, stream>>>(pooled, p1_w, p1_b, p2_w, p2_b, p3_w,
                                        p3_b, out);

  hipMemcpyAsync(out + BDIM * 40, d_in[0], (size_t)BDIM * 3 * NDIM * 4,
                 hipMemcpyDeviceToDevice, stream);
}

// Round 3
// 674.743 us; speedup vs baseline: 2.6785x; 1.5818x over previous
//
#include <hip/hip_runtime.h>

#define BDIM 8
#define NDIM 1024
#define KNN 20

typedef unsigned short u16;
typedef float f32x4 __attribute__((ext_vector_type(4)));
typedef short short8 __attribute__((ext_vector_type(8)));
typedef unsigned short ushort8 __attribute__((ext_vector_type(8)));

__device__ inline u16 f2bf(float f) {
  unsigned u = __float_as_uint(f);
  unsigned r = (u + 0x7fffu + ((u >> 16) & 1u)) >> 16;
  return (u16)r;
}
__device__ inline float bf2f(u16 v) {
  return __uint_as_float(((unsigned)v) << 16);
}

// ---------------- KNN: one wave per point, wave-parallel top-20 (bit-exact) ----------------
__global__ __launch_bounds__(256) void knn_kernel(const float* __restrict__ x,
                                                  int* __restrict__ nn) {
#pragma clang fp contract(off)
  __shared__ float xs0[NDIM], xs1[NDIM], xs2[NDIM], sq[NDIM];
  const int tid = threadIdx.x;
  const int lane = tid & 63;
  const int w = tid >> 6;
  const int b = blockIdx.x >> 8;
  const int n = ((blockIdx.x & 255) << 2) + w;
  for (int i = tid; i < NDIM; i += 256) {
    float a0 = x[(b * 3 + 0) * NDIM + i];
    float a1 = x[(b * 3 + 1) * NDIM + i];
    float a2 = x[(b * 3 + 2) * NDIM + i];
    xs0[i] = a0; xs1[i] = a1; xs2[i] = a2;
    sq[i] = (a0 * a0 + a1 * a1) + a2 * a2;
  }
  __syncthreads();
  const float xn0 = xs0[n], xn1 = xs1[n], xn2 = xs2[n], sqn = sq[n];
  float dl[16];
#pragma unroll
  for (int t = 0; t < 16; ++t) {
    int m = t * 64 + lane;
    float dot = (xn0 * xs0[m] + xn1 * xs1[m]) + xn2 * xs2[m];
    dl[t] = (sqn - 2.0f * dot) + sq[m];
  }
  int* nnrow = &nn[(b * NDIM + n) * KNN];
  for (int r = 0; r < KNN; ++r) {
    float bd = dl[0];
    int bt = 0;
#pragma unroll
    for (int t = 1; t < 16; ++t) {
      if (dl[t] < bd) { bd = dl[t]; bt = t; }
    }
    int bi = bt * 64 + lane;
#pragma unroll
    for (int off = 1; off < 64; off <<= 1) {
      float pd = __shfl_xor(bd, off);
      int pi = __shfl_xor(bi, off);
      if (pd < bd || (pd == bd && pi < bi)) { bd = pd; bi = pi; }
    }
    if (lane == 0) nnrow[r] = bi;
    if ((bi & 63) == lane) {
      int wt = bi >> 6;
#pragma unroll
      for (int t = 0; t < 16; ++t) {
        if (t == wt) dl[t] = 3.4e38f;
      }
    }
  }
}

// ---------------- weight fp32 -> bf16 conversion (once per launch) ----------------
__global__ __launch_bounds__(256) void wcvt4(
    const float* __restrict__ a0, const float* __restrict__ a1,
    const float* __restrict__ a2, const float* __restrict__ a3,
    u16* __restrict__ o0, u16* __restrict__ o1, u16* __restrict__ o2,
    u16* __restrict__ o3) {
  const int idx = blockIdx.x * 256 + threadIdx.x;
  if (idx < 96 * 384) o0[idx] = f2bf(a0[idx]);              // b2e_w1 [96][384]
  if (idx < 192 * 96) o1[idx] = f2bf(a1[idx]);              // b2e_w2 [192][96]
  if (idx < 48 * 192) o2[idx] = f2bf(a2[idx]);              // b1e_w1 [48][192]
  if (idx < 128 * 64) {                                     // b1e_w2 [128][48->64 pad0]
    int o = idx >> 6, i = idx & 63;
    o3[idx] = (i < 48) ? f2bf(a3[o * 48 + i]) : (u16)0;
  }
}

// ---------------- MFMA edge MP (blocks 2,3): 40 edges (2 points) per block ----------------
template <int CE, int CH, int CMID, int COUT, bool EPREV_BF16, bool WRITE_E>
__global__ __launch_bounds__(256) void edge_mfma(
    const void* __restrict__ eprev_v, const float* __restrict__ h,
    const int* __restrict__ nnb, const u16* __restrict__ w1b,
    const float* __restrict__ b1v, const u16* __restrict__ w2b,
    const float* __restrict__ b2v, u16* __restrict__ eout,
    float* __restrict__ mout) {
  constexpr int CIN = CE + 2 * CH;                 // K1 (mult of 32)
  constexpr int K2 = (CMID + 31) & ~31;            // padded K for conv2
  constexpr int MT = 2 * KNN;                      // 40 real edges
  constexpr int MPAD = 48;                         // 3 M-tiles of 16
  constexpr int XPB = CIN + 8;                     // u16 pitches (16B-aligned rows)
  constexpr int Y1PB = K2 + 8;
  constexpr int Y2PB = COUT + 8;
  __shared__ u16 Xs[MPAD * XPB];
  __shared__ u16 Y1s[MPAD * Y1PB];
  __shared__ u16 Y2s[MT * Y2PB];
  __shared__ int nns[MT];
  const int tid = threadIdx.x;
  const int lane = tid & 63;
  const int wv = tid >> 6;
  const int bn0 = blockIdx.x * 2;
  const int b = bn0 >> 10;
  if (tid < MT) nns[tid] = nnb[(size_t)bn0 * KNN + tid];
  // zero Y1s so pad columns (CMID..K2) contribute 0 in conv2
  for (int i = tid; i < MPAD * Y1PB; i += 256) Y1s[i] = 0;
  __syncthreads();
  // ---- stage X = [e_prev | h_i | h_j] as bf16 into LDS ----
  constexpr int KC = CIN / 8;
  for (int ch = tid; ch < MT * KC; ch += 256) {
    int p = ch / KC, kc = ch - p * KC;
    int k0 = kc * 8;
    int bn = bn0 + (p >= KNN);
    if (k0 < CE) {
      size_t eoff = ((size_t)blockIdx.x * MT + p) * CE + k0;
      if (EPREV_BF16) {
        const u16* ep = (const u16*)eprev_v + eoff;
        *(uint4*)&Xs[p * XPB + k0] = *(const uint4*)ep;
      } else {
        const float* ep = (const float*)eprev_v + eoff;
        float4 f0 = *(const float4*)ep;
        float4 f1 = *(const float4*)(ep + 4);
        ushort8 r;
        r[0] = f2bf(f0.x); r[1] = f2bf(f0.y); r[2] = f2bf(f0.z); r[3] = f2bf(f0.w);
        r[4] = f2bf(f1.x); r[5] = f2bf(f1.y); r[6] = f2bf(f1.z); r[7] = f2bf(f1.w);
        *(ushort8*)&Xs[p * XPB + k0] = r;
      }
    } else {
      int c = k0 - CE;
      const float* src;
      if (c < CH) src = &h[(size_t)bn * CH + c];
      else src = &h[((size_t)(b << 10) + nns[p]) * CH + (c - CH)];
      float4 f0 = *(const float4*)src;
      float4 f1 = *(const float4*)(src + 4);
      ushort8 r;
      r[0] = f2bf(f0.x); r[1] = f2bf(f0.y); r[2] = f2bf(f0.z); r[3] = f2bf(f0.w);
      r[4] = f2bf(f1.x); r[5] = f2bf(f1.y); r[6] = f2bf(f1.z); r[7] = f2bf(f1.w);
      *(ushort8*)&Xs[p * XPB + k0] = r;
    }
  }
  __syncthreads();
  // ---- conv1: [MPAD x CIN] @ W1^T -> Y1 [MPAD x CMID] ----
  {
    constexpr int NT1 = CMID / 16;
    constexpr int J1 = 3 * NT1;
    constexpr int KS1 = CIN / 32;
    for (int job = wv; job < J1; job += 4) {
      int mt = job / NT1, nt = job - mt * NT1;
      int row = mt * 16 + (lane & 15);
      int ncol = nt * 16 + (lane & 15);
      int kb = (lane >> 4) * 8;
      f32x4 acc = {0.f, 0.f, 0.f, 0.f};
      const u16* ap = &Xs[row * XPB + kb];
      const u16* bp = &w1b[(size_t)ncol * CIN + kb];
#pragma unroll
      for (int ks = 0; ks < KS1; ++ks) {
        short8 a = *(const short8*)(ap + ks * 32);
        short8 bb = *(const short8*)(bp + ks * 32);
        acc = __builtin_amdgcn_mfma_f32_16x16x32_bf16(a, bb, acc, 0, 0, 0);
      }
      float bias = b1v[ncol];
      int m0 = mt * 16 + (lane >> 4) * 4;
#pragma unroll
      for (int r = 0; r < 4; ++r) {
        float yv = fmaxf(acc[r] + bias, 0.0f);
        Y1s[(m0 + r) * Y1PB + ncol] = f2bf(yv);
      }
    }
  }
  __syncthreads();
  // ---- conv2: [MPAD x K2] @ W2^T -> e [MT x COUT] ----
  {
    constexpr int NT2 = COUT / 16;
    constexpr int J2 = 3 * NT2;
    constexpr int KS2 = K2 / 32;
    for (int job = wv; job < J2; job += 4) {
      int mt = job / NT2, nt = job - mt * NT2;
      int row = mt * 16 + (lane & 15);
      int ncol = nt * 16 + (lane & 15);
      int kb = (lane >> 4) * 8;
      f32x4 acc = {0.f, 0.f, 0.f, 0.f};
      const u16* ap = &Y1s[row * Y1PB + kb];
      const u16* bp = &w2b[(size_t)ncol * K2 + kb];
#pragma unroll
      for (int ks = 0; ks < KS2; ++ks) {
        short8 a = *(const short8*)(ap + ks * 32);
        short8 bb = *(const short8*)(bp + ks * 32);
        acc = __builtin_amdgcn_mfma_f32_16x16x32_bf16(a, bb, acc, 0, 0, 0);
      }
      float bias = b2v[ncol];
      int m0 = mt * 16 + (lane >> 4) * 4;
#pragma unroll
      for (int r = 0; r < 4; ++r) {
        int m = m0 + r;
        if (m < MT) {
          float yv = fmaxf(acc[r] + bias, 0.0f);
          u16 bv = f2bf(yv);
          Y2s[m * Y2PB + ncol] = bv;
          if (WRITE_E)
            eout[((size_t)blockIdx.x * MT + m) * COUT + ncol] = bv;
        }
      }
    }
  }
  __syncthreads();
  // ---- deterministic m = sum_k e (fp32, ascending k) ----
  for (int idx = tid; idx < 2 * COUT; idx += 256) {
    int r = idx / COUT, c = idx - r * COUT;
    float s = 0.0f;
#pragma unroll
    for (int k = 0; k < KNN; ++k) s += bf2f(Y2s[(r * KNN + k) * Y2PB + c]);
    mout[(size_t)(bn0 + r) * COUT + c] = s;
  }
}

// ---------------- fp32 edge MP (block 1 only, tiny CIN=12) ----------------
template <int CINC, int COUTC, int INP, int OUTP>
__device__ inline void tile_conv(const float* __restrict__ Xls,
                                 const float* __restrict__ w,
                                 const float* __restrict__ bias,
                                 float* __restrict__ Yls, int tid) {
  constexpr int PG = (2 * KNN) / 4;
  constexpr int NT = PG * (COUTC / 4);
  for (int t = tid; t < NT; t += 256) {
    int pg = t % PG, og = t / PG;
    float acc[4][4];
#pragma unroll
    for (int j = 0; j < 4; ++j) {
      float bj = bias[og * 4 + j];
#pragma unroll
      for (int i = 0; i < 4; ++i) acc[i][j] = bj;
    }
    for (int cin = 0; cin < CINC; cin += 4) {
      float4 xr[4], wr[4];
#pragma unroll
      for (int i = 0; i < 4; ++i)
        xr[i] = *(const float4*)&Xls[(pg * 4 + i) * INP + cin];
#pragma unroll
      for (int j = 0; j < 4; ++j)
        wr[j] = *(const float4*)&w[(og * 4 + j) * CINC + cin];
#pragma unroll
      for (int i = 0; i < 4; ++i)
#pragma unroll
        for (int j = 0; j < 4; ++j) {
          acc[i][j] += xr[i].x * wr[j].x;
          acc[i][j] += xr[i].y * wr[j].y;
          acc[i][j] += xr[i].z * wr[j].z;
          acc[i][j] += xr[i].w * wr[j].w;
        }
    }
#pragma unroll
    for (int i = 0; i < 4; ++i)
#pragma unroll
      for (int j = 0; j < 4; ++j)
        Yls[(pg * 4 + i) * OUTP + og * 4 + j] = fmaxf(acc[i][j], 0.0f);
  }
}

template <int CE, int CH, int CMID, int COUT>
__global__ __launch_bounds__(256) void edge_mp_first(
    const float* __restrict__ inputs, const int* __restrict__ nnb,
    const float* __restrict__ w1, const float* __restrict__ b1v,
    const float* __restrict__ w2, const float* __restrict__ b2v,
    float* __restrict__ eout, float* __restrict__ mout) {
  constexpr int CIN = CE + 2 * CH;
  constexpr int TP = 2 * KNN;
  constexpr int XP = CIN + 4;
  constexpr int Y1P = CMID + 4;
  constexpr int Y2P = COUT + 4;
  __shared__ float Xs[TP * XP];
  __shared__ float Y1s[TP * Y1P];
  __shared__ float Y2s[TP * Y2P];
  __shared__ int nns[TP];
  const int tid = threadIdx.x;
  const int bn0 = blockIdx.x * 2;
  const int b = bn0 >> 10;
  if (tid < TP) nns[tid] = nnb[bn0 * KNN + tid];
  __syncthreads();
  for (int idx = tid; idx < TP * CIN; idx += 256) {
    int p = idx / CIN, c = idx - p * CIN;
    int bn = bn0 + (p >= KNN ? 1 : 0);
    int n = bn & (NDIM - 1);
    int j = nns[p];
    int cc = c % 3;
    int seg = c / 3;
    float hi = inputs[(b * 3 + cc) * NDIM + n];
    float hj = inputs[(b * 3 + cc) * NDIM + j];
    Xs[p * XP + c] = (seg == 1) ? (hi - hj) : ((seg == 3) ? hj : hi);
  }
  __syncthreads();
  tile_conv<CIN, CMID, XP, Y1P>(Xs, w1, b1v, Y1s, tid);
  __syncthreads();
  tile_conv<CMID, COUT, Y1P, Y2P>(Y1s, w2, b2v, Y2s, tid);
  __syncthreads();
  for (int idx = tid; idx < TP * COUT / 4; idx += 256) {
    int p = idx / (COUT / 4), c4 = idx - p * (COUT / 4);
    float4 v = *(const float4*)&Y2s[p * Y2P + c4 * 4];
    *(float4*)&eout[((size_t)bn0 * KNN + p) * COUT + c4 * 4] = v;
  }
  for (int idx = tid; idx < 2 * COUT; idx += 256) {
    int r = idx / COUT, c = idx - r * COUT;
    float s = 0.0f;
#pragma unroll
    for (int k = 0; k < KNN; ++k) s += Y2s[(r * KNN + k) * Y2P + c];
    mout[(bn0 + r) * COUT + c] = s;
  }
}

// ---------------- node MP: one wave per (b,n) row ----------------
template <int CH, int CM, int CMID, int COUT, bool FIRSTH>
__global__ __launch_bounds__(64) void node_mp(
    const float* __restrict__ h, const float* __restrict__ inputs,
    const float* __restrict__ mbuf, const float* __restrict__ w1,
    const float* __restrict__ b1v, const float* __restrict__ w2,
    const float* __restrict__ b2v, float* __restrict__ hout) {
  constexpr int CIN = CH + CM;
  __shared__ float xs[CIN];
  __shared__ float ys[CMID];
  const int bn = blockIdx.x;
  const int tid = threadIdx.x;
  if (FIRSTH) {
    int b = bn >> 10, n = bn & (NDIM - 1);
    if (tid < CH) xs[tid] = inputs[(b * 3 + tid) * NDIM + n];
  } else {
    for (int c = tid; c < CH; c += 64) xs[c] = h[bn * CH + c];
  }
  for (int c = tid; c < CM; c += 64) xs[CH + c] = mbuf[(size_t)bn * CM + c];
  __syncthreads();
  for (int oc = tid; oc < CMID; oc += 64) {
    float acc = b1v[oc];
    for (int cin = 0; cin < CIN; ++cin) acc += xs[cin] * w1[oc * CIN + cin];
    ys[oc] = fmaxf(acc, 0.0f);
  }
  __syncthreads();
  for (int oc = tid; oc < COUT; oc += 64) {
    float acc = b2v[oc];
#pragma unroll 4
    for (int cin = 0; cin < CMID; ++cin) acc += ys[cin] * w2[oc * CMID + cin];
    hout[(size_t)bn * COUT + oc] = fmaxf(acc, 0.0f);
  }
}

// ---------------- fusion conv (384->512) + relu + global max pool ----------------
__global__ __launch_bounds__(256) void fuse_pool(
    const float* __restrict__ h1, const float* __restrict__ h2,
    const float* __restrict__ h3, const float* __restrict__ fw,
    const float* __restrict__ fb, int* __restrict__ pooled) {
  constexpr int CIN = 384, COUT = 512, TP = 16, XP = CIN + 4;
  __shared__ float Xs[TP * XP];
  __shared__ int pmax[COUT];
  const int tid = threadIdx.x;
  const int bn0 = blockIdx.x * TP;
  const int b = bn0 >> 10;
  for (int i = tid; i < COUT; i += 256) pmax[i] = 0;
  for (int idx = tid; idx < TP * CIN; idx += 256) {
    int p = idx / CIN, c = idx - p * CIN;
    int bn = bn0 + p;
    float v;
    if (c < 64) v = h1[bn * 64 + c];
    else if (c < 192) v = h2[bn * 128 + (c - 64)];
    else v = h3[bn * 192 + (c - 192)];
    Xs[p * XP + c] = v;
  }
  __syncthreads();
  constexpr int PG = TP / 4;
  constexpr int NT = PG * (COUT / 4);
  for (int t = tid; t < NT; t += 256) {
    int pg = t % PG, og = t / PG;
    float acc[4][4];
#pragma unroll
    for (int j = 0; j < 4; ++j) {
      float bj = fb[og * 4 + j];
#pragma unroll
      for (int i = 0; i < 4; ++i) acc[i][j] = bj;
    }
    for (int cin = 0; cin < CIN; cin += 4) {
      float4 xr[4], wr[4];
#pragma unroll
      for (int i = 0; i < 4; ++i)
        xr[i] = *(const float4*)&Xs[(pg * 4 + i) * XP + cin];
#pragma unroll
      for (int j = 0; j < 4; ++j)
        wr[j] = *(const float4*)&fw[(og * 4 + j) * CIN + cin];
#pragma unroll
      for (int i = 0; i < 4; ++i)
#pragma unroll
        for (int j = 0; j < 4; ++j) {
          acc[i][j] += xr[i].x * wr[j].x;
          acc[i][j] += xr[i].y * wr[j].y;
          acc[i][j] += xr[i].z * wr[j].z;
          acc[i][j] += xr[i].w * wr[j].w;
        }
    }
#pragma unroll
    for (int j = 0; j < 4; ++j) {
      float v = fmaxf(fmaxf(acc[0][j], acc[1][j]), fmaxf(acc[2][j], acc[3][j]));
      v = fmaxf(v, 0.0f);
      atomicMax(&pmax[og * 4 + j], __float_as_int(v));
    }
  }
  __syncthreads();
  for (int i = tid; i < COUT; i += 256)
    atomicMax(&pooled[b * COUT + i], pmax[i]);
}

// ---------------- prediction head ----------------
__global__ __launch_bounds__(256) void head_kernel(
    const int* __restrict__ pooledi, const float* __restrict__ p1w,
    const float* __restrict__ p1b, const float* __restrict__ p2w,
    const float* __restrict__ p2b, const float* __restrict__ p3w,
    const float* __restrict__ p3b, float* __restrict__ out) {
  __shared__ float xs[512], y1[256], y2[128];
  const int b = blockIdx.x, tid = threadIdx.x;
  for (int i = tid; i < 512; i += 256) xs[i] = __int_as_float(pooledi[b * 512 + i]);
  __syncthreads();
  {
    float acc = p1b[tid];
    for (int c = 0; c < 512; ++c) acc += xs[c] * p1w[tid * 512 + c];
    y1[tid] = fmaxf(acc, 0.0f);
  }
  __syncthreads();
  if (tid < 128) {
    float acc = p2b[tid];
    for (int c = 0; c < 256; ++c) acc += y1[c] * p2w[tid * 256 + c];
    y2[tid] = fmaxf(acc, 0.0f);
  }
  __syncthreads();
  if (tid < 40) {
    float acc = p3b[tid];
    for (int c = 0; c < 128; ++c) acc += y2[c] * p3w[tid * 128 + c];
    out[b * 40 + tid] = acc;
  }
}

__global__ void zero_kernel(int* __restrict__ p, int nel) {
  int i = blockIdx.x * 256 + threadIdx.x;
  if (i < nel) p[i] = 0;
}

extern "C" void kernel_launch(void* const* d_in, const int* in_sizes, int n_in,
                              void* d_out, int out_size, void* d_ws,
                              size_t ws_size, hipStream_t stream) {
  const float* inputs = (const float*)d_in[0];
  const float* he_w1 = (const float*)d_in[1];
  const float* he_b1 = (const float*)d_in[2];
  const float* he_w2 = (const float*)d_in[3];
  const float* he_b2 = (const float*)d_in[4];
  const float* hn_w1 = (const float*)d_in[5];
  const float* hn_b1 = (const float*)d_in[6];
  const float* hn_w2 = (const float*)d_in[7];
  const float* hn_b2 = (const float*)d_in[8];
  const float* b1e_w1 = (const float*)d_in[9];
  const float* b1e_b1 = (const float*)d_in[10];
  const float* b1e_w2 = (const float*)d_in[11];
  const float* b1e_b2 = (const float*)d_in[12];
  const float* b1n_w1 = (const float*)d_in[13];
  const float* b1n_b1 = (const float*)d_in[14];
  const float* b1n_w2 = (const float*)d_in[15];
  const float* b1n_b2 = (const float*)d_in[16];
  const float* b2e_w1 = (const float*)d_in[17];
  const float* b2e_b1 = (const float*)d_in[18];
  const float* b2e_w2 = (const float*)d_in[19];
  const float* b2e_b2 = (const float*)d_in[20];
  const float* b2n_w1 = (const float*)d_in[21];
  const float* b2n_b1 = (const float*)d_in[22];
  const float* b2n_w2 = (const float*)d_in[23];
  const float* b2n_b2 = (const float*)d_in[24];
  const float* f_w = (const float*)d_in[25];
  const float* f_b = (const float*)d_in[26];
  const float* p1_w = (const float*)d_in[27];
  const float* p1_b = (const float*)d_in[28];
  const float* p2_w = (const float*)d_in[29];
  const float* p2_b = (const float*)d_in[30];
  const float* p3_w = (const float*)d_in[31];
  const float* p3_b = (const float*)d_in[32];
  float* out = (float*)d_out;

  char* ws = (char*)d_ws;
  size_t off = 0;
  auto alloc = [&](size_t bytes) {
    void* p = ws + off;
    off += (bytes + 255) & ~(size_t)255;
    return p;
  };
  int* nn = (int*)alloc((size_t)BDIM * NDIM * KNN * 4);
  float* m1 = (float*)alloc((size_t)BDIM * NDIM * 64 * 4);
  float* h1 = (float*)alloc((size_t)BDIM * NDIM * 64 * 4);
  float* e1 = (float*)alloc((size_t)BDIM * NDIM * KNN * 64 * 4);   // fp32
  float* m2 = (float*)alloc((size_t)BDIM * NDIM * 128 * 4);
  float* h2 = (float*)alloc((size_t)BDIM * NDIM * 128 * 4);
  u16* e2 = (u16*)alloc((size_t)BDIM * NDIM * KNN * 128 * 2);      // bf16
  float* m3 = (float*)alloc((size_t)BDIM * NDIM * 192 * 4);
  float* h3 = (float*)alloc((size_t)BDIM * NDIM * 192 * 4);
  int* pooled = (int*)alloc((size_t)BDIM * 512 * 4);
  u16* w1b2 = (u16*)alloc((size_t)48 * 192 * 2);
  u16* w2b2 = (u16*)alloc((size_t)128 * 64 * 2);
  u16* w1b3 = (u16*)alloc((size_t)96 * 384 * 2);
  u16* w2b3 = (u16*)alloc((size_t)192 * 96 * 2);

  wcvt4<<<(96 * 384 + 255) / 256, 256, 0, stream>>>(b2e_w1, b2e_w2, b1e_w1,
                                                    b1e_w2, w1b3, w2b3, w1b2,
                                                    w2b2);
  knn_kernel<<<BDIM * 256, 256, 0, stream>>>(inputs, nn);

  edge_mp_first<6, 3, 32, 64><<<BDIM * NDIM / 2, 256, 0, stream>>>(
      inputs, nn, he_w1, he_b1, he_w2, he_b2, e1, m1);
  node_mp<3, 64, 32, 64, true><<<BDIM * NDIM, 64, 0, stream>>>(
      nullptr, inputs, m1, hn_w1, hn_b1, hn_w2, hn_b2, h1);

  edge_mfma<64, 64, 48, 128, false, true><<<BDIM * NDIM / 2, 256, 0, stream>>>(
      (const void*)e1, h1, nn, w1b2, b1e_b1, w2b2, b1e_b2, e2, m2);
  node_mp<64, 128, 48, 128, false><<<BDIM * NDIM, 64, 0, stream>>>(
      h1, nullptr, m2, b1n_w1, b1n_b1, b1n_w2, b1n_b2, h2);

  edge_mfma<128, 128, 96, 192, true, false><<<BDIM * NDIM / 2, 256, 0, stream>>>(
      (const void*)e2, h2, nn, w1b3, b2e_b1, w2b3, b2e_b2, nullptr, m3);
  node_mp<128, 192, 96, 192, false><<<BDIM * NDIM, 64, 0, stream>>>(
      h2, nullptr, m3, b2n_w1, b2n_b1, b2n_w2, b2n_b2, h3);

  zero_kernel<<<(BDIM * 512 + 255) / 256, 256, 0, stream>>>(pooled, BDIM * 512);
  fuse_pool<<<BDIM * NDIM / 16, 256, 0, stream>>>(h1, h2, h3, f_w, f_b, pooled);
  head_kernel<<<BDIM, 256, 0, stream>>>(pooled, p1_w, p1_b, p2_w, p2_b, p3_w,
                                        p3_b, out);

  hipMemcpyAsync(out + BDIM * 40, d_in[0], (size_t)BDIM * 3 * NDIM * 4,
                 hipMemcpyDeviceToDevice, stream);
}

// Round 4
// 544.000 us; speedup vs baseline: 3.3222x; 1.2403x over previous
//
#include <hip/hip_runtime.h>

#define BDIM 8
#define NDIM 1024
#define KNN 20

typedef unsigned short u16;
typedef float f32x4 __attribute__((ext_vector_type(4)));
typedef short short8 __attribute__((ext_vector_type(8)));
typedef unsigned short ushort8 __attribute__((ext_vector_type(8)));

__device__ inline u16 f2bf(float f) {
  unsigned u = __float_as_uint(f);
  unsigned r = (u + 0x7fffu + ((u >> 16) & 1u)) >> 16;
  return (u16)r;
}
__device__ inline float bf2f(u16 v) {
  return __uint_as_float(((unsigned)v) << 16);
}

// ---------------- KNN: one wave per point, wave-parallel top-20 (bit-exact) ----------------
__global__ __launch_bounds__(256) void knn_kernel(const float* __restrict__ x,
                                                  int* __restrict__ nn) {
#pragma clang fp contract(off)
  __shared__ float xs0[NDIM], xs1[NDIM], xs2[NDIM], sq[NDIM];
  const int tid = threadIdx.x;
  const int lane = tid & 63;
  const int w = tid >> 6;
  const int b = blockIdx.x >> 8;
  const int n = ((blockIdx.x & 255) << 2) + w;
  for (int i = tid; i < NDIM; i += 256) {
    float a0 = x[(b * 3 + 0) * NDIM + i];
    float a1 = x[(b * 3 + 1) * NDIM + i];
    float a2 = x[(b * 3 + 2) * NDIM + i];
    xs0[i] = a0; xs1[i] = a1; xs2[i] = a2;
    sq[i] = (a0 * a0 + a1 * a1) + a2 * a2;
  }
  __syncthreads();
  const float xn0 = xs0[n], xn1 = xs1[n], xn2 = xs2[n], sqn = sq[n];
  float dl[16];
#pragma unroll
  for (int t = 0; t < 16; ++t) {
    int m = t * 64 + lane;
    float dot = (xn0 * xs0[m] + xn1 * xs1[m]) + xn2 * xs2[m];
    dl[t] = (sqn - 2.0f * dot) + sq[m];
  }
  int* nnrow = &nn[(b * NDIM + n) * KNN];
  for (int r = 0; r < KNN; ++r) {
    float bd = dl[0];
    int bt = 0;
#pragma unroll
    for (int t = 1; t < 16; ++t) {
      if (dl[t] < bd) { bd = dl[t]; bt = t; }
    }
    int bi = bt * 64 + lane;
#pragma unroll
    for (int off = 1; off < 64; off <<= 1) {
      float pd = __shfl_xor(bd, off);
      int pi = __shfl_xor(bi, off);
      if (pd < bd || (pd == bd && pi < bi)) { bd = pd; bi = pi; }
    }
    if (lane == 0) nnrow[r] = bi;
    if ((bi & 63) == lane) {
      int wt = bi >> 6;
#pragma unroll
      for (int t = 0; t < 16; ++t) {
        if (t == wt) dl[t] = 3.4e38f;
      }
    }
  }
}

// ---------------- weight fp32 -> bf16 tables (split into e-part / hi,hj-part) ----------------
__global__ __launch_bounds__(256) void wcvt(
    const float* __restrict__ w1_3, const float* __restrict__ w2_3,
    const float* __restrict__ w1_2, const float* __restrict__ w2_2,
    u16* __restrict__ w1b3e, u16* __restrict__ wpq3, u16* __restrict__ w2b3,
    u16* __restrict__ w1b2e, u16* __restrict__ wpq2, u16* __restrict__ w2b2) {
  const int idx = blockIdx.x * 256 + threadIdx.x;
  // block3 (b2e): w1 [96][384] = [e(128) | hi(128) | hj(128)], w2 [192][96]
  if (idx < 96 * 128) {
    int oc = idx >> 7, c = idx & 127;
    w1b3e[idx] = f2bf(w1_3[oc * 384 + c]);
  }
  if (idx < 192 * 128) {
    int n = idx >> 7, c = idx & 127;
    wpq3[idx] = f2bf(n < 96 ? w1_3[n * 384 + 128 + c]
                            : w1_3[(n - 96) * 384 + 256 + c]);
  }
  if (idx < 192 * 96) w2b3[idx] = f2bf(w2_3[idx]);
  // block2 (b1e): w1 [48][192] = [e(64) | hi(64) | hj(64)], w2 [128][48->64 pad]
  if (idx < 48 * 64) {
    int oc = idx >> 6, c = idx & 63;
    w1b2e[idx] = f2bf(w1_2[oc * 192 + c]);
  }
  if (idx < 96 * 64) {
    int n = idx >> 6, c = idx & 63;
    wpq2[idx] = f2bf(n < 48 ? w1_2[n * 192 + 64 + c]
                            : w1_2[(n - 48) * 192 + 128 + c]);
  }
  if (idx < 128 * 64) {
    int oc = idx >> 6, i = idx & 63;
    w2b2[idx] = (i < 48) ? f2bf(w2_2[oc * 48 + i]) : (u16)0;
  }
}

// ---------------- PQ = h @ [W1hi;W1hj]^T  (per-point, fp32 out, no bias/relu) ----------------
template <int CH, int NPQ>
__global__ __launch_bounds__(256) void pq_gemm(const float* __restrict__ h,
                                               const u16* __restrict__ wpq,
                                               float* __restrict__ pq) {
  constexpr int BM = 32;
  constexpr int AP = CH + 8;
  __shared__ u16 As[BM * AP];
  const int tid = threadIdx.x;
  const int lane = tid & 63;
  const int wv = tid >> 6;
  const int row0 = blockIdx.x * BM;
  constexpr int KC = CH / 8;
  for (int ch = tid; ch < BM * KC; ch += 256) {
    int p = ch / KC, kc = ch - p * KC;
    int k0 = kc * 8;
    const float* src = &h[(size_t)(row0 + p) * CH + k0];
    float4 f0 = *(const float4*)src;
    float4 f1 = *(const float4*)(src + 4);
    ushort8 r;
    r[0] = f2bf(f0.x); r[1] = f2bf(f0.y); r[2] = f2bf(f0.z); r[3] = f2bf(f0.w);
    r[4] = f2bf(f1.x); r[5] = f2bf(f1.y); r[6] = f2bf(f1.z); r[7] = f2bf(f1.w);
    *(ushort8*)&As[p * AP + k0] = r;
  }
  __syncthreads();
  constexpr int NT = NPQ / 16;
  constexpr int JOBS = (BM / 16) * NT;
  constexpr int KS = CH / 32;
  for (int job = wv; job < JOBS; job += 4) {
    int mt = job / NT, nt = job - mt * NT;
    int row = mt * 16 + (lane & 15);
    int ncol = nt * 16 + (lane & 15);
    int kb = (lane >> 4) * 8;
    f32x4 acc = {0.f, 0.f, 0.f, 0.f};
    const u16* ap = &As[row * AP + kb];
    const u16* bp = &wpq[(size_t)ncol * CH + kb];
#pragma unroll
    for (int ks = 0; ks < KS; ++ks) {
      short8 a = *(const short8*)(ap + ks * 32);
      short8 bb = *(const short8*)(bp + ks * 32);
      acc = __builtin_amdgcn_mfma_f32_16x16x32_bf16(a, bb, acc, 0, 0, 0);
    }
    int m0 = mt * 16 + (lane >> 4) * 4;
#pragma unroll
    for (int r = 0; r < 4; ++r)
      pq[(size_t)(row0 + m0 + r) * NPQ + ncol] = acc[r];
  }
}

// ---------------- MFMA edge MP v2: e-only GEMM + PQ add (blocks 2,3) ----------------
template <int CE, int CMID, int COUT, bool WRITE_E>
__global__ __launch_bounds__(256) void edge_mfma(
    const u16* __restrict__ eprev, const int* __restrict__ nnb,
    const u16* __restrict__ w1b, const float* __restrict__ b1v,
    const u16* __restrict__ w2b, const float* __restrict__ b2v,
    const float* __restrict__ pq, u16* __restrict__ eout,
    float* __restrict__ mout) {
  constexpr int K2 = (CMID + 31) & ~31;
  constexpr int NPQ = 2 * CMID;
  constexpr int MT = 2 * KNN;   // 40 edges
  constexpr int MPAD = 48;      // 3 M-tiles
  constexpr int XPB = CE + 8;
  constexpr int Y1PB = K2 + 8;
  constexpr int Y2PB = COUT + 8;
  __shared__ u16 Xs[MPAD * XPB];
  __shared__ u16 Y1s[MPAD * Y1PB];
  __shared__ u16 Y2s[MT * Y2PB];
  __shared__ int nns[MT];
  const int tid = threadIdx.x;
  const int lane = tid & 63;
  const int wv = tid >> 6;
  const int bn0 = blockIdx.x * 2;
  const int b = bn0 >> 10;
  if (tid < MT) nns[tid] = nnb[(size_t)bn0 * KNN + tid];
  // zero Y1s (pad cols must be 0; pad rows masked later)
  for (int i = tid; i < MPAD * Y1PB; i += 256) Y1s[i] = 0;
  // stage e_prev tile: pure 16B copies (already bf16)
  constexpr int KC = CE / 8;
  for (int ch = tid; ch < MT * KC; ch += 256) {
    int p = ch / KC, kc = ch - p * KC;
    int k0 = kc * 8;
    *(uint4*)&Xs[p * XPB + k0] =
        *(const uint4*)&eprev[((size_t)blockIdx.x * MT + p) * CE + k0];
  }
  __syncthreads();
  // ---- conv1: e @ W1e^T + P_i + Q_j + b -> relu -> Y1 ----
  {
    constexpr int NT1 = CMID / 16;
    constexpr int J1 = 3 * NT1;
    constexpr int KS1 = CE / 32;
    for (int job = wv; job < J1; job += 4) {
      int mt = job / NT1, nt = job - mt * NT1;
      int row = mt * 16 + (lane & 15);
      int ncol = nt * 16 + (lane & 15);
      int kb = (lane >> 4) * 8;
      f32x4 acc = {0.f, 0.f, 0.f, 0.f};
      const u16* ap = &Xs[row * XPB + kb];
      const u16* bp = &w1b[(size_t)ncol * CE + kb];
#pragma unroll
      for (int ks = 0; ks < KS1; ++ks) {
        short8 a = *(const short8*)(ap + ks * 32);
        short8 bb = *(const short8*)(bp + ks * 32);
        acc = __builtin_amdgcn_mfma_f32_16x16x32_bf16(a, bb, acc, 0, 0, 0);
      }
      float bias = b1v[ncol];
      int m0 = mt * 16 + (lane >> 4) * 4;
#pragma unroll
      for (int r = 0; r < 4; ++r) {
        int m = m0 + r;
        int pt = bn0 + (m >= KNN);            // valid even for pad rows
        int jm = nns[m < MT ? m : MT - 1];
        float padd = pq[(size_t)pt * NPQ + ncol];
        float qadd = pq[((size_t)(b << 10) + jm) * NPQ + CMID + ncol];
        float yv = fmaxf(acc[r] + bias + padd + qadd, 0.0f);
        Y1s[m * Y1PB + ncol] = f2bf(yv);
      }
    }
  }
  __syncthreads();
  // ---- conv2: Y1 @ W2^T + b -> relu -> e ----
  {
    constexpr int NT2 = COUT / 16;
    constexpr int J2 = 3 * NT2;
    constexpr int KS2 = K2 / 32;
    for (int job = wv; job < J2; job += 4) {
      int mt = job / NT2, nt = job - mt * NT2;
      int row = mt * 16 + (lane & 15);
      int ncol = nt * 16 + (lane & 15);
      int kb = (lane >> 4) * 8;
      f32x4 acc = {0.f, 0.f, 0.f, 0.f};
      const u16* ap = &Y1s[row * Y1PB + kb];
      const u16* bp = &w2b[(size_t)ncol * K2 + kb];
#pragma unroll
      for (int ks = 0; ks < KS2; ++ks) {
        short8 a = *(const short8*)(ap + ks * 32);
        short8 bb = *(const short8*)(bp + ks * 32);
        acc = __builtin_amdgcn_mfma_f32_16x16x32_bf16(a, bb, acc, 0, 0, 0);
      }
      float bias = b2v[ncol];
      int m0 = mt * 16 + (lane >> 4) * 4;
#pragma unroll
      for (int r = 0; r < 4; ++r) {
        int m = m0 + r;
        if (m < MT) {
          float yv = fmaxf(acc[r] + bias, 0.0f);
          u16 bv = f2bf(yv);
          Y2s[m * Y2PB + ncol] = bv;
          if (WRITE_E)
            eout[((size_t)blockIdx.x * MT + m) * COUT + ncol] = bv;
        }
      }
    }
  }
  __syncthreads();
  // ---- deterministic m = sum_k e (fp32, ascending k) ----
  for (int idx = tid; idx < 2 * COUT; idx += 256) {
    int r = idx / COUT, c = idx - r * COUT;
    float s = 0.0f;
#pragma unroll
    for (int k = 0; k < KNN; ++k) s += bf2f(Y2s[(r * KNN + k) * Y2PB + c]);
    mout[(size_t)(bn0 + r) * COUT + c] = s;
  }
}

// ---------------- fp32 edge MP (block 1 only, tiny CIN=12), bf16 e1 out ----------------
template <int CINC, int COUTC, int INP, int OUTP>
__device__ inline void tile_conv(const float* __restrict__ Xls,
                                 const float* __restrict__ w,
                                 const float* __restrict__ bias,
                                 float* __restrict__ Yls, int tid) {
  constexpr int PG = (2 * KNN) / 4;
  constexpr int NT = PG * (COUTC / 4);
  for (int t = tid; t < NT; t += 256) {
    int pg = t % PG, og = t / PG;
    float acc[4][4];
#pragma unroll
    for (int j = 0; j < 4; ++j) {
      float bj = bias[og * 4 + j];
#pragma unroll
      for (int i = 0; i < 4; ++i) acc[i][j] = bj;
    }
    for (int cin = 0; cin < CINC; cin += 4) {
      float4 xr[4], wr[4];
#pragma unroll
      for (int i = 0; i < 4; ++i)
        xr[i] = *(const float4*)&Xls[(pg * 4 + i) * INP + cin];
#pragma unroll
      for (int j = 0; j < 4; ++j)
        wr[j] = *(const float4*)&w[(og * 4 + j) * CINC + cin];
#pragma unroll
      for (int i = 0; i < 4; ++i)
#pragma unroll
        for (int j = 0; j < 4; ++j) {
          acc[i][j] += xr[i].x * wr[j].x;
          acc[i][j] += xr[i].y * wr[j].y;
          acc[i][j] += xr[i].z * wr[j].z;
          acc[i][j] += xr[i].w * wr[j].w;
        }
    }
#pragma unroll
    for (int i = 0; i < 4; ++i)
#pragma unroll
      for (int j = 0; j < 4; ++j)
        Yls[(pg * 4 + i) * OUTP + og * 4 + j] = fmaxf(acc[i][j], 0.0f);
  }
}

template <int CE, int CH, int CMID, int COUT>
__global__ __launch_bounds__(256) void edge_mp_first(
    const float* __restrict__ inputs, const int* __restrict__ nnb,
    const float* __restrict__ w1, const float* __restrict__ b1v,
    const float* __restrict__ w2, const float* __restrict__ b2v,
    u16* __restrict__ eout, float* __restrict__ mout) {
  constexpr int CIN = CE + 2 * CH;
  constexpr int TP = 2 * KNN;
  constexpr int XP = CIN + 4;
  constexpr int Y1P = CMID + 4;
  constexpr int Y2P = COUT + 4;
  __shared__ float Xs[TP * XP];
  __shared__ float Y1s[TP * Y1P];
  __shared__ float Y2s[TP * Y2P];
  __shared__ int nns[TP];
  const int tid = threadIdx.x;
  const int bn0 = blockIdx.x * 2;
  const int b = bn0 >> 10;
  if (tid < TP) nns[tid] = nnb[bn0 * KNN + tid];
  __syncthreads();
  for (int idx = tid; idx < TP * CIN; idx += 256) {
    int p = idx / CIN, c = idx - p * CIN;
    int bn = bn0 + (p >= KNN ? 1 : 0);
    int n = bn & (NDIM - 1);
    int j = nns[p];
    int cc = c % 3;
    int seg = c / 3;
    float hi = inputs[(b * 3 + cc) * NDIM + n];
    float hj = inputs[(b * 3 + cc) * NDIM + j];
    Xs[p * XP + c] = (seg == 1) ? (hi - hj) : ((seg == 3) ? hj : hi);
  }
  __syncthreads();
  tile_conv<CIN, CMID, XP, Y1P>(Xs, w1, b1v, Y1s, tid);
  __syncthreads();
  tile_conv<CMID, COUT, Y1P, Y2P>(Y1s, w2, b2v, Y2s, tid);
  __syncthreads();
  for (int idx = tid; idx < TP * COUT / 4; idx += 256) {
    int p = idx / (COUT / 4), c4 = idx - p * (COUT / 4);
    float4 v = *(const float4*)&Y2s[p * Y2P + c4 * 4];
    ushort4 o;
    o.x = f2bf(v.x); o.y = f2bf(v.y); o.z = f2bf(v.z); o.w = f2bf(v.w);
    *(ushort4*)&eout[((size_t)bn0 * KNN + p) * COUT + c4 * 4] = o;
  }
  for (int idx = tid; idx < 2 * COUT; idx += 256) {
    int r = idx / COUT, c = idx - r * COUT;
    float s = 0.0f;
#pragma unroll
    for (int k = 0; k < KNN; ++k) s += Y2s[(r * KNN + k) * Y2P + c];
    mout[(bn0 + r) * COUT + c] = s;
  }
}

// ---------------- node MP: one wave per (b,n) row ----------------
template <int CH, int CM, int CMID, int COUT, bool FIRSTH>
__global__ __launch_bounds__(64) void node_mp(
    const float* __restrict__ h, const float* __restrict__ inputs,
    const float* __restrict__ mbuf, const float* __restrict__ w1,
    const float* __restrict__ b1v, const float* __restrict__ w2,
    const float* __restrict__ b2v, float* __restrict__ hout) {
  constexpr int CIN = CH + CM;
  __shared__ float xs[CIN];
  __shared__ float ys[CMID];
  const int bn = blockIdx.x;
  const int tid = threadIdx.x;
  if (FIRSTH) {
    int b = bn >> 10, n = bn & (NDIM - 1);
    if (tid < CH) xs[tid] = inputs[(b * 3 + tid) * NDIM + n];
  } else {
    for (int c = tid; c < CH; c += 64) xs[c] = h[bn * CH + c];
  }
  for (int c = tid; c < CM; c += 64) xs[CH + c] = mbuf[(size_t)bn * CM + c];
  __syncthreads();
  for (int oc = tid; oc < CMID; oc += 64) {
    float acc = b1v[oc];
    for (int cin = 0; cin < CIN; ++cin) acc += xs[cin] * w1[oc * CIN + cin];
    ys[oc] = fmaxf(acc, 0.0f);
  }
  __syncthreads();
  for (int oc = tid; oc < COUT; oc += 64) {
    float acc = b2v[oc];
#pragma unroll 4
    for (int cin = 0; cin < CMID; ++cin) acc += ys[cin] * w2[oc * CMID + cin];
    hout[(size_t)bn * COUT + oc] = fmaxf(acc, 0.0f);
  }
}

// ---------------- fusion conv (384->512) + relu + global max pool ----------------
__global__ __launch_bounds__(256) void fuse_pool(
    const float* __restrict__ h1, const float* __restrict__ h2,
    const float* __restrict__ h3, const float* __restrict__ fw,
    const float* __restrict__ fb, int* __restrict__ pooled) {
  constexpr int CIN = 384, COUT = 512, TP = 16, XP = CIN + 4;
  __shared__ float Xs[TP * XP];
  __shared__ int pmax[COUT];
  const int tid = threadIdx.x;
  const int bn0 = blockIdx.x * TP;
  const int b = bn0 >> 10;
  for (int i = tid; i < COUT; i += 256) pmax[i] = 0;
  for (int idx = tid; idx < TP * CIN; idx += 256) {
    int p = idx / CIN, c = idx - p * CIN;
    int bn = bn0 + p;
    float v;
    if (c < 64) v = h1[bn * 64 + c];
    else if (c < 192) v = h2[bn * 128 + (c - 64)];
    else v = h3[bn * 192 + (c - 192)];
    Xs[p * XP + c] = v;
  }
  __syncthreads();
  constexpr int PG = TP / 4;
  constexpr int NT = PG * (COUT / 4);
  for (int t = tid; t < NT; t += 256) {
    int pg = t % PG, og = t / PG;
    float acc[4][4];
#pragma unroll
    for (int j = 0; j < 4; ++j) {
      float bj = fb[og * 4 + j];
#pragma unroll
      for (int i = 0; i < 4; ++i) acc[i][j] = bj;
    }
    for (int cin = 0; cin < CIN; cin += 4) {
      float4 xr[4], wr[4];
#pragma unroll
      for (int i = 0; i < 4; ++i)
        xr[i] = *(const float4*)&Xs[(pg * 4 + i) * XP + cin];
#pragma unroll
      for (int j = 0; j < 4; ++j)
        wr[j] = *(const float4*)&fw[(og * 4 + j) * CIN + cin];
#pragma unroll
      for (int i = 0; i < 4; ++i)
#pragma unroll
        for (int j = 0; j < 4; ++j) {
          acc[i][j] += xr[i].x * wr[j].x;
          acc[i][j] += xr[i].y * wr[j].y;
          acc[i][j] += xr[i].z * wr[j].z;
          acc[i][j] += xr[i].w * wr[j].w;
        }
    }
#pragma unroll
    for (int j = 0; j < 4; ++j) {
      float v = fmaxf(fmaxf(acc[0][j], acc[1][j]), fmaxf(acc[2][j], acc[3][j]));
      v = fmaxf(v, 0.0f);
      atomicMax(&pmax[og * 4 + j], __float_as_int(v));
    }
  }
  __syncthreads();
  for (int i = tid; i < COUT; i += 256)
    atomicMax(&pooled[b * COUT + i], pmax[i]);
}

// ---------------- prediction head ----------------
__global__ __launch_bounds__(256) void head_kernel(
    const int* __restrict__ pooledi, const float* __restrict__ p1w,
    const float* __restrict__ p1b, const float* __restrict__ p2w,
    const float* __restrict__ p2b, const float* __restrict__ p3w,
    const float* __restrict__ p3b, float* __restrict__ out) {
  __shared__ float xs[512], y1[256], y2[128];
  const int b = blockIdx.x, tid = threadIdx.x;
  for (int i = tid; i < 512; i += 256) xs[i] = __int_as_float(pooledi[b * 512 + i]);
  __syncthreads();
  {
    float acc = p1b[tid];
    for (int c = 0; c < 512; ++c) acc += xs[c] * p1w[tid * 512 + c];
    y1[tid] = fmaxf(acc, 0.0f);
  }
  __syncthreads();
  if (tid < 128) {
    float acc = p2b[tid];
    for (int c = 0; c < 256; ++c) acc += y1[c] * p2w[tid * 256 + c];
    y2[tid] = fmaxf(acc, 0.0f);
  }
  __syncthreads();
  if (tid < 40) {
    float acc = p3b[tid];
    for (int c = 0; c < 128; ++c) acc += y2[c] * p3w[tid * 128 + c];
    out[b * 40 + tid] = acc;
  }
}

__global__ void zero_kernel(int* __restrict__ p, int nel) {
  int i = blockIdx.x * 256 + threadIdx.x;
  if (i < nel) p[i] = 0;
}

extern "C" void kernel_launch(void* const* d_in, const int* in_sizes, int n_in,
                              void* d_out, int out_size, void* d_ws,
                              size_t ws_size, hipStream_t stream) {
  const float* inputs = (const float*)d_in[0];
  const float* he_w1 = (const float*)d_in[1];
  const float* he_b1 = (const float*)d_in[2];
  const float* he_w2 = (const float*)d_in[3];
  const float* he_b2 = (const float*)d_in[4];
  const float* hn_w1 = (const float*)d_in[5];
  const float* hn_b1 = (const float*)d_in[6];
  const float* hn_w2 = (const float*)d_in[7];
  const float* hn_b2 = (const float*)d_in[8];
  const float* b1e_w1 = (const float*)d_in[9];
  const float* b1e_b1 = (const float*)d_in[10];
  const float* b1e_w2 = (const float*)d_in[11];
  const float* b1e_b2 = (const float*)d_in[12];
  const float* b1n_w1 = (const float*)d_in[13];
  const float* b1n_b1 = (const float*)d_in[14];
  const float* b1n_w2 = (const float*)d_in[15];
  const float* b1n_b2 = (const float*)d_in[16];
  const float* b2e_w1 = (const float*)d_in[17];
  const float* b2e_b1 = (const float*)d_in[18];
  const float* b2e_w2 = (const float*)d_in[19];
  const float* b2e_b2 = (const float*)d_in[20];
  const float* b2n_w1 = (const float*)d_in[21];
  const float* b2n_b1 = (const float*)d_in[22];
  const float* b2n_w2 = (const float*)d_in[23];
  const float* b2n_b2 = (const float*)d_in[24];
  const float* f_w = (const float*)d_in[25];
  const float* f_b = (const float*)d_in[26];
  const float* p1_w = (const float*)d_in[27];
  const float* p1_b = (const float*)d_in[28];
  const float* p2_w = (const float*)d_in[29];
  const float* p2_b = (const float*)d_in[30];
  const float* p3_w = (const float*)d_in[31];
  const float* p3_b = (const float*)d_in[32];
  float* out = (float*)d_out;

  char* ws = (char*)d_ws;
  size_t off = 0;
  auto alloc = [&](size_t bytes) {
    void* p = ws + off;
    off += (bytes + 255) & ~(size_t)255;
    return p;
  };
  int* nn = (int*)alloc((size_t)BDIM * NDIM * KNN * 4);
  float* m1 = (float*)alloc((size_t)BDIM * NDIM * 64 * 4);
  float* h1 = (float*)alloc((size_t)BDIM * NDIM * 64 * 4);
  u16* e1 = (u16*)alloc((size_t)BDIM * NDIM * KNN * 64 * 2);   // bf16
  float* m2 = (float*)alloc((size_t)BDIM * NDIM * 128 * 4);
  float* h2 = (float*)alloc((size_t)BDIM * NDIM * 128 * 4);
  u16* e2 = (u16*)alloc((size_t)BDIM * NDIM * KNN * 128 * 2);  // bf16
  float* m3 = (float*)alloc((size_t)BDIM * NDIM * 192 * 4);
  float* h3 = (float*)alloc((size_t)BDIM * NDIM * 192 * 4);
  float* pq2 = (float*)alloc((size_t)BDIM * NDIM * 96 * 4);
  float* pq3 = (float*)alloc((size_t)BDIM * NDIM * 192 * 4);
  int* pooled = (int*)alloc((size_t)BDIM * 512 * 4);
  u16* w1b3e = (u16*)alloc((size_t)96 * 128 * 2);
  u16* wpq3 = (u16*)alloc((size_t)192 * 128 * 2);
  u16* w2b3 = (u16*)alloc((size_t)192 * 96 * 2);
  u16* w1b2e = (u16*)alloc((size_t)48 * 64 * 2);
  u16* wpq2 = (u16*)alloc((size_t)96 * 64 * 2);
  u16* w2b2 = (u16*)alloc((size_t)128 * 64 * 2);

  wcvt<<<(192 * 128 + 255) / 256, 256, 0, stream>>>(
      b2e_w1, b2e_w2, b1e_w1, b1e_w2, w1b3e, wpq3, w2b3, w1b2e, wpq2, w2b2);
  knn_kernel<<<BDIM * 256, 256, 0, stream>>>(inputs, nn);

  edge_mp_first<6, 3, 32, 64><<<BDIM * NDIM / 2, 256, 0, stream>>>(
      inputs, nn, he_w1, he_b1, he_w2, he_b2, e1, m1);
  node_mp<3, 64, 32, 64, true><<<BDIM * NDIM, 64, 0, stream>>>(
      nullptr, inputs, m1, hn_w1, hn_b1, hn_w2, hn_b2, h1);

  pq_gemm<64, 96><<<BDIM * NDIM / 32, 256, 0, stream>>>(h1, wpq2, pq2);
  edge_mfma<64, 48, 128, true><<<BDIM * NDIM / 2, 256, 0, stream>>>(
      e1, nn, w1b2e, b1e_b1, w2b2, b1e_b2, pq2, e2, m2);
  node_mp<64, 128, 48, 128, false><<<BDIM * NDIM, 64, 0, stream>>>(
      h1, nullptr, m2, b1n_w1, b1n_b1, b1n_w2, b1n_b2, h2);

  pq_gemm<128, 192><<<BDIM * NDIM / 32, 256, 0, stream>>>(h2, wpq3, pq3);
  edge_mfma<128, 96, 192, false><<<BDIM * NDIM / 2, 256, 0, stream>>>(
      e2, nn, w1b3e, b2e_b1, w2b3, b2e_b2, pq3, nullptr, m3);
  node_mp<128, 192, 96, 192, false><<<BDIM * NDIM, 64, 0, stream>>>(
      h2, nullptr, m3, b2n_w1, b2n_b1, b2n_w2, b2n_b2, h3);

  zero_kernel<<<(BDIM * 512 + 255) / 256, 256, 0, stream>>>(pooled, BDIM * 512);
  fuse_pool<<<BDIM * NDIM / 16, 256, 0, stream>>>(h1, h2, h3, f_w, f_b, pooled);
  head_kernel<<<BDIM, 256, 0, stream>>>(pooled, p1_w, p1_b, p2_w, p2_b, p3_w,
                                        p3_b, out);

  hipMemcpyAsync(out + BDIM * 40, d_in[0], (size_t)BDIM * 3 * NDIM * 4,
                 hipMemcpyDeviceToDevice, stream);
}

// Round 5
// 358.479 us; speedup vs baseline: 5.0415x; 1.5175x over previous
//
#include <hip/hip_runtime.h>

#define BDIM 8
#define NDIM 1024
#define KNN 20

typedef unsigned short u16;
typedef float f32x4 __attribute__((ext_vector_type(4)));
typedef short short8 __attribute__((ext_vector_type(8)));
typedef unsigned short ushort8 __attribute__((ext_vector_type(8)));

__device__ inline u16 f2bf(float f) {
  unsigned u = __float_as_uint(f);
  unsigned r = (u + 0x7fffu + ((u >> 16) & 1u)) >> 16;
  return (u16)r;
}
__device__ inline float bf2f(u16 v) {
  return __uint_as_float(((unsigned)v) << 16);
}

// ---------------- KNN: one wave per point, wave-parallel top-20 (bit-exact) ----------------
__global__ __launch_bounds__(256) void knn_kernel(const float* __restrict__ x,
                                                  int* __restrict__ nn) {
#pragma clang fp contract(off)
  __shared__ float xs0[NDIM], xs1[NDIM], xs2[NDIM], sq[NDIM];
  const int tid = threadIdx.x;
  const int lane = tid & 63;
  const int w = tid >> 6;
  const int b = blockIdx.x >> 8;
  const int n = ((blockIdx.x & 255) << 2) + w;
  for (int i = tid; i < NDIM; i += 256) {
    float a0 = x[(b * 3 + 0) * NDIM + i];
    float a1 = x[(b * 3 + 1) * NDIM + i];
    float a2 = x[(b * 3 + 2) * NDIM + i];
    xs0[i] = a0; xs1[i] = a1; xs2[i] = a2;
    sq[i] = (a0 * a0 + a1 * a1) + a2 * a2;
  }
  __syncthreads();
  const float xn0 = xs0[n], xn1 = xs1[n], xn2 = xs2[n], sqn = sq[n];
  float dl[16];
#pragma unroll
  for (int t = 0; t < 16; ++t) {
    int m = t * 64 + lane;
    float dot = (xn0 * xs0[m] + xn1 * xs1[m]) + xn2 * xs2[m];
    dl[t] = (sqn - 2.0f * dot) + sq[m];
  }
  int* nnrow = &nn[(b * NDIM + n) * KNN];
  for (int r = 0; r < KNN; ++r) {
    float bd = dl[0];
    int bt = 0;
#pragma unroll
    for (int t = 1; t < 16; ++t) {
      if (dl[t] < bd) { bd = dl[t]; bt = t; }
    }
    int bi = bt * 64 + lane;
#pragma unroll
    for (int off = 1; off < 64; off <<= 1) {
      float pd = __shfl_xor(bd, off);
      int pi = __shfl_xor(bi, off);
      if (pd < bd || (pd == bd && pi < bi)) { bd = pd; bi = pi; }
    }
    if (lane == 0) nnrow[r] = bi;
    if ((bi & 63) == lane) {
      int wt = bi >> 6;
#pragma unroll
      for (int t = 0; t < 16; ++t) {
        if (t == wt) dl[t] = 3.4e38f;
      }
    }
  }
}

// ---------------- prep: bf16 weight tables + padded fp32 node1 w1 ----------------
__global__ __launch_bounds__(256) void wcvt(
    const float* __restrict__ w1_3, const float* __restrict__ w2_3,
    const float* __restrict__ w1_2, const float* __restrict__ w2_2,
    const float* __restrict__ hn_w1,
    u16* __restrict__ w1b3e, u16* __restrict__ wpq3, u16* __restrict__ w2b3,
    u16* __restrict__ w1b2e, u16* __restrict__ wpq2, u16* __restrict__ w2b2,
    float* __restrict__ w1p1) {
  const int idx = blockIdx.x * 256 + threadIdx.x;
  // block3 (b2e): w1 [96][384] = [e(128) | hi(128) | hj(128)], w2 [192][96]
  if (idx < 96 * 128) {
    int oc = idx >> 7, c = idx & 127;
    w1b3e[idx] = f2bf(w1_3[oc * 384 + c]);
  }
  if (idx < 192 * 128) {
    int n = idx >> 7, c = idx & 127;
    wpq3[idx] = f2bf(n < 96 ? w1_3[n * 384 + 128 + c]
                            : w1_3[(n - 96) * 384 + 256 + c]);
  }
  if (idx < 192 * 96) w2b3[idx] = f2bf(w2_3[idx]);
  // block2 (b1e): w1 [48][192] = [e(64) | hi(64) | hj(64)], w2 [128][48->64 pad]
  if (idx < 48 * 64) {
    int oc = idx >> 6, c = idx & 63;
    w1b2e[idx] = f2bf(w1_2[oc * 192 + c]);
  }
  if (idx < 96 * 64) {
    int n = idx >> 6, c = idx & 63;
    wpq2[idx] = f2bf(n < 48 ? w1_2[n * 192 + 64 + c]
                            : w1_2[(n - 48) * 192 + 128 + c]);
  }
  if (idx < 128 * 64) {
    int oc = idx >> 6, i = idx & 63;
    w2b2[idx] = (i < 48) ? f2bf(w2_2[oc * 48 + i]) : (u16)0;
  }
  // node1 w1 [32][67] -> padded fp32 [32][68]
  if (idx < 32 * 68) {
    int oc = idx / 68, c = idx - oc * 68;
    w1p1[idx] = (c < 67) ? hn_w1[oc * 67 + c] : 0.0f;
  }
}

// ---------------- PQ = h @ [W1hi;W1hj]^T  (per-point, fp32 out, no bias/relu) ----------------
template <int CH, int NPQ>
__global__ __launch_bounds__(256) void pq_gemm(const float* __restrict__ h,
                                               const u16* __restrict__ wpq,
                                               float* __restrict__ pq) {
  constexpr int BM = 32;
  constexpr int AP = CH + 8;
  __shared__ u16 As[BM * AP];
  const int tid = threadIdx.x;
  const int lane = tid & 63;
  const int wv = tid >> 6;
  const int row0 = blockIdx.x * BM;
  constexpr int KC = CH / 8;
  for (int ch = tid; ch < BM * KC; ch += 256) {
    int p = ch / KC, kc = ch - p * KC;
    int k0 = kc * 8;
    const float* src = &h[(size_t)(row0 + p) * CH + k0];
    float4 f0 = *(const float4*)src;
    float4 f1 = *(const float4*)(src + 4);
    ushort8 r;
    r[0] = f2bf(f0.x); r[1] = f2bf(f0.y); r[2] = f2bf(f0.z); r[3] = f2bf(f0.w);
    r[4] = f2bf(f1.x); r[5] = f2bf(f1.y); r[6] = f2bf(f1.z); r[7] = f2bf(f1.w);
    *(ushort8*)&As[p * AP + k0] = r;
  }
  __syncthreads();
  constexpr int NT = NPQ / 16;
  constexpr int JOBS = (BM / 16) * NT;
  constexpr int KS = CH / 32;
  for (int job = wv; job < JOBS; job += 4) {
    int mt = job / NT, nt = job - mt * NT;
    int row = mt * 16 + (lane & 15);
    int ncol = nt * 16 + (lane & 15);
    int kb = (lane >> 4) * 8;
    f32x4 acc = {0.f, 0.f, 0.f, 0.f};
    const u16* ap = &As[row * AP + kb];
    const u16* bp = &wpq[(size_t)ncol * CH + kb];
#pragma unroll
    for (int ks = 0; ks < KS; ++ks) {
      short8 a = *(const short8*)(ap + ks * 32);
      short8 bb = *(const short8*)(bp + ks * 32);
      acc = __builtin_amdgcn_mfma_f32_16x16x32_bf16(a, bb, acc, 0, 0, 0);
    }
    int m0 = mt * 16 + (lane >> 4) * 4;
#pragma unroll
    for (int r = 0; r < 4; ++r)
      pq[(size_t)(row0 + m0 + r) * NPQ + ncol] = acc[r];
  }
}

// ---------------- MFMA edge MP v2: e-only GEMM + PQ add (blocks 2,3) ----------------
template <int CE, int CMID, int COUT, bool WRITE_E>
__global__ __launch_bounds__(256) void edge_mfma(
    const u16* __restrict__ eprev, const int* __restrict__ nnb,
    const u16* __restrict__ w1b, const float* __restrict__ b1v,
    const u16* __restrict__ w2b, const float* __restrict__ b2v,
    const float* __restrict__ pq, u16* __restrict__ eout,
    float* __restrict__ mout) {
  constexpr int K2 = (CMID + 31) & ~31;
  constexpr int NPQ = 2 * CMID;
  constexpr int MT = 2 * KNN;   // 40 edges
  constexpr int MPAD = 48;      // 3 M-tiles
  constexpr int XPB = CE + 8;
  constexpr int Y1PB = K2 + 8;
  constexpr int Y2PB = COUT + 8;
  __shared__ u16 Xs[MPAD * XPB];
  __shared__ u16 Y1s[MPAD * Y1PB];
  __shared__ u16 Y2s[MT * Y2PB];
  __shared__ int nns[MT];
  const int tid = threadIdx.x;
  const int lane = tid & 63;
  const int wv = tid >> 6;
  const int bn0 = blockIdx.x * 2;
  const int b = bn0 >> 10;
  if (tid < MT) nns[tid] = nnb[(size_t)bn0 * KNN + tid];
  for (int i = tid; i < MPAD * Y1PB; i += 256) Y1s[i] = 0;
  constexpr int KC = CE / 8;
  for (int ch = tid; ch < MT * KC; ch += 256) {
    int p = ch / KC, kc = ch - p * KC;
    int k0 = kc * 8;
    *(uint4*)&Xs[p * XPB + k0] =
        *(const uint4*)&eprev[((size_t)blockIdx.x * MT + p) * CE + k0];
  }
  __syncthreads();
  // ---- conv1: e @ W1e^T + P_i + Q_j + b -> relu -> Y1 ----
  {
    constexpr int NT1 = CMID / 16;
    constexpr int J1 = 3 * NT1;
    constexpr int KS1 = CE / 32;
    for (int job = wv; job < J1; job += 4) {
      int mt = job / NT1, nt = job - mt * NT1;
      int row = mt * 16 + (lane & 15);
      int ncol = nt * 16 + (lane & 15);
      int kb = (lane >> 4) * 8;
      f32x4 acc = {0.f, 0.f, 0.f, 0.f};
      const u16* ap = &Xs[row * XPB + kb];
      const u16* bp = &w1b[(size_t)ncol * CE + kb];
#pragma unroll
      for (int ks = 0; ks < KS1; ++ks) {
        short8 a = *(const short8*)(ap + ks * 32);
        short8 bb = *(const short8*)(bp + ks * 32);
        acc = __builtin_amdgcn_mfma_f32_16x16x32_bf16(a, bb, acc, 0, 0, 0);
      }
      float bias = b1v[ncol];
      int m0 = mt * 16 + (lane >> 4) * 4;
#pragma unroll
      for (int r = 0; r < 4; ++r) {
        int m = m0 + r;
        int pt = bn0 + (m >= KNN);
        int jm = nns[m < MT ? m : MT - 1];
        float padd = pq[(size_t)pt * NPQ + ncol];
        float qadd = pq[((size_t)(b << 10) + jm) * NPQ + CMID + ncol];
        float yv = fmaxf(acc[r] + bias + padd + qadd, 0.0f);
        Y1s[m * Y1PB + ncol] = f2bf(yv);
      }
    }
  }
  __syncthreads();
  // ---- conv2: Y1 @ W2^T + b -> relu -> e ----
  {
    constexpr int NT2 = COUT / 16;
    constexpr int J2 = 3 * NT2;
    constexpr int KS2 = K2 / 32;
    for (int job = wv; job < J2; job += 4) {
      int mt = job / NT2, nt = job - mt * NT2;
      int row = mt * 16 + (lane & 15);
      int ncol = nt * 16 + (lane & 15);
      int kb = (lane >> 4) * 8;
      f32x4 acc = {0.f, 0.f, 0.f, 0.f};
      const u16* ap = &Y1s[row * Y1PB + kb];
      const u16* bp = &w2b[(size_t)ncol * K2 + kb];
#pragma unroll
      for (int ks = 0; ks < KS2; ++ks) {
        short8 a = *(const short8*)(ap + ks * 32);
        short8 bb = *(const short8*)(bp + ks * 32);
        acc = __builtin_amdgcn_mfma_f32_16x16x32_bf16(a, bb, acc, 0, 0, 0);
      }
      float bias = b2v[ncol];
      int m0 = mt * 16 + (lane >> 4) * 4;
#pragma unroll
      for (int r = 0; r < 4; ++r) {
        int m = m0 + r;
        if (m < MT) {
          float yv = fmaxf(acc[r] + bias, 0.0f);
          u16 bv = f2bf(yv);
          Y2s[m * Y2PB + ncol] = bv;
          if (WRITE_E)
            eout[((size_t)blockIdx.x * MT + m) * COUT + ncol] = bv;
        }
      }
    }
  }
  __syncthreads();
  for (int idx = tid; idx < 2 * COUT; idx += 256) {
    int r = idx / COUT, c = idx - r * COUT;
    float s = 0.0f;
#pragma unroll
    for (int k = 0; k < KNN; ++k) s += bf2f(Y2s[(r * KNN + k) * Y2PB + c]);
    mout[(size_t)(bn0 + r) * COUT + c] = s;
  }
}

// ---------------- fp32 edge MP (block 1 only, tiny CIN=12), bf16 e1 out ----------------
template <int CINC, int COUTC, int INP, int OUTP>
__device__ inline void tile_conv(const float* __restrict__ Xls,
                                 const float* __restrict__ w,
                                 const float* __restrict__ bias,
                                 float* __restrict__ Yls, int tid) {
  constexpr int PG = (2 * KNN) / 4;
  constexpr int NT = PG * (COUTC / 4);
  for (int t = tid; t < NT; t += 256) {
    int pg = t % PG, og = t / PG;
    float acc[4][4];
#pragma unroll
    for (int j = 0; j < 4; ++j) {
      float bj = bias[og * 4 + j];
#pragma unroll
      for (int i = 0; i < 4; ++i) acc[i][j] = bj;
    }
    for (int cin = 0; cin < CINC; cin += 4) {
      float4 xr[4], wr[4];
#pragma unroll
      for (int i = 0; i < 4; ++i)
        xr[i] = *(const float4*)&Xls[(pg * 4 + i) * INP + cin];
#pragma unroll
      for (int j = 0; j < 4; ++j)
        wr[j] = *(const float4*)&w[(og * 4 + j) * CINC + cin];
#pragma unroll
      for (int i = 0; i < 4; ++i)
#pragma unroll
        for (int j = 0; j < 4; ++j) {
          acc[i][j] += xr[i].x * wr[j].x;
          acc[i][j] += xr[i].y * wr[j].y;
          acc[i][j] += xr[i].z * wr[j].z;
          acc[i][j] += xr[i].w * wr[j].w;
        }
    }
#pragma unroll
    for (int i = 0; i < 4; ++i)
#pragma unroll
      for (int j = 0; j < 4; ++j)
        Yls[(pg * 4 + i) * OUTP + og * 4 + j] = fmaxf(acc[i][j], 0.0f);
  }
}

template <int CE, int CH, int CMID, int COUT>
__global__ __launch_bounds__(256) void edge_mp_first(
    const float* __restrict__ inputs, const int* __restrict__ nnb,
    const float* __restrict__ w1, const float* __restrict__ b1v,
    const float* __restrict__ w2, const float* __restrict__ b2v,
    u16* __restrict__ eout, float* __restrict__ mout) {
  constexpr int CIN = CE + 2 * CH;
  constexpr int TP = 2 * KNN;
  constexpr int XP = CIN + 4;
  constexpr int Y1P = CMID + 4;
  constexpr int Y2P = COUT + 4;
  __shared__ float Xs[TP * XP];
  __shared__ float Y1s[TP * Y1P];
  __shared__ float Y2s[TP * Y2P];
  __shared__ int nns[TP];
  const int tid = threadIdx.x;
  const int bn0 = blockIdx.x * 2;
  const int b = bn0 >> 10;
  if (tid < TP) nns[tid] = nnb[bn0 * KNN + tid];
  __syncthreads();
  for (int idx = tid; idx < TP * CIN; idx += 256) {
    int p = idx / CIN, c = idx - p * CIN;
    int bn = bn0 + (p >= KNN ? 1 : 0);
    int n = bn & (NDIM - 1);
    int j = nns[p];
    int cc = c % 3;
    int seg = c / 3;
    float hi = inputs[(b * 3 + cc) * NDIM + n];
    float hj = inputs[(b * 3 + cc) * NDIM + j];
    Xs[p * XP + c] = (seg == 1) ? (hi - hj) : ((seg == 3) ? hj : hi);
  }
  __syncthreads();
  tile_conv<CIN, CMID, XP, Y1P>(Xs, w1, b1v, Y1s, tid);
  __syncthreads();
  tile_conv<CMID, COUT, Y1P, Y2P>(Y1s, w2, b2v, Y2s, tid);
  __syncthreads();
  for (int idx = tid; idx < TP * COUT / 4; idx += 256) {
    int p = idx / (COUT / 4), c4 = idx - p * (COUT / 4);
    float4 v = *(const float4*)&Y2s[p * Y2P + c4 * 4];
    ushort4 o;
    o.x = f2bf(v.x); o.y = f2bf(v.y); o.z = f2bf(v.z); o.w = f2bf(v.w);
    *(ushort4*)&eout[((size_t)bn0 * KNN + p) * COUT + c4 * 4] = o;
  }
  for (int idx = tid; idx < 2 * COUT; idx += 256) {
    int r = idx / COUT, c = idx - r * COUT;
    float s = 0.0f;
#pragma unroll
    for (int k = 0; k < KNN; ++k) s += Y2s[(r * KNN + k) * Y2P + c];
    mout[(bn0 + r) * COUT + c] = s;
  }
}

// ---------------- node conv v2: fp32 microtile GEMM, TP rows per 256-thread block ----------------
template <int TP, int CH, int CM, int CINP, int CMID, int COUT, bool FIRSTH>
__global__ __launch_bounds__(256) void node_conv(
    const float* __restrict__ h, const float* __restrict__ inputs,
    const float* __restrict__ mbuf, const float* __restrict__ w1p,
    const float* __restrict__ b1v, const float* __restrict__ w2,
    const float* __restrict__ b2v, float* __restrict__ hout) {
  constexpr int CIN = CH + CM;
  constexpr int XP = CINP + 4;
  constexpr int Y1P = CMID + 4;
  constexpr int PG = TP / 4;
  __shared__ float Xs[TP * XP];
  __shared__ float Y1s[TP * Y1P];
  const int tid = threadIdx.x;
  const int bn0 = blockIdx.x * TP;
  // ---- stage X = [h | m] (+ zero pad cols) ----
  if (FIRSTH) {
    for (int idx = tid; idx < TP * CIN; idx += 256) {
      int p = idx / CIN, c = idx - p * CIN;
      int bn = bn0 + p;
      int b = bn >> 10, n = bn & (NDIM - 1);
      Xs[p * XP + c] = (c < CH) ? inputs[(b * 3 + c) * NDIM + n]
                                : mbuf[(size_t)bn * CM + (c - CH)];
    }
    for (int idx = tid; idx < TP * (CINP - CIN); idx += 256) {
      int p = idx / (CINP - CIN), c = CIN + idx % (CINP - CIN);
      Xs[p * XP + c] = 0.0f;
    }
  } else {
    constexpr int C4 = CIN / 4;
    for (int idx = tid; idx < TP * C4; idx += 256) {
      int p = idx / C4, c = (idx - p * C4) * 4;
      int bn = bn0 + p;
      float4 v = (c < CH) ? *(const float4*)&h[(size_t)bn * CH + c]
                          : *(const float4*)&mbuf[(size_t)bn * CM + (c - CH)];
      *(float4*)&Xs[p * XP + c] = v;
    }
  }
  __syncthreads();
  // ---- conv1 -> Y1 (relu) ----
  {
    constexpr int NT1 = PG * (CMID / 4);
    for (int t = tid; t < NT1; t += 256) {
      int pg = t % PG, og = t / PG;
      float acc[4][4];
#pragma unroll
      for (int j = 0; j < 4; ++j) {
        float bj = b1v[og * 4 + j];
#pragma unroll
        for (int i = 0; i < 4; ++i) acc[i][j] = bj;
      }
      for (int cin = 0; cin < CINP; cin += 4) {
        float4 xr[4], wr[4];
#pragma unroll
        for (int i = 0; i < 4; ++i)
          xr[i] = *(const float4*)&Xs[(pg * 4 + i) * XP + cin];
#pragma unroll
        for (int j = 0; j < 4; ++j)
          wr[j] = *(const float4*)&w1p[(size_t)(og * 4 + j) * CINP + cin];
#pragma unroll
        for (int i = 0; i < 4; ++i)
#pragma unroll
          for (int j = 0; j < 4; ++j) {
            acc[i][j] += xr[i].x * wr[j].x;
            acc[i][j] += xr[i].y * wr[j].y;
            acc[i][j] += xr[i].z * wr[j].z;
            acc[i][j] += xr[i].w * wr[j].w;
          }
      }
#pragma unroll
      for (int i = 0; i < 4; ++i)
#pragma unroll
        for (int j = 0; j < 4; ++j)
          Y1s[(pg * 4 + i) * Y1P + og * 4 + j] = fmaxf(acc[i][j], 0.0f);
    }
  }
  __syncthreads();
  // ---- conv2 -> global (relu) ----
  {
    constexpr int NT2 = PG * (COUT / 4);
    for (int t = tid; t < NT2; t += 256) {
      int pg = t % PG, og = t / PG;
      float acc[4][4];
#pragma unroll
      for (int j = 0; j < 4; ++j) {
        float bj = b2v[og * 4 + j];
#pragma unroll
        for (int i = 0; i < 4; ++i) acc[i][j] = bj;
      }
      for (int cin = 0; cin < CMID; cin += 4) {
        float4 xr[4], wr[4];
#pragma unroll
        for (int i = 0; i < 4; ++i)
          xr[i] = *(const float4*)&Y1s[(pg * 4 + i) * Y1P + cin];
#pragma unroll
        for (int j = 0; j < 4; ++j)
          wr[j] = *(const float4*)&w2[(size_t)(og * 4 + j) * CMID + cin];
#pragma unroll
        for (int i = 0; i < 4; ++i)
#pragma unroll
          for (int j = 0; j < 4; ++j) {
            acc[i][j] += xr[i].x * wr[j].x;
            acc[i][j] += xr[i].y * wr[j].y;
            acc[i][j] += xr[i].z * wr[j].z;
            acc[i][j] += xr[i].w * wr[j].w;
          }
      }
#pragma unroll
      for (int i = 0; i < 4; ++i) {
        int bn = bn0 + pg * 4 + i;
#pragma unroll
        for (int j = 0; j < 4; ++j)
          hout[(size_t)bn * COUT + og * 4 + j] = fmaxf(acc[i][j], 0.0f);
      }
    }
  }
}

// ---------------- fusion conv (384->512) + relu + global max pool ----------------
__global__ __launch_bounds__(256) void fuse_pool(
    const float* __restrict__ h1, const float* __restrict__ h2,
    const float* __restrict__ h3, const float* __restrict__ fw,
    const float* __restrict__ fb, int* __restrict__ pooled) {
  constexpr int CIN = 384, COUT = 512, TP = 16, XP = CIN + 4;
  __shared__ float Xs[TP * XP];
  __shared__ int pmax[COUT];
  const int tid = threadIdx.x;
  const int bn0 = blockIdx.x * TP;
  const int b = bn0 >> 10;
  for (int i = tid; i < COUT; i += 256) pmax[i] = 0;
  for (int idx = tid; idx < TP * CIN; idx += 256) {
    int p = idx / CIN, c = idx - p * CIN;
    int bn = bn0 + p;
    float v;
    if (c < 64) v = h1[bn * 64 + c];
    else if (c < 192) v = h2[bn * 128 + (c - 64)];
    else v = h3[bn * 192 + (c - 192)];
    Xs[p * XP + c] = v;
  }
  __syncthreads();
  constexpr int PG = TP / 4;
  constexpr int NT = PG * (COUT / 4);
  for (int t = tid; t < NT; t += 256) {
    int pg = t % PG, og = t / PG;
    float acc[4][4];
#pragma unroll
    for (int j = 0; j < 4; ++j) {
      float bj = fb[og * 4 + j];
#pragma unroll
      for (int i = 0; i < 4; ++i) acc[i][j] = bj;
    }
    for (int cin = 0; cin < CIN; cin += 4) {
      float4 xr[4], wr[4];
#pragma unroll
      for (int i = 0; i < 4; ++i)
        xr[i] = *(const float4*)&Xs[(pg * 4 + i) * XP + cin];
#pragma unroll
      for (int j = 0; j < 4; ++j)
        wr[j] = *(const float4*)&fw[(og * 4 + j) * CIN + cin];
#pragma unroll
      for (int i = 0; i < 4; ++i)
#pragma unroll
        for (int j = 0; j < 4; ++j) {
          acc[i][j] += xr[i].x * wr[j].x;
          acc[i][j] += xr[i].y * wr[j].y;
          acc[i][j] += xr[i].z * wr[j].z;
          acc[i][j] += xr[i].w * wr[j].w;
        }
    }
#pragma unroll
    for (int j = 0; j < 4; ++j) {
      float v = fmaxf(fmaxf(acc[0][j], acc[1][j]), fmaxf(acc[2][j], acc[3][j]));
      v = fmaxf(v, 0.0f);
      atomicMax(&pmax[og * 4 + j], __float_as_int(v));
    }
  }
  __syncthreads();
  for (int i = tid; i < COUT; i += 256)
    atomicMax(&pooled[b * COUT + i], pmax[i]);
}

// ---------------- prediction head ----------------
__global__ __launch_bounds__(256) void head_kernel(
    const int* __restrict__ pooledi, const float* __restrict__ p1w,
    const float* __restrict__ p1b, const float* __restrict__ p2w,
    const float* __restrict__ p2b, const float* __restrict__ p3w,
    const float* __restrict__ p3b, float* __restrict__ out) {
  __shared__ float xs[512], y1[256], y2[128];
  const int b = blockIdx.x, tid = threadIdx.x;
  for (int i = tid; i < 512; i += 256) xs[i] = __int_as_float(pooledi[b * 512 + i]);
  __syncthreads();
  {
    float acc = p1b[tid];
    for (int c = 0; c < 512; ++c) acc += xs[c] * p1w[tid * 512 + c];
    y1[tid] = fmaxf(acc, 0.0f);
  }
  __syncthreads();
  if (tid < 128) {
    float acc = p2b[tid];
    for (int c = 0; c < 256; ++c) acc += y1[c] * p2w[tid * 256 + c];
    y2[tid] = fmaxf(acc, 0.0f);
  }
  __syncthreads();
  if (tid < 40) {
    float acc = p3b[tid];
    for (int c = 0; c < 128; ++c) acc += y2[c] * p3w[tid * 128 + c];
    out[b * 40 + tid] = acc;
  }
}

__global__ void zero_kernel(int* __restrict__ p, int nel) {
  int i = blockIdx.x * 256 + threadIdx.x;
  if (i < nel) p[i] = 0;
}

extern "C" void kernel_launch(void* const* d_in, const int* in_sizes, int n_in,
                              void* d_out, int out_size, void* d_ws,
                              size_t ws_size, hipStream_t stream) {
  const float* inputs = (const float*)d_in[0];
  const float* he_w1 = (const float*)d_in[1];
  const float* he_b1 = (const float*)d_in[2];
  const float* he_w2 = (const float*)d_in[3];
  const float* he_b2 = (const float*)d_in[4];
  const float* hn_w1 = (const float*)d_in[5];
  const float* hn_b1 = (const float*)d_in[6];
  const float* hn_w2 = (const float*)d_in[7];
  const float* hn_b2 = (const float*)d_in[8];
  const float* b1e_w1 = (const float*)d_in[9];
  const float* b1e_b1 = (const float*)d_in[10];
  const float* b1e_w2 = (const float*)d_in[11];
  const float* b1e_b2 = (const float*)d_in[12];
  const float* b1n_w1 = (const float*)d_in[13];
  const float* b1n_b1 = (const float*)d_in[14];
  const float* b1n_w2 = (const float*)d_in[15];
  const float* b1n_b2 = (const float*)d_in[16];
  const float* b2e_w1 = (const float*)d_in[17];
  const float* b2e_b1 = (const float*)d_in[18];
  const float* b2e_w2 = (const float*)d_in[19];
  const float* b2e_b2 = (const float*)d_in[20];
  const float* b2n_w1 = (const float*)d_in[21];
  const float* b2n_b1 = (const float*)d_in[22];
  const float* b2n_w2 = (const float*)d_in[23];
  const float* b2n_b2 = (const float*)d_in[24];
  const float* f_w = (const float*)d_in[25];
  const float* f_b = (const float*)d_in[26];
  const float* p1_w = (const float*)d_in[27];
  const float* p1_b = (const float*)d_in[28];
  const float* p2_w = (const float*)d_in[29];
  const float* p2_b = (const float*)d_in[30];
  const float* p3_w = (const float*)d_in[31];
  const float* p3_b = (const float*)d_in[32];
  float* out = (float*)d_out;

  char* ws = (char*)d_ws;
  size_t off = 0;
  auto alloc = [&](size_t bytes) {
    void* p = ws + off;
    off += (bytes + 255) & ~(size_t)255;
    return p;
  };
  int* nn = (int*)alloc((size_t)BDIM * NDIM * KNN * 4);
  float* m1 = (float*)alloc((size_t)BDIM * NDIM * 64 * 4);
  float* h1 = (float*)alloc((size_t)BDIM * NDIM * 64 * 4);
  u16* e1 = (u16*)alloc((size_t)BDIM * NDIM * KNN * 64 * 2);   // bf16
  float* m2 = (float*)alloc((size_t)BDIM * NDIM * 128 * 4);
  float* h2 = (float*)alloc((size_t)BDIM * NDIM * 128 * 4);
  u16* e2 = (u16*)alloc((size_t)BDIM * NDIM * KNN * 128 * 2);  // bf16
  float* m3 = (float*)alloc((size_t)BDIM * NDIM * 192 * 4);
  float* h3 = (float*)alloc((size_t)BDIM * NDIM * 192 * 4);
  float* pq2 = (float*)alloc((size_t)BDIM * NDIM * 96 * 4);
  float* pq3 = (float*)alloc((size_t)BDIM * NDIM * 192 * 4);
  int* pooled = (int*)alloc((size_t)BDIM * 512 * 4);
  u16* w1b3e = (u16*)alloc((size_t)96 * 128 * 2);
  u16* wpq3 = (u16*)alloc((size_t)192 * 128 * 2);
  u16* w2b3 = (u16*)alloc((size_t)192 * 96 * 2);
  u16* w1b2e = (u16*)alloc((size_t)48 * 64 * 2);
  u16* wpq2 = (u16*)alloc((size_t)96 * 64 * 2);
  u16* w2b2 = (u16*)alloc((size_t)128 * 64 * 2);
  float* w1p1 = (float*)alloc((size_t)32 * 68 * 4);

  wcvt<<<(192 * 128 + 255) / 256, 256, 0, stream>>>(
      b2e_w1, b2e_w2, b1e_w1, b1e_w2, hn_w1, w1b3e, wpq3, w2b3, w1b2e, wpq2,
      w2b2, w1p1);
  knn_kernel<<<BDIM * 256, 256, 0, stream>>>(inputs, nn);

  edge_mp_first<6, 3, 32, 64><<<BDIM * NDIM / 2, 256, 0, stream>>>(
      inputs, nn, he_w1, he_b1, he_w2, he_b2, e1, m1);
  node_conv<64, 3, 64, 68, 32, 64, true><<<BDIM * NDIM / 64, 256, 0, stream>>>(
      nullptr, inputs, m1, w1p1, hn_b1, hn_w2, hn_b2, h1);

  pq_gemm<64, 96><<<BDIM * NDIM / 32, 256, 0, stream>>>(h1, wpq2, pq2);
  edge_mfma<64, 48, 128, true><<<BDIM * NDIM / 2, 256, 0, stream>>>(
      e1, nn, w1b2e, b1e_b1, w2b2, b1e_b2, pq2, e2, m2);
  node_conv<32, 64, 128, 192, 48, 128, false><<<BDIM * NDIM / 32, 256, 0, stream>>>(
      h1, nullptr, m2, b1n_w1, b1n_b1, b1n_w2, b1n_b2, h2);

  pq_gemm<128, 192><<<BDIM * NDIM / 32, 256, 0, stream>>>(h2, wpq3, pq3);
  edge_mfma<128, 96, 192, false><<<BDIM * NDIM / 2, 256, 0, stream>>>(
      e2, nn, w1b3e, b2e_b1, w2b3, b2e_b2, pq3, nullptr, m3);
  node_conv<16, 128, 192, 320, 96, 192, false><<<BDIM * NDIM / 16, 256, 0, stream>>>(
      h2, nullptr, m3, b2n_w1, b2n_b1, b2n_w2, b2n_b2, h3);

  zero_kernel<<<(BDIM * 512 + 255) / 256, 256, 0, stream>>>(pooled, BDIM * 512);
  fuse_pool<<<BDIM * NDIM / 16, 256, 0, stream>>>(h1, h2, h3, f_w, f_b, pooled);
  head_kernel<<<BDIM, 256, 0, stream>>>(pooled, p1_w, p1_b, p2_w, p2_b, p3_w,
                                        p3_b, out);

  hipMemcpyAsync(out + BDIM * 40, d_in[0], (size_t)BDIM * 3 * NDIM * 4,
                 hipMemcpyDeviceToDevice, stream);
}

// Round 6
// 324.192 us; speedup vs baseline: 5.5747x; 1.1058x over previous
//
#include <hip/hip_runtime.h>

#define BDIM 8
#define NDIM 1024
#define KNN 20

typedef unsigned short u16;
typedef float f32x4 __attribute__((ext_vector_type(4)));
typedef short short8 __attribute__((ext_vector_type(8)));
typedef unsigned short ushort8 __attribute__((ext_vector_type(8)));

__device__ inline u16 f2bf(float f) {
  unsigned u = __float_as_uint(f);
  unsigned r = (u + 0x7fffu + ((u >> 16) & 1u)) >> 16;
  return (u16)r;
}
__device__ inline float bf2f(u16 v) {
  return __uint_as_float(((unsigned)v) << 16);
}

// ---------------- KNN: one wave per point, wave-parallel top-20 (bit-exact) ----------------
__global__ __launch_bounds__(256) void knn_kernel(const float* __restrict__ x,
                                                  int* __restrict__ nn) {
#pragma clang fp contract(off)
  __shared__ float xs0[NDIM], xs1[NDIM], xs2[NDIM], sq[NDIM];
  const int tid = threadIdx.x;
  const int lane = tid & 63;
  const int w = tid >> 6;
  const int b = blockIdx.x >> 8;
  const int n = ((blockIdx.x & 255) << 2) + w;
  for (int i = tid; i < NDIM; i += 256) {
    float a0 = x[(b * 3 + 0) * NDIM + i];
    float a1 = x[(b * 3 + 1) * NDIM + i];
    float a2 = x[(b * 3 + 2) * NDIM + i];
    xs0[i] = a0; xs1[i] = a1; xs2[i] = a2;
    sq[i] = (a0 * a0 + a1 * a1) + a2 * a2;
  }
  __syncthreads();
  const float xn0 = xs0[n], xn1 = xs1[n], xn2 = xs2[n], sqn = sq[n];
  float dl[16];
#pragma unroll
  for (int t = 0; t < 16; ++t) {
    int m = t * 64 + lane;
    float dot = (xn0 * xs0[m] + xn1 * xs1[m]) + xn2 * xs2[m];
    dl[t] = (sqn - 2.0f * dot) + sq[m];
  }
  int* nnrow = &nn[(b * NDIM + n) * KNN];
  for (int r = 0; r < KNN; ++r) {
    float bd = dl[0];
    int bt = 0;
#pragma unroll
    for (int t = 1; t < 16; ++t) {
      if (dl[t] < bd) { bd = dl[t]; bt = t; }
    }
    int bi = bt * 64 + lane;
#pragma unroll
    for (int off = 1; off < 64; off <<= 1) {
      float pd = __shfl_xor(bd, off);
      int pi = __shfl_xor(bi, off);
      if (pd < bd || (pd == bd && pi < bi)) { bd = pd; bi = pi; }
    }
    if (lane == 0) nnrow[r] = bi;
    if ((bi & 63) == lane) {
      int wt = bi >> 6;
#pragma unroll
      for (int t = 0; t < 16; ++t) {
        if (t == wt) dl[t] = 3.4e38f;
      }
    }
  }
}

// ---------------- prep: bf16 weight tables + padded fp32 node1 w1 ----------------
__global__ __launch_bounds__(256) void wcvt(
    const float* __restrict__ w1_3, const float* __restrict__ w2_3,
    const float* __restrict__ w1_2, const float* __restrict__ w2_2,
    const float* __restrict__ hn_w1, const float* __restrict__ f_w,
    u16* __restrict__ w1b3e, u16* __restrict__ wpq3, u16* __restrict__ w2b3,
    u16* __restrict__ w1b2e, u16* __restrict__ wpq2, u16* __restrict__ w2b2,
    float* __restrict__ w1p1, u16* __restrict__ fwb) {
  const int idx = blockIdx.x * 256 + threadIdx.x;
  // fusion conv weight [512][384] -> bf16
  if (idx < 512 * 384) fwb[idx] = f2bf(f_w[idx]);
  // block3 (b2e): w1 [96][384] = [e(128) | hi(128) | hj(128)], w2 [192][96]
  if (idx < 96 * 128) {
    int oc = idx >> 7, c = idx & 127;
    w1b3e[idx] = f2bf(w1_3[oc * 384 + c]);
  }
  if (idx < 192 * 128) {
    int n = idx >> 7, c = idx & 127;
    wpq3[idx] = f2bf(n < 96 ? w1_3[n * 384 + 128 + c]
                            : w1_3[(n - 96) * 384 + 256 + c]);
  }
  if (idx < 192 * 96) w2b3[idx] = f2bf(w2_3[idx]);
  // block2 (b1e): w1 [48][192] = [e(64) | hi(64) | hj(64)], w2 [128][48->64 pad]
  if (idx < 48 * 64) {
    int oc = idx >> 6, c = idx & 63;
    w1b2e[idx] = f2bf(w1_2[oc * 192 + c]);
  }
  if (idx < 96 * 64) {
    int n = idx >> 6, c = idx & 63;
    wpq2[idx] = f2bf(n < 48 ? w1_2[n * 192 + 64 + c]
                            : w1_2[(n - 48) * 192 + 128 + c]);
  }
  if (idx < 128 * 64) {
    int oc = idx >> 6, i = idx & 63;
    w2b2[idx] = (i < 48) ? f2bf(w2_2[oc * 48 + i]) : (u16)0;
  }
  // node1 w1 [32][67] -> padded fp32 [32][68]
  if (idx < 32 * 68) {
    int oc = idx / 68, c = idx - oc * 68;
    w1p1[idx] = (c < 67) ? hn_w1[oc * 67 + c] : 0.0f;
  }
}

// ---------------- PQ = h @ [W1hi;W1hj]^T  (per-point, fp32 out, no bias/relu) ----------------
template <int CH, int NPQ>
__global__ __launch_bounds__(256) void pq_gemm(const float* __restrict__ h,
                                               const u16* __restrict__ wpq,
                                               float* __restrict__ pq) {
  constexpr int BM = 32;
  constexpr int AP = CH + 8;
  __shared__ u16 As[BM * AP];
  const int tid = threadIdx.x;
  const int lane = tid & 63;
  const int wv = tid >> 6;
  const int row0 = blockIdx.x * BM;
  constexpr int KC = CH / 8;
  for (int ch = tid; ch < BM * KC; ch += 256) {
    int p = ch / KC, kc = ch - p * KC;
    int k0 = kc * 8;
    const float* src = &h[(size_t)(row0 + p) * CH + k0];
    float4 f0 = *(const float4*)src;
    float4 f1 = *(const float4*)(src + 4);
    ushort8 r;
    r[0] = f2bf(f0.x); r[1] = f2bf(f0.y); r[2] = f2bf(f0.z); r[3] = f2bf(f0.w);
    r[4] = f2bf(f1.x); r[5] = f2bf(f1.y); r[6] = f2bf(f1.z); r[7] = f2bf(f1.w);
    *(ushort8*)&As[p * AP + k0] = r;
  }
  __syncthreads();
  constexpr int NT = NPQ / 16;
  constexpr int JOBS = (BM / 16) * NT;
  constexpr int KS = CH / 32;
  for (int job = wv; job < JOBS; job += 4) {
    int mt = job / NT, nt = job - mt * NT;
    int row = mt * 16 + (lane & 15);
    int ncol = nt * 16 + (lane & 15);
    int kb = (lane >> 4) * 8;
    f32x4 acc = {0.f, 0.f, 0.f, 0.f};
    const u16* ap = &As[row * AP + kb];
    const u16* bp = &wpq[(size_t)ncol * CH + kb];
#pragma unroll
    for (int ks = 0; ks < KS; ++ks) {
      short8 a = *(const short8*)(ap + ks * 32);
      short8 bb = *(const short8*)(bp + ks * 32);
      acc = __builtin_amdgcn_mfma_f32_16x16x32_bf16(a, bb, acc, 0, 0, 0);
    }
    int m0 = mt * 16 + (lane >> 4) * 4;
#pragma unroll
    for (int r = 0; r < 4; ++r)
      pq[(size_t)(row0 + m0 + r) * NPQ + ncol] = acc[r];
  }
}

// ---------------- MFMA edge MP v2: e-only GEMM + PQ add (blocks 2,3) ----------------
template <int CE, int CMID, int COUT, bool WRITE_E>
__global__ __launch_bounds__(256) void edge_mfma(
    const u16* __restrict__ eprev, const int* __restrict__ nnb,
    const u16* __restrict__ w1b, const float* __restrict__ b1v,
    const u16* __restrict__ w2b, const float* __restrict__ b2v,
    const float* __restrict__ pq, u16* __restrict__ eout,
    float* __restrict__ mout) {
  constexpr int K2 = (CMID + 31) & ~31;
  constexpr int NPQ = 2 * CMID;
  constexpr int MT = 2 * KNN;   // 40 edges
  constexpr int MPAD = 48;      // 3 M-tiles
  constexpr int XPB = CE + 8;
  constexpr int Y1PB = K2 + 8;
  constexpr int Y2PB = COUT + 8;
  __shared__ u16 Xs[MPAD * XPB];
  __shared__ u16 Y1s[MPAD * Y1PB];
  __shared__ u16 Y2s[MT * Y2PB];
  __shared__ int nns[MT];
  const int tid = threadIdx.x;
  const int lane = tid & 63;
  const int wv = tid >> 6;
  const int bn0 = blockIdx.x * 2;
  const int b = bn0 >> 10;
  if (tid < MT) nns[tid] = nnb[(size_t)bn0 * KNN + tid];
  for (int i = tid; i < MPAD * Y1PB; i += 256) Y1s[i] = 0;
  constexpr int KC = CE / 8;
  for (int ch = tid; ch < MT * KC; ch += 256) {
    int p = ch / KC, kc = ch - p * KC;
    int k0 = kc * 8;
    *(uint4*)&Xs[p * XPB + k0] =
        *(const uint4*)&eprev[((size_t)blockIdx.x * MT + p) * CE + k0];
  }
  __syncthreads();
  // ---- conv1: e @ W1e^T + P_i + Q_j + b -> relu -> Y1 ----
  {
    constexpr int NT1 = CMID / 16;
    constexpr int J1 = 3 * NT1;
    constexpr int KS1 = CE / 32;
    for (int job = wv; job < J1; job += 4) {
      int mt = job / NT1, nt = job - mt * NT1;
      int row = mt * 16 + (lane & 15);
      int ncol = nt * 16 + (lane & 15);
      int kb = (lane >> 4) * 8;
      f32x4 acc = {0.f, 0.f, 0.f, 0.f};
      const u16* ap = &Xs[row * XPB + kb];
      const u16* bp = &w1b[(size_t)ncol * CE + kb];
#pragma unroll
      for (int ks = 0; ks < KS1; ++ks) {
        short8 a = *(const short8*)(ap + ks * 32);
        short8 bb = *(const short8*)(bp + ks * 32);
        acc = __builtin_amdgcn_mfma_f32_16x16x32_bf16(a, bb, acc, 0, 0, 0);
      }
      float bias = b1v[ncol];
      int m0 = mt * 16 + (lane >> 4) * 4;
#pragma unroll
      for (int r = 0; r < 4; ++r) {
        int m = m0 + r;
        int pt = bn0 + (m >= KNN);
        int jm = nns[m < MT ? m : MT - 1];
        float padd = pq[(size_t)pt * NPQ + ncol];
        float qadd = pq[((size_t)(b << 10) + jm) * NPQ + CMID + ncol];
        float yv = fmaxf(acc[r] + bias + padd + qadd, 0.0f);
        Y1s[m * Y1PB + ncol] = f2bf(yv);
      }
    }
  }
  __syncthreads();
  // ---- conv2: Y1 @ W2^T + b -> relu -> e ----
  {
    constexpr int NT2 = COUT / 16;
    constexpr int J2 = 3 * NT2;
    constexpr int KS2 = K2 / 32;
    for (int job = wv; job < J2; job += 4) {
      int mt = job / NT2, nt = job - mt * NT2;
      int row = mt * 16 + (lane & 15);
      int ncol = nt * 16 + (lane & 15);
      int kb = (lane >> 4) * 8;
      f32x4 acc = {0.f, 0.f, 0.f, 0.f};
      const u16* ap = &Y1s[row * Y1PB + kb];
      const u16* bp = &w2b[(size_t)ncol * K2 + kb];
#pragma unroll
      for (int ks = 0; ks < KS2; ++ks) {
        short8 a = *(const short8*)(ap + ks * 32);
        short8 bb = *(const short8*)(bp + ks * 32);
        acc = __builtin_amdgcn_mfma_f32_16x16x32_bf16(a, bb, acc, 0, 0, 0);
      }
      float bias = b2v[ncol];
      int m0 = mt * 16 + (lane >> 4) * 4;
#pragma unroll
      for (int r = 0; r < 4; ++r) {
        int m = m0 + r;
        if (m < MT) {
          float yv = fmaxf(acc[r] + bias, 0.0f);
          u16 bv = f2bf(yv);
          Y2s[m * Y2PB + ncol] = bv;
          if (WRITE_E)
            eout[((size_t)blockIdx.x * MT + m) * COUT + ncol] = bv;
        }
      }
    }
  }
  __syncthreads();
  for (int idx = tid; idx < 2 * COUT; idx += 256) {
    int r = idx / COUT, c = idx - r * COUT;
    float s = 0.0f;
#pragma unroll
    for (int k = 0; k < KNN; ++k) s += bf2f(Y2s[(r * KNN + k) * Y2PB + c]);
    mout[(size_t)(bn0 + r) * COUT + c] = s;
  }
}

// ---------------- fp32 edge MP (block 1 only, tiny CIN=12), bf16 e1 out ----------------
template <int CINC, int COUTC, int INP, int OUTP>
__device__ inline void tile_conv(const float* __restrict__ Xls,
                                 const float* __restrict__ w,
                                 const float* __restrict__ bias,
                                 float* __restrict__ Yls, int tid) {
  constexpr int PG = (2 * KNN) / 4;
  constexpr int NT = PG * (COUTC / 4);
  for (int t = tid; t < NT; t += 256) {
    int pg = t % PG, og = t / PG;
    float acc[4][4];
#pragma unroll
    for (int j = 0; j < 4; ++j) {
      float bj = bias[og * 4 + j];
#pragma unroll
      for (int i = 0; i < 4; ++i) acc[i][j] = bj;
    }
    for (int cin = 0; cin < CINC; cin += 4) {
      float4 xr[4], wr[4];
#pragma unroll
      for (int i = 0; i < 4; ++i)
        xr[i] = *(const float4*)&Xls[(pg * 4 + i) * INP + cin];
#pragma unroll
      for (int j = 0; j < 4; ++j)
        wr[j] = *(const float4*)&w[(og * 4 + j) * CINC + cin];
#pragma unroll
      for (int i = 0; i < 4; ++i)
#pragma unroll
        for (int j = 0; j < 4; ++j) {
          acc[i][j] += xr[i].x * wr[j].x;
          acc[i][j] += xr[i].y * wr[j].y;
          acc[i][j] += xr[i].z * wr[j].z;
          acc[i][j] += xr[i].w * wr[j].w;
        }
    }
#pragma unroll
    for (int i = 0; i < 4; ++i)
#pragma unroll
      for (int j = 0; j < 4; ++j)
        Yls[(pg * 4 + i) * OUTP + og * 4 + j] = fmaxf(acc[i][j], 0.0f);
  }
}

template <int CE, int CH, int CMID, int COUT>
__global__ __launch_bounds__(256) void edge_mp_first(
    const float* __restrict__ inputs, const int* __restrict__ nnb,
    const float* __restrict__ w1, const float* __restrict__ b1v,
    const float* __restrict__ w2, const float* __restrict__ b2v,
    u16* __restrict__ eout, float* __restrict__ mout) {
  constexpr int CIN = CE + 2 * CH;
  constexpr int TP = 2 * KNN;
  constexpr int XP = CIN + 4;
  constexpr int Y1P = CMID + 4;
  constexpr int Y2P = COUT + 4;
  __shared__ float Xs[TP * XP];
  __shared__ float Y1s[TP * Y1P];
  __shared__ float Y2s[TP * Y2P];
  __shared__ int nns[TP];
  const int tid = threadIdx.x;
  const int bn0 = blockIdx.x * 2;
  const int b = bn0 >> 10;
  if (tid < TP) nns[tid] = nnb[bn0 * KNN + tid];
  __syncthreads();
  for (int idx = tid; idx < TP * CIN; idx += 256) {
    int p = idx / CIN, c = idx - p * CIN;
    int bn = bn0 + (p >= KNN ? 1 : 0);
    int n = bn & (NDIM - 1);
    int j = nns[p];
    int cc = c % 3;
    int seg = c / 3;
    float hi = inputs[(b * 3 + cc) * NDIM + n];
    float hj = inputs[(b * 3 + cc) * NDIM + j];
    Xs[p * XP + c] = (seg == 1) ? (hi - hj) : ((seg == 3) ? hj : hi);
  }
  __syncthreads();
  tile_conv<CIN, CMID, XP, Y1P>(Xs, w1, b1v, Y1s, tid);
  __syncthreads();
  tile_conv<CMID, COUT, Y1P, Y2P>(Y1s, w2, b2v, Y2s, tid);
  __syncthreads();
  for (int idx = tid; idx < TP * COUT / 4; idx += 256) {
    int p = idx / (COUT / 4), c4 = idx - p * (COUT / 4);
    float4 v = *(const float4*)&Y2s[p * Y2P + c4 * 4];
    ushort4 o;
    o.x = f2bf(v.x); o.y = f2bf(v.y); o.z = f2bf(v.z); o.w = f2bf(v.w);
    *(ushort4*)&eout[((size_t)bn0 * KNN + p) * COUT + c4 * 4] = o;
  }
  for (int idx = tid; idx < 2 * COUT; idx += 256) {
    int r = idx / COUT, c = idx - r * COUT;
    float s = 0.0f;
#pragma unroll
    for (int k = 0; k < KNN; ++k) s += Y2s[(r * KNN + k) * Y2P + c];
    mout[(bn0 + r) * COUT + c] = s;
  }
}

// ---------------- node conv v2: fp32 microtile GEMM, TP rows per 256-thread block ----------------
template <int TP, int CH, int CM, int CINP, int CMID, int COUT, bool FIRSTH>
__global__ __launch_bounds__(256) void node_conv(
    const float* __restrict__ h, const float* __restrict__ inputs,
    const float* __restrict__ mbuf, const float* __restrict__ w1p,
    const float* __restrict__ b1v, const float* __restrict__ w2,
    const float* __restrict__ b2v, float* __restrict__ hout) {
  constexpr int CIN = CH + CM;
  constexpr int XP = CINP + 4;
  constexpr int Y1P = CMID + 4;
  constexpr int PG = TP / 4;
  __shared__ float Xs[TP * XP];
  __shared__ float Y1s[TP * Y1P];
  const int tid = threadIdx.x;
  const int bn0 = blockIdx.x * TP;
  if (FIRSTH) {
    for (int idx = tid; idx < TP * CIN; idx += 256) {
      int p = idx / CIN, c = idx - p * CIN;
      int bn = bn0 + p;
      int b = bn >> 10, n = bn & (NDIM - 1);
      Xs[p * XP + c] = (c < CH) ? inputs[(b * 3 + c) * NDIM + n]
                                : mbuf[(size_t)bn * CM + (c - CH)];
    }
    for (int idx = tid; idx < TP * (CINP - CIN); idx += 256) {
      int p = idx / (CINP - CIN), c = CIN + idx % (CINP - CIN);
      Xs[p * XP + c] = 0.0f;
    }
  } else {
    constexpr int C4 = CIN / 4;
    for (int idx = tid; idx < TP * C4; idx += 256) {
      int p = idx / C4, c = (idx - p * C4) * 4;
      int bn = bn0 + p;
      float4 v = (c < CH) ? *(const float4*)&h[(size_t)bn * CH + c]
                          : *(const float4*)&mbuf[(size_t)bn * CM + (c - CH)];
      *(float4*)&Xs[p * XP + c] = v;
    }
  }
  __syncthreads();
  {
    constexpr int NT1 = PG * (CMID / 4);
    for (int t = tid; t < NT1; t += 256) {
      int pg = t % PG, og = t / PG;
      float acc[4][4];
#pragma unroll
      for (int j = 0; j < 4; ++j) {
        float bj = b1v[og * 4 + j];
#pragma unroll
        for (int i = 0; i < 4; ++i) acc[i][j] = bj;
      }
      for (int cin = 0; cin < CINP; cin += 4) {
        float4 xr[4], wr[4];
#pragma unroll
        for (int i = 0; i < 4; ++i)
          xr[i] = *(const float4*)&Xs[(pg * 4 + i) * XP + cin];
#pragma unroll
        for (int j = 0; j < 4; ++j)
          wr[j] = *(const float4*)&w1p[(size_t)(og * 4 + j) * CINP + cin];
#pragma unroll
        for (int i = 0; i < 4; ++i)
#pragma unroll
          for (int j = 0; j < 4; ++j) {
            acc[i][j] += xr[i].x * wr[j].x;
            acc[i][j] += xr[i].y * wr[j].y;
            acc[i][j] += xr[i].z * wr[j].z;
            acc[i][j] += xr[i].w * wr[j].w;
          }
      }
#pragma unroll
      for (int i = 0; i < 4; ++i)
#pragma unroll
        for (int j = 0; j < 4; ++j)
          Y1s[(pg * 4 + i) * Y1P + og * 4 + j] = fmaxf(acc[i][j], 0.0f);
    }
  }
  __syncthreads();
  {
    constexpr int NT2 = PG * (COUT / 4);
    for (int t = tid; t < NT2; t += 256) {
      int pg = t % PG, og = t / PG;
      float acc[4][4];
#pragma unroll
      for (int j = 0; j < 4; ++j) {
        float bj = b2v[og * 4 + j];
#pragma unroll
        for (int i = 0; i < 4; ++i) acc[i][j] = bj;
      }
      for (int cin = 0; cin < CMID; cin += 4) {
        float4 xr[4], wr[4];
#pragma unroll
        for (int i = 0; i < 4; ++i)
          xr[i] = *(const float4*)&Y1s[(pg * 4 + i) * Y1P + cin];
#pragma unroll
        for (int j = 0; j < 4; ++j)
          wr[j] = *(const float4*)&w2[(size_t)(og * 4 + j) * CMID + cin];
#pragma unroll
        for (int i = 0; i < 4; ++i)
#pragma unroll
          for (int j = 0; j < 4; ++j) {
            acc[i][j] += xr[i].x * wr[j].x;
            acc[i][j] += xr[i].y * wr[j].y;
            acc[i][j] += xr[i].z * wr[j].z;
            acc[i][j] += xr[i].w * wr[j].w;
          }
      }
#pragma unroll
      for (int i = 0; i < 4; ++i) {
        int bn = bn0 + pg * 4 + i;
#pragma unroll
        for (int j = 0; j < 4; ++j)
          hout[(size_t)bn * COUT + og * 4 + j] = fmaxf(acc[i][j], 0.0f);
      }
    }
  }
}

// ---------------- fusion conv (384->512) via MFMA + relu + global max pool ----------------
__global__ __launch_bounds__(256) void fuse_pool_mfma(
    const float* __restrict__ h1, const float* __restrict__ h2,
    const float* __restrict__ h3, const u16* __restrict__ fwb,
    const float* __restrict__ fb, int* __restrict__ pooled) {
  constexpr int CIN = 384, COUT = 512, TP = 32;
  constexpr int XPB = CIN + 8;  // 392 u16 -> 784 B rows (16B multiple)
  __shared__ u16 Xs[TP * XPB];
  __shared__ int pmax[COUT];
  const int tid = threadIdx.x;
  const int lane = tid & 63;
  const int wv = tid >> 6;
  const int bn0 = blockIdx.x * TP;
  const int b = bn0 >> 10;
  for (int i = tid; i < COUT; i += 256) pmax[i] = 0;
  // stage X = [h1|h2|h3] bf16
  constexpr int KC = CIN / 8;  // 48 chunks per row
  for (int ch = tid; ch < TP * KC; ch += 256) {
    int p = ch / KC, kc = ch - p * KC;
    int k0 = kc * 8;
    int bn = bn0 + p;
    const float* src;
    if (k0 < 64) src = &h1[(size_t)bn * 64 + k0];
    else if (k0 < 192) src = &h2[(size_t)bn * 128 + (k0 - 64)];
    else src = &h3[(size_t)bn * 192 + (k0 - 192)];
    float4 f0 = *(const float4*)src;
    float4 f1 = *(const float4*)(src + 4);
    ushort8 r;
    r[0] = f2bf(f0.x); r[1] = f2bf(f0.y); r[2] = f2bf(f0.z); r[3] = f2bf(f0.w);
    r[4] = f2bf(f1.x); r[5] = f2bf(f1.y); r[6] = f2bf(f1.z); r[7] = f2bf(f1.w);
    *(ushort8*)&Xs[p * XPB + k0] = r;
  }
  __syncthreads();
  constexpr int NT = COUT / 16;         // 32
  constexpr int JOBS = (TP / 16) * NT;  // 64
  constexpr int KS = CIN / 32;          // 12
  for (int job = wv; job < JOBS; job += 4) {
    int mt = job / NT, nt = job - mt * NT;
    int row = mt * 16 + (lane & 15);
    int ncol = nt * 16 + (lane & 15);
    int kb = (lane >> 4) * 8;
    f32x4 acc = {0.f, 0.f, 0.f, 0.f};
    const u16* ap = &Xs[row * XPB + kb];
    const u16* bp = &fwb[(size_t)ncol * CIN + kb];
#pragma unroll
    for (int ks = 0; ks < KS; ++ks) {
      short8 a = *(const short8*)(ap + ks * 32);
      short8 bb = *(const short8*)(bp + ks * 32);
      acc = __builtin_amdgcn_mfma_f32_16x16x32_bf16(a, bb, acc, 0, 0, 0);
    }
    float bias = fb[ncol];
    float v = fmaxf(fmaxf(acc[0], acc[1]), fmaxf(acc[2], acc[3])) + 0.0f;
    v = fmaxf(v + bias, 0.0f);
    // fold the four 16-lane groups (same ncol)
    v = fmaxf(v, __shfl_xor(v, 16));
    v = fmaxf(v, __shfl_xor(v, 32));
    if (lane < 16) atomicMax(&pmax[ncol], __float_as_int(v));
  }
  __syncthreads();
  for (int i = tid; i < COUT; i += 256)
    atomicMax(&pooled[b * COUT + i], pmax[i]);
}

// ---------------- prediction head ----------------
__global__ __launch_bounds__(256) void head_kernel(
    const int* __restrict__ pooledi, const float* __restrict__ p1w,
    const float* __restrict__ p1b, const float* __restrict__ p2w,
    const float* __restrict__ p2b, const float* __restrict__ p3w,
    const float* __restrict__ p3b, float* __restrict__ out) {
  __shared__ float xs[512], y1[256], y2[128];
  const int b = blockIdx.x, tid = threadIdx.x;
  for (int i = tid; i < 512; i += 256) xs[i] = __int_as_float(pooledi[b * 512 + i]);
  __syncthreads();
  {
    float acc = p1b[tid];
    for (int c = 0; c < 512; ++c) acc += xs[c] * p1w[tid * 512 + c];
    y1[tid] = fmaxf(acc, 0.0f);
  }
  __syncthreads();
  if (tid < 128) {
    float acc = p2b[tid];
    for (int c = 0; c < 256; ++c) acc += y1[c] * p2w[tid * 256 + c];
    y2[tid] = fmaxf(acc, 0.0f);
  }
  __syncthreads();
  if (tid < 40) {
    float acc = p3b[tid];
    for (int c = 0; c < 128; ++c) acc += y2[c] * p3w[tid * 128 + c];
    out[b * 40 + tid] = acc;
  }
}

__global__ void zero_kernel(int* __restrict__ p, int nel) {
  int i = blockIdx.x * 256 + threadIdx.x;
  if (i < nel) p[i] = 0;
}

extern "C" void kernel_launch(void* const* d_in, const int* in_sizes, int n_in,
                              void* d_out, int out_size, void* d_ws,
                              size_t ws_size, hipStream_t stream) {
  const float* inputs = (const float*)d_in[0];
  const float* he_w1 = (const float*)d_in[1];
  const float* he_b1 = (const float*)d_in[2];
  const float* he_w2 = (const float*)d_in[3];
  const float* he_b2 = (const float*)d_in[4];
  const float* hn_w1 = (const float*)d_in[5];
  const float* hn_b1 = (const float*)d_in[6];
  const float* hn_w2 = (const float*)d_in[7];
  const float* hn_b2 = (const float*)d_in[8];
  const float* b1e_w1 = (const float*)d_in[9];
  const float* b1e_b1 = (const float*)d_in[10];
  const float* b1e_w2 = (const float*)d_in[11];
  const float* b1e_b2 = (const float*)d_in[12];
  const float* b1n_w1 = (const float*)d_in[13];
  const float* b1n_b1 = (const float*)d_in[14];
  const float* b1n_w2 = (const float*)d_in[15];
  const float* b1n_b2 = (const float*)d_in[16];
  const float* b2e_w1 = (const float*)d_in[17];
  const float* b2e_b1 = (const float*)d_in[18];
  const float* b2e_w2 = (const float*)d_in[19];
  const float* b2e_b2 = (const float*)d_in[20];
  const float* b2n_w1 = (const float*)d_in[21];
  const float* b2n_b1 = (const float*)d_in[22];
  const float* b2n_w2 = (const float*)d_in[23];
  const float* b2n_b2 = (const float*)d_in[24];
  const float* f_w = (const float*)d_in[25];
  const float* f_b = (const float*)d_in[26];
  const float* p1_w = (const float*)d_in[27];
  const float* p1_b = (const float*)d_in[28];
  const float* p2_w = (const float*)d_in[29];
  const float* p2_b = (const float*)d_in[30];
  const float* p3_w = (const float*)d_in[31];
  const float* p3_b = (const float*)d_in[32];
  float* out = (float*)d_out;

  char* ws = (char*)d_ws;
  size_t off = 0;
  auto alloc = [&](size_t bytes) {
    void* p = ws + off;
    off += (bytes + 255) & ~(size_t)255;
    return p;
  };
  int* nn = (int*)alloc((size_t)BDIM * NDIM * KNN * 4);
  float* m1 = (float*)alloc((size_t)BDIM * NDIM * 64 * 4);
  float* h1 = (float*)alloc((size_t)BDIM * NDIM * 64 * 4);
  u16* e1 = (u16*)alloc((size_t)BDIM * NDIM * KNN * 64 * 2);   // bf16
  float* m2 = (float*)alloc((size_t)BDIM * NDIM * 128 * 4);
  float* h2 = (float*)alloc((size_t)BDIM * NDIM * 128 * 4);
  u16* e2 = (u16*)alloc((size_t)BDIM * NDIM * KNN * 128 * 2);  // bf16
  float* m3 = (float*)alloc((size_t)BDIM * NDIM * 192 * 4);
  float* h3 = (float*)alloc((size_t)BDIM * NDIM * 192 * 4);
  float* pq2 = (float*)alloc((size_t)BDIM * NDIM * 96 * 4);
  float* pq3 = (float*)alloc((size_t)BDIM * NDIM * 192 * 4);
  int* pooled = (int*)alloc((size_t)BDIM * 512 * 4);
  u16* w1b3e = (u16*)alloc((size_t)96 * 128 * 2);
  u16* wpq3 = (u16*)alloc((size_t)192 * 128 * 2);
  u16* w2b3 = (u16*)alloc((size_t)192 * 96 * 2);
  u16* w1b2e = (u16*)alloc((size_t)48 * 64 * 2);
  u16* wpq2 = (u16*)alloc((size_t)96 * 64 * 2);
  u16* w2b2 = (u16*)alloc((size_t)128 * 64 * 2);
  float* w1p1 = (float*)alloc((size_t)32 * 68 * 4);
  u16* fwb = (u16*)alloc((size_t)512 * 384 * 2);

  wcvt<<<(512 * 384 + 255) / 256, 256, 0, stream>>>(
      b2e_w1, b2e_w2, b1e_w1, b1e_w2, hn_w1, f_w, w1b3e, wpq3, w2b3, w1b2e,
      wpq2, w2b2, w1p1, fwb);
  knn_kernel<<<BDIM * 256, 256, 0, stream>>>(inputs, nn);

  edge_mp_first<6, 3, 32, 64><<<BDIM * NDIM / 2, 256, 0, stream>>>(
      inputs, nn, he_w1, he_b1, he_w2, he_b2, e1, m1);
  node_conv<64, 3, 64, 68, 32, 64, true><<<BDIM * NDIM / 64, 256, 0, stream>>>(
      nullptr, inputs, m1, w1p1, hn_b1, hn_w2, hn_b2, h1);

  pq_gemm<64, 96><<<BDIM * NDIM / 32, 256, 0, stream>>>(h1, wpq2, pq2);
  edge_mfma<64, 48, 128, true><<<BDIM * NDIM / 2, 256, 0, stream>>>(
      e1, nn, w1b2e, b1e_b1, w2b2, b1e_b2, pq2, e2, m2);
  node_conv<32, 64, 128, 192, 48, 128, false><<<BDIM * NDIM / 32, 256, 0, stream>>>(
      h1, nullptr, m2, b1n_w1, b1n_b1, b1n_w2, b1n_b2, h2);

  pq_gemm<128, 192><<<BDIM * NDIM / 32, 256, 0, stream>>>(h2, wpq3, pq3);
  edge_mfma<128, 96, 192, false><<<BDIM * NDIM / 2, 256, 0, stream>>>(
      e2, nn, w1b3e, b2e_b1, w2b3, b2e_b2, pq3, nullptr, m3);
  node_conv<16, 128, 192, 320, 96, 192, false><<<BDIM * NDIM / 16, 256, 0, stream>>>(
      h2, nullptr, m3, b2n_w1, b2n_b1, b2n_w2, b2n_b2, h3);

  zero_kernel<<<(BDIM * 512 + 255) / 256, 256, 0, stream>>>(pooled, BDIM * 512);
  fuse_pool_mfma<<<BDIM * NDIM / 32, 256, 0, stream>>>(h1, h2, h3, fwb, f_b,
                                                       pooled);
  head_kernel<<<BDIM, 256, 0, stream>>>(pooled, p1_w, p1_b, p2_w, p2_b, p3_w,
                                        p3_b, out);

  hipMemcpyAsync(out + BDIM * 40, d_in[0], (size_t)BDIM * 3 * NDIM * 4,
                 hipMemcpyDeviceToDevice, stream);
}

// Round 7
// 313.364 us; speedup vs baseline: 5.7673x; 1.0346x over previous
//
#include <hip/hip_runtime.h>

#define BDIM 8
#define NDIM 1024
#define KNN 20

typedef unsigned short u16;
typedef float f32x4 __attribute__((ext_vector_type(4)));
typedef short short8 __attribute__((ext_vector_type(8)));
typedef unsigned short ushort8 __attribute__((ext_vector_type(8)));

__device__ inline u16 f2bf(float f) {
  unsigned u = __float_as_uint(f);
  unsigned r = (u + 0x7fffu + ((u >> 16) & 1u)) >> 16;
  return (u16)r;
}
__device__ inline float bf2f(u16 v) {
  return __uint_as_float(((unsigned)v) << 16);
}

// ---------------- KNN: one wave per point, wave-parallel top-20 (bit-exact) ----------------
__global__ __launch_bounds__(256) void knn_kernel(const float* __restrict__ x,
                                                  int* __restrict__ nn) {
#pragma clang fp contract(off)
  __shared__ float xs0[NDIM], xs1[NDIM], xs2[NDIM], sq[NDIM];
  const int tid = threadIdx.x;
  const int lane = tid & 63;
  const int w = tid >> 6;
  const int b = blockIdx.x >> 8;
  const int n = ((blockIdx.x & 255) << 2) + w;
  for (int i = tid; i < NDIM; i += 256) {
    float a0 = x[(b * 3 + 0) * NDIM + i];
    float a1 = x[(b * 3 + 1) * NDIM + i];
    float a2 = x[(b * 3 + 2) * NDIM + i];
    xs0[i] = a0; xs1[i] = a1; xs2[i] = a2;
    sq[i] = (a0 * a0 + a1 * a1) + a2 * a2;
  }
  __syncthreads();
  const float xn0 = xs0[n], xn1 = xs1[n], xn2 = xs2[n], sqn = sq[n];
  float dl[16];
#pragma unroll
  for (int t = 0; t < 16; ++t) {
    int m = t * 64 + lane;
    float dot = (xn0 * xs0[m] + xn1 * xs1[m]) + xn2 * xs2[m];
    dl[t] = (sqn - 2.0f * dot) + sq[m];
  }
  int* nnrow = &nn[(b * NDIM + n) * KNN];
  for (int r = 0; r < KNN; ++r) {
    float bd = dl[0];
    int bt = 0;
#pragma unroll
    for (int t = 1; t < 16; ++t) {
      if (dl[t] < bd) { bd = dl[t]; bt = t; }
    }
    int bi = bt * 64 + lane;
#pragma unroll
    for (int off = 1; off < 64; off <<= 1) {
      float pd = __shfl_xor(bd, off);
      int pi = __shfl_xor(bi, off);
      if (pd < bd || (pd == bd && pi < bi)) { bd = pd; bi = pi; }
    }
    if (lane == 0) nnrow[r] = bi;
    if ((bi & 63) == lane) {
      int wt = bi >> 6;
#pragma unroll
      for (int t = 0; t < 16; ++t) {
        if (t == wt) dl[t] = 3.4e38f;
      }
    }
  }
}

// ---------------- prep: bf16 weight tables + padded fp32 node1 w1 ----------------
__global__ __launch_bounds__(256) void wcvt(
    const float* __restrict__ w1_3, const float* __restrict__ w2_3,
    const float* __restrict__ w1_2, const float* __restrict__ w2_2,
    const float* __restrict__ hn_w1, const float* __restrict__ f_w,
    u16* __restrict__ w1b3e, u16* __restrict__ wpq3, u16* __restrict__ w2b3,
    u16* __restrict__ w1b2e, u16* __restrict__ wpq2, u16* __restrict__ w2b2,
    float* __restrict__ w1p1, u16* __restrict__ fwb) {
  const int idx = blockIdx.x * 256 + threadIdx.x;
  if (idx < 512 * 384) fwb[idx] = f2bf(f_w[idx]);
  if (idx < 96 * 128) {
    int oc = idx >> 7, c = idx & 127;
    w1b3e[idx] = f2bf(w1_3[oc * 384 + c]);
  }
  if (idx < 192 * 128) {
    int n = idx >> 7, c = idx & 127;
    wpq3[idx] = f2bf(n < 96 ? w1_3[n * 384 + 128 + c]
                            : w1_3[(n - 96) * 384 + 256 + c]);
  }
  if (idx < 192 * 96) w2b3[idx] = f2bf(w2_3[idx]);
  if (idx < 48 * 64) {
    int oc = idx >> 6, c = idx & 63;
    w1b2e[idx] = f2bf(w1_2[oc * 192 + c]);
  }
  if (idx < 96 * 64) {
    int n = idx >> 6, c = idx & 63;
    wpq2[idx] = f2bf(n < 48 ? w1_2[n * 192 + 64 + c]
                            : w1_2[(n - 48) * 192 + 128 + c]);
  }
  if (idx < 128 * 64) {
    int oc = idx >> 6, i = idx & 63;
    w2b2[idx] = (i < 48) ? f2bf(w2_2[oc * 48 + i]) : (u16)0;
  }
  if (idx < 32 * 68) {
    int oc = idx / 68, c = idx - oc * 68;
    w1p1[idx] = (c < 67) ? hn_w1[oc * 67 + c] : 0.0f;
  }
}

// ---------------- PQ = h @ [W1hi;W1hj]^T  (per-point, fp32 out, no bias/relu) ----------------
template <int CH, int NPQ>
__global__ __launch_bounds__(256) void pq_gemm(const float* __restrict__ h,
                                               const u16* __restrict__ wpq,
                                               float* __restrict__ pq) {
  constexpr int BM = 32;
  constexpr int AP = CH + 8;
  __shared__ u16 As[BM * AP];
  const int tid = threadIdx.x;
  const int lane = tid & 63;
  const int wv = tid >> 6;
  const int row0 = blockIdx.x * BM;
  constexpr int KC = CH / 8;
  for (int ch = tid; ch < BM * KC; ch += 256) {
    int p = ch / KC, kc = ch - p * KC;
    int k0 = kc * 8;
    const float* src = &h[(size_t)(row0 + p) * CH + k0];
    float4 f0 = *(const float4*)src;
    float4 f1 = *(const float4*)(src + 4);
    ushort8 r;
    r[0] = f2bf(f0.x); r[1] = f2bf(f0.y); r[2] = f2bf(f0.z); r[3] = f2bf(f0.w);
    r[4] = f2bf(f1.x); r[5] = f2bf(f1.y); r[6] = f2bf(f1.z); r[7] = f2bf(f1.w);
    *(ushort8*)&As[p * AP + k0] = r;
  }
  __syncthreads();
  constexpr int NT = NPQ / 16;
  constexpr int JOBS = (BM / 16) * NT;
  constexpr int KS = CH / 32;
  for (int job = wv; job < JOBS; job += 4) {
    int mt = job / NT, nt = job - mt * NT;
    int row = mt * 16 + (lane & 15);
    int ncol = nt * 16 + (lane & 15);
    int kb = (lane >> 4) * 8;
    f32x4 acc = {0.f, 0.f, 0.f, 0.f};
    const u16* ap = &As[row * AP + kb];
    const u16* bp = &wpq[(size_t)ncol * CH + kb];
#pragma unroll
    for (int ks = 0; ks < KS; ++ks) {
      short8 a = *(const short8*)(ap + ks * 32);
      short8 bb = *(const short8*)(bp + ks * 32);
      acc = __builtin_amdgcn_mfma_f32_16x16x32_bf16(a, bb, acc, 0, 0, 0);
    }
    int m0 = mt * 16 + (lane >> 4) * 4;
#pragma unroll
    for (int r = 0; r < 4; ++r)
      pq[(size_t)(row0 + m0 + r) * NPQ + ncol] = acc[r];
  }
}

// ---------------- MFMA edge MP v3: global-A conv1, in-register m-sum ----------------
template <int CE, int CMID, int COUT, bool WRITE_E>
__global__ __launch_bounds__(256) void edge_mfma(
    const u16* __restrict__ eprev, const int* __restrict__ nnb,
    const u16* __restrict__ w1b, const float* __restrict__ b1v,
    const u16* __restrict__ w2b, const float* __restrict__ b2v,
    const float* __restrict__ pq, u16* __restrict__ eout,
    float* __restrict__ mout) {
  constexpr int K2 = (CMID + 31) & ~31;
  constexpr int NPQ = 2 * CMID;
  constexpr int MT = 2 * KNN;   // 40 edges
  constexpr int MPAD = 48;      // 3 M-tiles
  constexpr int Y1PB = K2 + 8;
  __shared__ u16 Y1s[MPAD * Y1PB];
  __shared__ float pld[2 * CMID];
  __shared__ int nns[MT];
  const int tid = threadIdx.x;
  const int lane = tid & 63;
  const int wv = tid >> 6;
  const int bn0 = blockIdx.x * 2;
  const int b = bn0 >> 10;
  if (tid < MT) nns[tid] = nnb[(size_t)bn0 * KNN + tid];
  for (int i = tid; i < 2 * CMID; i += 256)
    pld[i] = pq[(size_t)(bn0 + (i >= CMID)) * NPQ + (i >= CMID ? i - CMID : i)];
  if constexpr (K2 != CMID) {
    // zero pad columns region so conv2 pad-K contributes 0
    for (int i = tid; i < MPAD * Y1PB; i += 256) Y1s[i] = 0;
  }
  __syncthreads();
  // ---- conv1: A direct from global e_prev; +P(LDS) +Q(gather) +b -> relu -> Y1s ----
  {
    constexpr int NT1 = CMID / 16;
    constexpr int J1 = 3 * NT1;
    constexpr int KS1 = CE / 32;
    for (int job = wv; job < J1; job += 4) {
      int mt = job / NT1, nt = job - mt * NT1;
      int row = mt * 16 + (lane & 15);
      int srow = row < MT ? row : MT - 1;  // clamp pad rows (values unused)
      int ncol = nt * 16 + (lane & 15);
      int kb = (lane >> 4) * 8;
      f32x4 acc = {0.f, 0.f, 0.f, 0.f};
      const u16* ap = &eprev[((size_t)blockIdx.x * MT + srow) * CE + kb];
      const u16* bp = &w1b[(size_t)ncol * CE + kb];
#pragma unroll
      for (int ks = 0; ks < KS1; ++ks) {
        short8 a = *(const short8*)(ap + ks * 32);
        short8 bb = *(const short8*)(bp + ks * 32);
        acc = __builtin_amdgcn_mfma_f32_16x16x32_bf16(a, bb, acc, 0, 0, 0);
      }
      float bias = b1v[ncol];
      int m0 = mt * 16 + (lane >> 4) * 4;
#pragma unroll
      for (int r = 0; r < 4; ++r) {
        int m = m0 + r;
        int jm = nns[m < MT ? m : MT - 1];
        float padd = pld[(m >= KNN) * CMID + ncol];
        float qadd = pq[((size_t)(b << 10) + jm) * NPQ + CMID + ncol];
        float yv = fmaxf(acc[r] + bias + padd + qadd, 0.0f);
        Y1s[m * Y1PB + ncol] = f2bf(yv);
      }
    }
  }
  __syncthreads();
  // ---- conv2: one wave owns all 3 M-tiles per N-tile; m-sum in-register ----
  {
    constexpr int NT2 = COUT / 16;
    constexpr int KS2 = K2 / 32;
    for (int nt = wv; nt < NT2; nt += 4) {
      int ncol = nt * 16 + (lane & 15);
      int kb = (lane >> 4) * 8;
      short8 bfrag[KS2];
      const u16* bp = &w2b[(size_t)ncol * K2 + kb];
#pragma unroll
      for (int ks = 0; ks < KS2; ++ks)
        bfrag[ks] = *(const short8*)(bp + ks * 32);
      float bias = b2v[ncol];
      float s0 = 0.0f, s1 = 0.0f;
#pragma unroll
      for (int mt = 0; mt < 3; ++mt) {
        f32x4 acc = {0.f, 0.f, 0.f, 0.f};
        const u16* ap = &Y1s[(mt * 16 + (lane & 15)) * Y1PB + kb];
#pragma unroll
        for (int ks = 0; ks < KS2; ++ks) {
          short8 a = *(const short8*)(ap + ks * 32);
          acc = __builtin_amdgcn_mfma_f32_16x16x32_bf16(a, bfrag[ks], acc, 0, 0, 0);
        }
        int m0 = mt * 16 + (lane >> 4) * 4;
#pragma unroll
        for (int r = 0; r < 4; ++r) {
          int m = m0 + r;
          if (m < MT) {
            float yv = fmaxf(acc[r] + bias, 0.0f);
            u16 bv = f2bf(yv);
            float v = bf2f(bv);
            if (WRITE_E)
              eout[((size_t)blockIdx.x * MT + m) * COUT + ncol] = bv;
            if (m < KNN) s0 += v; else s1 += v;
          }
        }
      }
      // fold the four 16-lane groups (deterministic fixed-order tree)
      s0 += __shfl_xor(s0, 16); s0 += __shfl_xor(s0, 32);
      s1 += __shfl_xor(s1, 16); s1 += __shfl_xor(s1, 32);
      if (lane < 16) {
        mout[(size_t)bn0 * COUT + nt * 16 + lane] = s0;
        mout[(size_t)(bn0 + 1) * COUT + nt * 16 + lane] = s1;
      }
    }
  }
}

// ---------------- fp32 edge MP (block 1 only, tiny CIN=12), bf16 e1 out ----------------
template <int CINC, int COUTC, int INP, int OUTP>
__device__ inline void tile_conv(const float* __restrict__ Xls,
                                 const float* __restrict__ w,
                                 const float* __restrict__ bias,
                                 float* __restrict__ Yls, int tid) {
  constexpr int PG = (2 * KNN) / 4;
  constexpr int NT = PG * (COUTC / 4);
  for (int t = tid; t < NT; t += 256) {
    int pg = t % PG, og = t / PG;
    float acc[4][4];
#pragma unroll
    for (int j = 0; j < 4; ++j) {
      float bj = bias[og * 4 + j];
#pragma unroll
      for (int i = 0; i < 4; ++i) acc[i][j] = bj;
    }
    for (int cin = 0; cin < CINC; cin += 4) {
      float4 xr[4], wr[4];
#pragma unroll
      for (int i = 0; i < 4; ++i)
        xr[i] = *(const float4*)&Xls[(pg * 4 + i) * INP + cin];
#pragma unroll
      for (int j = 0; j < 4; ++j)
        wr[j] = *(const float4*)&w[(og * 4 + j) * CINC + cin];
#pragma unroll
      for (int i = 0; i < 4; ++i)
#pragma unroll
        for (int j = 0; j < 4; ++j) {
          acc[i][j] += xr[i].x * wr[j].x;
          acc[i][j] += xr[i].y * wr[j].y;
          acc[i][j] += xr[i].z * wr[j].z;
          acc[i][j] += xr[i].w * wr[j].w;
        }
    }
#pragma unroll
    for (int i = 0; i < 4; ++i)
#pragma unroll
      for (int j = 0; j < 4; ++j)
        Yls[(pg * 4 + i) * OUTP + og * 4 + j] = fmaxf(acc[i][j], 0.0f);
  }
}

template <int CE, int CH, int CMID, int COUT>
__global__ __launch_bounds__(256) void edge_mp_first(
    const float* __restrict__ inputs, const int* __restrict__ nnb,
    const float* __restrict__ w1, const float* __restrict__ b1v,
    const float* __restrict__ w2, const float* __restrict__ b2v,
    u16* __restrict__ eout, float* __restrict__ mout) {
  constexpr int CIN = CE + 2 * CH;
  constexpr int TP = 2 * KNN;
  constexpr int XP = CIN + 4;
  constexpr int Y1P = CMID + 4;
  constexpr int Y2P = COUT + 4;
  __shared__ float Xs[TP * XP];
  __shared__ float Y1s[TP * Y1P];
  __shared__ float Y2s[TP * Y2P];
  __shared__ int nns[TP];
  const int tid = threadIdx.x;
  const int bn0 = blockIdx.x * 2;
  const int b = bn0 >> 10;
  if (tid < TP) nns[tid] = nnb[bn0 * KNN + tid];
  __syncthreads();
  for (int idx = tid; idx < TP * CIN; idx += 256) {
    int p = idx / CIN, c = idx - p * CIN;
    int bn = bn0 + (p >= KNN ? 1 : 0);
    int n = bn & (NDIM - 1);
    int j = nns[p];
    int cc = c % 3;
    int seg = c / 3;
    float hi = inputs[(b * 3 + cc) * NDIM + n];
    float hj = inputs[(b * 3 + cc) * NDIM + j];
    Xs[p * XP + c] = (seg == 1) ? (hi - hj) : ((seg == 3) ? hj : hi);
  }
  __syncthreads();
  tile_conv<CIN, CMID, XP, Y1P>(Xs, w1, b1v, Y1s, tid);
  __syncthreads();
  tile_conv<CMID, COUT, Y1P, Y2P>(Y1s, w2, b2v, Y2s, tid);
  __syncthreads();
  for (int idx = tid; idx < TP * COUT / 4; idx += 256) {
    int p = idx / (COUT / 4), c4 = idx - p * (COUT / 4);
    float4 v = *(const float4*)&Y2s[p * Y2P + c4 * 4];
    ushort4 o;
    o.x = f2bf(v.x); o.y = f2bf(v.y); o.z = f2bf(v.z); o.w = f2bf(v.w);
    *(ushort4*)&eout[((size_t)bn0 * KNN + p) * COUT + c4 * 4] = o;
  }
  for (int idx = tid; idx < 2 * COUT; idx += 256) {
    int r = idx / COUT, c = idx - r * COUT;
    float s = 0.0f;
#pragma unroll
    for (int k = 0; k < KNN; ++k) s += Y2s[(r * KNN + k) * Y2P + c];
    mout[(bn0 + r) * COUT + c] = s;
  }
}

// ---------------- node conv: fp32 microtile GEMM, TP rows per 256-thread block ----------------
template <int TP, int CH, int CM, int CINP, int CMID, int COUT, bool FIRSTH>
__global__ __launch_bounds__(256) void node_conv(
    const float* __restrict__ h, const float* __restrict__ inputs,
    const float* __restrict__ mbuf, const float* __restrict__ w1p,
    const float* __restrict__ b1v, const float* __restrict__ w2,
    const float* __restrict__ b2v, float* __restrict__ hout) {
  constexpr int CIN = CH + CM;
  constexpr int XP = CINP + 4;
  constexpr int Y1P = CMID + 4;
  constexpr int PG = TP / 4;
  __shared__ float Xs[TP * XP];
  __shared__ float Y1s[TP * Y1P];
  const int tid = threadIdx.x;
  const int bn0 = blockIdx.x * TP;
  if (FIRSTH) {
    for (int idx = tid; idx < TP * CIN; idx += 256) {
      int p = idx / CIN, c = idx - p * CIN;
      int bn = bn0 + p;
      int b = bn >> 10, n = bn & (NDIM - 1);
      Xs[p * XP + c] = (c < CH) ? inputs[(b * 3 + c) * NDIM + n]
                                : mbuf[(size_t)bn * CM + (c - CH)];
    }
    for (int idx = tid; idx < TP * (CINP - CIN); idx += 256) {
      int p = idx / (CINP - CIN), c = CIN + idx % (CINP - CIN);
      Xs[p * XP + c] = 0.0f;
    }
  } else {
    constexpr int C4 = CIN / 4;
    for (int idx = tid; idx < TP * C4; idx += 256) {
      int p = idx / C4, c = (idx - p * C4) * 4;
      int bn = bn0 + p;
      float4 v = (c < CH) ? *(const float4*)&h[(size_t)bn * CH + c]
                          : *(const float4*)&mbuf[(size_t)bn * CM + (c - CH)];
      *(float4*)&Xs[p * XP + c] = v;
    }
  }
  __syncthreads();
  {
    constexpr int NT1 = PG * (CMID / 4);
    for (int t = tid; t < NT1; t += 256) {
      int pg = t % PG, og = t / PG;
      float acc[4][4];
#pragma unroll
      for (int j = 0; j < 4; ++j) {
        float bj = b1v[og * 4 + j];
#pragma unroll
        for (int i = 0; i < 4; ++i) acc[i][j] = bj;
      }
      for (int cin = 0; cin < CINP; cin += 4) {
        float4 xr[4], wr[4];
#pragma unroll
        for (int i = 0; i < 4; ++i)
          xr[i] = *(const float4*)&Xs[(pg * 4 + i) * XP + cin];
#pragma unroll
        for (int j = 0; j < 4; ++j)
          wr[j] = *(const float4*)&w1p[(size_t)(og * 4 + j) * CINP + cin];
#pragma unroll
        for (int i = 0; i < 4; ++i)
#pragma unroll
          for (int j = 0; j < 4; ++j) {
            acc[i][j] += xr[i].x * wr[j].x;
            acc[i][j] += xr[i].y * wr[j].y;
            acc[i][j] += xr[i].z * wr[j].z;
            acc[i][j] += xr[i].w * wr[j].w;
          }
      }
#pragma unroll
      for (int i = 0; i < 4; ++i)
#pragma unroll
        for (int j = 0; j < 4; ++j)
          Y1s[(pg * 4 + i) * Y1P + og * 4 + j] = fmaxf(acc[i][j], 0.0f);
    }
  }
  __syncthreads();
  {
    constexpr int NT2 = PG * (COUT / 4);
    for (int t = tid; t < NT2; t += 256) {
      int pg = t % PG, og = t / PG;
      float acc[4][4];
#pragma unroll
      for (int j = 0; j < 4; ++j) {
        float bj = b2v[og * 4 + j];
#pragma unroll
        for (int i = 0; i < 4; ++i) acc[i][j] = bj;
      }
      for (int cin = 0; cin < CMID; cin += 4) {
        float4 xr[4], wr[4];
#pragma unroll
        for (int i = 0; i < 4; ++i)
          xr[i] = *(const float4*)&Y1s[(pg * 4 + i) * Y1P + cin];
#pragma unroll
        for (int j = 0; j < 4; ++j)
          wr[j] = *(const float4*)&w2[(size_t)(og * 4 + j) * CMID + cin];
#pragma unroll
        for (int i = 0; i < 4; ++i)
#pragma unroll
          for (int j = 0; j < 4; ++j) {
            acc[i][j] += xr[i].x * wr[j].x;
            acc[i][j] += xr[i].y * wr[j].y;
            acc[i][j] += xr[i].z * wr[j].z;
            acc[i][j] += xr[i].w * wr[j].w;
          }
      }
#pragma unroll
      for (int i = 0; i < 4; ++i) {
        int bn = bn0 + pg * 4 + i;
#pragma unroll
        for (int j = 0; j < 4; ++j)
          hout[(size_t)bn * COUT + og * 4 + j] = fmaxf(acc[i][j], 0.0f);
      }
    }
  }
}

// ---------------- fusion conv (384->512) via MFMA + relu + global max pool ----------------
__global__ __launch_bounds__(256) void fuse_pool_mfma(
    const float* __restrict__ h1, const float* __restrict__ h2,
    const float* __restrict__ h3, const u16* __restrict__ fwb,
    const float* __restrict__ fb, int* __restrict__ pooled) {
  constexpr int CIN = 384, COUT = 512, TP = 32;
  constexpr int XPB = CIN + 8;
  __shared__ u16 Xs[TP * XPB];
  __shared__ int pmax[COUT];
  const int tid = threadIdx.x;
  const int lane = tid & 63;
  const int wv = tid >> 6;
  const int bn0 = blockIdx.x * TP;
  const int b = bn0 >> 10;
  for (int i = tid; i < COUT; i += 256) pmax[i] = 0;
  constexpr int KC = CIN / 8;
  for (int ch = tid; ch < TP * KC; ch += 256) {
    int p = ch / KC, kc = ch - p * KC;
    int k0 = kc * 8;
    int bn = bn0 + p;
    const float* src;
    if (k0 < 64) src = &h1[(size_t)bn * 64 + k0];
    else if (k0 < 192) src = &h2[(size_t)bn * 128 + (k0 - 64)];
    else src = &h3[(size_t)bn * 192 + (k0 - 192)];
    float4 f0 = *(const float4*)src;
    float4 f1 = *(const float4*)(src + 4);
    ushort8 r;
    r[0] = f2bf(f0.x); r[1] = f2bf(f0.y); r[2] = f2bf(f0.z); r[3] = f2bf(f0.w);
    r[4] = f2bf(f1.x); r[5] = f2bf(f1.y); r[6] = f2bf(f1.z); r[7] = f2bf(f1.w);
    *(ushort8*)&Xs[p * XPB + k0] = r;
  }
  __syncthreads();
  constexpr int NT = COUT / 16;
  constexpr int JOBS = (TP / 16) * NT;
  constexpr int KS = CIN / 32;
  for (int job = wv; job < JOBS; job += 4) {
    int mt = job / NT, nt = job - mt * NT;
    int row = mt * 16 + (lane & 15);
    int ncol = nt * 16 + (lane & 15);
    int kb = (lane >> 4) * 8;
    f32x4 acc = {0.f, 0.f, 0.f, 0.f};
    const u16* ap = &Xs[row * XPB + kb];
    const u16* bp = &fwb[(size_t)ncol * CIN + kb];
#pragma unroll
    for (int ks = 0; ks < KS; ++ks) {
      short8 a = *(const short8*)(ap + ks * 32);
      short8 bb = *(const short8*)(bp + ks * 32);
      acc = __builtin_amdgcn_mfma_f32_16x16x32_bf16(a, bb, acc, 0, 0, 0);
    }
    float bias = fb[ncol];
    float v = fmaxf(fmaxf(acc[0], acc[1]), fmaxf(acc[2], acc[3]));
    v = fmaxf(v + bias, 0.0f);
    v = fmaxf(v, __shfl_xor(v, 16));
    v = fmaxf(v, __shfl_xor(v, 32));
    if (lane < 16) atomicMax(&pmax[ncol], __float_as_int(v));
  }
  __syncthreads();
  for (int i = tid; i < COUT; i += 256)
    atomicMax(&pooled[b * COUT + i], pmax[i]);
}

// ---------------- prediction head ----------------
__global__ __launch_bounds__(256) void head_kernel(
    const int* __restrict__ pooledi, const float* __restrict__ p1w,
    const float* __restrict__ p1b, const float* __restrict__ p2w,
    const float* __restrict__ p2b, const float* __restrict__ p3w,
    const float* __restrict__ p3b, float* __restrict__ out) {
  __shared__ float xs[512], y1[256], y2[128];
  const int b = blockIdx.x, tid = threadIdx.x;
  for (int i = tid; i < 512; i += 256) xs[i] = __int_as_float(pooledi[b * 512 + i]);
  __syncthreads();
  {
    float acc = p1b[tid];
    for (int c = 0; c < 512; ++c) acc += xs[c] * p1w[tid * 512 + c];
    y1[tid] = fmaxf(acc, 0.0f);
  }
  __syncthreads();
  if (tid < 128) {
    float acc = p2b[tid];
    for (int c = 0; c < 256; ++c) acc += y1[c] * p2w[tid * 256 + c];
    y2[tid] = fmaxf(acc, 0.0f);
  }
  __syncthreads();
  if (tid < 40) {
    float acc = p3b[tid];
    for (int c = 0; c < 128; ++c) acc += y2[c] * p3w[tid * 128 + c];
    out[b * 40 + tid] = acc;
  }
}

__global__ void zero_kernel(int* __restrict__ p, int nel) {
  int i = blockIdx.x * 256 + threadIdx.x;
  if (i < nel) p[i] = 0;
}

extern "C" void kernel_launch(void* const* d_in, const int* in_sizes, int n_in,
                              void* d_out, int out_size, void* d_ws,
                              size_t ws_size, hipStream_t stream) {
  const float* inputs = (const float*)d_in[0];
  const float* he_w1 = (const float*)d_in[1];
  const float* he_b1 = (const float*)d_in[2];
  const float* he_w2 = (const float*)d_in[3];
  const float* he_b2 = (const float*)d_in[4];
  const float* hn_w1 = (const float*)d_in[5];
  const float* hn_b1 = (const float*)d_in[6];
  const float* hn_w2 = (const float*)d_in[7];
  const float* hn_b2 = (const float*)d_in[8];
  const float* b1e_w1 = (const float*)d_in[9];
  const float* b1e_b1 = (const float*)d_in[10];
  const float* b1e_w2 = (const float*)d_in[11];
  const float* b1e_b2 = (const float*)d_in[12];
  const float* b1n_w1 = (const float*)d_in[13];
  const float* b1n_b1 = (const float*)d_in[14];
  const float* b1n_w2 = (const float*)d_in[15];
  const float* b1n_b2 = (const float*)d_in[16];
  const float* b2e_w1 = (const float*)d_in[17];
  const float* b2e_b1 = (const float*)d_in[18];
  const float* b2e_w2 = (const float*)d_in[19];
  const float* b2e_b2 = (const float*)d_in[20];
  const float* b2n_w1 = (const float*)d_in[21];
  const float* b2n_b1 = (const float*)d_in[22];
  const float* b2n_w2 = (const float*)d_in[23];
  const float* b2n_b2 = (const float*)d_in[24];
  const float* f_w = (const float*)d_in[25];
  const float* f_b = (const float*)d_in[26];
  const float* p1_w = (const float*)d_in[27];
  const float* p1_b = (const float*)d_in[28];
  const float* p2_w = (const float*)d_in[29];
  const float* p2_b = (const float*)d_in[30];
  const float* p3_w = (const float*)d_in[31];
  const float* p3_b = (const float*)d_in[32];
  float* out = (float*)d_out;

  char* ws = (char*)d_ws;
  size_t off = 0;
  auto alloc = [&](size_t bytes) {
    void* p = ws + off;
    off += (bytes + 255) & ~(size_t)255;
    return p;
  };
  int* nn = (int*)alloc((size_t)BDIM * NDIM * KNN * 4);
  float* m1 = (float*)alloc((size_t)BDIM * NDIM * 64 * 4);
  float* h1 = (float*)alloc((size_t)BDIM * NDIM * 64 * 4);
  u16* e1 = (u16*)alloc((size_t)BDIM * NDIM * KNN * 64 * 2);   // bf16
  float* m2 = (float*)alloc((size_t)BDIM * NDIM * 128 * 4);
  float* h2 = (float*)alloc((size_t)BDIM * NDIM * 128 * 4);
  u16* e2 = (u16*)alloc((size_t)BDIM * NDIM * KNN * 128 * 2);  // bf16
  float* m3 = (float*)alloc((size_t)BDIM * NDIM * 192 * 4);
  float* h3 = (float*)alloc((size_t)BDIM * NDIM * 192 * 4);
  float* pq2 = (float*)alloc((size_t)BDIM * NDIM * 96 * 4);
  float* pq3 = (float*)alloc((size_t)BDIM * NDIM * 192 * 4);
  int* pooled = (int*)alloc((size_t)BDIM * 512 * 4);
  u16* w1b3e = (u16*)alloc((size_t)96 * 128 * 2);
  u16* wpq3 = (u16*)alloc((size_t)192 * 128 * 2);
  u16* w2b3 = (u16*)alloc((size_t)192 * 96 * 2);
  u16* w1b2e = (u16*)alloc((size_t)48 * 64 * 2);
  u16* wpq2 = (u16*)alloc((size_t)96 * 64 * 2);
  u16* w2b2 = (u16*)alloc((size_t)128 * 64 * 2);
  float* w1p1 = (float*)alloc((size_t)32 * 68 * 4);
  u16* fwb = (u16*)alloc((size_t)512 * 384 * 2);

  wcvt<<<(512 * 384 + 255) / 256, 256, 0, stream>>>(
      b2e_w1, b2e_w2, b1e_w1, b1e_w2, hn_w1, f_w, w1b3e, wpq3, w2b3, w1b2e,
      wpq2, w2b2, w1p1, fwb);
  knn_kernel<<<BDIM * 256, 256, 0, stream>>>(inputs, nn);

  edge_mp_first<6, 3, 32, 64><<<BDIM * NDIM / 2, 256, 0, stream>>>(
      inputs, nn, he_w1, he_b1, he_w2, he_b2, e1, m1);
  node_conv<64, 3, 64, 68, 32, 64, true><<<BDIM * NDIM / 64, 256, 0, stream>>>(
      nullptr, inputs, m1, w1p1, hn_b1, hn_w2, hn_b2, h1);

  pq_gemm<64, 96><<<BDIM * NDIM / 32, 256, 0, stream>>>(h1, wpq2, pq2);
  edge_mfma<64, 48, 128, true><<<BDIM * NDIM / 2, 256, 0, stream>>>(
      e1, nn, w1b2e, b1e_b1, w2b2, b1e_b2, pq2, e2, m2);
  node_conv<32, 64, 128, 192, 48, 128, false><<<BDIM * NDIM / 32, 256, 0, stream>>>(
      h1, nullptr, m2, b1n_w1, b1n_b1, b1n_w2, b1n_b2, h2);

  pq_gemm<128, 192><<<BDIM * NDIM / 32, 256, 0, stream>>>(h2, wpq3, pq3);
  edge_mfma<128, 96, 192, false><<<BDIM * NDIM / 2, 256, 0, stream>>>(
      e2, nn, w1b3e, b2e_b1, w2b3, b2e_b2, pq3, nullptr, m3);
  node_conv<16, 128, 192, 320, 96, 192, false><<<BDIM * NDIM / 16, 256, 0, stream>>>(
      h2, nullptr, m3, b2n_w1, b2n_b1, b2n_w2, b2n_b2, h3);

  zero_kernel<<<(BDIM * 512 + 255) / 256, 256, 0, stream>>>(pooled, BDIM * 512);
  fuse_pool_mfma<<<BDIM * NDIM / 32, 256, 0, stream>>>(h1, h2, h3, fwb, f_b,
                                                       pooled);
  head_kernel<<<BDIM, 256, 0, stream>>>(pooled, p1_w, p1_b, p2_w, p2_b, p3_w,
                                        p3_b, out);

  hipMemcpyAsync(out + BDIM * 40, d_in[0], (size_t)BDIM * 3 * NDIM * 4,
                 hipMemcpyDeviceToDevice, stream);
}

// Round 8
// 293.770 us; speedup vs baseline: 6.1520x; 1.0667x over previous
//
#include <hip/hip_runtime.h>

#define BDIM 8
#define NDIM 1024
#define KNN 20

typedef unsigned short u16;
typedef float f32x4 __attribute__((ext_vector_type(4)));
typedef short short8 __attribute__((ext_vector_type(8)));
typedef unsigned short ushort8 __attribute__((ext_vector_type(8)));

__device__ inline u16 f2bf(float f) {
  unsigned u = __float_as_uint(f);
  unsigned r = (u + 0x7fffu + ((u >> 16) & 1u)) >> 16;
  return (u16)r;
}
__device__ inline float bf2f(u16 v) {
  return __uint_as_float(((unsigned)v) << 16);
}

// ---------------- KNN: one wave per point, wave-parallel top-20 (bit-exact) ----------------
__global__ __launch_bounds__(256) void knn_kernel(const float* __restrict__ x,
                                                  int* __restrict__ nn) {
#pragma clang fp contract(off)
  __shared__ float xs0[NDIM], xs1[NDIM], xs2[NDIM], sq[NDIM];
  const int tid = threadIdx.x;
  const int lane = tid & 63;
  const int w = tid >> 6;
  const int b = blockIdx.x >> 8;
  const int n = ((blockIdx.x & 255) << 2) + w;
  for (int i = tid; i < NDIM; i += 256) {
    float a0 = x[(b * 3 + 0) * NDIM + i];
    float a1 = x[(b * 3 + 1) * NDIM + i];
    float a2 = x[(b * 3 + 2) * NDIM + i];
    xs0[i] = a0; xs1[i] = a1; xs2[i] = a2;
    sq[i] = (a0 * a0 + a1 * a1) + a2 * a2;
  }
  __syncthreads();
  const float xn0 = xs0[n], xn1 = xs1[n], xn2 = xs2[n], sqn = sq[n];
  float dl[16];
#pragma unroll
  for (int t = 0; t < 16; ++t) {
    int m = t * 64 + lane;
    float dot = (xn0 * xs0[m] + xn1 * xs1[m]) + xn2 * xs2[m];
    dl[t] = (sqn - 2.0f * dot) + sq[m];
  }
  int* nnrow = &nn[(b * NDIM + n) * KNN];
  for (int r = 0; r < KNN; ++r) {
    float bd = dl[0];
    int bt = 0;
#pragma unroll
    for (int t = 1; t < 16; ++t) {
      if (dl[t] < bd) { bd = dl[t]; bt = t; }
    }
    int bi = bt * 64 + lane;
#pragma unroll
    for (int off = 1; off < 64; off <<= 1) {
      float pd = __shfl_xor(bd, off);
      int pi = __shfl_xor(bi, off);
      if (pd < bd || (pd == bd && pi < bi)) { bd = pd; bi = pi; }
    }
    if (lane == 0) nnrow[r] = bi;
    if ((bi & 63) == lane) {
      int wt = bi >> 6;
#pragma unroll
      for (int t = 0; t < 16; ++t) {
        if (t == wt) dl[t] = 3.4e38f;
      }
    }
  }
}

// ---------------- prep: bf16 weight tables + padded fp32 node1 w1 ----------------
__global__ __launch_bounds__(256) void wcvt(
    const float* __restrict__ w1_3, const float* __restrict__ w2_3,
    const float* __restrict__ w1_2, const float* __restrict__ w2_2,
    const float* __restrict__ hn_w1, const float* __restrict__ f_w,
    u16* __restrict__ w1b3e, u16* __restrict__ wpq3, u16* __restrict__ w2b3,
    u16* __restrict__ w1b2e, u16* __restrict__ wpq2, u16* __restrict__ w2b2,
    float* __restrict__ w1p1, u16* __restrict__ fwb) {
  const int idx = blockIdx.x * 256 + threadIdx.x;
  if (idx < 512 * 384) fwb[idx] = f2bf(f_w[idx]);
  if (idx < 96 * 128) {
    int oc = idx >> 7, c = idx & 127;
    w1b3e[idx] = f2bf(w1_3[oc * 384 + c]);
  }
  if (idx < 192 * 128) {
    int n = idx >> 7, c = idx & 127;
    wpq3[idx] = f2bf(n < 96 ? w1_3[n * 384 + 128 + c]
                            : w1_3[(n - 96) * 384 + 256 + c]);
  }
  if (idx < 192 * 96) w2b3[idx] = f2bf(w2_3[idx]);
  if (idx < 48 * 64) {
    int oc = idx >> 6, c = idx & 63;
    w1b2e[idx] = f2bf(w1_2[oc * 192 + c]);
  }
  if (idx < 96 * 64) {
    int n = idx >> 6, c = idx & 63;
    wpq2[idx] = f2bf(n < 48 ? w1_2[n * 192 + 64 + c]
                            : w1_2[(n - 48) * 192 + 128 + c]);
  }
  if (idx < 128 * 64) {
    int oc = idx >> 6, i = idx & 63;
    w2b2[idx] = (i < 48) ? f2bf(w2_2[oc * 48 + i]) : (u16)0;
  }
  if (idx < 32 * 68) {
    int oc = idx / 68, c = idx - oc * 68;
    w1p1[idx] = (c < 67) ? hn_w1[oc * 67 + c] : 0.0f;
  }
}

// ---------------- PQ = h @ [W1hi;W1hj]^T  (per-point, fp32 out, no bias/relu) ----------------
template <int CH, int NPQ>
__global__ __launch_bounds__(256) void pq_gemm(const float* __restrict__ h,
                                               const u16* __restrict__ wpq,
                                               float* __restrict__ pq) {
  constexpr int BM = 32;
  constexpr int AP = CH + 8;
  __shared__ u16 As[BM * AP];
  const int tid = threadIdx.x;
  const int lane = tid & 63;
  const int wv = tid >> 6;
  const int row0 = blockIdx.x * BM;
  constexpr int KC = CH / 8;
  for (int ch = tid; ch < BM * KC; ch += 256) {
    int p = ch / KC, kc = ch - p * KC;
    int k0 = kc * 8;
    const float* src = &h[(size_t)(row0 + p) * CH + k0];
    float4 f0 = *(const float4*)src;
    float4 f1 = *(const float4*)(src + 4);
    ushort8 r;
    r[0] = f2bf(f0.x); r[1] = f2bf(f0.y); r[2] = f2bf(f0.z); r[3] = f2bf(f0.w);
    r[4] = f2bf(f1.x); r[5] = f2bf(f1.y); r[6] = f2bf(f1.z); r[7] = f2bf(f1.w);
    *(ushort8*)&As[p * AP + k0] = r;
  }
  __syncthreads();
  constexpr int NT = NPQ / 16;
  constexpr int JOBS = (BM / 16) * NT;
  constexpr int KS = CH / 32;
  for (int job = wv; job < JOBS; job += 4) {
    int mt = job / NT, nt = job - mt * NT;
    int row = mt * 16 + (lane & 15);
    int ncol = nt * 16 + (lane & 15);
    int kb = (lane >> 4) * 8;
    f32x4 acc = {0.f, 0.f, 0.f, 0.f};
    const u16* ap = &As[row * AP + kb];
    const u16* bp = &wpq[(size_t)ncol * CH + kb];
#pragma unroll
    for (int ks = 0; ks < KS; ++ks) {
      short8 a = *(const short8*)(ap + ks * 32);
      short8 bb = *(const short8*)(bp + ks * 32);
      acc = __builtin_amdgcn_mfma_f32_16x16x32_bf16(a, bb, acc, 0, 0, 0);
    }
    int m0 = mt * 16 + (lane >> 4) * 4;
#pragma unroll
    for (int r = 0; r < 4; ++r)
      pq[(size_t)(row0 + m0 + r) * NPQ + ncol] = acc[r];
  }
}

// ---------------- MFMA edge MP v4: staged A + staged Q, in-register m-sum ----------------
template <int CE, int CMID, int COUT, bool WRITE_E>
__global__ __launch_bounds__(256) void edge_mfma(
    const u16* __restrict__ eprev, const int* __restrict__ nnb,
    const u16* __restrict__ w1b, const float* __restrict__ b1v,
    const u16* __restrict__ w2b, const float* __restrict__ b2v,
    const float* __restrict__ pq, u16* __restrict__ eout,
    float* __restrict__ mout) {
  constexpr int K2 = (CMID + 31) & ~31;
  constexpr int NPQ = 2 * CMID;
  constexpr int MT = 2 * KNN;   // 40 edges
  constexpr int MPAD = 48;      // 3 M-tiles
  constexpr int XPB = CE + 8;
  constexpr int Y1PB = K2 + 8;
  constexpr int QP = CMID + 4;  // Q pitch (breaks mod-32 bank alias)
  __shared__ u16 Xs[MT * XPB];
  __shared__ u16 Y1s[MPAD * Y1PB];
  __shared__ float Qs[MT * QP];
  __shared__ float pld[2 * CMID];
  __shared__ int nns[MT];
  const int tid = threadIdx.x;
  const int lane = tid & 63;
  const int wv = tid >> 6;
  const int bn0 = blockIdx.x * 2;
  const int b = bn0 >> 10;
  if (tid < MT) nns[tid] = nnb[(size_t)bn0 * KNN + tid];
  __syncthreads();
  // ---- bulk staging phase (high MLP, coalesced) ----
  constexpr int KC = CE / 8;
  for (int ch = tid; ch < MT * KC; ch += 256) {
    int p = ch / KC, kc = ch - p * KC;
    int k0 = kc * 8;
    *(uint4*)&Xs[p * XPB + k0] =
        *(const uint4*)&eprev[((size_t)blockIdx.x * MT + p) * CE + k0];
  }
  constexpr int QC = CMID / 4;
  for (int i = tid; i < MT * QC; i += 256) {
    int p = i / QC, c4 = (i - p * QC) * 4;
    float4 v = *(const float4*)&pq[((size_t)(b << 10) + nns[p]) * NPQ + CMID + c4];
    *(float4*)&Qs[p * QP + c4] = v;
  }
  for (int i = tid; i < 2 * CMID; i += 256)
    pld[i] = pq[(size_t)(bn0 + (i >= CMID)) * NPQ + (i >= CMID ? i - CMID : i)];
  if constexpr (K2 != CMID) {
    for (int i = tid; i < MPAD * Y1PB; i += 256) Y1s[i] = 0;
  }
  __syncthreads();
  // ---- conv1: Xs @ W1e^T + P(LDS) + Q(LDS) + b -> relu -> Y1s ----
  {
    constexpr int NT1 = CMID / 16;
    constexpr int J1 = 3 * NT1;
    constexpr int KS1 = CE / 32;
    for (int job = wv; job < J1; job += 4) {
      int mt = job / NT1, nt = job - mt * NT1;
      int row = mt * 16 + (lane & 15);
      int srow = row < MT ? row : MT - 1;
      int ncol = nt * 16 + (lane & 15);
      int kb = (lane >> 4) * 8;
      f32x4 acc = {0.f, 0.f, 0.f, 0.f};
      const u16* ap = &Xs[srow * XPB + kb];
      const u16* bp = &w1b[(size_t)ncol * CE + kb];
#pragma unroll
      for (int ks = 0; ks < KS1; ++ks) {
        short8 a = *(const short8*)(ap + ks * 32);
        short8 bb = *(const short8*)(bp + ks * 32);
        acc = __builtin_amdgcn_mfma_f32_16x16x32_bf16(a, bb, acc, 0, 0, 0);
      }
      float bias = b1v[ncol];
      int m0 = mt * 16 + (lane >> 4) * 4;
#pragma unroll
      for (int r = 0; r < 4; ++r) {
        int m = m0 + r;
        int sm = m < MT ? m : MT - 1;
        float padd = pld[(m >= KNN) * CMID + ncol];
        float qadd = Qs[sm * QP + ncol];
        float yv = fmaxf(acc[r] + bias + padd + qadd, 0.0f);
        Y1s[m * Y1PB + ncol] = f2bf(yv);
      }
    }
  }
  __syncthreads();
  // ---- conv2: one wave owns all 3 M-tiles per N-tile; m-sum in-register ----
  {
    constexpr int NT2 = COUT / 16;
    constexpr int KS2 = K2 / 32;
    for (int nt = wv; nt < NT2; nt += 4) {
      int ncol = nt * 16 + (lane & 15);
      int kb = (lane >> 4) * 8;
      short8 bfrag[KS2];
      const u16* bp = &w2b[(size_t)ncol * K2 + kb];
#pragma unroll
      for (int ks = 0; ks < KS2; ++ks)
        bfrag[ks] = *(const short8*)(bp + ks * 32);
      float bias = b2v[ncol];
      float s0 = 0.0f, s1 = 0.0f;
#pragma unroll
      for (int mt = 0; mt < 3; ++mt) {
        f32x4 acc = {0.f, 0.f, 0.f, 0.f};
        const u16* ap = &Y1s[(mt * 16 + (lane & 15)) * Y1PB + kb];
#pragma unroll
        for (int ks = 0; ks < KS2; ++ks) {
          short8 a = *(const short8*)(ap + ks * 32);
          acc = __builtin_amdgcn_mfma_f32_16x16x32_bf16(a, bfrag[ks], acc, 0, 0, 0);
        }
        int m0 = mt * 16 + (lane >> 4) * 4;
#pragma unroll
        for (int r = 0; r < 4; ++r) {
          int m = m0 + r;
          if (m < MT) {
            float yv = fmaxf(acc[r] + bias, 0.0f);
            u16 bv = f2bf(yv);
            float v = bf2f(bv);
            if (WRITE_E)
              eout[((size_t)blockIdx.x * MT + m) * COUT + ncol] = bv;
            if (m < KNN) s0 += v; else s1 += v;
          }
        }
      }
      s0 += __shfl_xor(s0, 16); s0 += __shfl_xor(s0, 32);
      s1 += __shfl_xor(s1, 16); s1 += __shfl_xor(s1, 32);
      if (lane < 16) {
        mout[(size_t)bn0 * COUT + nt * 16 + lane] = s0;
        mout[(size_t)(bn0 + 1) * COUT + nt * 16 + lane] = s1;
      }
    }
  }
}

// ---------------- fp32 edge MP (block 1 only, tiny CIN=12), bf16 e1 out ----------------
template <int CINC, int COUTC, int INP, int OUTP>
__device__ inline void tile_conv(const float* __restrict__ Xls,
                                 const float* __restrict__ w,
                                 const float* __restrict__ bias,
                                 float* __restrict__ Yls, int tid) {
  constexpr int PG = (2 * KNN) / 4;
  constexpr int NT = PG * (COUTC / 4);
  for (int t = tid; t < NT; t += 256) {
    int pg = t % PG, og = t / PG;
    float acc[4][4];
#pragma unroll
    for (int j = 0; j < 4; ++j) {
      float bj = bias[og * 4 + j];
#pragma unroll
      for (int i = 0; i < 4; ++i) acc[i][j] = bj;
    }
    for (int cin = 0; cin < CINC; cin += 4) {
      float4 xr[4], wr[4];
#pragma unroll
      for (int i = 0; i < 4; ++i)
        xr[i] = *(const float4*)&Xls[(pg * 4 + i) * INP + cin];
#pragma unroll
      for (int j = 0; j < 4; ++j)
        wr[j] = *(const float4*)&w[(og * 4 + j) * CINC + cin];
#pragma unroll
      for (int i = 0; i < 4; ++i)
#pragma unroll
        for (int j = 0; j < 4; ++j) {
          acc[i][j] += xr[i].x * wr[j].x;
          acc[i][j] += xr[i].y * wr[j].y;
          acc[i][j] += xr[i].z * wr[j].z;
          acc[i][j] += xr[i].w * wr[j].w;
        }
    }
#pragma unroll
    for (int i = 0; i < 4; ++i)
#pragma unroll
      for (int j = 0; j < 4; ++j)
        Yls[(pg * 4 + i) * OUTP + og * 4 + j] = fmaxf(acc[i][j], 0.0f);
  }
}

template <int CE, int CH, int CMID, int COUT>
__global__ __launch_bounds__(256) void edge_mp_first(
    const float* __restrict__ inputs, const int* __restrict__ nnb,
    const float* __restrict__ w1, const float* __restrict__ b1v,
    const float* __restrict__ w2, const float* __restrict__ b2v,
    u16* __restrict__ eout, float* __restrict__ mout) {
  constexpr int CIN = CE + 2 * CH;
  constexpr int TP = 2 * KNN;
  constexpr int XP = CIN + 4;
  constexpr int Y1P = CMID + 4;
  constexpr int Y2P = COUT + 4;
  __shared__ float Xs[TP * XP];
  __shared__ float Y1s[TP * Y1P];
  __shared__ float Y2s[TP * Y2P];
  __shared__ int nns[TP];
  const int tid = threadIdx.x;
  const int bn0 = blockIdx.x * 2;
  const int b = bn0 >> 10;
  if (tid < TP) nns[tid] = nnb[bn0 * KNN + tid];
  __syncthreads();
  for (int idx = tid; idx < TP * CIN; idx += 256) {
    int p = idx / CIN, c = idx - p * CIN;
    int bn = bn0 + (p >= KNN ? 1 : 0);
    int n = bn & (NDIM - 1);
    int j = nns[p];
    int cc = c % 3;
    int seg = c / 3;
    float hi = inputs[(b * 3 + cc) * NDIM + n];
    float hj = inputs[(b * 3 + cc) * NDIM + j];
    Xs[p * XP + c] = (seg == 1) ? (hi - hj) : ((seg == 3) ? hj : hi);
  }
  __syncthreads();
  tile_conv<CIN, CMID, XP, Y1P>(Xs, w1, b1v, Y1s, tid);
  __syncthreads();
  tile_conv<CMID, COUT, Y1P, Y2P>(Y1s, w2, b2v, Y2s, tid);
  __syncthreads();
  for (int idx = tid; idx < TP * COUT / 4; idx += 256) {
    int p = idx / (COUT / 4), c4 = idx - p * (COUT / 4);
    float4 v = *(const float4*)&Y2s[p * Y2P + c4 * 4];
    ushort4 o;
    o.x = f2bf(v.x); o.y = f2bf(v.y); o.z = f2bf(v.z); o.w = f2bf(v.w);
    *(ushort4*)&eout[((size_t)bn0 * KNN + p) * COUT + c4 * 4] = o;
  }
  for (int idx = tid; idx < 2 * COUT; idx += 256) {
    int r = idx / COUT, c = idx - r * COUT;
    float s = 0.0f;
#pragma unroll
    for (int k = 0; k < KNN; ++k) s += Y2s[(r * KNN + k) * Y2P + c];
    mout[(bn0 + r) * COUT + c] = s;
  }
}

// ---------------- node conv: fp32 microtile GEMM, TP rows per 256-thread block ----------------
template <int TP, int CH, int CM, int CINP, int CMID, int COUT, bool FIRSTH>
__global__ __launch_bounds__(256) void node_conv(
    const float* __restrict__ h, const float* __restrict__ inputs,
    const float* __restrict__ mbuf, const float* __restrict__ w1p,
    const float* __restrict__ b1v, const float* __restrict__ w2,
    const float* __restrict__ b2v, float* __restrict__ hout) {
  constexpr int CIN = CH + CM;
  constexpr int XP = CINP + 4;
  constexpr int Y1P = CMID + 4;
  constexpr int PG = TP / 4;
  __shared__ float Xs[TP * XP];
  __shared__ float Y1s[TP * Y1P];
  const int tid = threadIdx.x;
  const int bn0 = blockIdx.x * TP;
  if (FIRSTH) {
    for (int idx = tid; idx < TP * CIN; idx += 256) {
      int p = idx / CIN, c = idx - p * CIN;
      int bn = bn0 + p;
      int b = bn >> 10, n = bn & (NDIM - 1);
      Xs[p * XP + c] = (c < CH) ? inputs[(b * 3 + c) * NDIM + n]
                                : mbuf[(size_t)bn * CM + (c - CH)];
    }
    for (int idx = tid; idx < TP * (CINP - CIN); idx += 256) {
      int p = idx / (CINP - CIN), c = CIN + idx % (CINP - CIN);
      Xs[p * XP + c] = 0.0f;
    }
  } else {
    constexpr int C4 = CIN / 4;
    for (int idx = tid; idx < TP * C4; idx += 256) {
      int p = idx / C4, c = (idx - p * C4) * 4;
      int bn = bn0 + p;
      float4 v = (c < CH) ? *(const float4*)&h[(size_t)bn * CH + c]
                          : *(const float4*)&mbuf[(size_t)bn * CM + (c - CH)];
      *(float4*)&Xs[p * XP + c] = v;
    }
  }
  __syncthreads();
  {
    constexpr int NT1 = PG * (CMID / 4);
    for (int t = tid; t < NT1; t += 256) {
      int pg = t % PG, og = t / PG;
      float acc[4][4];
#pragma unroll
      for (int j = 0; j < 4; ++j) {
        float bj = b1v[og * 4 + j];
#pragma unroll
        for (int i = 0; i < 4; ++i) acc[i][j] = bj;
      }
      for (int cin = 0; cin < CINP; cin += 4) {
        float4 xr[4], wr[4];
#pragma unroll
        for (int i = 0; i < 4; ++i)
          xr[i] = *(const float4*)&Xs[(pg * 4 + i) * XP + cin];
#pragma unroll
        for (int j = 0; j < 4; ++j)
          wr[j] = *(const float4*)&w1p[(size_t)(og * 4 + j) * CINP + cin];
#pragma unroll
        for (int i = 0; i < 4; ++i)
#pragma unroll
          for (int j = 0; j < 4; ++j) {
            acc[i][j] += xr[i].x * wr[j].x;
            acc[i][j] += xr[i].y * wr[j].y;
            acc[i][j] += xr[i].z * wr[j].z;
            acc[i][j] += xr[i].w * wr[j].w;
          }
      }
#pragma unroll
      for (int i = 0; i < 4; ++i)
#pragma unroll
        for (int j = 0; j < 4; ++j)
          Y1s[(pg * 4 + i) * Y1P + og * 4 + j] = fmaxf(acc[i][j], 0.0f);
    }
  }
  __syncthreads();
  {
    constexpr int NT2 = PG * (COUT / 4);
    for (int t = tid; t < NT2; t += 256) {
      int pg = t % PG, og = t / PG;
      float acc[4][4];
#pragma unroll
      for (int j = 0; j < 4; ++j) {
        float bj = b2v[og * 4 + j];
#pragma unroll
        for (int i = 0; i < 4; ++i) acc[i][j] = bj;
      }
      for (int cin = 0; cin < CMID; cin += 4) {
        float4 xr[4], wr[4];
#pragma unroll
        for (int i = 0; i < 4; ++i)
          xr[i] = *(const float4*)&Y1s[(pg * 4 + i) * Y1P + cin];
#pragma unroll
        for (int j = 0; j < 4; ++j)
          wr[j] = *(const float4*)&w2[(size_t)(og * 4 + j) * CMID + cin];
#pragma unroll
        for (int i = 0; i < 4; ++i)
#pragma unroll
          for (int j = 0; j < 4; ++j) {
            acc[i][j] += xr[i].x * wr[j].x;
            acc[i][j] += xr[i].y * wr[j].y;
            acc[i][j] += xr[i].z * wr[j].z;
            acc[i][j] += xr[i].w * wr[j].w;
          }
      }
#pragma unroll
      for (int i = 0; i < 4; ++i) {
        int bn = bn0 + pg * 4 + i;
#pragma unroll
        for (int j = 0; j < 4; ++j)
          hout[(size_t)bn * COUT + og * 4 + j] = fmaxf(acc[i][j], 0.0f);
      }
    }
  }
}

// ---------------- fusion conv (384->512) via MFMA + relu + global max pool ----------------
__global__ __launch_bounds__(256) void fuse_pool_mfma(
    const float* __restrict__ h1, const float* __restrict__ h2,
    const float* __restrict__ h3, const u16* __restrict__ fwb,
    const float* __restrict__ fb, int* __restrict__ pooled) {
  constexpr int CIN = 384, COUT = 512, TP = 32;
  constexpr int XPB = CIN + 8;
  __shared__ u16 Xs[TP * XPB];
  __shared__ int pmax[COUT];
  const int tid = threadIdx.x;
  const int lane = tid & 63;
  const int wv = tid >> 6;
  const int bn0 = blockIdx.x * TP;
  const int b = bn0 >> 10;
  for (int i = tid; i < COUT; i += 256) pmax[i] = 0;
  constexpr int KC = CIN / 8;
  for (int ch = tid; ch < TP * KC; ch += 256) {
    int p = ch / KC, kc = ch - p * KC;
    int k0 = kc * 8;
    int bn = bn0 + p;
    const float* src;
    if (k0 < 64) src = &h1[(size_t)bn * 64 + k0];
    else if (k0 < 192) src = &h2[(size_t)bn * 128 + (k0 - 64)];
    else src = &h3[(size_t)bn * 192 + (k0 - 192)];
    float4 f0 = *(const float4*)src;
    float4 f1 = *(const float4*)(src + 4);
    ushort8 r;
    r[0] = f2bf(f0.x); r[1] = f2bf(f0.y); r[2] = f2bf(f0.z); r[3] = f2bf(f0.w);
    r[4] = f2bf(f1.x); r[5] = f2bf(f1.y); r[6] = f2bf(f1.z); r[7] = f2bf(f1.w);
    *(ushort8*)&Xs[p * XPB + k0] = r;
  }
  __syncthreads();
  constexpr int NT = COUT / 16;
  constexpr int JOBS = (TP / 16) * NT;
  constexpr int KS = CIN / 32;
  for (int job = wv; job < JOBS; job += 4) {
    int mt = job / NT, nt = job - mt * NT;
    int row = mt * 16 + (lane & 15);
    int ncol = nt * 16 + (lane & 15);
    int kb = (lane >> 4) * 8;
    f32x4 acc = {0.f, 0.f, 0.f, 0.f};
    const u16* ap = &Xs[row * XPB + kb];
    const u16* bp = &fwb[(size_t)ncol * CIN + kb];
#pragma unroll
    for (int ks = 0; ks < KS; ++ks) {
      short8 a = *(const short8*)(ap + ks * 32);
      short8 bb = *(const short8*)(bp + ks * 32);
      acc = __builtin_amdgcn_mfma_f32_16x16x32_bf16(a, bb, acc, 0, 0, 0);
    }
    float bias = fb[ncol];
    float v = fmaxf(fmaxf(acc[0], acc[1]), fmaxf(acc[2], acc[3]));
    v = fmaxf(v + bias, 0.0f);
    v = fmaxf(v, __shfl_xor(v, 16));
    v = fmaxf(v, __shfl_xor(v, 32));
    if (lane < 16) atomicMax(&pmax[ncol], __float_as_int(v));
  }
  __syncthreads();
  for (int i = tid; i < COUT; i += 256)
    atomicMax(&pooled[b * COUT + i], pmax[i]);
}

// ---------------- prediction head ----------------
__global__ __launch_bounds__(256) void head_kernel(
    const int* __restrict__ pooledi, const float* __restrict__ p1w,
    const float* __restrict__ p1b, const float* __restrict__ p2w,
    const float* __restrict__ p2b, const float* __restrict__ p3w,
    const float* __restrict__ p3b, float* __restrict__ out) {
  __shared__ float xs[512], y1[256], y2[128];
  const int b = blockIdx.x, tid = threadIdx.x;
  for (int i = tid; i < 512; i += 256) xs[i] = __int_as_float(pooledi[b * 512 + i]);
  __syncthreads();
  {
    float acc = p1b[tid];
    for (int c = 0; c < 512; ++c) acc += xs[c] * p1w[tid * 512 + c];
    y1[tid] = fmaxf(acc, 0.0f);
  }
  __syncthreads();
  if (tid < 128) {
    float acc = p2b[tid];
    for (int c = 0; c < 256; ++c) acc += y1[c] * p2w[tid * 256 + c];
    y2[tid] = fmaxf(acc, 0.0f);
  }
  __syncthreads();
  if (tid < 40) {
    float acc = p3b[tid];
    for (int c = 0; c < 128; ++c) acc += y2[c] * p3w[tid * 128 + c];
    out[b * 40 + tid] = acc;
  }
}

__global__ void zero_kernel(int* __restrict__ p, int nel) {
  int i = blockIdx.x * 256 + threadIdx.x;
  if (i < nel) p[i] = 0;
}

extern "C" void kernel_launch(void* const* d_in, const int* in_sizes, int n_in,
                              void* d_out, int out_size, void* d_ws,
                              size_t ws_size, hipStream_t stream) {
  const float* inputs = (const float*)d_in[0];
  const float* he_w1 = (const float*)d_in[1];
  const float* he_b1 = (const float*)d_in[2];
  const float* he_w2 = (const float*)d_in[3];
  const float* he_b2 = (const float*)d_in[4];
  const float* hn_w1 = (const float*)d_in[5];
  const float* hn_b1 = (const float*)d_in[6];
  const float* hn_w2 = (const float*)d_in[7];
  const float* hn_b2 = (const float*)d_in[8];
  const float* b1e_w1 = (const float*)d_in[9];
  const float* b1e_b1 = (const float*)d_in[10];
  const float* b1e_w2 = (const float*)d_in[11];
  const float* b1e_b2 = (const float*)d_in[12];
  const float* b1n_w1 = (const float*)d_in[13];
  const float* b1n_b1 = (const float*)d_in[14];
  const float* b1n_w2 = (const float*)d_in[15];
  const float* b1n_b2 = (const float*)d_in[16];
  const float* b2e_w1 = (const float*)d_in[17];
  const float* b2e_b1 = (const float*)d_in[18];
  const float* b2e_w2 = (const float*)d_in[19];
  const float* b2e_b2 = (const float*)d_in[20];
  const float* b2n_w1 = (const float*)d_in[21];
  const float* b2n_b1 = (const float*)d_in[22];
  const float* b2n_w2 = (const float*)d_in[23];
  const float* b2n_b2 = (const float*)d_in[24];
  const float* f_w = (const float*)d_in[25];
  const float* f_b = (const float*)d_in[26];
  const float* p1_w = (const float*)d_in[27];
  const float* p1_b = (const float*)d_in[28];
  const float* p2_w = (const float*)d_in[29];
  const float* p2_b = (const float*)d_in[30];
  const float* p3_w = (const float*)d_in[31];
  const float* p3_b = (const float*)d_in[32];
  float* out = (float*)d_out;

  char* ws = (char*)d_ws;
  size_t off = 0;
  auto alloc = [&](size_t bytes) {
    void* p = ws + off;
    off += (bytes + 255) & ~(size_t)255;
    return p;
  };
  int* nn = (int*)alloc((size_t)BDIM * NDIM * KNN * 4);
  float* m1 = (float*)alloc((size_t)BDIM * NDIM * 64 * 4);
  float* h1 = (float*)alloc((size_t)BDIM * NDIM * 64 * 4);
  u16* e1 = (u16*)alloc((size_t)BDIM * NDIM * KNN * 64 * 2);   // bf16
  float* m2 = (float*)alloc((size_t)BDIM * NDIM * 128 * 4);
  float* h2 = (float*)alloc((size_t)BDIM * NDIM * 128 * 4);
  u16* e2 = (u16*)alloc((size_t)BDIM * NDIM * KNN * 128 * 2);  // bf16
  float* m3 = (float*)alloc((size_t)BDIM * NDIM * 192 * 4);
  float* h3 = (float*)alloc((size_t)BDIM * NDIM * 192 * 4);
  float* pq2 = (float*)alloc((size_t)BDIM * NDIM * 96 * 4);
  float* pq3 = (float*)alloc((size_t)BDIM * NDIM * 192 * 4);
  int* pooled = (int*)alloc((size_t)BDIM * 512 * 4);
  u16* w1b3e = (u16*)alloc((size_t)96 * 128 * 2);
  u16* wpq3 = (u16*)alloc((size_t)192 * 128 * 2);
  u16* w2b3 = (u16*)alloc((size_t)192 * 96 * 2);
  u16* w1b2e = (u16*)alloc((size_t)48 * 64 * 2);
  u16* wpq2 = (u16*)alloc((size_t)96 * 64 * 2);
  u16* w2b2 = (u16*)alloc((size_t)128 * 64 * 2);
  float* w1p1 = (float*)alloc((size_t)32 * 68 * 4);
  u16* fwb = (u16*)alloc((size_t)512 * 384 * 2);

  wcvt<<<(512 * 384 + 255) / 256, 256, 0, stream>>>(
      b2e_w1, b2e_w2, b1e_w1, b1e_w2, hn_w1, f_w, w1b3e, wpq3, w2b3, w1b2e,
      wpq2, w2b2, w1p1, fwb);
  knn_kernel<<<BDIM * 256, 256, 0, stream>>>(inputs, nn);

  edge_mp_first<6, 3, 32, 64><<<BDIM * NDIM / 2, 256, 0, stream>>>(
      inputs, nn, he_w1, he_b1, he_w2, he_b2, e1, m1);
  node_conv<64, 3, 64, 68, 32, 64, true><<<BDIM * NDIM / 64, 256, 0, stream>>>(
      nullptr, inputs, m1, w1p1, hn_b1, hn_w2, hn_b2, h1);

  pq_gemm<64, 96><<<BDIM * NDIM / 32, 256, 0, stream>>>(h1, wpq2, pq2);
  edge_mfma<64, 48, 128, true><<<BDIM * NDIM / 2, 256, 0, stream>>>(
      e1, nn, w1b2e, b1e_b1, w2b2, b1e_b2, pq2, e2, m2);
  node_conv<32, 64, 128, 192, 48, 128, false><<<BDIM * NDIM / 32, 256, 0, stream>>>(
      h1, nullptr, m2, b1n_w1, b1n_b1, b1n_w2, b1n_b2, h2);

  pq_gemm<128, 192><<<BDIM * NDIM / 32, 256, 0, stream>>>(h2, wpq3, pq3);
  edge_mfma<128, 96, 192, false><<<BDIM * NDIM / 2, 256, 0, stream>>>(
      e2, nn, w1b3e, b2e_b1, w2b3, b2e_b2, pq3, nullptr, m3);
  node_conv<16, 128, 192, 320, 96, 192, false><<<BDIM * NDIM / 16, 256, 0, stream>>>(
      h2, nullptr, m3, b2n_w1, b2n_b1, b2n_w2, b2n_b2, h3);

  zero_kernel<<<(BDIM * 512 + 255) / 256, 256, 0, stream>>>(pooled, BDIM * 512);
  fuse_pool_mfma<<<BDIM * NDIM / 32, 256, 0, stream>>>(h1, h2, h3, fwb, f_b,
                                                       pooled);
  head_kernel<<<BDIM, 256, 0, stream>>>(pooled, p1_w, p1_b, p2_w, p2_b, p3_w,
                                        p3_b, out);

  hipMemcpyAsync(out + BDIM * 40, d_in[0], (size_t)BDIM * 3 * NDIM * 4,
                 hipMemcpyDeviceToDevice, stream);
}

// Round 9
// 291.983 us; speedup vs baseline: 6.1896x; 1.0061x over previous
//
#include <hip/hip_runtime.h>

#define BDIM 8
#define NDIM 1024
#define KNN 20

typedef unsigned short u16;
typedef float f32x4 __attribute__((ext_vector_type(4)));
typedef short short8 __attribute__((ext_vector_type(8)));
typedef unsigned short ushort8 __attribute__((ext_vector_type(8)));

__device__ inline u16 f2bf(float f) {
  unsigned u = __float_as_uint(f);
  unsigned r = (u + 0x7fffu + ((u >> 16) & 1u)) >> 16;
  return (u16)r;
}
__device__ inline float bf2f(u16 v) {
  return __uint_as_float(((unsigned)v) << 16);
}

// ---------------- KNN: one wave per point, wave-parallel top-20 (bit-exact) ----------------
__global__ __launch_bounds__(256) void knn_kernel(const float* __restrict__ x,
                                                  int* __restrict__ nn) {
#pragma clang fp contract(off)
  __shared__ float xs0[NDIM], xs1[NDIM], xs2[NDIM], sq[NDIM];
  const int tid = threadIdx.x;
  const int lane = tid & 63;
  const int w = tid >> 6;
  const int b = blockIdx.x >> 8;
  const int n = ((blockIdx.x & 255) << 2) + w;
  for (int i = tid; i < NDIM; i += 256) {
    float a0 = x[(b * 3 + 0) * NDIM + i];
    float a1 = x[(b * 3 + 1) * NDIM + i];
    float a2 = x[(b * 3 + 2) * NDIM + i];
    xs0[i] = a0; xs1[i] = a1; xs2[i] = a2;
    sq[i] = (a0 * a0 + a1 * a1) + a2 * a2;
  }
  __syncthreads();
  const float xn0 = xs0[n], xn1 = xs1[n], xn2 = xs2[n], sqn = sq[n];
  float dl[16];
#pragma unroll
  for (int t = 0; t < 16; ++t) {
    int m = t * 64 + lane;
    float dot = (xn0 * xs0[m] + xn1 * xs1[m]) + xn2 * xs2[m];
    dl[t] = (sqn - 2.0f * dot) + sq[m];
  }
  int* nnrow = &nn[(b * NDIM + n) * KNN];
  for (int r = 0; r < KNN; ++r) {
    float bd = dl[0];
    int bt = 0;
#pragma unroll
    for (int t = 1; t < 16; ++t) {
      if (dl[t] < bd) { bd = dl[t]; bt = t; }
    }
    int bi = bt * 64 + lane;
#pragma unroll
    for (int off = 1; off < 64; off <<= 1) {
      float pd = __shfl_xor(bd, off);
      int pi = __shfl_xor(bi, off);
      if (pd < bd || (pd == bd && pi < bi)) { bd = pd; bi = pi; }
    }
    if (lane == 0) nnrow[r] = bi;
    if ((bi & 63) == lane) {
      int wt = bi >> 6;
#pragma unroll
      for (int t = 0; t < 16; ++t) {
        if (t == wt) dl[t] = 3.4e38f;
      }
    }
  }
}

// ---------------- prep: bf16 weight tables + padded fp32 node1 w1 + zero pooled ----------------
__global__ __launch_bounds__(256) void wcvt(
    const float* __restrict__ w1_3, const float* __restrict__ w2_3,
    const float* __restrict__ w1_2, const float* __restrict__ w2_2,
    const float* __restrict__ hn_w1, const float* __restrict__ f_w,
    u16* __restrict__ w1b3e, u16* __restrict__ wpq3, u16* __restrict__ w2b3,
    u16* __restrict__ w1b2e, u16* __restrict__ wpq2, u16* __restrict__ w2b2,
    float* __restrict__ w1p1, u16* __restrict__ fwb, int* __restrict__ pooled) {
  const int idx = blockIdx.x * 256 + threadIdx.x;
  if (idx < 512 * 384) fwb[idx] = f2bf(f_w[idx]);
  if (idx < 96 * 128) {
    int oc = idx >> 7, c = idx & 127;
    w1b3e[idx] = f2bf(w1_3[oc * 384 + c]);
  }
  if (idx < 192 * 128) {
    int n = idx >> 7, c = idx & 127;
    wpq3[idx] = f2bf(n < 96 ? w1_3[n * 384 + 128 + c]
                            : w1_3[(n - 96) * 384 + 256 + c]);
  }
  if (idx < 192 * 96) w2b3[idx] = f2bf(w2_3[idx]);
  if (idx < 48 * 64) {
    int oc = idx >> 6, c = idx & 63;
    w1b2e[idx] = f2bf(w1_2[oc * 192 + c]);
  }
  if (idx < 96 * 64) {
    int n = idx >> 6, c = idx & 63;
    wpq2[idx] = f2bf(n < 48 ? w1_2[n * 192 + 64 + c]
                            : w1_2[(n - 48) * 192 + 128 + c]);
  }
  if (idx < 128 * 64) {
    int oc = idx >> 6, i = idx & 63;
    w2b2[idx] = (i < 48) ? f2bf(w2_2[oc * 48 + i]) : (u16)0;
  }
  if (idx < 32 * 68) {
    int oc = idx / 68, c = idx - oc * 68;
    w1p1[idx] = (c < 67) ? hn_w1[oc * 67 + c] : 0.0f;
  }
  if (idx < BDIM * 512) pooled[idx] = 0;
}

// ---------------- PQ = h @ [W1hi;W1hj]^T  (per-point, fp32 out, no bias/relu) ----------------
template <int CH, int NPQ>
__global__ __launch_bounds__(256) void pq_gemm(const float* __restrict__ h,
                                               const u16* __restrict__ wpq,
                                               float* __restrict__ pq) {
  constexpr int BM = 32;
  constexpr int AP = CH + 8;
  __shared__ u16 As[BM * AP];
  const int tid = threadIdx.x;
  const int lane = tid & 63;
  const int wv = tid >> 6;
  const int row0 = blockIdx.x * BM;
  constexpr int KC = CH / 8;
  for (int ch = tid; ch < BM * KC; ch += 256) {
    int p = ch / KC, kc = ch - p * KC;
    int k0 = kc * 8;
    const float* src = &h[(size_t)(row0 + p) * CH + k0];
    float4 f0 = *(const float4*)src;
    float4 f1 = *(const float4*)(src + 4);
    ushort8 r;
    r[0] = f2bf(f0.x); r[1] = f2bf(f0.y); r[2] = f2bf(f0.z); r[3] = f2bf(f0.w);
    r[4] = f2bf(f1.x); r[5] = f2bf(f1.y); r[6] = f2bf(f1.z); r[7] = f2bf(f1.w);
    *(ushort8*)&As[p * AP + k0] = r;
  }
  __syncthreads();
  constexpr int NT = NPQ / 16;
  constexpr int JOBS = (BM / 16) * NT;
  constexpr int KS = CH / 32;
  for (int job = wv; job < JOBS; job += 4) {
    int mt = job / NT, nt = job - mt * NT;
    int row = mt * 16 + (lane & 15);
    int ncol = nt * 16 + (lane & 15);
    int kb = (lane >> 4) * 8;
    f32x4 acc = {0.f, 0.f, 0.f, 0.f};
    const u16* ap = &As[row * AP + kb];
    const u16* bp = &wpq[(size_t)ncol * CH + kb];
#pragma unroll
    for (int ks = 0; ks < KS; ++ks) {
      short8 a = *(const short8*)(ap + ks * 32);
      short8 bb = *(const short8*)(bp + ks * 32);
      acc = __builtin_amdgcn_mfma_f32_16x16x32_bf16(a, bb, acc, 0, 0, 0);
    }
    int m0 = mt * 16 + (lane >> 4) * 4;
#pragma unroll
    for (int r = 0; r < 4; ++r)
      pq[(size_t)(row0 + m0 + r) * NPQ + ncol] = acc[r];
  }
}

// ---------------- MFMA edge MP v5: staged A + bf16-staged Q, in-register m-sum ----------------
template <int CE, int CMID, int COUT, bool WRITE_E>
__global__ __launch_bounds__(256) void edge_mfma(
    const u16* __restrict__ eprev, const int* __restrict__ nnb,
    const u16* __restrict__ w1b, const float* __restrict__ b1v,
    const u16* __restrict__ w2b, const float* __restrict__ b2v,
    const float* __restrict__ pq, u16* __restrict__ eout,
    float* __restrict__ mout) {
  constexpr int K2 = (CMID + 31) & ~31;
  constexpr int NPQ = 2 * CMID;
  constexpr int MT = 2 * KNN;   // 40 edges
  constexpr int MPAD = 48;      // 3 M-tiles
  constexpr int XPB = CE + 8;
  constexpr int Y1PB = K2 + 8;
  constexpr int QP = CMID + 8;  // bf16 Q pitch (16B-aligned rows, breaks bank alias)
  __shared__ u16 Xs[MT * XPB];
  __shared__ u16 Y1s[MPAD * Y1PB];
  __shared__ u16 Qs[MT * QP];
  __shared__ float pld[2 * CMID];
  __shared__ int nns[MT];
  const int tid = threadIdx.x;
  const int lane = tid & 63;
  const int wv = tid >> 6;
  const int bn0 = blockIdx.x * 2;
  const int b = bn0 >> 10;
  if (tid < MT) nns[tid] = nnb[(size_t)bn0 * KNN + tid];
  __syncthreads();
  // ---- bulk staging phase (high MLP, coalesced) ----
  constexpr int KC = CE / 8;
  for (int ch = tid; ch < MT * KC; ch += 256) {
    int p = ch / KC, kc = ch - p * KC;
    int k0 = kc * 8;
    *(uint4*)&Xs[p * XPB + k0] =
        *(const uint4*)&eprev[((size_t)blockIdx.x * MT + p) * CE + k0];
  }
  constexpr int QC = CMID / 8;
  for (int i = tid; i < MT * QC; i += 256) {
    int p = i / QC, c8 = (i - p * QC) * 8;
    const float* src = &pq[((size_t)(b << 10) + nns[p]) * NPQ + CMID + c8];
    float4 f0 = *(const float4*)src;
    float4 f1 = *(const float4*)(src + 4);
    ushort8 r;
    r[0] = f2bf(f0.x); r[1] = f2bf(f0.y); r[2] = f2bf(f0.z); r[3] = f2bf(f0.w);
    r[4] = f2bf(f1.x); r[5] = f2bf(f1.y); r[6] = f2bf(f1.z); r[7] = f2bf(f1.w);
    *(ushort8*)&Qs[p * QP + c8] = r;
  }
  for (int i = tid; i < 2 * CMID; i += 256)
    pld[i] = pq[(size_t)(bn0 + (i >= CMID)) * NPQ + (i >= CMID ? i - CMID : i)];
  if constexpr (K2 != CMID) {
    for (int i = tid; i < MPAD * Y1PB; i += 256) Y1s[i] = 0;
  }
  __syncthreads();
  // ---- conv1: Xs @ W1e^T + P(LDS) + Q(LDS,bf16) + b -> relu -> Y1s ----
  {
    constexpr int NT1 = CMID / 16;
    constexpr int J1 = 3 * NT1;
    constexpr int KS1 = CE / 32;
    for (int job = wv; job < J1; job += 4) {
      int mt = job / NT1, nt = job - mt * NT1;
      int row = mt * 16 + (lane & 15);
      int srow = row < MT ? row : MT - 1;
      int ncol = nt * 16 + (lane & 15);
      int kb = (lane >> 4) * 8;
      f32x4 acc = {0.f, 0.f, 0.f, 0.f};
      const u16* ap = &Xs[srow * XPB + kb];
      const u16* bp = &w1b[(size_t)ncol * CE + kb];
#pragma unroll
      for (int ks = 0; ks < KS1; ++ks) {
        short8 a = *(const short8*)(ap + ks * 32);
        short8 bb = *(const short8*)(bp + ks * 32);
        acc = __builtin_amdgcn_mfma_f32_16x16x32_bf16(a, bb, acc, 0, 0, 0);
      }
      float bias = b1v[ncol];
      int m0 = mt * 16 + (lane >> 4) * 4;
#pragma unroll
      for (int r = 0; r < 4; ++r) {
        int m = m0 + r;
        int sm = m < MT ? m : MT - 1;
        float padd = pld[(m >= KNN) * CMID + ncol];
        float qadd = bf2f(Qs[sm * QP + ncol]);
        float yv = fmaxf(acc[r] + bias + padd + qadd, 0.0f);
        Y1s[m * Y1PB + ncol] = f2bf(yv);
      }
    }
  }
  __syncthreads();
  // ---- conv2: one wave owns all 3 M-tiles per N-tile; m-sum in-register ----
  {
    constexpr int NT2 = COUT / 16;
    constexpr int KS2 = K2 / 32;
    for (int nt = wv; nt < NT2; nt += 4) {
      int ncol = nt * 16 + (lane & 15);
      int kb = (lane >> 4) * 8;
      short8 bfrag[KS2];
      const u16* bp = &w2b[(size_t)ncol * K2 + kb];
#pragma unroll
      for (int ks = 0; ks < KS2; ++ks)
        bfrag[ks] = *(const short8*)(bp + ks * 32);
      float bias = b2v[ncol];
      float s0 = 0.0f, s1 = 0.0f;
#pragma unroll
      for (int mt = 0; mt < 3; ++mt) {
        f32x4 acc = {0.f, 0.f, 0.f, 0.f};
        const u16* ap = &Y1s[(mt * 16 + (lane & 15)) * Y1PB + kb];
#pragma unroll
        for (int ks = 0; ks < KS2; ++ks) {
          short8 a = *(const short8*)(ap + ks * 32);
          acc = __builtin_amdgcn_mfma_f32_16x16x32_bf16(a, bfrag[ks], acc, 0, 0, 0);
        }
        int m0 = mt * 16 + (lane >> 4) * 4;
#pragma unroll
        for (int r = 0; r < 4; ++r) {
          int m = m0 + r;
          if (m < MT) {
            float yv = fmaxf(acc[r] + bias, 0.0f);
            u16 bv = f2bf(yv);
            float v = bf2f(bv);
            if (WRITE_E)
              eout[((size_t)blockIdx.x * MT + m) * COUT + ncol] = bv;
            if (m < KNN) s0 += v; else s1 += v;
          }
        }
      }
      s0 += __shfl_xor(s0, 16); s0 += __shfl_xor(s0, 32);
      s1 += __shfl_xor(s1, 16); s1 += __shfl_xor(s1, 32);
      if (lane < 16) {
        mout[(size_t)bn0 * COUT + nt * 16 + lane] = s0;
        mout[(size_t)(bn0 + 1) * COUT + nt * 16 + lane] = s1;
      }
    }
  }
}

// ---------------- fp32 edge MP (block 1 only, tiny CIN=12), bf16 e1 out ----------------
template <int CINC, int COUTC, int INP, int OUTP>
__device__ inline void tile_conv(const float* __restrict__ Xls,
                                 const float* __restrict__ w,
                                 const float* __restrict__ bias,
                                 float* __restrict__ Yls, int tid) {
  constexpr int PG = (2 * KNN) / 4;
  constexpr int NT = PG * (COUTC / 4);
  for (int t = tid; t < NT; t += 256) {
    int pg = t % PG, og = t / PG;
    float acc[4][4];
#pragma unroll
    for (int j = 0; j < 4; ++j) {
      float bj = bias[og * 4 + j];
#pragma unroll
      for (int i = 0; i < 4; ++i) acc[i][j] = bj;
    }
    for (int cin = 0; cin < CINC; cin += 4) {
      float4 xr[4], wr[4];
#pragma unroll
      for (int i = 0; i < 4; ++i)
        xr[i] = *(const float4*)&Xls[(pg * 4 + i) * INP + cin];
#pragma unroll
      for (int j = 0; j < 4; ++j)
        wr[j] = *(const float4*)&w[(og * 4 + j) * CINC + cin];
#pragma unroll
      for (int i = 0; i < 4; ++i)
#pragma unroll
        for (int j = 0; j < 4; ++j) {
          acc[i][j] += xr[i].x * wr[j].x;
          acc[i][j] += xr[i].y * wr[j].y;
          acc[i][j] += xr[i].z * wr[j].z;
          acc[i][j] += xr[i].w * wr[j].w;
        }
    }
#pragma unroll
    for (int i = 0; i < 4; ++i)
#pragma unroll
      for (int j = 0; j < 4; ++j)
        Yls[(pg * 4 + i) * OUTP + og * 4 + j] = fmaxf(acc[i][j], 0.0f);
  }
}

template <int CE, int CH, int CMID, int COUT>
__global__ __launch_bounds__(256) void edge_mp_first(
    const float* __restrict__ inputs, const int* __restrict__ nnb,
    const float* __restrict__ w1, const float* __restrict__ b1v,
    const float* __restrict__ w2, const float* __restrict__ b2v,
    u16* __restrict__ eout, float* __restrict__ mout) {
  constexpr int CIN = CE + 2 * CH;
  constexpr int TP = 2 * KNN;
  constexpr int XP = CIN + 4;
  constexpr int Y1P = CMID + 4;
  constexpr int Y2P = COUT + 4;
  __shared__ float Xs[TP * XP];
  __shared__ float Y1s[TP * Y1P];
  __shared__ float Y2s[TP * Y2P];
  __shared__ int nns[TP];
  const int tid = threadIdx.x;
  const int bn0 = blockIdx.x * 2;
  const int b = bn0 >> 10;
  if (tid < TP) nns[tid] = nnb[bn0 * KNN + tid];
  __syncthreads();
  for (int idx = tid; idx < TP * CIN; idx += 256) {
    int p = idx / CIN, c = idx - p * CIN;
    int bn = bn0 + (p >= KNN ? 1 : 0);
    int n = bn & (NDIM - 1);
    int j = nns[p];
    int cc = c % 3;
    int seg = c / 3;
    float hi = inputs[(b * 3 + cc) * NDIM + n];
    float hj = inputs[(b * 3 + cc) * NDIM + j];
    Xs[p * XP + c] = (seg == 1) ? (hi - hj) : ((seg == 3) ? hj : hi);
  }
  __syncthreads();
  tile_conv<CIN, CMID, XP, Y1P>(Xs, w1, b1v, Y1s, tid);
  __syncthreads();
  tile_conv<CMID, COUT, Y1P, Y2P>(Y1s, w2, b2v, Y2s, tid);
  __syncthreads();
  for (int idx = tid; idx < TP * COUT / 4; idx += 256) {
    int p = idx / (COUT / 4), c4 = idx - p * (COUT / 4);
    float4 v = *(const float4*)&Y2s[p * Y2P + c4 * 4];
    ushort4 o;
    o.x = f2bf(v.x); o.y = f2bf(v.y); o.z = f2bf(v.z); o.w = f2bf(v.w);
    *(ushort4*)&eout[((size_t)bn0 * KNN + p) * COUT + c4 * 4] = o;
  }
  for (int idx = tid; idx < 2 * COUT; idx += 256) {
    int r = idx / COUT, c = idx - r * COUT;
    float s = 0.0f;
#pragma unroll
    for (int k = 0; k < KNN; ++k) s += Y2s[(r * KNN + k) * Y2P + c];
    mout[(bn0 + r) * COUT + c] = s;
  }
}

// ---------------- node conv: fp32 microtile GEMM, TP rows per 256-thread block ----------------
template <int TP, int CH, int CM, int CINP, int CMID, int COUT, bool FIRSTH>
__global__ __launch_bounds__(256) void node_conv(
    const float* __restrict__ h, const float* __restrict__ inputs,
    const float* __restrict__ mbuf, const float* __restrict__ w1p,
    const float* __restrict__ b1v, const float* __restrict__ w2,
    const float* __restrict__ b2v, float* __restrict__ hout) {
  constexpr int CIN = CH + CM;
  constexpr int XP = CINP + 4;
  constexpr int Y1P = CMID + 4;
  constexpr int PG = TP / 4;
  __shared__ float Xs[TP * XP];
  __shared__ float Y1s[TP * Y1P];
  const int tid = threadIdx.x;
  const int bn0 = blockIdx.x * TP;
  if (FIRSTH) {
    for (int idx = tid; idx < TP * CIN; idx += 256) {
      int p = idx / CIN, c = idx - p * CIN;
      int bn = bn0 + p;
      int b = bn >> 10, n = bn & (NDIM - 1);
      Xs[p * XP + c] = (c < CH) ? inputs[(b * 3 + c) * NDIM + n]
                                : mbuf[(size_t)bn * CM + (c - CH)];
    }
    for (int idx = tid; idx < TP * (CINP - CIN); idx += 256) {
      int p = idx / (CINP - CIN), c = CIN + idx % (CINP - CIN);
      Xs[p * XP + c] = 0.0f;
    }
  } else {
    constexpr int C4 = CIN / 4;
    for (int idx = tid; idx < TP * C4; idx += 256) {
      int p = idx / C4, c = (idx - p * C4) * 4;
      int bn = bn0 + p;
      float4 v = (c < CH) ? *(const float4*)&h[(size_t)bn * CH + c]
                          : *(const float4*)&mbuf[(size_t)bn * CM + (c - CH)];
      *(float4*)&Xs[p * XP + c] = v;
    }
  }
  __syncthreads();
  {
    constexpr int NT1 = PG * (CMID / 4);
    for (int t = tid; t < NT1; t += 256) {
      int pg = t % PG, og = t / PG;
      float acc[4][4];
#pragma unroll
      for (int j = 0; j < 4; ++j) {
        float bj = b1v[og * 4 + j];
#pragma unroll
        for (int i = 0; i < 4; ++i) acc[i][j] = bj;
      }
      for (int cin = 0; cin < CINP; cin += 4) {
        float4 xr[4], wr[4];
#pragma unroll
        for (int i = 0; i < 4; ++i)
          xr[i] = *(const float4*)&Xs[(pg * 4 + i) * XP + cin];
#pragma unroll
        for (int j = 0; j < 4; ++j)
          wr[j] = *(const float4*)&w1p[(size_t)(og * 4 + j) * CINP + cin];
#pragma unroll
        for (int i = 0; i < 4; ++i)
#pragma unroll
          for (int j = 0; j < 4; ++j) {
            acc[i][j] += xr[i].x * wr[j].x;
            acc[i][j] += xr[i].y * wr[j].y;
            acc[i][j] += xr[i].z * wr[j].z;
            acc[i][j] += xr[i].w * wr[j].w;
          }
      }
#pragma unroll
      for (int i = 0; i < 4; ++i)
#pragma unroll
        for (int j = 0; j < 4; ++j)
          Y1s[(pg * 4 + i) * Y1P + og * 4 + j] = fmaxf(acc[i][j], 0.0f);
    }
  }
  __syncthreads();
  {
    constexpr int NT2 = PG * (COUT / 4);
    for (int t = tid; t < NT2; t += 256) {
      int pg = t % PG, og = t / PG;
      float acc[4][4];
#pragma unroll
      for (int j = 0; j < 4; ++j) {
        float bj = b2v[og * 4 + j];
#pragma unroll
        for (int i = 0; i < 4; ++i) acc[i][j] = bj;
      }
      for (int cin = 0; cin < CMID; cin += 4) {
        float4 xr[4], wr[4];
#pragma unroll
        for (int i = 0; i < 4; ++i)
          xr[i] = *(const float4*)&Y1s[(pg * 4 + i) * Y1P + cin];
#pragma unroll
        for (int j = 0; j < 4; ++j)
          wr[j] = *(const float4*)&w2[(size_t)(og * 4 + j) * CMID + cin];
#pragma unroll
        for (int i = 0; i < 4; ++i)
#pragma unroll
          for (int j = 0; j < 4; ++j) {
            acc[i][j] += xr[i].x * wr[j].x;
            acc[i][j] += xr[i].y * wr[j].y;
            acc[i][j] += xr[i].z * wr[j].z;
            acc[i][j] += xr[i].w * wr[j].w;
          }
      }
#pragma unroll
      for (int i = 0; i < 4; ++i) {
        int bn = bn0 + pg * 4 + i;
#pragma unroll
        for (int j = 0; j < 4; ++j)
          hout[(size_t)bn * COUT + og * 4 + j] = fmaxf(acc[i][j], 0.0f);
      }
    }
  }
}

// ---------------- fusion conv (384->512) via MFMA + relu + global max pool ----------------
__global__ __launch_bounds__(256) void fuse_pool_mfma(
    const float* __restrict__ h1, const float* __restrict__ h2,
    const float* __restrict__ h3, const u16* __restrict__ fwb,
    const float* __restrict__ fb, int* __restrict__ pooled) {
  constexpr int CIN = 384, COUT = 512, TP = 32;
  constexpr int XPB = CIN + 8;
  __shared__ u16 Xs[TP * XPB];
  __shared__ int pmax[COUT];
  const int tid = threadIdx.x;
  const int lane = tid & 63;
  const int wv = tid >> 6;
  const int bn0 = blockIdx.x * TP;
  const int b = bn0 >> 10;
  for (int i = tid; i < COUT; i += 256) pmax[i] = 0;
  constexpr int KC = CIN / 8;
  for (int ch = tid; ch < TP * KC; ch += 256) {
    int p = ch / KC, kc = ch - p * KC;
    int k0 = kc * 8;
    int bn = bn0 + p;
    const float* src;
    if (k0 < 64) src = &h1[(size_t)bn * 64 + k0];
    else if (k0 < 192) src = &h2[(size_t)bn * 128 + (k0 - 64)];
    else src = &h3[(size_t)bn * 192 + (k0 - 192)];
    float4 f0 = *(const float4*)src;
    float4 f1 = *(const float4*)(src + 4);
    ushort8 r;
    r[0] = f2bf(f0.x); r[1] = f2bf(f0.y); r[2] = f2bf(f0.z); r[3] = f2bf(f0.w);
    r[4] = f2bf(f1.x); r[5] = f2bf(f1.y); r[6] = f2bf(f1.z); r[7] = f2bf(f1.w);
    *(ushort8*)&Xs[p * XPB + k0] = r;
  }
  __syncthreads();
  constexpr int NT = COUT / 16;
  constexpr int JOBS = (TP / 16) * NT;
  constexpr int KS = CIN / 32;
  for (int job = wv; job < JOBS; job += 4) {
    int mt = job / NT, nt = job - mt * NT;
    int row = mt * 16 + (lane & 15);
    int ncol = nt * 16 + (lane & 15);
    int kb = (lane >> 4) * 8;
    f32x4 acc = {0.f, 0.f, 0.f, 0.f};
    const u16* ap = &Xs[row * XPB + kb];
    const u16* bp = &fwb[(size_t)ncol * CIN + kb];
#pragma unroll
    for (int ks = 0; ks < KS; ++ks) {
      short8 a = *(const short8*)(ap + ks * 32);
      short8 bb = *(const short8*)(bp + ks * 32);
      acc = __builtin_amdgcn_mfma_f32_16x16x32_bf16(a, bb, acc, 0, 0, 0);
    }
    float bias = fb[ncol];
    float v = fmaxf(fmaxf(acc[0], acc[1]), fmaxf(acc[2], acc[3]));
    v = fmaxf(v + bias, 0.0f);
    v = fmaxf(v, __shfl_xor(v, 16));
    v = fmaxf(v, __shfl_xor(v, 32));
    if (lane < 16) atomicMax(&pmax[ncol], __float_as_int(v));
  }
  __syncthreads();
  for (int i = tid; i < COUT; i += 256)
    atomicMax(&pooled[b * COUT + i], pmax[i]);
}

// ---------------- prediction head ----------------
__global__ __launch_bounds__(256) void head_kernel(
    const int* __restrict__ pooledi, const float* __restrict__ p1w,
    const float* __restrict__ p1b, const float* __restrict__ p2w,
    const float* __restrict__ p2b, const float* __restrict__ p3w,
    const float* __restrict__ p3b, float* __restrict__ out) {
  __shared__ float xs[512], y1[256], y2[128];
  const int b = blockIdx.x, tid = threadIdx.x;
  for (int i = tid; i < 512; i += 256) xs[i] = __int_as_float(pooledi[b * 512 + i]);
  __syncthreads();
  {
    float acc = p1b[tid];
    for (int c = 0; c < 512; ++c) acc += xs[c] * p1w[tid * 512 + c];
    y1[tid] = fmaxf(acc, 0.0f);
  }
  __syncthreads();
  if (tid < 128) {
    float acc = p2b[tid];
    for (int c = 0; c < 256; ++c) acc += y1[c] * p2w[tid * 256 + c];
    y2[tid] = fmaxf(acc, 0.0f);
  }
  __syncthreads();
  if (tid < 40) {
    float acc = p3b[tid];
    for (int c = 0; c < 128; ++c) acc += y2[c] * p3w[tid * 128 + c];
    out[b * 40 + tid] = acc;
  }
}

extern "C" void kernel_launch(void* const* d_in, const int* in_sizes, int n_in,
                              void* d_out, int out_size, void* d_ws,
                              size_t ws_size, hipStream_t stream) {
  const float* inputs = (const float*)d_in[0];
  const float* he_w1 = (const float*)d_in[1];
  const float* he_b1 = (const float*)d_in[2];
  const float* he_w2 = (const float*)d_in[3];
  const float* he_b2 = (const float*)d_in[4];
  const float* hn_w1 = (const float*)d_in[5];
  const float* hn_b1 = (const float*)d_in[6];
  const float* hn_w2 = (const float*)d_in[7];
  const float* hn_b2 = (const float*)d_in[8];
  const float* b1e_w1 = (const float*)d_in[9];
  const float* b1e_b1 = (const float*)d_in[10];
  const float* b1e_w2 = (const float*)d_in[11];
  const float* b1e_b2 = (const float*)d_in[12];
  const float* b1n_w1 = (const float*)d_in[13];
  const float* b1n_b1 = (const float*)d_in[14];
  const float* b1n_w2 = (const float*)d_in[15];
  const float* b1n_b2 = (const float*)d_in[16];
  const float* b2e_w1 = (const float*)d_in[17];
  const float* b2e_b1 = (const float*)d_in[18];
  const float* b2e_w2 = (const float*)d_in[19];
  const float* b2e_b2 = (const float*)d_in[20];
  const float* b2n_w1 = (const float*)d_in[21];
  const float* b2n_b1 = (const float*)d_in[22];
  const float* b2n_w2 = (const float*)d_in[23];
  const float* b2n_b2 = (const float*)d_in[24];
  const float* f_w = (const float*)d_in[25];
  const float* f_b = (const float*)d_in[26];
  const float* p1_w = (const float*)d_in[27];
  const float* p1_b = (const float*)d_in[28];
  const float* p2_w = (const float*)d_in[29];
  const float* p2_b = (const float*)d_in[30];
  const float* p3_w = (const float*)d_in[31];
  const float* p3_b = (const float*)d_in[32];
  float* out = (float*)d_out;

  char* ws = (char*)d_ws;
  size_t off = 0;
  auto alloc = [&](size_t bytes) {
    void* p = ws + off;
    off += (bytes + 255) & ~(size_t)255;
    return p;
  };
  int* nn = (int*)alloc((size_t)BDIM * NDIM * KNN * 4);
  float* m1 = (float*)alloc((size_t)BDIM * NDIM * 64 * 4);
  float* h1 = (float*)alloc((size_t)BDIM * NDIM * 64 * 4);
  u16* e1 = (u16*)alloc((size_t)BDIM * NDIM * KNN * 64 * 2);   // bf16
  float* m2 = (float*)alloc((size_t)BDIM * NDIM * 128 * 4);
  float* h2 = (float*)alloc((size_t)BDIM * NDIM * 128 * 4);
  u16* e2 = (u16*)alloc((size_t)BDIM * NDIM * KNN * 128 * 2);  // bf16
  float* m3 = (float*)alloc((size_t)BDIM * NDIM * 192 * 4);
  float* h3 = (float*)alloc((size_t)BDIM * NDIM * 192 * 4);
  float* pq2 = (float*)alloc((size_t)BDIM * NDIM * 96 * 4);
  float* pq3 = (float*)alloc((size_t)BDIM * NDIM * 192 * 4);
  int* pooled = (int*)alloc((size_t)BDIM * 512 * 4);
  u16* w1b3e = (u16*)alloc((size_t)96 * 128 * 2);
  u16* wpq3 = (u16*)alloc((size_t)192 * 128 * 2);
  u16* w2b3 = (u16*)alloc((size_t)192 * 96 * 2);
  u16* w1b2e = (u16*)alloc((size_t)48 * 64 * 2);
  u16* wpq2 = (u16*)alloc((size_t)96 * 64 * 2);
  u16* w2b2 = (u16*)alloc((size_t)128 * 64 * 2);
  float* w1p1 = (float*)alloc((size_t)32 * 68 * 4);
  u16* fwb = (u16*)alloc((size_t)512 * 384 * 2);

  wcvt<<<(512 * 384 + 255) / 256, 256, 0, stream>>>(
      b2e_w1, b2e_w2, b1e_w1, b1e_w2, hn_w1, f_w, w1b3e, wpq3, w2b3, w1b2e,
      wpq2, w2b2, w1p1, fwb, pooled);
  knn_kernel<<<BDIM * 256, 256, 0, stream>>>(inputs, nn);

  edge_mp_first<6, 3, 32, 64><<<BDIM * NDIM / 2, 256, 0, stream>>>(
      inputs, nn, he_w1, he_b1, he_w2, he_b2, e1, m1);
  node_conv<64, 3, 64, 68, 32, 64, true><<<BDIM * NDIM / 64, 256, 0, stream>>>(
      nullptr, inputs, m1, w1p1, hn_b1, hn_w2, hn_b2, h1);

  pq_gemm<64, 96><<<BDIM * NDIM / 32, 256, 0, stream>>>(h1, wpq2, pq2);
  edge_mfma<64, 48, 128, true><<<BDIM * NDIM / 2, 256, 0, stream>>>(
      e1, nn, w1b2e, b1e_b1, w2b2, b1e_b2, pq2, e2, m2);
  node_conv<32, 64, 128, 192, 48, 128, false><<<BDIM * NDIM / 32, 256, 0, stream>>>(
      h1, nullptr, m2, b1n_w1, b1n_b1, b1n_w2, b1n_b2, h2);

  pq_gemm<128, 192><<<BDIM * NDIM / 32, 256, 0, stream>>>(h2, wpq3, pq3);
  edge_mfma<128, 96, 192, false><<<BDIM * NDIM / 2, 256, 0, stream>>>(
      e2, nn, w1b3e, b2e_b1, w2b3, b2e_b2, pq3, nullptr, m3);
  node_conv<16, 128, 192, 320, 96, 192, false><<<BDIM * NDIM / 16, 256, 0, stream>>>(
      h2, nullptr, m3, b2n_w1, b2n_b1, b2n_w2, b2n_b2, h3);

  fuse_pool_mfma<<<BDIM * NDIM / 32, 256, 0, stream>>>(h1, h2, h3, fwb, f_b,
                                                       pooled);
  head_kernel<<<BDIM, 256, 0, stream>>>(pooled, p1_w, p1_b, p2_w, p2_b, p3_w,
                                        p3_b, out);

  hipMemcpyAsync(out + BDIM * 40, d_in[0], (size_t)BDIM * 3 * NDIM * 4,
                 hipMemcpyDeviceToDevice, stream);
}

// Round 10
// 276.011 us; speedup vs baseline: 6.5478x; 1.0579x over previous
//
#include <hip/hip_runtime.h>

#define BDIM 8
#define NDIM 1024
#define KNN 20

typedef unsigned short u16;
typedef float f32x4 __attribute__((ext_vector_type(4)));
typedef short short8 __attribute__((ext_vector_type(8)));
typedef unsigned short ushort8 __attribute__((ext_vector_type(8)));

__device__ inline u16 f2bf(float f) {
  unsigned u = __float_as_uint(f);
  unsigned r = (u + 0x7fffu + ((u >> 16) & 1u)) >> 16;
  return (u16)r;
}
__device__ inline float bf2f(u16 v) {
  return __uint_as_float(((unsigned)v) << 16);
}

// ---------------- KNN: one wave per point, wave-parallel top-20 (bit-exact) ----------------
__global__ __launch_bounds__(256) void knn_kernel(const float* __restrict__ x,
                                                  int* __restrict__ nn) {
#pragma clang fp contract(off)
  __shared__ float xs0[NDIM], xs1[NDIM], xs2[NDIM], sq[NDIM];
  const int tid = threadIdx.x;
  const int lane = tid & 63;
  const int w = tid >> 6;
  const int b = blockIdx.x >> 8;
  const int n = ((blockIdx.x & 255) << 2) + w;
  for (int i = tid; i < NDIM; i += 256) {
    float a0 = x[(b * 3 + 0) * NDIM + i];
    float a1 = x[(b * 3 + 1) * NDIM + i];
    float a2 = x[(b * 3 + 2) * NDIM + i];
    xs0[i] = a0; xs1[i] = a1; xs2[i] = a2;
    sq[i] = (a0 * a0 + a1 * a1) + a2 * a2;
  }
  __syncthreads();
  const float xn0 = xs0[n], xn1 = xs1[n], xn2 = xs2[n], sqn = sq[n];
  float dl[16];
#pragma unroll
  for (int t = 0; t < 16; ++t) {
    int m = t * 64 + lane;
    float dot = (xn0 * xs0[m] + xn1 * xs1[m]) + xn2 * xs2[m];
    dl[t] = (sqn - 2.0f * dot) + sq[m];
  }
  int* nnrow = &nn[(b * NDIM + n) * KNN];
  for (int r = 0; r < KNN; ++r) {
    float bd = dl[0];
    int bt = 0;
#pragma unroll
    for (int t = 1; t < 16; ++t) {
      if (dl[t] < bd) { bd = dl[t]; bt = t; }
    }
    int bi = bt * 64 + lane;
#pragma unroll
    for (int off = 1; off < 64; off <<= 1) {
      float pd = __shfl_xor(bd, off);
      int pi = __shfl_xor(bi, off);
      if (pd < bd || (pd == bd && pi < bi)) { bd = pd; bi = pi; }
    }
    if (lane == 0) nnrow[r] = bi;
    if ((bi & 63) == lane) {
      int wt = bi >> 6;
#pragma unroll
      for (int t = 0; t < 16; ++t) {
        if (t == wt) dl[t] = 3.4e38f;
      }
    }
  }
}

// ---------------- prep: bf16 weight tables + padded fp32 node1 w1 + zero pooled ----------------
__global__ __launch_bounds__(256) void wcvt(
    const float* __restrict__ w1_3, const float* __restrict__ w2_3,
    const float* __restrict__ w1_2, const float* __restrict__ w2_2,
    const float* __restrict__ hn_w1, const float* __restrict__ f_w,
    const float* __restrict__ he_w1, const float* __restrict__ he_w2,
    u16* __restrict__ w1b3e, u16* __restrict__ wpq3, u16* __restrict__ w2b3,
    u16* __restrict__ w1b2e, u16* __restrict__ wpq2, u16* __restrict__ w2b2,
    float* __restrict__ w1p1, u16* __restrict__ fwb,
    u16* __restrict__ w1b1, u16* __restrict__ w2b1, int* __restrict__ pooled) {
  const int idx = blockIdx.x * 256 + threadIdx.x;
  if (idx < 512 * 384) fwb[idx] = f2bf(f_w[idx]);
  if (idx < 96 * 128) {
    int oc = idx >> 7, c = idx & 127;
    w1b3e[idx] = f2bf(w1_3[oc * 384 + c]);
  }
  if (idx < 192 * 128) {
    int n = idx >> 7, c = idx & 127;
    wpq3[idx] = f2bf(n < 96 ? w1_3[n * 384 + 128 + c]
                            : w1_3[(n - 96) * 384 + 256 + c]);
  }
  if (idx < 192 * 96) w2b3[idx] = f2bf(w2_3[idx]);
  if (idx < 48 * 64) {
    int oc = idx >> 6, c = idx & 63;
    w1b2e[idx] = f2bf(w1_2[oc * 192 + c]);
  }
  if (idx < 96 * 64) {
    int n = idx >> 6, c = idx & 63;
    wpq2[idx] = f2bf(n < 48 ? w1_2[n * 192 + 64 + c]
                            : w1_2[(n - 48) * 192 + 128 + c]);
  }
  if (idx < 128 * 64) {
    int oc = idx >> 6, i = idx & 63;
    w2b2[idx] = (i < 48) ? f2bf(w2_2[oc * 48 + i]) : (u16)0;
  }
  if (idx < 32 * 68) {
    int oc = idx / 68, c = idx - oc * 68;
    w1p1[idx] = (c < 67) ? hn_w1[oc * 67 + c] : 0.0f;
  }
  // block1 edge weights: w1 [32][12 -> 32 pad0], w2 [64][32]
  if (idx < 32 * 32) {
    int oc = idx >> 5, c = idx & 31;
    w1b1[idx] = (c < 12) ? f2bf(he_w1[oc * 12 + c]) : (u16)0;
  }
  if (idx < 64 * 32) w2b1[idx] = f2bf(he_w2[idx]);
  if (idx < BDIM * 512) pooled[idx] = 0;
}

// ---------------- PQ = h @ [W1hi;W1hj]^T  (per-point, bf16 out, no relu) ----------------
template <int CH, int NPQ>
__global__ __launch_bounds__(256) void pq_gemm(const float* __restrict__ h,
                                               const u16* __restrict__ wpq,
                                               u16* __restrict__ pq) {
  constexpr int BM = 32;
  constexpr int AP = CH + 8;
  __shared__ u16 As[BM * AP];
  const int tid = threadIdx.x;
  const int lane = tid & 63;
  const int wv = tid >> 6;
  const int row0 = blockIdx.x * BM;
  constexpr int KC = CH / 8;
  for (int ch = tid; ch < BM * KC; ch += 256) {
    int p = ch / KC, kc = ch - p * KC;
    int k0 = kc * 8;
    const float* src = &h[(size_t)(row0 + p) * CH + k0];
    float4 f0 = *(const float4*)src;
    float4 f1 = *(const float4*)(src + 4);
    ushort8 r;
    r[0] = f2bf(f0.x); r[1] = f2bf(f0.y); r[2] = f2bf(f0.z); r[3] = f2bf(f0.w);
    r[4] = f2bf(f1.x); r[5] = f2bf(f1.y); r[6] = f2bf(f1.z); r[7] = f2bf(f1.w);
    *(ushort8*)&As[p * AP + k0] = r;
  }
  __syncthreads();
  constexpr int NT = NPQ / 16;
  constexpr int JOBS = (BM / 16) * NT;
  constexpr int KS = CH / 32;
  for (int job = wv; job < JOBS; job += 4) {
    int mt = job / NT, nt = job - mt * NT;
    int row = mt * 16 + (lane & 15);
    int ncol = nt * 16 + (lane & 15);
    int kb = (lane >> 4) * 8;
    f32x4 acc = {0.f, 0.f, 0.f, 0.f};
    const u16* ap = &As[row * AP + kb];
    const u16* bp = &wpq[(size_t)ncol * CH + kb];
#pragma unroll
    for (int ks = 0; ks < KS; ++ks) {
      short8 a = *(const short8*)(ap + ks * 32);
      short8 bb = *(const short8*)(bp + ks * 32);
      acc = __builtin_amdgcn_mfma_f32_16x16x32_bf16(a, bb, acc, 0, 0, 0);
    }
    int m0 = mt * 16 + (lane >> 4) * 4;
#pragma unroll
    for (int r = 0; r < 4; ++r)
      pq[(size_t)(row0 + m0 + r) * NPQ + ncol] = f2bf(acc[r]);
  }
}

// ---- MFMA edge MP v6: unified template (FIRST builds X from inputs; else e_prev+PQ) ----
template <int CE, int CMID, int COUT, bool WRITE_E, bool FIRST>
__global__ __launch_bounds__(256) void edge_mfma(
    const u16* __restrict__ eprev, const float* __restrict__ finput,
    const int* __restrict__ nnb, const u16* __restrict__ w1b,
    const float* __restrict__ b1v, const u16* __restrict__ w2b,
    const float* __restrict__ b2v, const u16* __restrict__ pq,
    u16* __restrict__ eout, float* __restrict__ mout) {
  constexpr int K2 = (CMID + 31) & ~31;
  constexpr int NPQ = 2 * CMID;
  constexpr int MT = 2 * KNN;   // 40 edges
  constexpr int MPAD = 48;      // 3 M-tiles
  constexpr int XPB = CE + 8;
  constexpr int Y1PB = K2 + 8;
  constexpr int QP = CMID + 8;
  __shared__ u16 Xs[MT * XPB];
  __shared__ u16 Y1s[MPAD * Y1PB];
  __shared__ u16 Qs[FIRST ? 8 : MT * QP];
  __shared__ float pld[FIRST ? 8 : 2 * CMID];
  __shared__ int nns[MT];
  const int tid = threadIdx.x;
  const int lane = tid & 63;
  const int wv = tid >> 6;
  const int bn0 = blockIdx.x * 2;
  const int b = bn0 >> 10;
  if (tid < MT) nns[tid] = nnb[(size_t)bn0 * KNN + tid];
  __syncthreads();
  // ---- bulk staging (high MLP, coalesced / pure copies) ----
  if constexpr (FIRST) {
    // X = [x_i(3) | x_i-x_j(3) | x_i(3) | x_j(3) | 0-pad] bf16
    for (int idx = tid; idx < MT * (CE / 8); idx += 256) {
      int p = idx / (CE / 8), kc = idx - p * (CE / 8);
      int k0 = kc * 8;
      int bn = bn0 + (p >= KNN);
      int n = bn & (NDIM - 1);
      int j = nns[p];
      ushort8 r;
#pragma unroll
      for (int t = 0; t < 8; ++t) {
        int c = k0 + t;
        float v = 0.0f;
        if (c < 3) v = finput[(b * 3 + c) * NDIM + n];
        else if (c < 6)
          v = finput[(b * 3 + c - 3) * NDIM + n] -
              finput[(b * 3 + c - 3) * NDIM + j];
        else if (c < 9) v = finput[(b * 3 + c - 6) * NDIM + n];
        else if (c < 12) v = finput[(b * 3 + c - 9) * NDIM + j];
        r[t] = f2bf(v);
      }
      *(ushort8*)&Xs[p * XPB + k0] = r;
    }
  } else {
    constexpr int KC = CE / 8;
    for (int ch = tid; ch < MT * KC; ch += 256) {
      int p = ch / KC, kc = ch - p * KC;
      int k0 = kc * 8;
      *(uint4*)&Xs[p * XPB + k0] =
          *(const uint4*)&eprev[((size_t)blockIdx.x * MT + p) * CE + k0];
    }
    constexpr int QC = CMID / 8;  // uint4 chunks per Q row (bf16)
    for (int i = tid; i < MT * QC; i += 256) {
      int p = i / QC, c8 = (i - p * QC) * 8;
      *(uint4*)&Qs[p * QP + c8] =
          *(const uint4*)&pq[((size_t)(b << 10) + nns[p]) * NPQ + CMID + c8];
    }
    // pld = P + bias (both rows)
    for (int i = tid; i < 2 * CMID; i += 256) {
      int c = (i >= CMID) ? i - CMID : i;
      pld[i] = bf2f(pq[(size_t)(bn0 + (i >= CMID)) * NPQ + c]) + b1v[c];
    }
  }
  if constexpr (K2 != CMID) {
    for (int i = tid; i < MPAD * Y1PB; i += 256) Y1s[i] = 0;
  }
  __syncthreads();
  // ---- conv1: Xs @ W1^T (+P+Q folded) -> relu -> Y1s ----
  {
    constexpr int NT1 = CMID / 16;
    constexpr int J1 = 3 * NT1;
    constexpr int KS1 = CE / 32;
    for (int job = wv; job < J1; job += 4) {
      int mt = job / NT1, nt = job - mt * NT1;
      int row = mt * 16 + (lane & 15);
      int srow = row < MT ? row : MT - 1;
      int ncol = nt * 16 + (lane & 15);
      int kb = (lane >> 4) * 8;
      f32x4 acc = {0.f, 0.f, 0.f, 0.f};
      const u16* ap = &Xs[srow * XPB + kb];
      const u16* bp = &w1b[(size_t)ncol * CE + kb];
#pragma unroll
      for (int ks = 0; ks < KS1; ++ks) {
        short8 a = *(const short8*)(ap + ks * 32);
        short8 bb = *(const short8*)(bp + ks * 32);
        acc = __builtin_amdgcn_mfma_f32_16x16x32_bf16(a, bb, acc, 0, 0, 0);
      }
      int m0 = mt * 16 + (lane >> 4) * 4;
      if constexpr (FIRST) {
        float bias = b1v[ncol];
#pragma unroll
        for (int r = 0; r < 4; ++r) {
          float yv = fmaxf(acc[r] + bias, 0.0f);
          Y1s[(m0 + r) * Y1PB + ncol] = f2bf(yv);
        }
      } else {
#pragma unroll
        for (int r = 0; r < 4; ++r) {
          int m = m0 + r;
          int sm = m < MT ? m : MT - 1;
          float padd = pld[(m >= KNN) * CMID + ncol];
          float qadd = bf2f(Qs[sm * QP + ncol]);
          float yv = fmaxf(acc[r] + padd + qadd, 0.0f);
          Y1s[m * Y1PB + ncol] = f2bf(yv);
        }
      }
    }
  }
  __syncthreads();
  // ---- conv2: one wave owns all 3 M-tiles per N-tile; m-sum in-register ----
  {
    constexpr int NT2 = COUT / 16;
    constexpr int KS2 = K2 / 32;
    for (int nt = wv; nt < NT2; nt += 4) {
      int ncol = nt * 16 + (lane & 15);
      int kb = (lane >> 4) * 8;
      short8 bfrag[KS2];
      const u16* bp = &w2b[(size_t)ncol * K2 + kb];
#pragma unroll
      for (int ks = 0; ks < KS2; ++ks)
        bfrag[ks] = *(const short8*)(bp + ks * 32);
      float bias = b2v[ncol];
      float s0 = 0.0f, s1 = 0.0f;
#pragma unroll
      for (int mt = 0; mt < 3; ++mt) {
        f32x4 acc = {0.f, 0.f, 0.f, 0.f};
        const u16* ap = &Y1s[(mt * 16 + (lane & 15)) * Y1PB + kb];
#pragma unroll
        for (int ks = 0; ks < KS2; ++ks) {
          short8 a = *(const short8*)(ap + ks * 32);
          acc = __builtin_amdgcn_mfma_f32_16x16x32_bf16(a, bfrag[ks], acc, 0, 0, 0);
        }
        int m0 = mt * 16 + (lane >> 4) * 4;
#pragma unroll
        for (int r = 0; r < 4; ++r) {
          int m = m0 + r;
          if (m < MT) {
            float yv = fmaxf(acc[r] + bias, 0.0f);
            u16 bv = f2bf(yv);
            float v = bf2f(bv);
            if (WRITE_E)
              eout[((size_t)blockIdx.x * MT + m) * COUT + ncol] = bv;
            if (m < KNN) s0 += v; else s1 += v;
          }
        }
      }
      s0 += __shfl_xor(s0, 16); s0 += __shfl_xor(s0, 32);
      s1 += __shfl_xor(s1, 16); s1 += __shfl_xor(s1, 32);
      if (lane < 16) {
        mout[(size_t)bn0 * COUT + nt * 16 + lane] = s0;
        mout[(size_t)(bn0 + 1) * COUT + nt * 16 + lane] = s1;
      }
    }
  }
}

// ---------------- node conv: fp32 microtile GEMM, TP rows per 256-thread block ----------------
template <int TP, int CH, int CM, int CINP, int CMID, int COUT, bool FIRSTH>
__global__ __launch_bounds__(256) void node_conv(
    const float* __restrict__ h, const float* __restrict__ inputs,
    const float* __restrict__ mbuf, const float* __restrict__ w1p,
    const float* __restrict__ b1v, const float* __restrict__ w2,
    const float* __restrict__ b2v, float* __restrict__ hout) {
  constexpr int CIN = CH + CM;
  constexpr int XP = CINP + 4;
  constexpr int Y1P = CMID + 4;
  constexpr int PG = TP / 4;
  __shared__ float Xs[TP * XP];
  __shared__ float Y1s[TP * Y1P];
  const int tid = threadIdx.x;
  const int bn0 = blockIdx.x * TP;
  if (FIRSTH) {
    for (int idx = tid; idx < TP * CIN; idx += 256) {
      int p = idx / CIN, c = idx - p * CIN;
      int bn = bn0 + p;
      int b = bn >> 10, n = bn & (NDIM - 1);
      Xs[p * XP + c] = (c < CH) ? inputs[(b * 3 + c) * NDIM + n]
                                : mbuf[(size_t)bn * CM + (c - CH)];
    }
    for (int idx = tid; idx < TP * (CINP - CIN); idx += 256) {
      int p = idx / (CINP - CIN), c = CIN + idx % (CINP - CIN);
      Xs[p * XP + c] = 0.0f;
    }
  } else {
    constexpr int C4 = CIN / 4;
    for (int idx = tid; idx < TP * C4; idx += 256) {
      int p = idx / C4, c = (idx - p * C4) * 4;
      int bn = bn0 + p;
      float4 v = (c < CH) ? *(const float4*)&h[(size_t)bn * CH + c]
                          : *(const float4*)&mbuf[(size_t)bn * CM + (c - CH)];
      *(float4*)&Xs[p * XP + c] = v;
    }
  }
  __syncthreads();
  {
    constexpr int NT1 = PG * (CMID / 4);
    for (int t = tid; t < NT1; t += 256) {
      int pg = t % PG, og = t / PG;
      float acc[4][4];
#pragma unroll
      for (int j = 0; j < 4; ++j) {
        float bj = b1v[og * 4 + j];
#pragma unroll
        for (int i = 0; i < 4; ++i) acc[i][j] = bj;
      }
      for (int cin = 0; cin < CINP; cin += 4) {
        float4 xr[4], wr[4];
#pragma unroll
        for (int i = 0; i < 4; ++i)
          xr[i] = *(const float4*)&Xs[(pg * 4 + i) * XP + cin];
#pragma unroll
        for (int j = 0; j < 4; ++j)
          wr[j] = *(const float4*)&w1p[(size_t)(og * 4 + j) * CINP + cin];
#pragma unroll
        for (int i = 0; i < 4; ++i)
#pragma unroll
          for (int j = 0; j < 4; ++j) {
            acc[i][j] += xr[i].x * wr[j].x;
            acc[i][j] += xr[i].y * wr[j].y;
            acc[i][j] += xr[i].z * wr[j].z;
            acc[i][j] += xr[i].w * wr[j].w;
          }
      }
#pragma unroll
      for (int i = 0; i < 4; ++i)
#pragma unroll
        for (int j = 0; j < 4; ++j)
          Y1s[(pg * 4 + i) * Y1P + og * 4 + j] = fmaxf(acc[i][j], 0.0f);
    }
  }
  __syncthreads();
  {
    constexpr int NT2 = PG * (COUT / 4);
    for (int t = tid; t < NT2; t += 256) {
      int pg = t % PG, og = t / PG;
      float acc[4][4];
#pragma unroll
      for (int j = 0; j < 4; ++j) {
        float bj = b2v[og * 4 + j];
#pragma unroll
        for (int i = 0; i < 4; ++i) acc[i][j] = bj;
      }
      for (int cin = 0; cin < CMID; cin += 4) {
        float4 xr[4], wr[4];
#pragma unroll
        for (int i = 0; i < 4; ++i)
          xr[i] = *(const float4*)&Y1s[(pg * 4 + i) * Y1P + cin];
#pragma unroll
        for (int j = 0; j < 4; ++j)
          wr[j] = *(const float4*)&w2[(size_t)(og * 4 + j) * CMID + cin];
#pragma unroll
        for (int i = 0; i < 4; ++i)
#pragma unroll
          for (int j = 0; j < 4; ++j) {
            acc[i][j] += xr[i].x * wr[j].x;
            acc[i][j] += xr[i].y * wr[j].y;
            acc[i][j] += xr[i].z * wr[j].z;
            acc[i][j] += xr[i].w * wr[j].w;
          }
      }
#pragma unroll
      for (int i = 0; i < 4; ++i) {
        int bn = bn0 + pg * 4 + i;
#pragma unroll
        for (int j = 0; j < 4; ++j)
          hout[(size_t)bn * COUT + og * 4 + j] = fmaxf(acc[i][j], 0.0f);
      }
    }
  }
}

// ---------------- fusion conv (384->512) via MFMA + relu + global max pool ----------------
__global__ __launch_bounds__(256) void fuse_pool_mfma(
    const float* __restrict__ h1, const float* __restrict__ h2,
    const float* __restrict__ h3, const u16* __restrict__ fwb,
    const float* __restrict__ fb, int* __restrict__ pooled) {
  constexpr int CIN = 384, COUT = 512, TP = 32;
  constexpr int XPB = CIN + 8;
  __shared__ u16 Xs[TP * XPB];
  __shared__ int pmax[COUT];
  const int tid = threadIdx.x;
  const int lane = tid & 63;
  const int wv = tid >> 6;
  const int bn0 = blockIdx.x * TP;
  const int b = bn0 >> 10;
  for (int i = tid; i < COUT; i += 256) pmax[i] = 0;
  constexpr int KC = CIN / 8;
  for (int ch = tid; ch < TP * KC; ch += 256) {
    int p = ch / KC, kc = ch - p * KC;
    int k0 = kc * 8;
    int bn = bn0 + p;
    const float* src;
    if (k0 < 64) src = &h1[(size_t)bn * 64 + k0];
    else if (k0 < 192) src = &h2[(size_t)bn * 128 + (k0 - 64)];
    else src = &h3[(size_t)bn * 192 + (k0 - 192)];
    float4 f0 = *(const float4*)src;
    float4 f1 = *(const float4*)(src + 4);
    ushort8 r;
    r[0] = f2bf(f0.x); r[1] = f2bf(f0.y); r[2] = f2bf(f0.z); r[3] = f2bf(f0.w);
    r[4] = f2bf(f1.x); r[5] = f2bf(f1.y); r[6] = f2bf(f1.z); r[7] = f2bf(f1.w);
    *(ushort8*)&Xs[p * XPB + k0] = r;
  }
  __syncthreads();
  constexpr int NT = COUT / 16;
  constexpr int JOBS = (TP / 16) * NT;
  constexpr int KS = CIN / 32;
  for (int job = wv; job < JOBS; job += 4) {
    int mt = job / NT, nt = job - mt * NT;
    int row = mt * 16 + (lane & 15);
    int ncol = nt * 16 + (lane & 15);
    int kb = (lane >> 4) * 8;
    f32x4 acc = {0.f, 0.f, 0.f, 0.f};
    const u16* ap = &Xs[row * XPB + kb];
    const u16* bp = &fwb[(size_t)ncol * CIN + kb];
#pragma unroll
    for (int ks = 0; ks < KS; ++ks) {
      short8 a = *(const short8*)(ap + ks * 32);
      short8 bb = *(const short8*)(bp + ks * 32);
      acc = __builtin_amdgcn_mfma_f32_16x16x32_bf16(a, bb, acc, 0, 0, 0);
    }
    float bias = fb[ncol];
    float v = fmaxf(fmaxf(acc[0], acc[1]), fmaxf(acc[2], acc[3]));
    v = fmaxf(v + bias, 0.0f);
    v = fmaxf(v, __shfl_xor(v, 16));
    v = fmaxf(v, __shfl_xor(v, 32));
    if (lane < 16) atomicMax(&pmax[ncol], __float_as_int(v));
  }
  __syncthreads();
  for (int i = tid; i < COUT; i += 256)
    atomicMax(&pooled[b * COUT + i], pmax[i]);
}

// ---------------- prediction head ----------------
__global__ __launch_bounds__(256) void head_kernel(
    const int* __restrict__ pooledi, const float* __restrict__ p1w,
    const float* __restrict__ p1b, const float* __restrict__ p2w,
    const float* __restrict__ p2b, const float* __restrict__ p3w,
    const float* __restrict__ p3b, float* __restrict__ out) {
  __shared__ float xs[512], y1[256], y2[128];
  const int b = blockIdx.x, tid = threadIdx.x;
  for (int i = tid; i < 512; i += 256) xs[i] = __int_as_float(pooledi[b * 512 + i]);
  __syncthreads();
  {
    float acc = p1b[tid];
    for (int c = 0; c < 512; ++c) acc += xs[c] * p1w[tid * 512 + c];
    y1[tid] = fmaxf(acc, 0.0f);
  }
  __syncthreads();
  if (tid < 128) {
    float acc = p2b[tid];
    for (int c = 0; c < 256; ++c) acc += y1[c] * p2w[tid * 256 + c];
    y2[tid] = fmaxf(acc, 0.0f);
  }
  __syncthreads();
  if (tid < 40) {
    float acc = p3b[tid];
    for (int c = 0; c < 128; ++c) acc += y2[c] * p3w[tid * 128 + c];
    out[b * 40 + tid] = acc;
  }
}

extern "C" void kernel_launch(void* const* d_in, const int* in_sizes, int n_in,
                              void* d_out, int out_size, void* d_ws,
                              size_t ws_size, hipStream_t stream) {
  const float* inputs = (const float*)d_in[0];
  const float* he_w1 = (const float*)d_in[1];
  const float* he_b1 = (const float*)d_in[2];
  const float* he_w2 = (const float*)d_in[3];
  const float* he_b2 = (const float*)d_in[4];
  const float* hn_w1 = (const float*)d_in[5];
  const float* hn_b1 = (const float*)d_in[6];
  const float* hn_w2 = (const float*)d_in[7];
  const float* hn_b2 = (const float*)d_in[8];
  const float* b1e_w1 = (const float*)d_in[9];
  const float* b1e_b1 = (const float*)d_in[10];
  const float* b1e_w2 = (const float*)d_in[11];
  const float* b1e_b2 = (const float*)d_in[12];
  const float* b1n_w1 = (const float*)d_in[13];
  const float* b1n_b1 = (const float*)d_in[14];
  const float* b1n_w2 = (const float*)d_in[15];
  const float* b1n_b2 = (const float*)d_in[16];
  const float* b2e_w1 = (const float*)d_in[17];
  const float* b2e_b1 = (const float*)d_in[18];
  const float* b2e_w2 = (const float*)d_in[19];
  const float* b2e_b2 = (const float*)d_in[20];
  const float* b2n_w1 = (const float*)d_in[21];
  const float* b2n_b1 = (const float*)d_in[22];
  const float* b2n_w2 = (const float*)d_in[23];
  const float* b2n_b2 = (const float*)d_in[24];
  const float* f_w = (const float*)d_in[25];
  const float* f_b = (const float*)d_in[26];
  const float* p1_w = (const float*)d_in[27];
  const float* p1_b = (const float*)d_in[28];
  const float* p2_w = (const float*)d_in[29];
  const float* p2_b = (const float*)d_in[30];
  const float* p3_w = (const float*)d_in[31];
  const float* p3_b = (const float*)d_in[32];
  float* out = (float*)d_out;

  char* ws = (char*)d_ws;
  size_t off = 0;
  auto alloc = [&](size_t bytes) {
    void* p = ws + off;
    off += (bytes + 255) & ~(size_t)255;
    return p;
  };
  int* nn = (int*)alloc((size_t)BDIM * NDIM * KNN * 4);
  float* m1 = (float*)alloc((size_t)BDIM * NDIM * 64 * 4);
  float* h1 = (float*)alloc((size_t)BDIM * NDIM * 64 * 4);
  u16* e1 = (u16*)alloc((size_t)BDIM * NDIM * KNN * 64 * 2);   // bf16
  float* m2 = (float*)alloc((size_t)BDIM * NDIM * 128 * 4);
  float* h2 = (float*)alloc((size_t)BDIM * NDIM * 128 * 4);
  u16* e2 = (u16*)alloc((size_t)BDIM * NDIM * KNN * 128 * 2);  // bf16
  float* m3 = (float*)alloc((size_t)BDIM * NDIM * 192 * 4);
  float* h3 = (float*)alloc((size_t)BDIM * NDIM * 192 * 4);
  u16* pq2 = (u16*)alloc((size_t)BDIM * NDIM * 96 * 2);        // bf16
  u16* pq3 = (u16*)alloc((size_t)BDIM * NDIM * 192 * 2);       // bf16
  int* pooled = (int*)alloc((size_t)BDIM * 512 * 4);
  u16* w1b3e = (u16*)alloc((size_t)96 * 128 * 2);
  u16* wpq3 = (u16*)alloc((size_t)192 * 128 * 2);
  u16* w2b3 = (u16*)alloc((size_t)192 * 96 * 2);
  u16* w1b2e = (u16*)alloc((size_t)48 * 64 * 2);
  u16* wpq2 = (u16*)alloc((size_t)96 * 64 * 2);
  u16* w2b2 = (u16*)alloc((size_t)128 * 64 * 2);
  float* w1p1 = (float*)alloc((size_t)32 * 68 * 4);
  u16* fwb = (u16*)alloc((size_t)512 * 384 * 2);
  u16* w1b1 = (u16*)alloc((size_t)32 * 32 * 2);
  u16* w2b1 = (u16*)alloc((size_t)64 * 32 * 2);

  wcvt<<<(512 * 384 + 255) / 256, 256, 0, stream>>>(
      b2e_w1, b2e_w2, b1e_w1, b1e_w2, hn_w1, f_w, he_w1, he_w2, w1b3e, wpq3,
      w2b3, w1b2e, wpq2, w2b2, w1p1, fwb, w1b1, w2b1, pooled);
  knn_kernel<<<BDIM * 256, 256, 0, stream>>>(inputs, nn);

  edge_mfma<32, 32, 64, true, true><<<BDIM * NDIM / 2, 256, 0, stream>>>(
      nullptr, inputs, nn, w1b1, he_b1, w2b1, he_b2, nullptr, e1, m1);
  node_conv<64, 3, 64, 68, 32, 64, true><<<BDIM * NDIM / 64, 256, 0, stream>>>(
      nullptr, inputs, m1, w1p1, hn_b1, hn_w2, hn_b2, h1);

  pq_gemm<64, 96><<<BDIM * NDIM / 32, 256, 0, stream>>>(h1, wpq2, pq2);
  edge_mfma<64, 48, 128, true, false><<<BDIM * NDIM / 2, 256, 0, stream>>>(
      e1, nullptr, nn, w1b2e, b1e_b1, w2b2, b1e_b2, pq2, e2, m2);
  node_conv<32, 64, 128, 192, 48, 128, false><<<BDIM * NDIM / 32, 256, 0, stream>>>(
      h1, nullptr, m2, b1n_w1, b1n_b1, b1n_w2, b1n_b2, h2);

  pq_gemm<128, 192><<<BDIM * NDIM / 32, 256, 0, stream>>>(h2, wpq3, pq3);
  edge_mfma<128, 96, 192, false, false><<<BDIM * NDIM / 2, 256, 0, stream>>>(
      e2, nullptr, nn, w1b3e, b2e_b1, w2b3, b2e_b2, pq3, nullptr, m3);
  node_conv<16, 128, 192, 320, 96, 192, false><<<BDIM * NDIM / 16, 256, 0, stream>>>(
      h2, nullptr, m3, b2n_w1, b2n_b1, b2n_w2, b2n_b2, h3);

  fuse_pool_mfma<<<BDIM * NDIM / 32, 256, 0, stream>>>(h1, h2, h3, fwb, f_b,
                                                       pooled);
  head_kernel<<<BDIM, 256, 0, stream>>>(pooled, p1_w, p1_b, p2_w, p2_b, p3_w,
                                        p3_b, out);

  hipMemcpyAsync(out + BDIM * 40, d_in[0], (size_t)BDIM * 3 * NDIM * 4,
                 hipMemcpyDeviceToDevice, stream);
}

// Round 11
// 264.795 us; speedup vs baseline: 6.8251x; 1.0424x over previous
//
#include <hip/hip_runtime.h>

#define BDIM 8
#define NDIM 1024
#define KNN 20

typedef unsigned short u16;
typedef float f32x4 __attribute__((ext_vector_type(4)));
typedef short short8 __attribute__((ext_vector_type(8)));
typedef unsigned short ushort8 __attribute__((ext_vector_type(8)));

__device__ inline u16 f2bf(float f) {
  unsigned u = __float_as_uint(f);
  unsigned r = (u + 0x7fffu + ((u >> 16) & 1u)) >> 16;
  return (u16)r;
}
__device__ inline float bf2f(u16 v) {
  return __uint_as_float(((unsigned)v) << 16);
}

// ---------------- KNN: one wave per point, wave-parallel top-20 (bit-exact) ----------------
__global__ __launch_bounds__(256) void knn_kernel(const float* __restrict__ x,
                                                  int* __restrict__ nn) {
#pragma clang fp contract(off)
  __shared__ float xs0[NDIM], xs1[NDIM], xs2[NDIM], sq[NDIM];
  const int tid = threadIdx.x;
  const int lane = tid & 63;
  const int w = tid >> 6;
  const int b = blockIdx.x >> 8;
  const int n = ((blockIdx.x & 255) << 2) + w;
  for (int i = tid; i < NDIM; i += 256) {
    float a0 = x[(b * 3 + 0) * NDIM + i];
    float a1 = x[(b * 3 + 1) * NDIM + i];
    float a2 = x[(b * 3 + 2) * NDIM + i];
    xs0[i] = a0; xs1[i] = a1; xs2[i] = a2;
    sq[i] = (a0 * a0 + a1 * a1) + a2 * a2;
  }
  __syncthreads();
  const float xn0 = xs0[n], xn1 = xs1[n], xn2 = xs2[n], sqn = sq[n];
  float dl[16];
#pragma unroll
  for (int t = 0; t < 16; ++t) {
    int m = t * 64 + lane;
    float dot = (xn0 * xs0[m] + xn1 * xs1[m]) + xn2 * xs2[m];
    dl[t] = (sqn - 2.0f * dot) + sq[m];
  }
  int* nnrow = &nn[(b * NDIM + n) * KNN];
  for (int r = 0; r < KNN; ++r) {
    float bd = dl[0];
    int bt = 0;
#pragma unroll
    for (int t = 1; t < 16; ++t) {
      if (dl[t] < bd) { bd = dl[t]; bt = t; }
    }
    int bi = bt * 64 + lane;
#pragma unroll
    for (int off = 1; off < 64; off <<= 1) {
      float pd = __shfl_xor(bd, off);
      int pi = __shfl_xor(bi, off);
      if (pd < bd || (pd == bd && pi < bi)) { bd = pd; bi = pi; }
    }
    if (lane == 0) nnrow[r] = bi;
    if ((bi & 63) == lane) {
      int wt = bi >> 6;
#pragma unroll
      for (int t = 0; t < 16; ++t) {
        if (t == wt) dl[t] = 3.4e38f;
      }
    }
  }
}

// ---------------- prep: bf16 weight tables + padded fp32 node1 w1 + zero pooled ----------------
__global__ __launch_bounds__(256) void wcvt(
    const float* __restrict__ w1_3, const float* __restrict__ w2_3,
    const float* __restrict__ w1_2, const float* __restrict__ w2_2,
    const float* __restrict__ hn_w1, const float* __restrict__ f_w,
    const float* __restrict__ he_w1, const float* __restrict__ he_w2,
    u16* __restrict__ w1b3e, u16* __restrict__ wpq3, u16* __restrict__ w2b3,
    u16* __restrict__ w1b2e, u16* __restrict__ wpq2, u16* __restrict__ w2b2,
    float* __restrict__ w1p1, u16* __restrict__ fwb,
    u16* __restrict__ w1b1, u16* __restrict__ w2b1, int* __restrict__ pooled) {
  const int idx = blockIdx.x * 256 + threadIdx.x;
  if (idx < 512 * 384) fwb[idx] = f2bf(f_w[idx]);
  if (idx < 96 * 128) {
    int oc = idx >> 7, c = idx & 127;
    w1b3e[idx] = f2bf(w1_3[oc * 384 + c]);
  }
  if (idx < 192 * 128) {
    int n = idx >> 7, c = idx & 127;
    wpq3[idx] = f2bf(n < 96 ? w1_3[n * 384 + 128 + c]
                            : w1_3[(n - 96) * 384 + 256 + c]);
  }
  if (idx < 192 * 96) w2b3[idx] = f2bf(w2_3[idx]);
  if (idx < 48 * 64) {
    int oc = idx >> 6, c = idx & 63;
    w1b2e[idx] = f2bf(w1_2[oc * 192 + c]);
  }
  if (idx < 96 * 64) {
    int n = idx >> 6, c = idx & 63;
    wpq2[idx] = f2bf(n < 48 ? w1_2[n * 192 + 64 + c]
                            : w1_2[(n - 48) * 192 + 128 + c]);
  }
  if (idx < 128 * 64) {
    int oc = idx >> 6, i = idx & 63;
    w2b2[idx] = (i < 48) ? f2bf(w2_2[oc * 48 + i]) : (u16)0;
  }
  if (idx < 32 * 68) {
    int oc = idx / 68, c = idx - oc * 68;
    w1p1[idx] = (c < 67) ? hn_w1[oc * 67 + c] : 0.0f;
  }
  if (idx < 32 * 32) {
    int oc = idx >> 5, c = idx & 31;
    w1b1[idx] = (c < 12) ? f2bf(he_w1[oc * 12 + c]) : (u16)0;
  }
  if (idx < 64 * 32) w2b1[idx] = f2bf(he_w2[idx]);
  if (idx < BDIM * 512) pooled[idx] = 0;
}

// ---- MFMA edge MP v7: PTS points/block (zero M-pad), FIRST builds X from inputs ----
template <int PTS, int CE, int CMID, int COUT, bool WRITE_E, bool FIRST>
__global__ __launch_bounds__(256) void edge_mfma(
    const u16* __restrict__ eprev, const float* __restrict__ finput,
    const int* __restrict__ nnb, const u16* __restrict__ w1b,
    const float* __restrict__ b1v, const u16* __restrict__ w2b,
    const float* __restrict__ b2v, const u16* __restrict__ pq,
    u16* __restrict__ eout, float* __restrict__ mout) {
  constexpr int K2 = (CMID + 31) & ~31;
  constexpr int NPQ = 2 * CMID;
  constexpr int MT = PTS * KNN;       // 80 edges
  constexpr int MTL = MT / 16;        // 5 M-tiles (exact)
  constexpr int XPB = CE + 8;
  constexpr int Y1PB = K2 + 8;
  constexpr int QP = CMID + 8;
  __shared__ u16 Xs[MT * XPB];
  __shared__ u16 Y1s[MT * Y1PB];
  __shared__ u16 Qs[FIRST ? 8 : MT * QP];
  __shared__ float pld[FIRST ? 8 : PTS * CMID];
  __shared__ int nns[MT];
  const int tid = threadIdx.x;
  const int lane = tid & 63;
  const int wv = tid >> 6;
  const int q = lane >> 4;
  const int bn0 = blockIdx.x * PTS;
  const int b = bn0 >> 10;
  if (tid < MT) nns[tid] = nnb[(size_t)bn0 * KNN + tid];
  __syncthreads();
  // ---- bulk staging (high MLP, coalesced / pure copies) ----
  if constexpr (FIRST) {
    for (int idx = tid; idx < MT * (CE / 8); idx += 256) {
      int p = idx / (CE / 8), kc = idx - p * (CE / 8);
      int k0 = kc * 8;
      int bn = bn0 + p / KNN;
      int n = bn & (NDIM - 1);
      int j = nns[p];
      ushort8 r;
#pragma unroll
      for (int t = 0; t < 8; ++t) {
        int c = k0 + t;
        float v = 0.0f;
        if (c < 3) v = finput[(b * 3 + c) * NDIM + n];
        else if (c < 6)
          v = finput[(b * 3 + c - 3) * NDIM + n] -
              finput[(b * 3 + c - 3) * NDIM + j];
        else if (c < 9) v = finput[(b * 3 + c - 6) * NDIM + n];
        else if (c < 12) v = finput[(b * 3 + c - 9) * NDIM + j];
        r[t] = f2bf(v);
      }
      *(ushort8*)&Xs[p * XPB + k0] = r;
    }
  } else {
    constexpr int KC = CE / 8;
    for (int ch = tid; ch < MT * KC; ch += 256) {
      int p = ch / KC, kc = ch - p * KC;
      int k0 = kc * 8;
      *(uint4*)&Xs[p * XPB + k0] =
          *(const uint4*)&eprev[((size_t)blockIdx.x * MT + p) * CE + k0];
    }
    constexpr int QC = CMID / 8;
    for (int i = tid; i < MT * QC; i += 256) {
      int p = i / QC, c8 = (i - p * QC) * 8;
      *(uint4*)&Qs[p * QP + c8] =
          *(const uint4*)&pq[((size_t)(b << 10) + nns[p]) * NPQ + CMID + c8];
    }
    for (int i = tid; i < PTS * CMID; i += 256) {
      int pt = i / CMID, c = i - pt * CMID;
      pld[i] = bf2f(pq[(size_t)(bn0 + pt) * NPQ + c]) + b1v[c];
    }
  }
  if constexpr (K2 != CMID) {
    for (int i = tid; i < MT * Y1PB; i += 256) Y1s[i] = 0;
  }
  __syncthreads();
  // ---- conv1: Xs @ W1^T (+P+Q folded) -> relu -> Y1s ----
  {
    constexpr int NT1 = CMID / 16;
    constexpr int J1 = MTL * NT1;
    constexpr int KS1 = CE / 32;
    for (int job = wv; job < J1; job += 4) {
      int mt = job / NT1, nt = job - mt * NT1;
      int row = mt * 16 + (lane & 15);
      int ncol = nt * 16 + (lane & 15);
      int kb = q * 8;
      f32x4 acc = {0.f, 0.f, 0.f, 0.f};
      const u16* ap = &Xs[row * XPB + kb];
      const u16* bp = &w1b[(size_t)ncol * CE + kb];
#pragma unroll
      for (int ks = 0; ks < KS1; ++ks) {
        short8 a = *(const short8*)(ap + ks * 32);
        short8 bb = *(const short8*)(bp + ks * 32);
        acc = __builtin_amdgcn_mfma_f32_16x16x32_bf16(a, bb, acc, 0, 0, 0);
      }
      int m0 = mt * 16 + q * 4;
      if constexpr (FIRST) {
        float bias = b1v[ncol];
#pragma unroll
        for (int r = 0; r < 4; ++r) {
          float yv = fmaxf(acc[r] + bias, 0.0f);
          Y1s[(m0 + r) * Y1PB + ncol] = f2bf(yv);
        }
      } else {
        // all 4 rows of this (mt,q) group belong to one point (4 | 20)
        int pt = m0 / KNN;
        float padd = pld[pt * CMID + ncol];
#pragma unroll
        for (int r = 0; r < 4; ++r) {
          int m = m0 + r;
          float qadd = bf2f(Qs[m * QP + ncol]);
          float yv = fmaxf(acc[r] + padd + qadd, 0.0f);
          Y1s[m * Y1PB + ncol] = f2bf(yv);
        }
      }
    }
  }
  __syncthreads();
  // ---- conv2: one wave owns all M-tiles per N-tile; m-sum via per-point selects ----
  {
    constexpr int NT2 = COUT / 16;
    constexpr int KS2 = K2 / 32;
    for (int nt = wv; nt < NT2; nt += 4) {
      int ncol = nt * 16 + (lane & 15);
      int kb = q * 8;
      short8 bfrag[KS2];
      const u16* bp = &w2b[(size_t)ncol * K2 + kb];
#pragma unroll
      for (int ks = 0; ks < KS2; ++ks)
        bfrag[ks] = *(const short8*)(bp + ks * 32);
      float bias = b2v[ncol];
      float s[PTS];
#pragma unroll
      for (int pt = 0; pt < PTS; ++pt) s[pt] = 0.0f;
#pragma unroll
      for (int mt = 0; mt < MTL; ++mt) {
        f32x4 acc = {0.f, 0.f, 0.f, 0.f};
        const u16* ap = &Y1s[(mt * 16 + (lane & 15)) * Y1PB + kb];
#pragma unroll
        for (int ks = 0; ks < KS2; ++ks) {
          short8 a = *(const short8*)(ap + ks * 32);
          acc = __builtin_amdgcn_mfma_f32_16x16x32_bf16(a, bfrag[ks], acc, 0, 0, 0);
        }
        int m0 = mt * 16 + q * 4;
        int pt = m0 / KNN;  // whole group in one point
        float part = 0.0f;
#pragma unroll
        for (int r = 0; r < 4; ++r) {
          float yv = fmaxf(acc[r] + bias, 0.0f);
          u16 bv = f2bf(yv);
          float v = bf2f(bv);
          if (WRITE_E)
            eout[((size_t)blockIdx.x * MT + m0 + r) * COUT + ncol] = bv;
          part += v;
        }
#pragma unroll
        for (int pt2 = 0; pt2 < PTS; ++pt2)
          s[pt2] += (pt == pt2) ? part : 0.0f;
      }
#pragma unroll
      for (int pt = 0; pt < PTS; ++pt) {
        float sv = s[pt];
        sv += __shfl_xor(sv, 16);
        sv += __shfl_xor(sv, 32);
        if (lane < 16)
          mout[(size_t)(bn0 + pt) * COUT + nt * 16 + lane] = sv;
      }
    }
  }
}

// ---- node conv: fp32 microtile GEMM + optional fused PQ MFMA phase ----
template <int TP, int CH, int CM, int CINP, int CMID, int COUT, int NPQ, bool FIRSTH>
__global__ __launch_bounds__(256) void node_conv(
    const float* __restrict__ h, const float* __restrict__ inputs,
    const float* __restrict__ mbuf, const float* __restrict__ w1p,
    const float* __restrict__ b1v, const float* __restrict__ w2,
    const float* __restrict__ b2v, float* __restrict__ hout,
    const u16* __restrict__ wpq, u16* __restrict__ pq) {
  constexpr int CIN = CH + CM;
  constexpr int XP = CINP + 4;
  constexpr int Y1P = CMID + 4;
  constexpr int PG = TP / 4;
  constexpr int HP = COUT + 8;
  __shared__ float Xs[TP * XP];
  __shared__ float Y1s[TP * Y1P];
  __shared__ u16 Hb[(NPQ > 0) ? TP * HP : 8];
  const int tid = threadIdx.x;
  const int bn0 = blockIdx.x * TP;
  if (FIRSTH) {
    for (int idx = tid; idx < TP * CIN; idx += 256) {
      int p = idx / CIN, c = idx - p * CIN;
      int bn = bn0 + p;
      int b = bn >> 10, n = bn & (NDIM - 1);
      Xs[p * XP + c] = (c < CH) ? inputs[(b * 3 + c) * NDIM + n]
                                : mbuf[(size_t)bn * CM + (c - CH)];
    }
    for (int idx = tid; idx < TP * (CINP - CIN); idx += 256) {
      int p = idx / (CINP - CIN), c = CIN + idx % (CINP - CIN);
      Xs[p * XP + c] = 0.0f;
    }
  } else {
    constexpr int C4 = CIN / 4;
    for (int idx = tid; idx < TP * C4; idx += 256) {
      int p = idx / C4, c = (idx - p * C4) * 4;
      int bn = bn0 + p;
      float4 v = (c < CH) ? *(const float4*)&h[(size_t)bn * CH + c]
                          : *(const float4*)&mbuf[(size_t)bn * CM + (c - CH)];
      *(float4*)&Xs[p * XP + c] = v;
    }
  }
  __syncthreads();
  {
    constexpr int NT1 = PG * (CMID / 4);
    for (int t = tid; t < NT1; t += 256) {
      int pg = t % PG, og = t / PG;
      float acc[4][4];
#pragma unroll
      for (int j = 0; j < 4; ++j) {
        float bj = b1v[og * 4 + j];
#pragma unroll
        for (int i = 0; i < 4; ++i) acc[i][j] = bj;
      }
      for (int cin = 0; cin < CINP; cin += 4) {
        float4 xr[4], wr[4];
#pragma unroll
        for (int i = 0; i < 4; ++i)
          xr[i] = *(const float4*)&Xs[(pg * 4 + i) * XP + cin];
#pragma unroll
        for (int j = 0; j < 4; ++j)
          wr[j] = *(const float4*)&w1p[(size_t)(og * 4 + j) * CINP + cin];
#pragma unroll
        for (int i = 0; i < 4; ++i)
#pragma unroll
          for (int j = 0; j < 4; ++j) {
            acc[i][j] += xr[i].x * wr[j].x;
            acc[i][j] += xr[i].y * wr[j].y;
            acc[i][j] += xr[i].z * wr[j].z;
            acc[i][j] += xr[i].w * wr[j].w;
          }
      }
#pragma unroll
      for (int i = 0; i < 4; ++i)
#pragma unroll
        for (int j = 0; j < 4; ++j)
          Y1s[(pg * 4 + i) * Y1P + og * 4 + j] = fmaxf(acc[i][j], 0.0f);
    }
  }
  __syncthreads();
  {
    constexpr int NT2 = PG * (COUT / 4);
    for (int t = tid; t < NT2; t += 256) {
      int pg = t % PG, og = t / PG;
      float acc[4][4];
#pragma unroll
      for (int j = 0; j < 4; ++j) {
        float bj = b2v[og * 4 + j];
#pragma unroll
        for (int i = 0; i < 4; ++i) acc[i][j] = bj;
      }
      for (int cin = 0; cin < CMID; cin += 4) {
        float4 xr[4], wr[4];
#pragma unroll
        for (int i = 0; i < 4; ++i)
          xr[i] = *(const float4*)&Y1s[(pg * 4 + i) * Y1P + cin];
#pragma unroll
        for (int j = 0; j < 4; ++j)
          wr[j] = *(const float4*)&w2[(size_t)(og * 4 + j) * CMID + cin];
#pragma unroll
        for (int i = 0; i < 4; ++i)
#pragma unroll
          for (int j = 0; j < 4; ++j) {
            acc[i][j] += xr[i].x * wr[j].x;
            acc[i][j] += xr[i].y * wr[j].y;
            acc[i][j] += xr[i].z * wr[j].z;
            acc[i][j] += xr[i].w * wr[j].w;
          }
      }
#pragma unroll
      for (int i = 0; i < 4; ++i) {
        int bn = bn0 + pg * 4 + i;
#pragma unroll
        for (int j = 0; j < 4; ++j) {
          float v = fmaxf(acc[i][j], 0.0f);
          hout[(size_t)bn * COUT + og * 4 + j] = v;
          if (NPQ > 0) Hb[(pg * 4 + i) * HP + og * 4 + j] = f2bf(v);
        }
      }
    }
  }
  if constexpr (NPQ > 0) {
    __syncthreads();
    const int lane = tid & 63;
    const int wv = tid >> 6;
    constexpr int NT = NPQ / 16;
    constexpr int JOBS = (TP / 16) * NT;
    constexpr int KS = COUT / 32;
    for (int job = wv; job < JOBS; job += 4) {
      int mt = job / NT, nt = job - mt * NT;
      int row = mt * 16 + (lane & 15);
      int ncol = nt * 16 + (lane & 15);
      int kb = (lane >> 4) * 8;
      f32x4 acc = {0.f, 0.f, 0.f, 0.f};
      const u16* ap = &Hb[row * HP + kb];
      const u16* bp = &wpq[(size_t)ncol * COUT + kb];
#pragma unroll
      for (int ks = 0; ks < KS; ++ks) {
        short8 a = *(const short8*)(ap + ks * 32);
        short8 bb = *(const short8*)(bp + ks * 32);
        acc = __builtin_amdgcn_mfma_f32_16x16x32_bf16(a, bb, acc, 0, 0, 0);
      }
      int m0 = mt * 16 + (lane >> 4) * 4;
#pragma unroll
      for (int r = 0; r < 4; ++r)
        pq[(size_t)(bn0 + m0 + r) * NPQ + ncol] = f2bf(acc[r]);
    }
  }
}

// ---------------- fusion conv (384->512) via MFMA + relu + global max pool ----------------
__global__ __launch_bounds__(256) void fuse_pool_mfma(
    const float* __restrict__ h1, const float* __restrict__ h2,
    const float* __restrict__ h3, const u16* __restrict__ fwb,
    const float* __restrict__ fb, int* __restrict__ pooled) {
  constexpr int CIN = 384, COUT = 512, TP = 32;
  constexpr int XPB = CIN + 8;
  __shared__ u16 Xs[TP * XPB];
  __shared__ int pmax[COUT];
  const int tid = threadIdx.x;
  const int lane = tid & 63;
  const int wv = tid >> 6;
  const int bn0 = blockIdx.x * TP;
  const int b = bn0 >> 10;
  for (int i = tid; i < COUT; i += 256) pmax[i] = 0;
  constexpr int KC = CIN / 8;
  for (int ch = tid; ch < TP * KC; ch += 256) {
    int p = ch / KC, kc = ch - p * KC;
    int k0 = kc * 8;
    int bn = bn0 + p;
    const float* src;
    if (k0 < 64) src = &h1[(size_t)bn * 64 + k0];
    else if (k0 < 192) src = &h2[(size_t)bn * 128 + (k0 - 64)];
    else src = &h3[(size_t)bn * 192 + (k0 - 192)];
    float4 f0 = *(const float4*)src;
    float4 f1 = *(const float4*)(src + 4);
    ushort8 r;
    r[0] = f2bf(f0.x); r[1] = f2bf(f0.y); r[2] = f2bf(f0.z); r[3] = f2bf(f0.w);
    r[4] = f2bf(f1.x); r[5] = f2bf(f1.y); r[6] = f2bf(f1.z); r[7] = f2bf(f1.w);
    *(ushort8*)&Xs[p * XPB + k0] = r;
  }
  __syncthreads();
  constexpr int NT = COUT / 16;
  constexpr int JOBS = (TP / 16) * NT;
  constexpr int KS = CIN / 32;
  for (int job = wv; job < JOBS; job += 4) {
    int mt = job / NT, nt = job - mt * NT;
    int row = mt * 16 + (lane & 15);
    int ncol = nt * 16 + (lane & 15);
    int kb = (lane >> 4) * 8;
    f32x4 acc = {0.f, 0.f, 0.f, 0.f};
    const u16* ap = &Xs[row * XPB + kb];
    const u16* bp = &fwb[(size_t)ncol * CIN + kb];
#pragma unroll
    for (int ks = 0; ks < KS; ++ks) {
      short8 a = *(const short8*)(ap + ks * 32);
      short8 bb = *(const short8*)(bp + ks * 32);
      acc = __builtin_amdgcn_mfma_f32_16x16x32_bf16(a, bb, acc, 0, 0, 0);
    }
    float bias = fb[ncol];
    float v = fmaxf(fmaxf(acc[0], acc[1]), fmaxf(acc[2], acc[3]));
    v = fmaxf(v + bias, 0.0f);
    v = fmaxf(v, __shfl_xor(v, 16));
    v = fmaxf(v, __shfl_xor(v, 32));
    if (lane < 16) atomicMax(&pmax[ncol], __float_as_int(v));
  }
  __syncthreads();
  for (int i = tid; i < COUT; i += 256)
    atomicMax(&pooled[b * COUT + i], pmax[i]);
}

// ---------------- prediction head ----------------
__global__ __launch_bounds__(256) void head_kernel(
    const int* __restrict__ pooledi, const float* __restrict__ p1w,
    const float* __restrict__ p1b, const float* __restrict__ p2w,
    const float* __restrict__ p2b, const float* __restrict__ p3w,
    const float* __restrict__ p3b, float* __restrict__ out) {
  __shared__ float xs[512], y1[256], y2[128];
  const int b = blockIdx.x, tid = threadIdx.x;
  for (int i = tid; i < 512; i += 256) xs[i] = __int_as_float(pooledi[b * 512 + i]);
  __syncthreads();
  {
    float acc = p1b[tid];
    for (int c = 0; c < 512; ++c) acc += xs[c] * p1w[tid * 512 + c];
    y1[tid] = fmaxf(acc, 0.0f);
  }
  __syncthreads();
  if (tid < 128) {
    float acc = p2b[tid];
    for (int c = 0; c < 256; ++c) acc += y1[c] * p2w[tid * 256 + c];
    y2[tid] = fmaxf(acc, 0.0f);
  }
  __syncthreads();
  if (tid < 40) {
    float acc = p3b[tid];
    for (int c = 0; c < 128; ++c) acc += y2[c] * p3w[tid * 128 + c];
    out[b * 40 + tid] = acc;
  }
}

extern "C" void kernel_launch(void* const* d_in, const int* in_sizes, int n_in,
                              void* d_out, int out_size, void* d_ws,
                              size_t ws_size, hipStream_t stream) {
  const float* inputs = (const float*)d_in[0];
  const float* he_w1 = (const float*)d_in[1];
  const float* he_b1 = (const float*)d_in[2];
  const float* he_w2 = (const float*)d_in[3];
  const float* he_b2 = (const float*)d_in[4];
  const float* hn_w1 = (const float*)d_in[5];
  const float* hn_b1 = (const float*)d_in[6];
  const float* hn_w2 = (const float*)d_in[7];
  const float* hn_b2 = (const float*)d_in[8];
  const float* b1e_w1 = (const float*)d_in[9];
  const float* b1e_b1 = (const float*)d_in[10];
  const float* b1e_w2 = (const float*)d_in[11];
  const float* b1e_b2 = (const float*)d_in[12];
  const float* b1n_w1 = (const float*)d_in[13];
  const float* b1n_b1 = (const float*)d_in[14];
  const float* b1n_w2 = (const float*)d_in[15];
  const float* b1n_b2 = (const float*)d_in[16];
  const float* b2e_w1 = (const float*)d_in[17];
  const float* b2e_b1 = (const float*)d_in[18];
  const float* b2e_w2 = (const float*)d_in[19];
  const float* b2e_b2 = (const float*)d_in[20];
  const float* b2n_w1 = (const float*)d_in[21];
  const float* b2n_b1 = (const float*)d_in[22];
  const float* b2n_w2 = (const float*)d_in[23];
  const float* b2n_b2 = (const float*)d_in[24];
  const float* f_w = (const float*)d_in[25];
  const float* f_b = (const float*)d_in[26];
  const float* p1_w = (const float*)d_in[27];
  const float* p1_b = (const float*)d_in[28];
  const float* p2_w = (const float*)d_in[29];
  const float* p2_b = (const float*)d_in[30];
  const float* p3_w = (const float*)d_in[31];
  const float* p3_b = (const float*)d_in[32];
  float* out = (float*)d_out;

  char* ws = (char*)d_ws;
  size_t off = 0;
  auto alloc = [&](size_t bytes) {
    void* p = ws + off;
    off += (bytes + 255) & ~(size_t)255;
    return p;
  };
  int* nn = (int*)alloc((size_t)BDIM * NDIM * KNN * 4);
  float* m1 = (float*)alloc((size_t)BDIM * NDIM * 64 * 4);
  float* h1 = (float*)alloc((size_t)BDIM * NDIM * 64 * 4);
  u16* e1 = (u16*)alloc((size_t)BDIM * NDIM * KNN * 64 * 2);   // bf16
  float* m2 = (float*)alloc((size_t)BDIM * NDIM * 128 * 4);
  float* h2 = (float*)alloc((size_t)BDIM * NDIM * 128 * 4);
  u16* e2 = (u16*)alloc((size_t)BDIM * NDIM * KNN * 128 * 2);  // bf16
  float* m3 = (float*)alloc((size_t)BDIM * NDIM * 192 * 4);
  float* h3 = (float*)alloc((size_t)BDIM * NDIM * 192 * 4);
  u16* pq2 = (u16*)alloc((size_t)BDIM * NDIM * 96 * 2);        // bf16
  u16* pq3 = (u16*)alloc((size_t)BDIM * NDIM * 192 * 2);       // bf16
  int* pooled = (int*)alloc((size_t)BDIM * 512 * 4);
  u16* w1b3e = (u16*)alloc((size_t)96 * 128 * 2);
  u16* wpq3 = (u16*)alloc((size_t)192 * 128 * 2);
  u16* w2b3 = (u16*)alloc((size_t)192 * 96 * 2);
  u16* w1b2e = (u16*)alloc((size_t)48 * 64 * 2);
  u16* wpq2 = (u16*)alloc((size_t)96 * 64 * 2);
  u16* w2b2 = (u16*)alloc((size_t)128 * 64 * 2);
  float* w1p1 = (float*)alloc((size_t)32 * 68 * 4);
  u16* fwb = (u16*)alloc((size_t)512 * 384 * 2);
  u16* w1b1 = (u16*)alloc((size_t)32 * 32 * 2);
  u16* w2b1 = (u16*)alloc((size_t)64 * 32 * 2);

  wcvt<<<(512 * 384 + 255) / 256, 256, 0, stream>>>(
      b2e_w1, b2e_w2, b1e_w1, b1e_w2, hn_w1, f_w, he_w1, he_w2, w1b3e, wpq3,
      w2b3, w1b2e, wpq2, w2b2, w1p1, fwb, w1b1, w2b1, pooled);
  knn_kernel<<<BDIM * 256, 256, 0, stream>>>(inputs, nn);

  edge_mfma<4, 32, 32, 64, true, true><<<BDIM * NDIM / 4, 256, 0, stream>>>(
      nullptr, inputs, nn, w1b1, he_b1, w2b1, he_b2, nullptr, e1, m1);
  node_conv<64, 3, 64, 68, 32, 64, 96, true><<<BDIM * NDIM / 64, 256, 0, stream>>>(
      nullptr, inputs, m1, w1p1, hn_b1, hn_w2, hn_b2, h1, wpq2, pq2);

  edge_mfma<4, 64, 48, 128, true, false><<<BDIM * NDIM / 4, 256, 0, stream>>>(
      e1, nullptr, nn, w1b2e, b1e_b1, w2b2, b1e_b2, pq2, e2, m2);
  node_conv<32, 64, 128, 192, 48, 128, 192, false><<<BDIM * NDIM / 32, 256, 0, stream>>>(
      h1, nullptr, m2, b1n_w1, b1n_b1, b1n_w2, b1n_b2, h2, wpq3, pq3);

  edge_mfma<4, 128, 96, 192, false, false><<<BDIM * NDIM / 4, 256, 0, stream>>>(
      e2, nullptr, nn, w1b3e, b2e_b1, w2b3, b2e_b2, pq3, nullptr, m3);
  node_conv<16, 128, 192, 320, 96, 192, 0, false><<<BDIM * NDIM / 16, 256, 0, stream>>>(
      h2, nullptr, m3, b2n_w1, b2n_b1, b2n_w2, b2n_b2, h3, nullptr, nullptr);

  fuse_pool_mfma<<<BDIM * NDIM / 32, 256, 0, stream>>>(h1, h2, h3, fwb, f_b,
                                                       pooled);
  head_kernel<<<BDIM, 256, 0, stream>>>(pooled, p1_w, p1_b, p2_w, p2_b, p3_w,
                                        p3_b, out);

  hipMemcpyAsync(out + BDIM * 40, d_in[0], (size_t)BDIM * 3 * NDIM * 4,
                 hipMemcpyDeviceToDevice, stream);
}

// Round 13
// 256.982 us; speedup vs baseline: 7.0327x; 1.0304x over previous
//
#include <hip/hip_runtime.h>

#define BDIM 8
#define NDIM 1024
#define KNN 20

typedef unsigned short u16;
typedef float f32x4 __attribute__((ext_vector_type(4)));
typedef short short8 __attribute__((ext_vector_type(8)));
typedef unsigned short ushort8 __attribute__((ext_vector_type(8)));

__device__ inline u16 f2bf(float f) {
  unsigned u = __float_as_uint(f);
  unsigned r = (u + 0x7fffu + ((u >> 16) & 1u)) >> 16;
  return (u16)r;
}
__device__ inline float bf2f(u16 v) {
  return __uint_as_float(((unsigned)v) << 16);
}

// ---- merged: KNN (blocks 0..2047, bit-exact) + weight prep (blocks 2048+) ----
__global__ __launch_bounds__(256) void knn_wcvt(
    const float* __restrict__ x, int* __restrict__ nn,
    const float* __restrict__ w1_3, const float* __restrict__ w2_3,
    const float* __restrict__ w1_2, const float* __restrict__ w2_2,
    const float* __restrict__ hn_w1, const float* __restrict__ f_w,
    const float* __restrict__ he_w1, const float* __restrict__ he_w2,
    u16* __restrict__ w1b3e, u16* __restrict__ wpq3, u16* __restrict__ w2b3,
    u16* __restrict__ w1b2e, u16* __restrict__ wpq2, u16* __restrict__ w2b2,
    float* __restrict__ w1p1, u16* __restrict__ fwb,
    u16* __restrict__ w1b1, u16* __restrict__ w2b1, int* __restrict__ pooled) {
  const int tid = threadIdx.x;
  if (blockIdx.x >= BDIM * 256) {
    // ---------------- weight conversion path ----------------
    const int idx = (blockIdx.x - BDIM * 256) * 256 + tid;
    if (idx < 512 * 384) fwb[idx] = f2bf(f_w[idx]);
    if (idx < 96 * 128) {
      int oc = idx >> 7, c = idx & 127;
      w1b3e[idx] = f2bf(w1_3[oc * 384 + c]);
    }
    if (idx < 192 * 128) {
      int n = idx >> 7, c = idx & 127;
      wpq3[idx] = f2bf(n < 96 ? w1_3[n * 384 + 128 + c]
                              : w1_3[(n - 96) * 384 + 256 + c]);
    }
    if (idx < 192 * 96) w2b3[idx] = f2bf(w2_3[idx]);
    if (idx < 48 * 64) {
      int oc = idx >> 6, c = idx & 63;
      w1b2e[idx] = f2bf(w1_2[oc * 192 + c]);
    }
    if (idx < 96 * 64) {
      int n = idx >> 6, c = idx & 63;
      wpq2[idx] = f2bf(n < 48 ? w1_2[n * 192 + 64 + c]
                              : w1_2[(n - 48) * 192 + 128 + c]);
    }
    if (idx < 128 * 64) {
      int oc = idx >> 6, i = idx & 63;
      w2b2[idx] = (i < 48) ? f2bf(w2_2[oc * 48 + i]) : (u16)0;
    }
    if (idx < 32 * 68) {
      int oc = idx / 68, c = idx - oc * 68;
      w1p1[idx] = (c < 67) ? hn_w1[oc * 67 + c] : 0.0f;
    }
    if (idx < 32 * 32) {
      int oc = idx >> 5, c = idx & 31;
      w1b1[idx] = (c < 12) ? f2bf(he_w1[oc * 12 + c]) : (u16)0;
    }
    if (idx < 64 * 32) w2b1[idx] = f2bf(he_w2[idx]);
    if (idx < BDIM * 512) pooled[idx] = 0;
    return;
  }
  // ---------------- KNN path (bit-exact fp32) ----------------
  {
#pragma clang fp contract(off)
    __shared__ float xs0[NDIM], xs1[NDIM], xs2[NDIM], sq[NDIM];
    const int lane = tid & 63;
    const int w = tid >> 6;
    const int b = blockIdx.x >> 8;
    const int n = ((blockIdx.x & 255) << 2) + w;
    for (int i = tid; i < NDIM; i += 256) {
      float a0 = x[(b * 3 + 0) * NDIM + i];
      float a1 = x[(b * 3 + 1) * NDIM + i];
      float a2 = x[(b * 3 + 2) * NDIM + i];
      xs0[i] = a0; xs1[i] = a1; xs2[i] = a2;
      sq[i] = (a0 * a0 + a1 * a1) + a2 * a2;
    }
    __syncthreads();
    const float xn0 = xs0[n], xn1 = xs1[n], xn2 = xs2[n], sqn = sq[n];
    float dl[16];
#pragma unroll
    for (int t = 0; t < 16; ++t) {
      int m = t * 64 + lane;
      float dot = (xn0 * xs0[m] + xn1 * xs1[m]) + xn2 * xs2[m];
      dl[t] = (sqn - 2.0f * dot) + sq[m];
    }
    int* nnrow = &nn[(b * NDIM + n) * KNN];
    for (int r = 0; r < KNN; ++r) {
      float bd = dl[0];
      int bt = 0;
#pragma unroll
      for (int t = 1; t < 16; ++t) {
        if (dl[t] < bd) { bd = dl[t]; bt = t; }
      }
      int bi = bt * 64 + lane;
#pragma unroll
      for (int off = 1; off < 64; off <<= 1) {
        float pd = __shfl_xor(bd, off);
        int pi = __shfl_xor(bi, off);
        if (pd < bd || (pd == bd && pi < bi)) { bd = pd; bi = pi; }
      }
      if (lane == 0) nnrow[r] = bi;
      if ((bi & 63) == lane) {
        int wt = bi >> 6;
#pragma unroll
        for (int t = 0; t < 16; ++t) {
          if (t == wt) dl[t] = 3.4e38f;
        }
      }
    }
  }
}

// ---- MFMA edge MP v8: PTS points/block, lean fp32 m-sum epilogue ----
template <int PTS, int CE, int CMID, int COUT, bool WRITE_E, bool FIRST>
__global__ __launch_bounds__(256) void edge_mfma(
    const u16* __restrict__ eprev, const float* __restrict__ finput,
    const int* __restrict__ nnb, const u16* __restrict__ w1b,
    const float* __restrict__ b1v, const u16* __restrict__ w2b,
    const float* __restrict__ b2v, const u16* __restrict__ pq,
    u16* __restrict__ eout, float* __restrict__ mout) {
  constexpr int K2 = (CMID + 31) & ~31;
  constexpr int NPQ = 2 * CMID;
  constexpr int MT = PTS * KNN;       // 80 edges
  constexpr int MTL = MT / 16;        // 5 M-tiles (exact)
  constexpr int XPB = CE + 8;
  constexpr int Y1PB = K2 + 8;
  constexpr int QP = CMID + 8;
  __shared__ u16 Xs[MT * XPB];
  __shared__ u16 Y1s[MT * Y1PB];
  __shared__ u16 Qs[FIRST ? 8 : MT * QP];
  __shared__ float pld[FIRST ? 8 : PTS * CMID];
  __shared__ int nns[MT];
  const int tid = threadIdx.x;
  const int lane = tid & 63;
  const int wv = tid >> 6;
  const int q = lane >> 4;
  const int bn0 = blockIdx.x * PTS;
  const int b = bn0 >> 10;
  if (tid < MT) nns[tid] = nnb[(size_t)bn0 * KNN + tid];
  __syncthreads();
  // ---- bulk staging (high MLP, coalesced / pure copies) ----
  if constexpr (FIRST) {
    for (int idx = tid; idx < MT * (CE / 8); idx += 256) {
      int p = idx / (CE / 8), kc = idx - p * (CE / 8);
      int k0 = kc * 8;
      int bn = bn0 + p / KNN;
      int n = bn & (NDIM - 1);
      int j = nns[p];
      ushort8 r;
#pragma unroll
      for (int t = 0; t < 8; ++t) {
        int c = k0 + t;
        float v = 0.0f;
        if (c < 3) v = finput[(b * 3 + c) * NDIM + n];
        else if (c < 6)
          v = finput[(b * 3 + c - 3) * NDIM + n] -
              finput[(b * 3 + c - 3) * NDIM + j];
        else if (c < 9) v = finput[(b * 3 + c - 6) * NDIM + n];
        else if (c < 12) v = finput[(b * 3 + c - 9) * NDIM + j];
        r[t] = f2bf(v);
      }
      *(ushort8*)&Xs[p * XPB + k0] = r;
    }
  } else {
    constexpr int KC = CE / 8;
    for (int ch = tid; ch < MT * KC; ch += 256) {
      int p = ch / KC, kc = ch - p * KC;
      int k0 = kc * 8;
      *(uint4*)&Xs[p * XPB + k0] =
          *(const uint4*)&eprev[((size_t)blockIdx.x * MT + p) * CE + k0];
    }
    constexpr int QC = CMID / 8;
    for (int i = tid; i < MT * QC; i += 256) {
      int p = i / QC, c8 = (i - p * QC) * 8;
      *(uint4*)&Qs[p * QP + c8] =
          *(const uint4*)&pq[((size_t)(b << 10) + nns[p]) * NPQ + CMID + c8];
    }
    for (int i = tid; i < PTS * CMID; i += 256) {
      int pt = i / CMID, c = i - pt * CMID;
      pld[i] = bf2f(pq[(size_t)(bn0 + pt) * NPQ + c]) + b1v[c];
    }
  }
  if constexpr (K2 != CMID) {
    for (int i = tid; i < MT * Y1PB; i += 256) Y1s[i] = 0;
  }
  __syncthreads();
  // ---- conv1: Xs @ W1^T (+P+Q folded) -> relu -> Y1s ----
  {
    constexpr int NT1 = CMID / 16;
    constexpr int J1 = MTL * NT1;
    constexpr int KS1 = CE / 32;
    for (int job = wv; job < J1; job += 4) {
      int mt = job / NT1, nt = job - mt * NT1;
      int row = mt * 16 + (lane & 15);
      int ncol = nt * 16 + (lane & 15);
      int kb = q * 8;
      f32x4 acc = {0.f, 0.f, 0.f, 0.f};
      const u16* ap = &Xs[row * XPB + kb];
      const u16* bp = &w1b[(size_t)ncol * CE + kb];
#pragma unroll
      for (int ks = 0; ks < KS1; ++ks) {
        short8 a = *(const short8*)(ap + ks * 32);
        short8 bb = *(const short8*)(bp + ks * 32);
        acc = __builtin_amdgcn_mfma_f32_16x16x32_bf16(a, bb, acc, 0, 0, 0);
      }
      int m0 = mt * 16 + q * 4;
      if constexpr (FIRST) {
        float bias = b1v[ncol];
#pragma unroll
        for (int r = 0; r < 4; ++r) {
          float yv = fmaxf(acc[r] + bias, 0.0f);
          Y1s[(m0 + r) * Y1PB + ncol] = f2bf(yv);
        }
      } else {
        int pt = m0 / KNN;  // whole 4-row group in one point (4 | 20)
        float padd = pld[pt * CMID + ncol];
#pragma unroll
        for (int r = 0; r < 4; ++r) {
          int m = m0 + r;
          float qadd = bf2f(Qs[m * QP + ncol]);
          float yv = fmaxf(acc[r] + padd + qadd, 0.0f);
          Y1s[m * Y1PB + ncol] = f2bf(yv);
        }
      }
    }
  }
  __syncthreads();
  // ---- conv2: one wave owns all M-tiles per N-tile; fp32 m-sum, const-folded pt map ----
  {
    constexpr int NT2 = COUT / 16;
    constexpr int KS2 = K2 / 32;
    for (int nt = wv; nt < NT2; nt += 4) {
      int ncol = nt * 16 + (lane & 15);
      int kb = q * 8;
      short8 bfrag[KS2];
      const u16* bp = &w2b[(size_t)ncol * K2 + kb];
#pragma unroll
      for (int ks = 0; ks < KS2; ++ks)
        bfrag[ks] = *(const short8*)(bp + ks * 32);
      float bias = b2v[ncol];
      float s[PTS];
#pragma unroll
      for (int pt = 0; pt < PTS; ++pt) s[pt] = 0.0f;
#pragma unroll
      for (int mt = 0; mt < MTL; ++mt) {
        f32x4 acc = {0.f, 0.f, 0.f, 0.f};
        const u16* ap = &Y1s[(mt * 16 + (lane & 15)) * Y1PB + kb];
#pragma unroll
        for (int ks = 0; ks < KS2; ++ks) {
          short8 a = *(const short8*)(ap + ks * 32);
          acc = __builtin_amdgcn_mfma_f32_16x16x32_bf16(a, bfrag[ks], acc, 0, 0, 0);
        }
        int m0 = mt * 16 + q * 4;
        float part = 0.0f;
#pragma unroll
        for (int r = 0; r < 4; ++r) {
          float yv = fmaxf(acc[r] + bias, 0.0f);
          if (WRITE_E)
            eout[((size_t)blockIdx.x * MT + m0 + r) * COUT + ncol] = f2bf(yv);
          part += yv;
        }
        // pt = (4*mt + q) / 5; constant-folds after unroll
        int ptA = (4 * mt) / 5;
        int ptB = (4 * mt + 3) / 5;
        int qb = 5 * ptB - 4 * mt;
#pragma unroll
        for (int pt2 = 0; pt2 < PTS; ++pt2) {
          if (pt2 == ptA && ptA == ptB) s[pt2] += part;
          else if (pt2 == ptA) s[pt2] += (q < qb) ? part : 0.0f;
          else if (pt2 == ptB) s[pt2] += (q < qb) ? 0.0f : part;
        }
      }
#pragma unroll
      for (int pt = 0; pt < PTS; ++pt) {
        float sv = s[pt];
        sv += __shfl_xor(sv, 16);
        sv += __shfl_xor(sv, 32);
        if (lane < 16)
          mout[(size_t)(bn0 + pt) * COUT + nt * 16 + lane] = sv;
      }
    }
  }
}

// ---- node conv: fp32 microtile GEMM + optional fused PQ MFMA phase ----
template <int TP, int CH, int CM, int CINP, int CMID, int COUT, int NPQ, bool FIRSTH>
__global__ __launch_bounds__(256) void node_conv(
    const float* __restrict__ h, const float* __restrict__ inputs,
    const float* __restrict__ mbuf, const float* __restrict__ w1p,
    const float* __restrict__ b1v, const float* __restrict__ w2,
    const float* __restrict__ b2v, float* __restrict__ hout,
    const u16* __restrict__ wpq, u16* __restrict__ pq) {
  constexpr int CIN = CH + CM;
  constexpr int XP = CINP + 4;
  constexpr int Y1P = CMID + 4;
  constexpr int PG = TP / 4;
  constexpr int HP = COUT + 8;
  __shared__ float Xs[TP * XP];
  __shared__ float Y1s[TP * Y1P];
  __shared__ u16 Hb[(NPQ > 0) ? TP * HP : 8];
  const int tid = threadIdx.x;
  const int bn0 = blockIdx.x * TP;
  if constexpr (FIRSTH) {
    for (int idx = tid; idx < TP * CIN; idx += 256) {
      int p = idx / CIN, c = idx - p * CIN;
      int bn = bn0 + p;
      int b = bn >> 10, n = bn & (NDIM - 1);
      Xs[p * XP + c] = (c < CH) ? inputs[(b * 3 + c) * NDIM + n]
                                : mbuf[(size_t)bn * CM + (c - CH)];
    }
    if constexpr (CINP > CIN) {
      constexpr int PAD = CINP - CIN;
      for (int idx = tid; idx < TP * PAD; idx += 256) {
        int p = idx / PAD, c = CIN + idx % PAD;
        Xs[p * XP + c] = 0.0f;
      }
    }
  } else {
    constexpr int C4 = CIN / 4;
    for (int idx = tid; idx < TP * C4; idx += 256) {
      int p = idx / C4, c = (idx - p * C4) * 4;
      int bn = bn0 + p;
      float4 v = (c < CH) ? *(const float4*)&h[(size_t)bn * CH + c]
                          : *(const float4*)&mbuf[(size_t)bn * CM + (c - CH)];
      *(float4*)&Xs[p * XP + c] = v;
    }
  }
  __syncthreads();
  {
    constexpr int NT1 = PG * (CMID / 4);
    for (int t = tid; t < NT1; t += 256) {
      int pg = t % PG, og = t / PG;
      float acc[4][4];
#pragma unroll
      for (int j = 0; j < 4; ++j) {
        float bj = b1v[og * 4 + j];
#pragma unroll
        for (int i = 0; i < 4; ++i) acc[i][j] = bj;
      }
      for (int cin = 0; cin < CINP; cin += 4) {
        float4 xr[4], wr[4];
#pragma unroll
        for (int i = 0; i < 4; ++i)
          xr[i] = *(const float4*)&Xs[(pg * 4 + i) * XP + cin];
#pragma unroll
        for (int j = 0; j < 4; ++j)
          wr[j] = *(const float4*)&w1p[(size_t)(og * 4 + j) * CINP + cin];
#pragma unroll
        for (int i = 0; i < 4; ++i)
#pragma unroll
          for (int j = 0; j < 4; ++j) {
            acc[i][j] += xr[i].x * wr[j].x;
            acc[i][j] += xr[i].y * wr[j].y;
            acc[i][j] += xr[i].z * wr[j].z;
            acc[i][j] += xr[i].w * wr[j].w;
          }
      }
#pragma unroll
      for (int i = 0; i < 4; ++i)
#pragma unroll
        for (int j = 0; j < 4; ++j)
          Y1s[(pg * 4 + i) * Y1P + og * 4 + j] = fmaxf(acc[i][j], 0.0f);
    }
  }
  __syncthreads();
  {
    constexpr int NT2 = PG * (COUT / 4);
    for (int t = tid; t < NT2; t += 256) {
      int pg = t % PG, og = t / PG;
      float acc[4][4];
#pragma unroll
      for (int j = 0; j < 4; ++j) {
        float bj = b2v[og * 4 + j];
#pragma unroll
        for (int i = 0; i < 4; ++i) acc[i][j] = bj;
      }
      for (int cin = 0; cin < CMID; cin += 4) {
        float4 xr[4], wr[4];
#pragma unroll
        for (int i = 0; i < 4; ++i)
          xr[i] = *(const float4*)&Y1s[(pg * 4 + i) * Y1P + cin];
#pragma unroll
        for (int j = 0; j < 4; ++j)
          wr[j] = *(const float4*)&w2[(size_t)(og * 4 + j) * CMID + cin];
#pragma unroll
        for (int i = 0; i < 4; ++i)
#pragma unroll
          for (int j = 0; j < 4; ++j) {
            acc[i][j] += xr[i].x * wr[j].x;
            acc[i][j] += xr[i].y * wr[j].y;
            acc[i][j] += xr[i].z * wr[j].z;
            acc[i][j] += xr[i].w * wr[j].w;
          }
      }
#pragma unroll
      for (int i = 0; i < 4; ++i) {
        int bn = bn0 + pg * 4 + i;
#pragma unroll
        for (int j = 0; j < 4; ++j) {
          float v = fmaxf(acc[i][j], 0.0f);
          hout[(size_t)bn * COUT + og * 4 + j] = v;
          if constexpr (NPQ > 0) Hb[(pg * 4 + i) * HP + og * 4 + j] = f2bf(v);
        }
      }
    }
  }
  if constexpr (NPQ > 0) {
    __syncthreads();
    const int lane = tid & 63;
    const int wv = tid >> 6;
    constexpr int NT = NPQ / 16;
    constexpr int JOBS = (TP / 16) * NT;
    constexpr int KS = COUT / 32;
    for (int job = wv; job < JOBS; job += 4) {
      int mt = job / NT, nt = job - mt * NT;
      int row = mt * 16 + (lane & 15);
      int ncol = nt * 16 + (lane & 15);
      int kb = (lane >> 4) * 8;
      f32x4 acc = {0.f, 0.f, 0.f, 0.f};
      const u16* ap = &Hb[row * HP + kb];
      const u16* bp = &wpq[(size_t)ncol * COUT + kb];
#pragma unroll
      for (int ks = 0; ks < KS; ++ks) {
        short8 a = *(const short8*)(ap + ks * 32);
        short8 bb = *(const short8*)(bp + ks * 32);
        acc = __builtin_amdgcn_mfma_f32_16x16x32_bf16(a, bb, acc, 0, 0, 0);
      }
      int m0 = mt * 16 + (lane >> 4) * 4;
#pragma unroll
      for (int r = 0; r < 4; ++r)
        pq[(size_t)(bn0 + m0 + r) * NPQ + ncol] = f2bf(acc[r]);
    }
  }
}

// ---------------- fusion conv (384->512) via MFMA + relu + global max pool ----------------
__global__ __launch_bounds__(256) void fuse_pool_mfma(
    const float* __restrict__ h1, const float* __restrict__ h2,
    const float* __restrict__ h3, const u16* __restrict__ fwb,
    const float* __restrict__ fb, int* __restrict__ pooled) {
  constexpr int CIN = 384, COUT = 512, TP = 32;
  constexpr int XPB = CIN + 8;
  __shared__ u16 Xs[TP * XPB];
  __shared__ int pmax[COUT];
  const int tid = threadIdx.x;
  const int lane = tid & 63;
  const int wv = tid >> 6;
  const int bn0 = blockIdx.x * TP;
  const int b = bn0 >> 10;
  for (int i = tid; i < COUT; i += 256) pmax[i] = 0;
  constexpr int KC = CIN / 8;
  for (int ch = tid; ch < TP * KC; ch += 256) {
    int p = ch / KC, kc = ch - p * KC;
    int k0 = kc * 8;
    int bn = bn0 + p;
    const float* src;
    if (k0 < 64) src = &h1[(size_t)bn * 64 + k0];
    else if (k0 < 192) src = &h2[(size_t)bn * 128 + (k0 - 64)];
    else src = &h3[(size_t)bn * 192 + (k0 - 192)];
    float4 f0 = *(const float4*)src;
    float4 f1 = *(const float4*)(src + 4);
    ushort8 r;
    r[0] = f2bf(f0.x); r[1] = f2bf(f0.y); r[2] = f2bf(f0.z); r[3] = f2bf(f0.w);
    r[4] = f2bf(f1.x); r[5] = f2bf(f1.y); r[6] = f2bf(f1.z); r[7] = f2bf(f1.w);
    *(ushort8*)&Xs[p * XPB + k0] = r;
  }
  __syncthreads();
  constexpr int NT = COUT / 16;
  constexpr int JOBS = (TP / 16) * NT;
  constexpr int KS = CIN / 32;
  for (int job = wv; job < JOBS; job += 4) {
    int mt = job / NT, nt = job - mt * NT;
    int row = mt * 16 + (lane & 15);
    int ncol = nt * 16 + (lane & 15);
    int kb = (lane >> 4) * 8;
    f32x4 acc = {0.f, 0.f, 0.f, 0.f};
    const u16* ap = &Xs[row * XPB + kb];
    const u16* bp = &fwb[(size_t)ncol * CIN + kb];
#pragma unroll
    for (int ks = 0; ks < KS; ++ks) {
      short8 a = *(const short8*)(ap + ks * 32);
      short8 bb = *(const short8*)(bp + ks * 32);
      acc = __builtin_amdgcn_mfma_f32_16x16x32_bf16(a, bb, acc, 0, 0, 0);
    }
    float bias = fb[ncol];
    float v = fmaxf(fmaxf(acc[0], acc[1]), fmaxf(acc[2], acc[3]));
    v = fmaxf(v + bias, 0.0f);
    v = fmaxf(v, __shfl_xor(v, 16));
    v = fmaxf(v, __shfl_xor(v, 32));
    if (lane < 16) atomicMax(&pmax[ncol], __float_as_int(v));
  }
  __syncthreads();
  for (int i = tid; i < COUT; i += 256)
    atomicMax(&pooled[b * COUT + i], pmax[i]);
}

// ---------------- prediction head (blocks 0..7) + inputs echo copy (blocks 8+) ----------------
__global__ __launch_bounds__(256) void head_kernel(
    const int* __restrict__ pooledi, const float* __restrict__ p1w,
    const float* __restrict__ p1b, const float* __restrict__ p2w,
    const float* __restrict__ p2b, const float* __restrict__ p3w,
    const float* __restrict__ p3b, const float* __restrict__ inputs,
    float* __restrict__ out) {
  const int tid = threadIdx.x;
  if (blockIdx.x >= BDIM) {
    int idx = (blockIdx.x - BDIM) * 256 + tid;
    if (idx < (BDIM * 3 * NDIM) / 4) {
      const float4* src = (const float4*)inputs;
      float4* dst = (float4*)(out + BDIM * 40);
      dst[idx] = src[idx];
    }
    return;
  }
  __shared__ float xs[512], y1[256], y2[128];
  const int b = blockIdx.x;
  for (int i = tid; i < 512; i += 256) xs[i] = __int_as_float(pooledi[b * 512 + i]);
  __syncthreads();
  {
    float acc = p1b[tid];
    for (int c = 0; c < 512; ++c) acc += xs[c] * p1w[tid * 512 + c];
    y1[tid] = fmaxf(acc, 0.0f);
  }
  __syncthreads();
  if (tid < 128) {
    float acc = p2b[tid];
    for (int c = 0; c < 256; ++c) acc += y1[c] * p2w[tid * 256 + c];
    y2[tid] = fmaxf(acc, 0.0f);
  }
  __syncthreads();
  if (tid < 40) {
    float acc = p3b[tid];
    for (int c = 0; c < 128; ++c) acc += y2[c] * p3w[tid * 128 + c];
    out[b * 40 + tid] = acc;
  }
}

extern "C" void kernel_launch(void* const* d_in, const int* in_sizes, int n_in,
                              void* d_out, int out_size, void* d_ws,
                              size_t ws_size, hipStream_t stream) {
  const float* inputs = (const float*)d_in[0];
  const float* he_w1 = (const float*)d_in[1];
  const float* he_b1 = (const float*)d_in[2];
  const float* he_w2 = (const float*)d_in[3];
  const float* he_b2 = (const float*)d_in[4];
  const float* hn_w1 = (const float*)d_in[5];
  const float* hn_b1 = (const float*)d_in[6];
  const float* hn_w2 = (const float*)d_in[7];
  const float* hn_b2 = (const float*)d_in[8];
  const float* b1e_w1 = (const float*)d_in[9];
  const float* b1e_b1 = (const float*)d_in[10];
  const float* b1e_w2 = (const float*)d_in[11];
  const float* b1e_b2 = (const float*)d_in[12];
  const float* b1n_w1 = (const float*)d_in[13];
  const float* b1n_b1 = (const float*)d_in[14];
  const float* b1n_w2 = (const float*)d_in[15];
  const float* b1n_b2 = (const float*)d_in[16];
  const float* b2e_w1 = (const float*)d_in[17];
  const float* b2e_b1 = (const float*)d_in[18];
  const float* b2e_w2 = (const float*)d_in[19];
  const float* b2e_b2 = (const float*)d_in[20];
  const float* b2n_w1 = (const float*)d_in[21];
  const float* b2n_b1 = (const float*)d_in[22];
  const float* b2n_w2 = (const float*)d_in[23];
  const float* b2n_b2 = (const float*)d_in[24];
  const float* f_w = (const float*)d_in[25];
  const float* f_b = (const float*)d_in[26];
  const float* p1_w = (const float*)d_in[27];
  const float* p1_b = (const float*)d_in[28];
  const float* p2_w = (const float*)d_in[29];
  const float* p2_b = (const float*)d_in[30];
  const float* p3_w = (const float*)d_in[31];
  const float* p3_b = (const float*)d_in[32];
  float* out = (float*)d_out;

  char* ws = (char*)d_ws;
  size_t off = 0;
  auto alloc = [&](size_t bytes) {
    void* p = ws + off;
    off += (bytes + 255) & ~(size_t)255;
    return p;
  };
  int* nn = (int*)alloc((size_t)BDIM * NDIM * KNN * 4);
  float* m1 = (float*)alloc((size_t)BDIM * NDIM * 64 * 4);
  float* h1 = (float*)alloc((size_t)BDIM * NDIM * 64 * 4);
  u16* e1 = (u16*)alloc((size_t)BDIM * NDIM * KNN * 64 * 2);   // bf16
  float* m2 = (float*)alloc((size_t)BDIM * NDIM * 128 * 4);
  float* h2 = (float*)alloc((size_t)BDIM * NDIM * 128 * 4);
  u16* e2 = (u16*)alloc((size_t)BDIM * NDIM * KNN * 128 * 2);  // bf16
  float* m3 = (float*)alloc((size_t)BDIM * NDIM * 192 * 4);
  float* h3 = (float*)alloc((size_t)BDIM * NDIM * 192 * 4);
  u16* pq2 = (u16*)alloc((size_t)BDIM * NDIM * 96 * 2);        // bf16
  u16* pq3 = (u16*)alloc((size_t)BDIM * NDIM * 192 * 2);       // bf16
  int* pooled = (int*)alloc((size_t)BDIM * 512 * 4);
  u16* w1b3e = (u16*)alloc((size_t)96 * 128 * 2);
  u16* wpq3 = (u16*)alloc((size_t)192 * 128 * 2);
  u16* w2b3 = (u16*)alloc((size_t)192 * 96 * 2);
  u16* w1b2e = (u16*)alloc((size_t)48 * 64 * 2);
  u16* wpq2 = (u16*)alloc((size_t)96 * 64 * 2);
  u16* w2b2 = (u16*)alloc((size_t)128 * 64 * 2);
  float* w1p1 = (float*)alloc((size_t)32 * 68 * 4);
  u16* fwb = (u16*)alloc((size_t)512 * 384 * 2);
  u16* w1b1 = (u16*)alloc((size_t)32 * 32 * 2);
  u16* w2b1 = (u16*)alloc((size_t)64 * 32 * 2);

  knn_wcvt<<<BDIM * 256 + 768, 256, 0, stream>>>(
      inputs, nn, b2e_w1, b2e_w2, b1e_w1, b1e_w2, hn_w1, f_w, he_w1, he_w2,
      w1b3e, wpq3, w2b3, w1b2e, wpq2, w2b2, w1p1, fwb, w1b1, w2b1, pooled);

  edge_mfma<4, 32, 32, 64, true, true><<<BDIM * NDIM / 4, 256, 0, stream>>>(
      nullptr, inputs, nn, w1b1, he_b1, w2b1, he_b2, nullptr, e1, m1);
  node_conv<64, 3, 64, 68, 32, 64, 96, true><<<BDIM * NDIM / 64, 256, 0, stream>>>(
      nullptr, inputs, m1, w1p1, hn_b1, hn_w2, hn_b2, h1, wpq2, pq2);

  edge_mfma<4, 64, 48, 128, true, false><<<BDIM * NDIM / 4, 256, 0, stream>>>(
      e1, nullptr, nn, w1b2e, b1e_b1, w2b2, b1e_b2, pq2, e2, m2);
  node_conv<32, 64, 128, 192, 48, 128, 192, false><<<BDIM * NDIM / 32, 256, 0, stream>>>(
      h1, nullptr, m2, b1n_w1, b1n_b1, b1n_w2, b1n_b2, h2, wpq3, pq3);

  edge_mfma<4, 128, 96, 192, false, false><<<BDIM * NDIM / 4, 256, 0, stream>>>(
      e2, nullptr, nn, w1b3e, b2e_b1, w2b3, b2e_b2, pq3, nullptr, m3);
  node_conv<16, 128, 192, 320, 96, 192, 0, false><<<BDIM * NDIM / 16, 256, 0, stream>>>(
      h2, nullptr, m3, b2n_w1, b2n_b1, b2n_w2, b2n_b2, h3, nullptr, nullptr);

  fuse_pool_mfma<<<BDIM * NDIM / 32, 256, 0, stream>>>(h1, h2, h3, fwb, f_b,
                                                       pooled);
  head_kernel<<<BDIM + 24, 256, 0, stream>>>(pooled, p1_w, p1_b, p2_w, p2_b,
                                             p3_w, p3_b, inputs, out);
}

// Round 14
// 247.588 us; speedup vs baseline: 7.2995x; 1.0379x over previous
//
#include <hip/hip_runtime.h>

#define BDIM 8
#define NDIM 1024
#define KNN 20

typedef unsigned short u16;
typedef float f32x4 __attribute__((ext_vector_type(4)));
typedef short short8 __attribute__((ext_vector_type(8)));
typedef unsigned short ushort8 __attribute__((ext_vector_type(8)));

__device__ inline u16 f2bf(float f) {
  unsigned u = __float_as_uint(f);
  unsigned r = (u + 0x7fffu + ((u >> 16) & 1u)) >> 16;
  return (u16)r;
}
__device__ inline float bf2f(u16 v) {
  return __uint_as_float(((unsigned)v) << 16);
}

// ---- merged: KNN (blocks 0..2047, bit-exact) + weight prep (blocks 2048+) ----
__global__ __launch_bounds__(256) void knn_wcvt(
    const float* __restrict__ x, int* __restrict__ nn,
    const float* __restrict__ w1_3, const float* __restrict__ w2_3,
    const float* __restrict__ w1_2, const float* __restrict__ w2_2,
    const float* __restrict__ hn_w1, const float* __restrict__ f_w,
    const float* __restrict__ he_w1, const float* __restrict__ he_w2,
    u16* __restrict__ w1b3e, u16* __restrict__ wpq3, u16* __restrict__ w2b3,
    u16* __restrict__ w1b2e, u16* __restrict__ wpq2, u16* __restrict__ w2b2,
    float* __restrict__ w1p1, u16* __restrict__ fwb,
    u16* __restrict__ w1b1, u16* __restrict__ w2b1, int* __restrict__ pooled) {
  const int tid = threadIdx.x;
  if (blockIdx.x >= BDIM * 256) {
    const int idx = (blockIdx.x - BDIM * 256) * 256 + tid;
    if (idx < 512 * 384) fwb[idx] = f2bf(f_w[idx]);
    if (idx < 96 * 128) {
      int oc = idx >> 7, c = idx & 127;
      w1b3e[idx] = f2bf(w1_3[oc * 384 + c]);
    }
    if (idx < 192 * 128) {
      int n = idx >> 7, c = idx & 127;
      wpq3[idx] = f2bf(n < 96 ? w1_3[n * 384 + 128 + c]
                              : w1_3[(n - 96) * 384 + 256 + c]);
    }
    if (idx < 192 * 96) w2b3[idx] = f2bf(w2_3[idx]);
    if (idx < 48 * 64) {
      int oc = idx >> 6, c = idx & 63;
      w1b2e[idx] = f2bf(w1_2[oc * 192 + c]);
    }
    if (idx < 96 * 64) {
      int n = idx >> 6, c = idx & 63;
      wpq2[idx] = f2bf(n < 48 ? w1_2[n * 192 + 64 + c]
                              : w1_2[(n - 48) * 192 + 128 + c]);
    }
    if (idx < 128 * 64) {
      int oc = idx >> 6, i = idx & 63;
      w2b2[idx] = (i < 48) ? f2bf(w2_2[oc * 48 + i]) : (u16)0;
    }
    if (idx < 32 * 68) {
      int oc = idx / 68, c = idx - oc * 68;
      w1p1[idx] = (c < 67) ? hn_w1[oc * 67 + c] : 0.0f;
    }
    if (idx < 32 * 32) {
      int oc = idx >> 5, c = idx & 31;
      w1b1[idx] = (c < 12) ? f2bf(he_w1[oc * 12 + c]) : (u16)0;
    }
    if (idx < 64 * 32) w2b1[idx] = f2bf(he_w2[idx]);
    if (idx < BDIM * 512) pooled[idx] = 0;
    return;
  }
  {
#pragma clang fp contract(off)
    __shared__ float xs0[NDIM], xs1[NDIM], xs2[NDIM], sq[NDIM];
    const int lane = tid & 63;
    const int w = tid >> 6;
    const int b = blockIdx.x >> 8;
    const int n = ((blockIdx.x & 255) << 2) + w;
    for (int i = tid; i < NDIM; i += 256) {
      float a0 = x[(b * 3 + 0) * NDIM + i];
      float a1 = x[(b * 3 + 1) * NDIM + i];
      float a2 = x[(b * 3 + 2) * NDIM + i];
      xs0[i] = a0; xs1[i] = a1; xs2[i] = a2;
      sq[i] = (a0 * a0 + a1 * a1) + a2 * a2;
    }
    __syncthreads();
    const float xn0 = xs0[n], xn1 = xs1[n], xn2 = xs2[n], sqn = sq[n];
    float dl[16];
#pragma unroll
    for (int t = 0; t < 16; ++t) {
      int m = t * 64 + lane;
      float dot = (xn0 * xs0[m] + xn1 * xs1[m]) + xn2 * xs2[m];
      dl[t] = (sqn - 2.0f * dot) + sq[m];
    }
    int* nnrow = &nn[(b * NDIM + n) * KNN];
    for (int r = 0; r < KNN; ++r) {
      float bd = dl[0];
      int bt = 0;
#pragma unroll
      for (int t = 1; t < 16; ++t) {
        if (dl[t] < bd) { bd = dl[t]; bt = t; }
      }
      int bi = bt * 64 + lane;
#pragma unroll
      for (int off = 1; off < 64; off <<= 1) {
        float pd = __shfl_xor(bd, off);
        int pi = __shfl_xor(bi, off);
        if (pd < bd || (pd == bd && pi < bi)) { bd = pd; bi = pi; }
      }
      if (lane == 0) nnrow[r] = bi;
      if ((bi & 63) == lane) {
        int wt = bi >> 6;
#pragma unroll
        for (int t = 0; t < 16; ++t) {
          if (t == wt) dl[t] = 3.4e38f;
        }
      }
    }
  }
}

// ---- MFMA edge MP v9: QY buffer aliasing (Q staged, overwritten by Y1), 2 barriers ----
template <int PTS, int CE, int CMID, int COUT, bool WRITE_E, bool FIRST>
__global__ __launch_bounds__(256) void edge_mfma(
    const u16* __restrict__ eprev, const float* __restrict__ finput,
    const int* __restrict__ nnb, const u16* __restrict__ w1b,
    const float* __restrict__ b1v, const u16* __restrict__ w2b,
    const float* __restrict__ b2v, const u16* __restrict__ pq,
    u16* __restrict__ eout, float* __restrict__ mout) {
  constexpr int K2 = (CMID + 31) & ~31;
  constexpr int NPQ = 2 * CMID;
  constexpr int MT = PTS * KNN;       // 80 edges
  constexpr int MTL = MT / 16;        // 5 M-tiles (exact)
  constexpr int XPB = CE + 8;
  constexpr int QYP = K2 + 8;         // unified Q / Y1 pitch
  __shared__ u16 Xs[MT * XPB];
  __shared__ u16 QY[MT * QYP];        // Q staged here, then overwritten by Y1
  __shared__ float pld[FIRST ? 8 : PTS * CMID];
  const int tid = threadIdx.x;
  const int lane = tid & 63;
  const int wv = tid >> 6;
  const int q = lane >> 4;
  const int bn0 = blockIdx.x * PTS;
  const int b = bn0 >> 10;
  // ---- bulk staging (high MLP, coalesced / pure copies); nn read direct ----
  if constexpr (FIRST) {
    for (int idx = tid; idx < MT * (CE / 8); idx += 256) {
      int p = idx / (CE / 8), kc = idx - p * (CE / 8);
      int k0 = kc * 8;
      int bn = bn0 + p / KNN;
      int n = bn & (NDIM - 1);
      int j = nnb[(size_t)bn0 * KNN + p];
      ushort8 r;
#pragma unroll
      for (int t = 0; t < 8; ++t) {
        int c = k0 + t;
        float v = 0.0f;
        if (c < 3) v = finput[(b * 3 + c) * NDIM + n];
        else if (c < 6)
          v = finput[(b * 3 + c - 3) * NDIM + n] -
              finput[(b * 3 + c - 3) * NDIM + j];
        else if (c < 9) v = finput[(b * 3 + c - 6) * NDIM + n];
        else if (c < 12) v = finput[(b * 3 + c - 9) * NDIM + j];
        r[t] = f2bf(v);
      }
      *(ushort8*)&Xs[p * XPB + k0] = r;
    }
  } else {
    constexpr int KC = CE / 8;
    for (int ch = tid; ch < MT * KC; ch += 256) {
      int p = ch / KC, kc = ch - p * KC;
      int k0 = kc * 8;
      *(uint4*)&Xs[p * XPB + k0] =
          *(const uint4*)&eprev[((size_t)blockIdx.x * MT + p) * CE + k0];
    }
    constexpr int QC = CMID / 8;
    for (int i = tid; i < MT * QC; i += 256) {
      int p = i / QC, c8 = (i - p * QC) * 8;
      int j = nnb[(size_t)bn0 * KNN + p];
      *(uint4*)&QY[p * QYP + c8] =
          *(const uint4*)&pq[((size_t)(b << 10) + j) * NPQ + CMID + c8];
    }
    if constexpr (K2 != CMID) {
      constexpr int PC = (K2 - CMID) / 8;  // pad chunks per row
      for (int i = tid; i < MT * PC; i += 256) {
        int p = i / PC, c8 = CMID + (i - p * PC) * 8;
        uint4 z = {0, 0, 0, 0};
        *(uint4*)&QY[p * QYP + c8] = z;
      }
    }
    for (int i = tid; i < PTS * CMID; i += 256) {
      int pt = i / CMID, c = i - pt * CMID;
      pld[i] = bf2f(pq[(size_t)(bn0 + pt) * NPQ + c]) + b1v[c];
    }
  }
  __syncthreads();
  // ---- conv1: Xs @ W1^T (+P+Q folded) -> relu -> QY (in-place over Q) ----
  {
    constexpr int NT1 = CMID / 16;
    constexpr int J1 = MTL * NT1;
    constexpr int KS1 = CE / 32;
    for (int job = wv; job < J1; job += 4) {
      int mt = job / NT1, nt = job - mt * NT1;
      int row = mt * 16 + (lane & 15);
      int ncol = nt * 16 + (lane & 15);
      int kb = q * 8;
      f32x4 acc = {0.f, 0.f, 0.f, 0.f};
      const u16* ap = &Xs[row * XPB + kb];
      const u16* bp = &w1b[(size_t)ncol * CE + kb];
#pragma unroll
      for (int ks = 0; ks < KS1; ++ks) {
        short8 a = *(const short8*)(ap + ks * 32);
        short8 bb = *(const short8*)(bp + ks * 32);
        acc = __builtin_amdgcn_mfma_f32_16x16x32_bf16(a, bb, acc, 0, 0, 0);
      }
      int m0 = mt * 16 + q * 4;
      if constexpr (FIRST) {
        float bias = b1v[ncol];
#pragma unroll
        for (int r = 0; r < 4; ++r) {
          float yv = fmaxf(acc[r] + bias, 0.0f);
          QY[(m0 + r) * QYP + ncol] = f2bf(yv);
        }
      } else {
        int pt = m0 / KNN;  // whole 4-row group in one point (4 | 20)
        float padd = pld[pt * CMID + ncol];
#pragma unroll
        for (int r = 0; r < 4; ++r) {
          int m = m0 + r;
          float qadd = bf2f(QY[m * QYP + ncol]);  // read Q, then overwrite
          float yv = fmaxf(acc[r] + padd + qadd, 0.0f);
          QY[m * QYP + ncol] = f2bf(yv);
        }
      }
    }
  }
  __syncthreads();
  // ---- conv2: one wave owns all M-tiles per N-tile; fp32 m-sum, const-folded pt map ----
  {
    constexpr int NT2 = COUT / 16;
    constexpr int KS2 = K2 / 32;
    for (int nt = wv; nt < NT2; nt += 4) {
      int ncol = nt * 16 + (lane & 15);
      int kb = q * 8;
      short8 bfrag[KS2];
      const u16* bp = &w2b[(size_t)ncol * K2 + kb];
#pragma unroll
      for (int ks = 0; ks < KS2; ++ks)
        bfrag[ks] = *(const short8*)(bp + ks * 32);
      float bias = b2v[ncol];
      float s[PTS];
#pragma unroll
      for (int pt = 0; pt < PTS; ++pt) s[pt] = 0.0f;
#pragma unroll
      for (int mt = 0; mt < MTL; ++mt) {
        f32x4 acc = {0.f, 0.f, 0.f, 0.f};
        const u16* ap = &QY[(mt * 16 + (lane & 15)) * QYP + kb];
#pragma unroll
        for (int ks = 0; ks < KS2; ++ks) {
          short8 a = *(const short8*)(ap + ks * 32);
          acc = __builtin_amdgcn_mfma_f32_16x16x32_bf16(a, bfrag[ks], acc, 0, 0, 0);
        }
        int m0 = mt * 16 + q * 4;
        float part = 0.0f;
#pragma unroll
        for (int r = 0; r < 4; ++r) {
          float yv = fmaxf(acc[r] + bias, 0.0f);
          if (WRITE_E)
            eout[((size_t)blockIdx.x * MT + m0 + r) * COUT + ncol] = f2bf(yv);
          part += yv;
        }
        int ptA = (4 * mt) / 5;
        int ptB = (4 * mt + 3) / 5;
        int qb = 5 * ptB - 4 * mt;
#pragma unroll
        for (int pt2 = 0; pt2 < PTS; ++pt2) {
          if (pt2 == ptA && ptA == ptB) s[pt2] += part;
          else if (pt2 == ptA) s[pt2] += (q < qb) ? part : 0.0f;
          else if (pt2 == ptB) s[pt2] += (q < qb) ? 0.0f : part;
        }
      }
#pragma unroll
      for (int pt = 0; pt < PTS; ++pt) {
        float sv = s[pt];
        sv += __shfl_xor(sv, 16);
        sv += __shfl_xor(sv, 32);
        if (lane < 16)
          mout[(size_t)(bn0 + pt) * COUT + nt * 16 + lane] = sv;
      }
    }
  }
}

// ---- node conv: fp32 microtile GEMM + optional fused PQ MFMA phase ----
template <int TP, int CH, int CM, int CINP, int CMID, int COUT, int NPQ, bool FIRSTH>
__global__ __launch_bounds__(256) void node_conv(
    const float* __restrict__ h, const float* __restrict__ inputs,
    const float* __restrict__ mbuf, const float* __restrict__ w1p,
    const float* __restrict__ b1v, const float* __restrict__ w2,
    const float* __restrict__ b2v, float* __restrict__ hout,
    const u16* __restrict__ wpq, u16* __restrict__ pq) {
  constexpr int CIN = CH + CM;
  constexpr int XP = CINP + 4;
  constexpr int Y1P = CMID + 4;
  constexpr int PG = TP / 4;
  constexpr int HP = COUT + 8;
  __shared__ float Xs[TP * XP];
  __shared__ float Y1s[TP * Y1P];
  __shared__ u16 Hb[(NPQ > 0) ? TP * HP : 8];
  const int tid = threadIdx.x;
  const int bn0 = blockIdx.x * TP;
  if constexpr (FIRSTH) {
    for (int idx = tid; idx < TP * CIN; idx += 256) {
      int p = idx / CIN, c = idx - p * CIN;
      int bn = bn0 + p;
      int b = bn >> 10, n = bn & (NDIM - 1);
      Xs[p * XP + c] = (c < CH) ? inputs[(b * 3 + c) * NDIM + n]
                                : mbuf[(size_t)bn * CM + (c - CH)];
    }
    if constexpr (CINP > CIN) {
      constexpr int PAD = CINP - CIN;
      for (int idx = tid; idx < TP * PAD; idx += 256) {
        int p = idx / PAD, c = CIN + idx % PAD;
        Xs[p * XP + c] = 0.0f;
      }
    }
  } else {
    constexpr int C4 = CIN / 4;
    for (int idx = tid; idx < TP * C4; idx += 256) {
      int p = idx / C4, c = (idx - p * C4) * 4;
      int bn = bn0 + p;
      float4 v = (c < CH) ? *(const float4*)&h[(size_t)bn * CH + c]
                          : *(const float4*)&mbuf[(size_t)bn * CM + (c - CH)];
      *(float4*)&Xs[p * XP + c] = v;
    }
  }
  __syncthreads();
  {
    constexpr int NT1 = PG * (CMID / 4);
    for (int t = tid; t < NT1; t += 256) {
      int pg = t % PG, og = t / PG;
      float acc[4][4];
#pragma unroll
      for (int j = 0; j < 4; ++j) {
        float bj = b1v[og * 4 + j];
#pragma unroll
        for (int i = 0; i < 4; ++i) acc[i][j] = bj;
      }
      for (int cin = 0; cin < CINP; cin += 4) {
        float4 xr[4], wr[4];
#pragma unroll
        for (int i = 0; i < 4; ++i)
          xr[i] = *(const float4*)&Xs[(pg * 4 + i) * XP + cin];
#pragma unroll
        for (int j = 0; j < 4; ++j)
          wr[j] = *(const float4*)&w1p[(size_t)(og * 4 + j) * CINP + cin];
#pragma unroll
        for (int i = 0; i < 4; ++i)
#pragma unroll
          for (int j = 0; j < 4; ++j) {
            acc[i][j] += xr[i].x * wr[j].x;
            acc[i][j] += xr[i].y * wr[j].y;
            acc[i][j] += xr[i].z * wr[j].z;
            acc[i][j] += xr[i].w * wr[j].w;
          }
      }
#pragma unroll
      for (int i = 0; i < 4; ++i)
#pragma unroll
        for (int j = 0; j < 4; ++j)
          Y1s[(pg * 4 + i) * Y1P + og * 4 + j] = fmaxf(acc[i][j], 0.0f);
    }
  }
  __syncthreads();
  {
    constexpr int NT2 = PG * (COUT / 4);
    for (int t = tid; t < NT2; t += 256) {
      int pg = t % PG, og = t / PG;
      float acc[4][4];
#pragma unroll
      for (int j = 0; j < 4; ++j) {
        float bj = b2v[og * 4 + j];
#pragma unroll
        for (int i = 0; i < 4; ++i) acc[i][j] = bj;
      }
      for (int cin = 0; cin < CMID; cin += 4) {
        float4 xr[4], wr[4];
#pragma unroll
        for (int i = 0; i < 4; ++i)
          xr[i] = *(const float4*)&Y1s[(pg * 4 + i) * Y1P + cin];
#pragma unroll
        for (int j = 0; j < 4; ++j)
          wr[j] = *(const float4*)&w2[(size_t)(og * 4 + j) * CMID + cin];
#pragma unroll
        for (int i = 0; i < 4; ++i)
#pragma unroll
          for (int j = 0; j < 4; ++j) {
            acc[i][j] += xr[i].x * wr[j].x;
            acc[i][j] += xr[i].y * wr[j].y;
            acc[i][j] += xr[i].z * wr[j].z;
            acc[i][j] += xr[i].w * wr[j].w;
          }
      }
#pragma unroll
      for (int i = 0; i < 4; ++i) {
        int bn = bn0 + pg * 4 + i;
#pragma unroll
        for (int j = 0; j < 4; ++j) {
          float v = fmaxf(acc[i][j], 0.0f);
          hout[(size_t)bn * COUT + og * 4 + j] = v;
          if constexpr (NPQ > 0) Hb[(pg * 4 + i) * HP + og * 4 + j] = f2bf(v);
        }
      }
    }
  }
  if constexpr (NPQ > 0) {
    __syncthreads();
    const int lane = tid & 63;
    const int wv = tid >> 6;
    constexpr int NT = NPQ / 16;
    constexpr int JOBS = (TP / 16) * NT;
    constexpr int KS = COUT / 32;
    for (int job = wv; job < JOBS; job += 4) {
      int mt = job / NT, nt = job - mt * NT;
      int row = mt * 16 + (lane & 15);
      int ncol = nt * 16 + (lane & 15);
      int kb = (lane >> 4) * 8;
      f32x4 acc = {0.f, 0.f, 0.f, 0.f};
      const u16* ap = &Hb[row * HP + kb];
      const u16* bp = &wpq[(size_t)ncol * COUT + kb];
#pragma unroll
      for (int ks = 0; ks < KS; ++ks) {
        short8 a = *(const short8*)(ap + ks * 32);
        short8 bb = *(const short8*)(bp + ks * 32);
        acc = __builtin_amdgcn_mfma_f32_16x16x32_bf16(a, bb, acc, 0, 0, 0);
      }
      int m0 = mt * 16 + (lane >> 4) * 4;
#pragma unroll
      for (int r = 0; r < 4; ++r)
        pq[(size_t)(bn0 + m0 + r) * NPQ + ncol] = f2bf(acc[r]);
    }
  }
}

// ---------------- fusion conv (384->512) via MFMA + relu + global max pool ----------------
__global__ __launch_bounds__(256) void fuse_pool_mfma(
    const float* __restrict__ h1, const float* __restrict__ h2,
    const float* __restrict__ h3, const u16* __restrict__ fwb,
    const float* __restrict__ fb, int* __restrict__ pooled) {
  constexpr int CIN = 384, COUT = 512, TP = 32;
  constexpr int XPB = CIN + 8;
  __shared__ u16 Xs[TP * XPB];
  __shared__ int pmax[COUT];
  const int tid = threadIdx.x;
  const int lane = tid & 63;
  const int wv = tid >> 6;
  const int bn0 = blockIdx.x * TP;
  const int b = bn0 >> 10;
  for (int i = tid; i < COUT; i += 256) pmax[i] = 0;
  constexpr int KC = CIN / 8;
  for (int ch = tid; ch < TP * KC; ch += 256) {
    int p = ch / KC, kc = ch - p * KC;
    int k0 = kc * 8;
    int bn = bn0 + p;
    const float* src;
    if (k0 < 64) src = &h1[(size_t)bn * 64 + k0];
    else if (k0 < 192) src = &h2[(size_t)bn * 128 + (k0 - 64)];
    else src = &h3[(size_t)bn * 192 + (k0 - 192)];
    float4 f0 = *(const float4*)src;
    float4 f1 = *(const float4*)(src + 4);
    ushort8 r;
    r[0] = f2bf(f0.x); r[1] = f2bf(f0.y); r[2] = f2bf(f0.z); r[3] = f2bf(f0.w);
    r[4] = f2bf(f1.x); r[5] = f2bf(f1.y); r[6] = f2bf(f1.z); r[7] = f2bf(f1.w);
    *(ushort8*)&Xs[p * XPB + k0] = r;
  }
  __syncthreads();
  constexpr int NT = COUT / 16;
  constexpr int JOBS = (TP / 16) * NT;
  constexpr int KS = CIN / 32;
  for (int job = wv; job < JOBS; job += 4) {
    int mt = job / NT, nt = job - mt * NT;
    int row = mt * 16 + (lane & 15);
    int ncol = nt * 16 + (lane & 15);
    int kb = (lane >> 4) * 8;
    f32x4 acc = {0.f, 0.f, 0.f, 0.f};
    const u16* ap = &Xs[row * XPB + kb];
    const u16* bp = &fwb[(size_t)ncol * CIN + kb];
#pragma unroll
    for (int ks = 0; ks < KS; ++ks) {
      short8 a = *(const short8*)(ap + ks * 32);
      short8 bb = *(const short8*)(bp + ks * 32);
      acc = __builtin_amdgcn_mfma_f32_16x16x32_bf16(a, bb, acc, 0, 0, 0);
    }
    float bias = fb[ncol];
    float v = fmaxf(fmaxf(acc[0], acc[1]), fmaxf(acc[2], acc[3]));
    v = fmaxf(v + bias, 0.0f);
    v = fmaxf(v, __shfl_xor(v, 16));
    v = fmaxf(v, __shfl_xor(v, 32));
    if (lane < 16) atomicMax(&pmax[ncol], __float_as_int(v));
  }
  __syncthreads();
  for (int i = tid; i < COUT; i += 256)
    atomicMax(&pooled[b * COUT + i], pmax[i]);
}

// ---------------- prediction head (blocks 0..7) + inputs echo copy (blocks 8+) ----------------
__global__ __launch_bounds__(256) void head_kernel(
    const int* __restrict__ pooledi, const float* __restrict__ p1w,
    const float* __restrict__ p1b, const float* __restrict__ p2w,
    const float* __restrict__ p2b, const float* __restrict__ p3w,
    const float* __restrict__ p3b, const float* __restrict__ inputs,
    float* __restrict__ out) {
  const int tid = threadIdx.x;
  if (blockIdx.x >= BDIM) {
    int idx = (blockIdx.x - BDIM) * 256 + tid;
    if (idx < (BDIM * 3 * NDIM) / 4) {
      const float4* src = (const float4*)inputs;
      float4* dst = (float4*)(out + BDIM * 40);
      dst[idx] = src[idx];
    }
    return;
  }
  __shared__ float xs[512], y1[256], y2[128];
  const int b = blockIdx.x;
  for (int i = tid; i < 512; i += 256) xs[i] = __int_as_float(pooledi[b * 512 + i]);
  __syncthreads();
  {
    float acc = p1b[tid];
    for (int c = 0; c < 512; ++c) acc += xs[c] * p1w[tid * 512 + c];
    y1[tid] = fmaxf(acc, 0.0f);
  }
  __syncthreads();
  if (tid < 128) {
    float acc = p2b[tid];
    for (int c = 0; c < 256; ++c) acc += y1[c] * p2w[tid * 256 + c];
    y2[tid] = fmaxf(acc, 0.0f);
  }
  __syncthreads();
  if (tid < 40) {
    float acc = p3b[tid];
    for (int c = 0; c < 128; ++c) acc += y2[c] * p3w[tid * 128 + c];
    out[b * 40 + tid] = acc;
  }
}

extern "C" void kernel_launch(void* const* d_in, const int* in_sizes, int n_in,
                              void* d_out, int out_size, void* d_ws,
                              size_t ws_size, hipStream_t stream) {
  const float* inputs = (const float*)d_in[0];
  const float* he_w1 = (const float*)d_in[1];
  const float* he_b1 = (const float*)d_in[2];
  const float* he_w2 = (const float*)d_in[3];
  const float* he_b2 = (const float*)d_in[4];
  const float* hn_w1 = (const float*)d_in[5];
  const float* hn_b1 = (const float*)d_in[6];
  const float* hn_w2 = (const float*)d_in[7];
  const float* hn_b2 = (const float*)d_in[8];
  const float* b1e_w1 = (const float*)d_in[9];
  const float* b1e_b1 = (const float*)d_in[10];
  const float* b1e_w2 = (const float*)d_in[11];
  const float* b1e_b2 = (const float*)d_in[12];
  const float* b1n_w1 = (const float*)d_in[13];
  const float* b1n_b1 = (const float*)d_in[14];
  const float* b1n_w2 = (const float*)d_in[15];
  const float* b1n_b2 = (const float*)d_in[16];
  const float* b2e_w1 = (const float*)d_in[17];
  const float* b2e_b1 = (const float*)d_in[18];
  const float* b2e_w2 = (const float*)d_in[19];
  const float* b2e_b2 = (const float*)d_in[20];
  const float* b2n_w1 = (const float*)d_in[21];
  const float* b2n_b1 = (const float*)d_in[22];
  const float* b2n_w2 = (const float*)d_in[23];
  const float* b2n_b2 = (const float*)d_in[24];
  const float* f_w = (const float*)d_in[25];
  const float* f_b = (const float*)d_in[26];
  const float* p1_w = (const float*)d_in[27];
  const float* p1_b = (const float*)d_in[28];
  const float* p2_w = (const float*)d_in[29];
  const float* p2_b = (const float*)d_in[30];
  const float* p3_w = (const float*)d_in[31];
  const float* p3_b = (const float*)d_in[32];
  float* out = (float*)d_out;

  char* ws = (char*)d_ws;
  size_t off = 0;
  auto alloc = [&](size_t bytes) {
    void* p = ws + off;
    off += (bytes + 255) & ~(size_t)255;
    return p;
  };
  int* nn = (int*)alloc((size_t)BDIM * NDIM * KNN * 4);
  float* m1 = (float*)alloc((size_t)BDIM * NDIM * 64 * 4);
  float* h1 = (float*)alloc((size_t)BDIM * NDIM * 64 * 4);
  u16* e1 = (u16*)alloc((size_t)BDIM * NDIM * KNN * 64 * 2);   // bf16
  float* m2 = (float*)alloc((size_t)BDIM * NDIM * 128 * 4);
  float* h2 = (float*)alloc((size_t)BDIM * NDIM * 128 * 4);
  u16* e2 = (u16*)alloc((size_t)BDIM * NDIM * KNN * 128 * 2);  // bf16
  float* m3 = (float*)alloc((size_t)BDIM * NDIM * 192 * 4);
  float* h3 = (float*)alloc((size_t)BDIM * NDIM * 192 * 4);
  u16* pq2 = (u16*)alloc((size_t)BDIM * NDIM * 96 * 2);        // bf16
  u16* pq3 = (u16*)alloc((size_t)BDIM * NDIM * 192 * 2);       // bf16
  int* pooled = (int*)alloc((size_t)BDIM * 512 * 4);
  u16* w1b3e = (u16*)alloc((size_t)96 * 128 * 2);
  u16* wpq3 = (u16*)alloc((size_t)192 * 128 * 2);
  u16* w2b3 = (u16*)alloc((size_t)192 * 96 * 2);
  u16* w1b2e = (u16*)alloc((size_t)48 * 64 * 2);
  u16* wpq2 = (u16*)alloc((size_t)96 * 64 * 2);
  u16* w2b2 = (u16*)alloc((size_t)128 * 64 * 2);
  float* w1p1 = (float*)alloc((size_t)32 * 68 * 4);
  u16* fwb = (u16*)alloc((size_t)512 * 384 * 2);
  u16* w1b1 = (u16*)alloc((size_t)32 * 32 * 2);
  u16* w2b1 = (u16*)alloc((size_t)64 * 32 * 2);

  knn_wcvt<<<BDIM * 256 + 768, 256, 0, stream>>>(
      inputs, nn, b2e_w1, b2e_w2, b1e_w1, b1e_w2, hn_w1, f_w, he_w1, he_w2,
      w1b3e, wpq3, w2b3, w1b2e, wpq2, w2b2, w1p1, fwb, w1b1, w2b1, pooled);

  edge_mfma<4, 32, 32, 64, true, true><<<BDIM * NDIM / 4, 256, 0, stream>>>(
      nullptr, inputs, nn, w1b1, he_b1, w2b1, he_b2, nullptr, e1, m1);
  node_conv<64, 3, 64, 68, 32, 64, 96, true><<<BDIM * NDIM / 64, 256, 0, stream>>>(
      nullptr, inputs, m1, w1p1, hn_b1, hn_w2, hn_b2, h1, wpq2, pq2);

  edge_mfma<4, 64, 48, 128, true, false><<<BDIM * NDIM / 4, 256, 0, stream>>>(
      e1, nullptr, nn, w1b2e, b1e_b1, w2b2, b1e_b2, pq2, e2, m2);
  node_conv<32, 64, 128, 192, 48, 128, 192, false><<<BDIM * NDIM / 32, 256, 0, stream>>>(
      h1, nullptr, m2, b1n_w1, b1n_b1, b1n_w2, b1n_b2, h2, wpq3, pq3);

  edge_mfma<4, 128, 96, 192, false, false><<<BDIM * NDIM / 4, 256, 0, stream>>>(
      e2, nullptr, nn, w1b3e, b2e_b1, w2b3, b2e_b2, pq3, nullptr, m3);
  node_conv<16, 128, 192, 320, 96, 192, 0, false><<<BDIM * NDIM / 16, 256, 0, stream>>>(
      h2, nullptr, m3, b2n_w1, b2n_b1, b2n_w2, b2n_b2, h3, nullptr, nullptr);

  fuse_pool_mfma<<<BDIM * NDIM / 32, 256, 0, stream>>>(h1, h2, h3, fwb, f_b,
                                                       pooled);
  head_kernel<<<BDIM + 24, 256, 0, stream>>>(pooled, p1_w, p1_b, p2_w, p2_b,
                                             p3_w, p3_b, inputs, out);
}

// Round 15
// 238.179 us; speedup vs baseline: 7.5878x; 1.0395x over previous
//
#include <hip/hip_runtime.h>

#define BDIM 8
#define NDIM 1024
#define KNN 20

typedef unsigned short u16;
typedef float f32x4 __attribute__((ext_vector_type(4)));
typedef short short8 __attribute__((ext_vector_type(8)));
typedef unsigned short ushort8 __attribute__((ext_vector_type(8)));

__device__ inline u16 f2bf(float f) {
  unsigned u = __float_as_uint(f);
  unsigned r = (u + 0x7fffu + ((u >> 16) & 1u)) >> 16;
  return (u16)r;
}
__device__ inline float bf2f(u16 v) {
  return __uint_as_float(((unsigned)v) << 16);
}

// ---- merged: KNN (blocks 0..2047, bit-exact) + weight prep (blocks 2048+) ----
__global__ __launch_bounds__(256) void knn_wcvt(
    const float* __restrict__ x, int* __restrict__ nn,
    const float* __restrict__ w1_3, const float* __restrict__ w2_3,
    const float* __restrict__ w1_2, const float* __restrict__ w2_2,
    const float* __restrict__ hn_w1, const float* __restrict__ f_w,
    const float* __restrict__ he_w1, const float* __restrict__ he_w2,
    const float* __restrict__ bn_w1, const float* __restrict__ bn_w2,
    u16* __restrict__ w1b3e, u16* __restrict__ wpq3, u16* __restrict__ w2b3,
    u16* __restrict__ w1b2e, u16* __restrict__ wpq2, u16* __restrict__ w2b2,
    float* __restrict__ w1p1, u16* __restrict__ fwb,
    u16* __restrict__ w1b1, u16* __restrict__ w2b1,
    u16* __restrict__ wn1b, u16* __restrict__ wn2b, int* __restrict__ pooled) {
  const int tid = threadIdx.x;
  if (blockIdx.x >= BDIM * 256) {
    const int idx = (blockIdx.x - BDIM * 256) * 256 + tid;
    if (idx < 512 * 384) fwb[idx] = f2bf(f_w[idx]);
    if (idx < 96 * 128) {
      int oc = idx >> 7, c = idx & 127;
      w1b3e[idx] = f2bf(w1_3[oc * 384 + c]);
    }
    if (idx < 192 * 128) {
      int n = idx >> 7, c = idx & 127;
      wpq3[idx] = f2bf(n < 96 ? w1_3[n * 384 + 128 + c]
                              : w1_3[(n - 96) * 384 + 256 + c]);
    }
    if (idx < 192 * 96) w2b3[idx] = f2bf(w2_3[idx]);
    if (idx < 48 * 64) {
      int oc = idx >> 6, c = idx & 63;
      w1b2e[idx] = f2bf(w1_2[oc * 192 + c]);
    }
    if (idx < 96 * 64) {
      int n = idx >> 6, c = idx & 63;
      wpq2[idx] = f2bf(n < 48 ? w1_2[n * 192 + 64 + c]
                              : w1_2[(n - 48) * 192 + 128 + c]);
    }
    if (idx < 128 * 64) {
      int oc = idx >> 6, i = idx & 63;
      w2b2[idx] = (i < 48) ? f2bf(w2_2[oc * 48 + i]) : (u16)0;
    }
    if (idx < 32 * 68) {
      int oc = idx / 68, c = idx - oc * 68;
      w1p1[idx] = (c < 67) ? hn_w1[oc * 67 + c] : 0.0f;
    }
    if (idx < 32 * 32) {
      int oc = idx >> 5, c = idx & 31;
      w1b1[idx] = (c < 12) ? f2bf(he_w1[oc * 12 + c]) : (u16)0;
    }
    if (idx < 64 * 32) w2b1[idx] = f2bf(he_w2[idx]);
    if (idx < 96 * 320) wn1b[idx] = f2bf(bn_w1[idx]);   // b2n_w1 [96][320]
    if (idx < 192 * 96) wn2b[idx] = f2bf(bn_w2[idx]);   // b2n_w2 [192][96]
    if (idx < BDIM * 512) pooled[idx] = 0;
    return;
  }
  {
#pragma clang fp contract(off)
    __shared__ float xs0[NDIM], xs1[NDIM], xs2[NDIM], sq[NDIM];
    const int lane = tid & 63;
    const int w = tid >> 6;
    const int b = blockIdx.x >> 8;
    const int n = ((blockIdx.x & 255) << 2) + w;
    for (int i = tid; i < NDIM; i += 256) {
      float a0 = x[(b * 3 + 0) * NDIM + i];
      float a1 = x[(b * 3 + 1) * NDIM + i];
      float a2 = x[(b * 3 + 2) * NDIM + i];
      xs0[i] = a0; xs1[i] = a1; xs2[i] = a2;
      sq[i] = (a0 * a0 + a1 * a1) + a2 * a2;
    }
    __syncthreads();
    const float xn0 = xs0[n], xn1 = xs1[n], xn2 = xs2[n], sqn = sq[n];
    float dl[16];
#pragma unroll
    for (int t = 0; t < 16; ++t) {
      int m = t * 64 + lane;
      float dot = (xn0 * xs0[m] + xn1 * xs1[m]) + xn2 * xs2[m];
      dl[t] = (sqn - 2.0f * dot) + sq[m];
    }
    int* nnrow = &nn[(b * NDIM + n) * KNN];
    for (int r = 0; r < KNN; ++r) {
      float bd = dl[0];
      int bt = 0;
#pragma unroll
      for (int t = 1; t < 16; ++t) {
        if (dl[t] < bd) { bd = dl[t]; bt = t; }
      }
      int bi = bt * 64 + lane;
#pragma unroll
      for (int off = 1; off < 64; off <<= 1) {
        float pd = __shfl_xor(bd, off);
        int pi = __shfl_xor(bi, off);
        if (pd < bd || (pd == bd && pi < bi)) { bd = pd; bi = pi; }
      }
      if (lane == 0) nnrow[r] = bi;
      if ((bi & 63) == lane) {
        int wt = bi >> 6;
#pragma unroll
        for (int t = 0; t < 16; ++t) {
          if (t == wt) dl[t] = 3.4e38f;
        }
      }
    }
  }
}

// ---- MFMA edge MP v10: QY aliasing + optional fused node conv (block3) ----
template <int PTS, int CE, int CMID, int COUT, bool WRITE_E, bool FIRST, bool FUSE_N>
__global__ __launch_bounds__(256) void edge_mfma(
    const u16* __restrict__ eprev, const float* __restrict__ finput,
    const int* __restrict__ nnb, const u16* __restrict__ w1b,
    const float* __restrict__ b1v, const u16* __restrict__ w2b,
    const float* __restrict__ b2v, const u16* __restrict__ pq,
    u16* __restrict__ eout, float* __restrict__ mout,
    const float* __restrict__ hprev, const u16* __restrict__ wn1b,
    const float* __restrict__ bn1v, const u16* __restrict__ wn2b,
    const float* __restrict__ bn2v, float* __restrict__ h3out) {
  constexpr int K2 = (CMID + 31) & ~31;
  constexpr int NPQ = 2 * CMID;
  constexpr int MT = PTS * KNN;       // 80 edges
  constexpr int MTL = MT / 16;        // 5 M-tiles (exact)
  constexpr int XPB = CE + 8;
  constexpr int QYP = K2 + 8;         // unified Q / Y1 pitch
  __shared__ __align__(16) char smem[MT * XPB * 2 + MT * QYP * 2];
  u16* Xs = (u16*)smem;
  u16* QY = (u16*)(smem + (size_t)MT * XPB * 2);
  // fused-node overlay (aliases dead Xs region after conv2)
  float* msum = (float*)smem;                       // 4*192*4 = 3072 B
  u16* Xn = (u16*)(smem + 3072);                    // 16*328*2 = 10496 B
  u16* Y1n = (u16*)(smem + 3072 + 16 * 328 * 2);    // 16*104*2 = 3328 B
  __shared__ float pld[FIRST ? 8 : PTS * CMID];
  const int tid = threadIdx.x;
  const int lane = tid & 63;
  const int wv = tid >> 6;
  const int q = lane >> 4;
  const int bn0 = blockIdx.x * PTS;
  const int b = bn0 >> 10;
  // ---- bulk staging ----
  if constexpr (FIRST) {
    for (int idx = tid; idx < MT * (CE / 8); idx += 256) {
      int p = idx / (CE / 8), kc = idx - p * (CE / 8);
      int k0 = kc * 8;
      int bn = bn0 + p / KNN;
      int n = bn & (NDIM - 1);
      int j = nnb[(size_t)bn0 * KNN + p];
      ushort8 r;
#pragma unroll
      for (int t = 0; t < 8; ++t) {
        int c = k0 + t;
        float v = 0.0f;
        if (c < 3) v = finput[(b * 3 + c) * NDIM + n];
        else if (c < 6)
          v = finput[(b * 3 + c - 3) * NDIM + n] -
              finput[(b * 3 + c - 3) * NDIM + j];
        else if (c < 9) v = finput[(b * 3 + c - 6) * NDIM + n];
        else if (c < 12) v = finput[(b * 3 + c - 9) * NDIM + j];
        r[t] = f2bf(v);
      }
      *(ushort8*)&Xs[p * XPB + k0] = r;
    }
  } else {
    constexpr int KC = CE / 8;
    for (int ch = tid; ch < MT * KC; ch += 256) {
      int p = ch / KC, kc = ch - p * KC;
      int k0 = kc * 8;
      *(uint4*)&Xs[p * XPB + k0] =
          *(const uint4*)&eprev[((size_t)blockIdx.x * MT + p) * CE + k0];
    }
    constexpr int QC = CMID / 8;
    for (int i = tid; i < MT * QC; i += 256) {
      int p = i / QC, c8 = (i - p * QC) * 8;
      int j = nnb[(size_t)bn0 * KNN + p];
      *(uint4*)&QY[p * QYP + c8] =
          *(const uint4*)&pq[((size_t)(b << 10) + j) * NPQ + CMID + c8];
    }
    if constexpr (K2 != CMID) {
      constexpr int PC = (K2 - CMID) / 8;
      for (int i = tid; i < MT * PC; i += 256) {
        int p = i / PC, c8 = CMID + (i - p * PC) * 8;
        uint4 z = {0, 0, 0, 0};
        *(uint4*)&QY[p * QYP + c8] = z;
      }
    }
    for (int i = tid; i < PTS * CMID; i += 256) {
      int pt = i / CMID, c = i - pt * CMID;
      pld[i] = bf2f(pq[(size_t)(bn0 + pt) * NPQ + c]) + b1v[c];
    }
  }
  __syncthreads();
  // ---- conv1 ----
  {
    constexpr int NT1 = CMID / 16;
    constexpr int J1 = MTL * NT1;
    constexpr int KS1 = CE / 32;
    for (int job = wv; job < J1; job += 4) {
      int mt = job / NT1, nt = job - mt * NT1;
      int row = mt * 16 + (lane & 15);
      int ncol = nt * 16 + (lane & 15);
      int kb = q * 8;
      f32x4 acc = {0.f, 0.f, 0.f, 0.f};
      const u16* ap = &Xs[row * XPB + kb];
      const u16* bp = &w1b[(size_t)ncol * CE + kb];
#pragma unroll
      for (int ks = 0; ks < KS1; ++ks) {
        short8 a = *(const short8*)(ap + ks * 32);
        short8 bb = *(const short8*)(bp + ks * 32);
        acc = __builtin_amdgcn_mfma_f32_16x16x32_bf16(a, bb, acc, 0, 0, 0);
      }
      int m0 = mt * 16 + q * 4;
      if constexpr (FIRST) {
        float bias = b1v[ncol];
#pragma unroll
        for (int r = 0; r < 4; ++r) {
          float yv = fmaxf(acc[r] + bias, 0.0f);
          QY[(m0 + r) * QYP + ncol] = f2bf(yv);
        }
      } else {
        int pt = m0 / KNN;
        float padd = pld[pt * CMID + ncol];
#pragma unroll
        for (int r = 0; r < 4; ++r) {
          int m = m0 + r;
          float qadd = bf2f(QY[m * QYP + ncol]);
          float yv = fmaxf(acc[r] + padd + qadd, 0.0f);
          QY[m * QYP + ncol] = f2bf(yv);
        }
      }
    }
  }
  __syncthreads();
  // ---- conv2 (+ m-sum) ----
  {
    constexpr int NT2 = COUT / 16;
    constexpr int KS2 = K2 / 32;
    for (int nt = wv; nt < NT2; nt += 4) {
      int ncol = nt * 16 + (lane & 15);
      int kb = q * 8;
      short8 bfrag[KS2];
      const u16* bp = &w2b[(size_t)ncol * K2 + kb];
#pragma unroll
      for (int ks = 0; ks < KS2; ++ks)
        bfrag[ks] = *(const short8*)(bp + ks * 32);
      float bias = b2v[ncol];
      float s[PTS];
#pragma unroll
      for (int pt = 0; pt < PTS; ++pt) s[pt] = 0.0f;
#pragma unroll
      for (int mt = 0; mt < MTL; ++mt) {
        f32x4 acc = {0.f, 0.f, 0.f, 0.f};
        const u16* ap = &QY[(mt * 16 + (lane & 15)) * QYP + kb];
#pragma unroll
        for (int ks = 0; ks < KS2; ++ks) {
          short8 a = *(const short8*)(ap + ks * 32);
          acc = __builtin_amdgcn_mfma_f32_16x16x32_bf16(a, bfrag[ks], acc, 0, 0, 0);
        }
        int m0 = mt * 16 + q * 4;
        float part = 0.0f;
#pragma unroll
        for (int r = 0; r < 4; ++r) {
          float yv = fmaxf(acc[r] + bias, 0.0f);
          if (WRITE_E)
            eout[((size_t)blockIdx.x * MT + m0 + r) * COUT + ncol] = f2bf(yv);
          part += yv;
        }
        int ptA = (4 * mt) / 5;
        int ptB = (4 * mt + 3) / 5;
        int qb = 5 * ptB - 4 * mt;
#pragma unroll
        for (int pt2 = 0; pt2 < PTS; ++pt2) {
          if (pt2 == ptA && ptA == ptB) s[pt2] += part;
          else if (pt2 == ptA) s[pt2] += (q < qb) ? part : 0.0f;
          else if (pt2 == ptB) s[pt2] += (q < qb) ? 0.0f : part;
        }
      }
#pragma unroll
      for (int pt = 0; pt < PTS; ++pt) {
        float sv = s[pt];
        sv += __shfl_xor(sv, 16);
        sv += __shfl_xor(sv, 32);
        if (lane < 16) {
          if constexpr (FUSE_N)
            msum[pt * COUT + nt * 16 + lane] = sv;
          else
            mout[(size_t)(bn0 + pt) * COUT + nt * 16 + lane] = sv;
        }
      }
    }
  }
  // ---- fused node conv (block3): h3 = conv2n(relu(conv1n([h2|m3]))) ----
  if constexpr (FUSE_N) {
    constexpr int XNP = 328;   // 320 + 8 pad
    constexpr int Y1NP = 104;  // 96 + 8
    __syncthreads();           // msum complete; Xs/QY dead
    // stage Xn rows 0..3 = [h2(128) | m3(192) | 0-pad(8)] bf16
    for (int i = tid; i < 4 * 41; i += 256) {
      int p = i / 41, kc = i - p * 41;
      int k0 = kc * 8;
      ushort8 r;
      if (kc < 16) {
        const float* src = &hprev[(size_t)(bn0 + p) * 128 + k0];
        float4 f0 = *(const float4*)src;
        float4 f1 = *(const float4*)(src + 4);
        r[0] = f2bf(f0.x); r[1] = f2bf(f0.y); r[2] = f2bf(f0.z); r[3] = f2bf(f0.w);
        r[4] = f2bf(f1.x); r[5] = f2bf(f1.y); r[6] = f2bf(f1.z); r[7] = f2bf(f1.w);
      } else if (kc < 40) {
        const float* src = &msum[p * 192 + (k0 - 128)];
#pragma unroll
        for (int t = 0; t < 8; ++t) r[t] = f2bf(src[t]);
      } else {
#pragma unroll
        for (int t = 0; t < 8; ++t) r[t] = 0;
      }
      *(ushort8*)&Xn[p * XNP + k0] = r;
    }
    __syncthreads();
    // conv1n: [16(4 valid) x 320] @ wn1^T -> relu -> Y1n [16 x 96]
    for (int nt = wv; nt < 6; nt += 4) {
      int ncol = nt * 16 + (lane & 15);
      int kb = q * 8;
      f32x4 acc = {0.f, 0.f, 0.f, 0.f};
      const u16* ap = &Xn[(lane & 15) * XNP + kb];
      const u16* bp = &wn1b[(size_t)ncol * 320 + kb];
#pragma unroll
      for (int ks = 0; ks < 10; ++ks) {
        short8 a = *(const short8*)(ap + ks * 32);
        short8 bb = *(const short8*)(bp + ks * 32);
        acc = __builtin_amdgcn_mfma_f32_16x16x32_bf16(a, bb, acc, 0, 0, 0);
      }
      float bias = bn1v[ncol];
      int m0 = q * 4;
#pragma unroll
      for (int r = 0; r < 4; ++r)
        Y1n[(m0 + r) * Y1NP + ncol] = f2bf(fmaxf(acc[r] + bias, 0.0f));
    }
    __syncthreads();
    // conv2n: [16 x 96] @ wn2^T -> relu -> h3 (rows 0..3)
    for (int nt = wv; nt < 12; nt += 4) {
      int ncol = nt * 16 + (lane & 15);
      int kb = q * 8;
      f32x4 acc = {0.f, 0.f, 0.f, 0.f};
      const u16* ap = &Y1n[(lane & 15) * Y1NP + kb];
      const u16* bp = &wn2b[(size_t)ncol * 96 + kb];
#pragma unroll
      for (int ks = 0; ks < 3; ++ks) {
        short8 a = *(const short8*)(ap + ks * 32);
        short8 bb = *(const short8*)(bp + ks * 32);
        acc = __builtin_amdgcn_mfma_f32_16x16x32_bf16(a, bb, acc, 0, 0, 0);
      }
      float bias = bn2v[ncol];
      int m0 = q * 4;
#pragma unroll
      for (int r = 0; r < 4; ++r) {
        int m = m0 + r;
        if (m < 4)
          h3out[(size_t)(bn0 + m) * 192 + ncol] = fmaxf(acc[r] + bias, 0.0f);
      }
    }
  }
}

// ---- node conv: fp32 microtile GEMM + optional fused PQ MFMA phase ----
template <int TP, int CH, int CM, int CINP, int CMID, int COUT, int NPQ, bool FIRSTH>
__global__ __launch_bounds__(256) void node_conv(
    const float* __restrict__ h, const float* __restrict__ inputs,
    const float* __restrict__ mbuf, const float* __restrict__ w1p,
    const float* __restrict__ b1v, const float* __restrict__ w2,
    const float* __restrict__ b2v, float* __restrict__ hout,
    const u16* __restrict__ wpq, u16* __restrict__ pq) {
  constexpr int CIN = CH + CM;
  constexpr int XP = CINP + 4;
  constexpr int Y1P = CMID + 4;
  constexpr int PG = TP / 4;
  constexpr int HP = COUT + 8;
  __shared__ float Xs[TP * XP];
  __shared__ float Y1s[TP * Y1P];
  __shared__ u16 Hb[(NPQ > 0) ? TP * HP : 8];
  const int tid = threadIdx.x;
  const int bn0 = blockIdx.x * TP;
  if constexpr (FIRSTH) {
    for (int idx = tid; idx < TP * CIN; idx += 256) {
      int p = idx / CIN, c = idx - p * CIN;
      int bn = bn0 + p;
      int b = bn >> 10, n = bn & (NDIM - 1);
      Xs[p * XP + c] = (c < CH) ? inputs[(b * 3 + c) * NDIM + n]
                                : mbuf[(size_t)bn * CM + (c - CH)];
    }
    if constexpr (CINP > CIN) {
      constexpr int PAD = CINP - CIN;
      for (int idx = tid; idx < TP * PAD; idx += 256) {
        int p = idx / PAD, c = CIN + idx % PAD;
        Xs[p * XP + c] = 0.0f;
      }
    }
  } else {
    constexpr int C4 = CIN / 4;
    for (int idx = tid; idx < TP * C4; idx += 256) {
      int p = idx / C4, c = (idx - p * C4) * 4;
      int bn = bn0 + p;
      float4 v = (c < CH) ? *(const float4*)&h[(size_t)bn * CH + c]
                          : *(const float4*)&mbuf[(size_t)bn * CM + (c - CH)];
      *(float4*)&Xs[p * XP + c] = v;
    }
  }
  __syncthreads();
  {
    constexpr int NT1 = PG * (CMID / 4);
    for (int t = tid; t < NT1; t += 256) {
      int pg = t % PG, og = t / PG;
      float acc[4][4];
#pragma unroll
      for (int j = 0; j < 4; ++j) {
        float bj = b1v[og * 4 + j];
#pragma unroll
        for (int i = 0; i < 4; ++i) acc[i][j] = bj;
      }
      for (int cin = 0; cin < CINP; cin += 4) {
        float4 xr[4], wr[4];
#pragma unroll
        for (int i = 0; i < 4; ++i)
          xr[i] = *(const float4*)&Xs[(pg * 4 + i) * XP + cin];
#pragma unroll
        for (int j = 0; j < 4; ++j)
          wr[j] = *(const float4*)&w1p[(size_t)(og * 4 + j) * CINP + cin];
#pragma unroll
        for (int i = 0; i < 4; ++i)
#pragma unroll
          for (int j = 0; j < 4; ++j) {
            acc[i][j] += xr[i].x * wr[j].x;
            acc[i][j] += xr[i].y * wr[j].y;
            acc[i][j] += xr[i].z * wr[j].z;
            acc[i][j] += xr[i].w * wr[j].w;
          }
      }
#pragma unroll
      for (int i = 0; i < 4; ++i)
#pragma unroll
        for (int j = 0; j < 4; ++j)
          Y1s[(pg * 4 + i) * Y1P + og * 4 + j] = fmaxf(acc[i][j], 0.0f);
    }
  }
  __syncthreads();
  {
    constexpr int NT2 = PG * (COUT / 4);
    for (int t = tid; t < NT2; t += 256) {
      int pg = t % PG, og = t / PG;
      float acc[4][4];
#pragma unroll
      for (int j = 0; j < 4; ++j) {
        float bj = b2v[og * 4 + j];
#pragma unroll
        for (int i = 0; i < 4; ++i) acc[i][j] = bj;
      }
      for (int cin = 0; cin < CMID; cin += 4) {
        float4 xr[4], wr[4];
#pragma unroll
        for (int i = 0; i < 4; ++i)
          xr[i] = *(const float4*)&Y1s[(pg * 4 + i) * Y1P + cin];
#pragma unroll
        for (int j = 0; j < 4; ++j)
          wr[j] = *(const float4*)&w2[(size_t)(og * 4 + j) * CMID + cin];
#pragma unroll
        for (int i = 0; i < 4; ++i)
#pragma unroll
          for (int j = 0; j < 4; ++j) {
            acc[i][j] += xr[i].x * wr[j].x;
            acc[i][j] += xr[i].y * wr[j].y;
            acc[i][j] += xr[i].z * wr[j].z;
            acc[i][j] += xr[i].w * wr[j].w;
          }
      }
#pragma unroll
      for (int i = 0; i < 4; ++i) {
        int bn = bn0 + pg * 4 + i;
#pragma unroll
        for (int j = 0; j < 4; ++j) {
          float v = fmaxf(acc[i][j], 0.0f);
          hout[(size_t)bn * COUT + og * 4 + j] = v;
          if constexpr (NPQ > 0) Hb[(pg * 4 + i) * HP + og * 4 + j] = f2bf(v);
        }
      }
    }
  }
  if constexpr (NPQ > 0) {
    __syncthreads();
    const int lane = tid & 63;
    const int wv = tid >> 6;
    constexpr int NT = NPQ / 16;
    constexpr int JOBS = (TP / 16) * NT;
    constexpr int KS = COUT / 32;
    for (int job = wv; job < JOBS; job += 4) {
      int mt = job / NT, nt = job - mt * NT;
      int row = mt * 16 + (lane & 15);
      int ncol = nt * 16 + (lane & 15);
      int kb = (lane >> 4) * 8;
      f32x4 acc = {0.f, 0.f, 0.f, 0.f};
      const u16* ap = &Hb[row * HP + kb];
      const u16* bp = &wpq[(size_t)ncol * COUT + kb];
#pragma unroll
      for (int ks = 0; ks < KS; ++ks) {
        short8 a = *(const short8*)(ap + ks * 32);
        short8 bb = *(const short8*)(bp + ks * 32);
        acc = __builtin_amdgcn_mfma_f32_16x16x32_bf16(a, bb, acc, 0, 0, 0);
      }
      int m0 = mt * 16 + (lane >> 4) * 4;
#pragma unroll
      for (int r = 0; r < 4; ++r)
        pq[(size_t)(bn0 + m0 + r) * NPQ + ncol] = f2bf(acc[r]);
    }
  }
}

// ---------------- fusion conv (384->512) via MFMA + relu + global max pool ----------------
__global__ __launch_bounds__(256) void fuse_pool_mfma(
    const float* __restrict__ h1, const float* __restrict__ h2,
    const float* __restrict__ h3, const u16* __restrict__ fwb,
    const float* __restrict__ fb, int* __restrict__ pooled) {
  constexpr int CIN = 384, COUT = 512, TP = 32;
  constexpr int XPB = CIN + 8;
  __shared__ u16 Xs[TP * XPB];
  __shared__ int pmax[COUT];
  const int tid = threadIdx.x;
  const int lane = tid & 63;
  const int wv = tid >> 6;
  const int bn0 = blockIdx.x * TP;
  const int b = bn0 >> 10;
  for (int i = tid; i < COUT; i += 256) pmax[i] = 0;
  constexpr int KC = CIN / 8;
  for (int ch = tid; ch < TP * KC; ch += 256) {
    int p = ch / KC, kc = ch - p * KC;
    int k0 = kc * 8;
    int bn = bn0 + p;
    const float* src;
    if (k0 < 64) src = &h1[(size_t)bn * 64 + k0];
    else if (k0 < 192) src = &h2[(size_t)bn * 128 + (k0 - 64)];
    else src = &h3[(size_t)bn * 192 + (k0 - 192)];
    float4 f0 = *(const float4*)src;
    float4 f1 = *(const float4*)(src + 4);
    ushort8 r;
    r[0] = f2bf(f0.x); r[1] = f2bf(f0.y); r[2] = f2bf(f0.z); r[3] = f2bf(f0.w);
    r[4] = f2bf(f1.x); r[5] = f2bf(f1.y); r[6] = f2bf(f1.z); r[7] = f2bf(f1.w);
    *(ushort8*)&Xs[p * XPB + k0] = r;
  }
  __syncthreads();
  constexpr int NT = COUT / 16;
  constexpr int JOBS = (TP / 16) * NT;
  constexpr int KS = CIN / 32;
  for (int job = wv; job < JOBS; job += 4) {
    int mt = job / NT, nt = job - mt * NT;
    int row = mt * 16 + (lane & 15);
    int ncol = nt * 16 + (lane & 15);
    int kb = (lane >> 4) * 8;
    f32x4 acc = {0.f, 0.f, 0.f, 0.f};
    const u16* ap = &Xs[row * XPB + kb];
    const u16* bp = &fwb[(size_t)ncol * CIN + kb];
#pragma unroll
    for (int ks = 0; ks < KS; ++ks) {
      short8 a = *(const short8*)(ap + ks * 32);
      short8 bb = *(const short8*)(bp + ks * 32);
      acc = __builtin_amdgcn_mfma_f32_16x16x32_bf16(a, bb, acc, 0, 0, 0);
    }
    float bias = fb[ncol];
    float v = fmaxf(fmaxf(acc[0], acc[1]), fmaxf(acc[2], acc[3]));
    v = fmaxf(v + bias, 0.0f);
    v = fmaxf(v, __shfl_xor(v, 16));
    v = fmaxf(v, __shfl_xor(v, 32));
    if (lane < 16) atomicMax(&pmax[ncol], __float_as_int(v));
  }
  __syncthreads();
  for (int i = tid; i < COUT; i += 256)
    atomicMax(&pooled[b * COUT + i], pmax[i]);
}

// ---------------- prediction head (blocks 0..7) + inputs echo copy (blocks 8+) ----------------
__global__ __launch_bounds__(256) void head_kernel(
    const int* __restrict__ pooledi, const float* __restrict__ p1w,
    const float* __restrict__ p1b, const float* __restrict__ p2w,
    const float* __restrict__ p2b, const float* __restrict__ p3w,
    const float* __restrict__ p3b, const float* __restrict__ inputs,
    float* __restrict__ out) {
  const int tid = threadIdx.x;
  if (blockIdx.x >= BDIM) {
    int idx = (blockIdx.x - BDIM) * 256 + tid;
    if (idx < (BDIM * 3 * NDIM) / 4) {
      const float4* src = (const float4*)inputs;
      float4* dst = (float4*)(out + BDIM * 40);
      dst[idx] = src[idx];
    }
    return;
  }
  __shared__ float xs[512], y1[256], y2[128];
  const int b = blockIdx.x;
  for (int i = tid; i < 512; i += 256) xs[i] = __int_as_float(pooledi[b * 512 + i]);
  __syncthreads();
  {
    float acc = p1b[tid];
    for (int c = 0; c < 512; ++c) acc += xs[c] * p1w[tid * 512 + c];
    y1[tid] = fmaxf(acc, 0.0f);
  }
  __syncthreads();
  if (tid < 128) {
    float acc = p2b[tid];
    for (int c = 0; c < 256; ++c) acc += y1[c] * p2w[tid * 256 + c];
    y2[tid] = fmaxf(acc, 0.0f);
  }
  __syncthreads();
  if (tid < 40) {
    float acc = p3b[tid];
    for (int c = 0; c < 128; ++c) acc += y2[c] * p3w[tid * 128 + c];
    out[b * 40 + tid] = acc;
  }
}

extern "C" void kernel_launch(void* const* d_in, const int* in_sizes, int n_in,
                              void* d_out, int out_size, void* d_ws,
                              size_t ws_size, hipStream_t stream) {
  const float* inputs = (const float*)d_in[0];
  const float* he_w1 = (const float*)d_in[1];
  const float* he_b1 = (const float*)d_in[2];
  const float* he_w2 = (const float*)d_in[3];
  const float* he_b2 = (const float*)d_in[4];
  const float* hn_w1 = (const float*)d_in[5];
  const float* hn_b1 = (const float*)d_in[6];
  const float* hn_w2 = (const float*)d_in[7];
  const float* hn_b2 = (const float*)d_in[8];
  const float* b1e_w1 = (const float*)d_in[9];
  const float* b1e_b1 = (const float*)d_in[10];
  const float* b1e_w2 = (const float*)d_in[11];
  const float* b1e_b2 = (const float*)d_in[12];
  const float* b1n_w1 = (const float*)d_in[13];
  const float* b1n_b1 = (const float*)d_in[14];
  const float* b1n_w2 = (const float*)d_in[15];
  const float* b1n_b2 = (const float*)d_in[16];
  const float* b2e_w1 = (const float*)d_in[17];
  const float* b2e_b1 = (const float*)d_in[18];
  const float* b2e_w2 = (const float*)d_in[19];
  const float* b2e_b2 = (const float*)d_in[20];
  const float* b2n_w1 = (const float*)d_in[21];
  const float* b2n_b1 = (const float*)d_in[22];
  const float* b2n_w2 = (const float*)d_in[23];
  const float* b2n_b2 = (const float*)d_in[24];
  const float* f_w = (const float*)d_in[25];
  const float* f_b = (const float*)d_in[26];
  const float* p1_w = (const float*)d_in[27];
  const float* p1_b = (const float*)d_in[28];
  const float* p2_w = (const float*)d_in[29];
  const float* p2_b = (const float*)d_in[30];
  const float* p3_w = (const float*)d_in[31];
  const float* p3_b = (const float*)d_in[32];
  float* out = (float*)d_out;

  char* ws = (char*)d_ws;
  size_t off = 0;
  auto alloc = [&](size_t bytes) {
    void* p = ws + off;
    off += (bytes + 255) & ~(size_t)255;
    return p;
  };
  int* nn = (int*)alloc((size_t)BDIM * NDIM * KNN * 4);
  float* m1 = (float*)alloc((size_t)BDIM * NDIM * 64 * 4);
  float* h1 = (float*)alloc((size_t)BDIM * NDIM * 64 * 4);
  u16* e1 = (u16*)alloc((size_t)BDIM * NDIM * KNN * 64 * 2);   // bf16
  float* m2 = (float*)alloc((size_t)BDIM * NDIM * 128 * 4);
  float* h2 = (float*)alloc((size_t)BDIM * NDIM * 128 * 4);
  u16* e2 = (u16*)alloc((size_t)BDIM * NDIM * KNN * 128 * 2);  // bf16
  float* h3 = (float*)alloc((size_t)BDIM * NDIM * 192 * 4);
  u16* pq2 = (u16*)alloc((size_t)BDIM * NDIM * 96 * 2);        // bf16
  u16* pq3 = (u16*)alloc((size_t)BDIM * NDIM * 192 * 2);       // bf16
  int* pooled = (int*)alloc((size_t)BDIM * 512 * 4);
  u16* w1b3e = (u16*)alloc((size_t)96 * 128 * 2);
  u16* wpq3 = (u16*)alloc((size_t)192 * 128 * 2);
  u16* w2b3 = (u16*)alloc((size_t)192 * 96 * 2);
  u16* w1b2e = (u16*)alloc((size_t)48 * 64 * 2);
  u16* wpq2 = (u16*)alloc((size_t)96 * 64 * 2);
  u16* w2b2 = (u16*)alloc((size_t)128 * 64 * 2);
  float* w1p1 = (float*)alloc((size_t)32 * 68 * 4);
  u16* fwb = (u16*)alloc((size_t)512 * 384 * 2);
  u16* w1b1 = (u16*)alloc((size_t)32 * 32 * 2);
  u16* w2b1 = (u16*)alloc((size_t)64 * 32 * 2);
  u16* wn1b = (u16*)alloc((size_t)96 * 320 * 2);
  u16* wn2b = (u16*)alloc((size_t)192 * 96 * 2);

  knn_wcvt<<<BDIM * 256 + 768, 256, 0, stream>>>(
      inputs, nn, b2e_w1, b2e_w2, b1e_w1, b1e_w2, hn_w1, f_w, he_w1, he_w2,
      b2n_w1, b2n_w2, w1b3e, wpq3, w2b3, w1b2e, wpq2, w2b2, w1p1, fwb, w1b1,
      w2b1, wn1b, wn2b, pooled);

  edge_mfma<4, 32, 32, 64, true, true, false><<<BDIM * NDIM / 4, 256, 0, stream>>>(
      nullptr, inputs, nn, w1b1, he_b1, w2b1, he_b2, nullptr, e1, m1, nullptr,
      nullptr, nullptr, nullptr, nullptr, nullptr);
  node_conv<64, 3, 64, 68, 32, 64, 96, true><<<BDIM * NDIM / 64, 256, 0, stream>>>(
      nullptr, inputs, m1, w1p1, hn_b1, hn_w2, hn_b2, h1, wpq2, pq2);

  edge_mfma<4, 64, 48, 128, true, false, false><<<BDIM * NDIM / 4, 256, 0, stream>>>(
      e1, nullptr, nn, w1b2e, b1e_b1, w2b2, b1e_b2, pq2, e2, m2, nullptr,
      nullptr, nullptr, nullptr, nullptr, nullptr);
  node_conv<32, 64, 128, 192, 48, 128, 192, false><<<BDIM * NDIM / 32, 256, 0, stream>>>(
      h1, nullptr, m2, b1n_w1, b1n_b1, b1n_w2, b1n_b2, h2, wpq3, pq3);

  edge_mfma<4, 128, 96, 192, false, false, true><<<BDIM * NDIM / 4, 256, 0, stream>>>(
      e2, nullptr, nn, w1b3e, b2e_b1, w2b3, b2e_b2, pq3, nullptr, nullptr, h2,
      wn1b, b2n_b1, wn2b, b2n_b2, h3);

  fuse_pool_mfma<<<BDIM * NDIM / 32, 256, 0, stream>>>(h1, h2, h3, fwb, f_b,
                                                       pooled);
  head_kernel<<<BDIM + 24, 256, 0, stream>>>(pooled, p1_w, p1_b, p2_w, p2_b,
                                             p3_w, p3_b, inputs, out);
}

// Round 16
// 237.009 us; speedup vs baseline: 7.6253x; 1.0049x over previous
//
#include <hip/hip_runtime.h>

#define BDIM 8
#define NDIM 1024
#define KNN 20

typedef unsigned short u16;
typedef float f32x4 __attribute__((ext_vector_type(4)));
typedef short short8 __attribute__((ext_vector_type(8)));
typedef unsigned short ushort8 __attribute__((ext_vector_type(8)));

__device__ inline u16 f2bf(float f) {
  unsigned u = __float_as_uint(f);
  unsigned r = (u + 0x7fffu + ((u >> 16) & 1u)) >> 16;
  return (u16)r;
}
__device__ inline float bf2f(u16 v) {
  return __uint_as_float(((unsigned)v) << 16);
}

// ---- merged: KNN (blocks 0..2047, bit-exact) + weight prep (blocks 2048+) ----
__global__ __launch_bounds__(256) void knn_wcvt(
    const float* __restrict__ x, int* __restrict__ nn,
    const float* __restrict__ w1_3, const float* __restrict__ w2_3,
    const float* __restrict__ w1_2, const float* __restrict__ w2_2,
    const float* __restrict__ hn_w1, const float* __restrict__ f_w,
    const float* __restrict__ he_w1, const float* __restrict__ he_w2,
    const float* __restrict__ bn_w1, const float* __restrict__ bn_w2,
    u16* __restrict__ w1b3e, u16* __restrict__ wpq3, u16* __restrict__ w2b3,
    u16* __restrict__ w1b2e, u16* __restrict__ wpq2, u16* __restrict__ w2b2,
    float* __restrict__ w1p1, u16* __restrict__ fwb,
    u16* __restrict__ w1b1, u16* __restrict__ w2b1,
    u16* __restrict__ wn1b, u16* __restrict__ wn2b, int* __restrict__ pooled) {
  const int tid = threadIdx.x;
  if (blockIdx.x >= BDIM * 256) {
    const int idx = (blockIdx.x - BDIM * 256) * 256 + tid;
    if (idx < 512 * 384) fwb[idx] = f2bf(f_w[idx]);
    if (idx < 96 * 128) {
      int oc = idx >> 7, c = idx & 127;
      w1b3e[idx] = f2bf(w1_3[oc * 384 + c]);
    }
    if (idx < 192 * 128) {
      int n = idx >> 7, c = idx & 127;
      wpq3[idx] = f2bf(n < 96 ? w1_3[n * 384 + 128 + c]
                              : w1_3[(n - 96) * 384 + 256 + c]);
    }
    if (idx < 192 * 96) w2b3[idx] = f2bf(w2_3[idx]);
    if (idx < 48 * 64) {
      int oc = idx >> 6, c = idx & 63;
      w1b2e[idx] = f2bf(w1_2[oc * 192 + c]);
    }
    if (idx < 96 * 64) {
      int n = idx >> 6, c = idx & 63;
      wpq2[idx] = f2bf(n < 48 ? w1_2[n * 192 + 64 + c]
                              : w1_2[(n - 48) * 192 + 128 + c]);
    }
    if (idx < 128 * 64) {
      int oc = idx >> 6, i = idx & 63;
      w2b2[idx] = (i < 48) ? f2bf(w2_2[oc * 48 + i]) : (u16)0;
    }
    if (idx < 32 * 68) {
      int oc = idx / 68, c = idx - oc * 68;
      w1p1[idx] = (c < 67) ? hn_w1[oc * 67 + c] : 0.0f;
    }
    if (idx < 32 * 32) {
      int oc = idx >> 5, c = idx & 31;
      w1b1[idx] = (c < 12) ? f2bf(he_w1[oc * 12 + c]) : (u16)0;
    }
    if (idx < 64 * 32) w2b1[idx] = f2bf(he_w2[idx]);
    if (idx < 96 * 320) wn1b[idx] = f2bf(bn_w1[idx]);   // b2n_w1 [96][320]
    if (idx < 192 * 96) wn2b[idx] = f2bf(bn_w2[idx]);   // b2n_w2 [192][96]
    if (idx < BDIM * 512) pooled[idx] = 0;
    return;
  }
  {
#pragma clang fp contract(off)
    __shared__ float xs0[NDIM], xs1[NDIM], xs2[NDIM], sq[NDIM];
    const int lane = tid & 63;
    const int w = tid >> 6;
    const int b = blockIdx.x >> 8;
    const int n = ((blockIdx.x & 255) << 2) + w;
    for (int i = tid; i < NDIM; i += 256) {
      float a0 = x[(b * 3 + 0) * NDIM + i];
      float a1 = x[(b * 3 + 1) * NDIM + i];
      float a2 = x[(b * 3 + 2) * NDIM + i];
      xs0[i] = a0; xs1[i] = a1; xs2[i] = a2;
      sq[i] = (a0 * a0 + a1 * a1) + a2 * a2;
    }
    __syncthreads();
    const float xn0 = xs0[n], xn1 = xs1[n], xn2 = xs2[n], sqn = sq[n];
    float dl[16];
#pragma unroll
    for (int t = 0; t < 16; ++t) {
      int m = t * 64 + lane;
      float dot = (xn0 * xs0[m] + xn1 * xs1[m]) + xn2 * xs2[m];
      dl[t] = (sqn - 2.0f * dot) + sq[m];
    }
    int* nnrow = &nn[(b * NDIM + n) * KNN];
    for (int r = 0; r < KNN; ++r) {
      float bd = dl[0];
      int bt = 0;
#pragma unroll
      for (int t = 1; t < 16; ++t) {
        if (dl[t] < bd) { bd = dl[t]; bt = t; }
      }
      int bi = bt * 64 + lane;
#pragma unroll
      for (int off = 1; off < 64; off <<= 1) {
        float pd = __shfl_xor(bd, off);
        int pi = __shfl_xor(bi, off);
        if (pd < bd || (pd == bd && pi < bi)) { bd = pd; bi = pi; }
      }
      if (lane == 0) nnrow[r] = bi;
      if ((bi & 63) == lane) {
        int wt = bi >> 6;
#pragma unroll
        for (int t = 0; t < 16; ++t) {
          if (t == wt) dl[t] = 3.4e38f;
        }
      }
    }
  }
}

// ---- MFMA edge MP v11: QY aliasing + lean fused node conv (block3) ----
template <int PTS, int CE, int CMID, int COUT, bool WRITE_E, bool FIRST, bool FUSE_N>
__global__ __launch_bounds__(256) void edge_mfma(
    const u16* __restrict__ eprev, const float* __restrict__ finput,
    const int* __restrict__ nnb, const u16* __restrict__ w1b,
    const float* __restrict__ b1v, const u16* __restrict__ w2b,
    const float* __restrict__ b2v, const u16* __restrict__ pq,
    u16* __restrict__ eout, float* __restrict__ mout,
    const float* __restrict__ hprev, const u16* __restrict__ wn1b,
    const float* __restrict__ bn1v, const u16* __restrict__ wn2b,
    const float* __restrict__ bn2v, float* __restrict__ h3out) {
  constexpr int K2 = (CMID + 31) & ~31;
  constexpr int NPQ = 2 * CMID;
  constexpr int MT = PTS * KNN;       // 80 edges
  constexpr int MTL = MT / 16;        // 5 M-tiles (exact)
  constexpr int XPB = CE + 8;
  constexpr int QYP = K2 + 8;         // unified Q / Y1 pitch
  constexpr int XNP = 328;            // fused node X pitch (320 + 8)
  constexpr int Y1NP = 104;           // fused node Y1 pitch (96 + 8)
  __shared__ __align__(16) char smem[MT * XPB * 2 + MT * QYP * 2];
  u16* Xs = (u16*)smem;
  u16* QY = (u16*)(smem + (size_t)MT * XPB * 2);
  // fused-node overlay (aliases dead Xs region after conv1)
  u16* Xn = (u16*)smem;                             // 16*328*2 = 10496 B
  u16* Y1n = (u16*)(smem + 16 * 328 * 2);           // 16*104*2 = 3328 B
  __shared__ float pld[FIRST ? 8 : PTS * CMID];
  const int tid = threadIdx.x;
  const int lane = tid & 63;
  const int wv = tid >> 6;
  const int q = lane >> 4;
  const int bn0 = blockIdx.x * PTS;
  const int b = bn0 >> 10;
  // ---- bulk staging ----
  if constexpr (FIRST) {
    for (int idx = tid; idx < MT * (CE / 8); idx += 256) {
      int p = idx / (CE / 8), kc = idx - p * (CE / 8);
      int k0 = kc * 8;
      int bn = bn0 + p / KNN;
      int n = bn & (NDIM - 1);
      int j = nnb[(size_t)bn0 * KNN + p];
      ushort8 r;
#pragma unroll
      for (int t = 0; t < 8; ++t) {
        int c = k0 + t;
        float v = 0.0f;
        if (c < 3) v = finput[(b * 3 + c) * NDIM + n];
        else if (c < 6)
          v = finput[(b * 3 + c - 3) * NDIM + n] -
              finput[(b * 3 + c - 3) * NDIM + j];
        else if (c < 9) v = finput[(b * 3 + c - 6) * NDIM + n];
        else if (c < 12) v = finput[(b * 3 + c - 9) * NDIM + j];
        r[t] = f2bf(v);
      }
      *(ushort8*)&Xs[p * XPB + k0] = r;
    }
  } else {
    constexpr int KC = CE / 8;
    for (int ch = tid; ch < MT * KC; ch += 256) {
      int p = ch / KC, kc = ch - p * KC;
      int k0 = kc * 8;
      *(uint4*)&Xs[p * XPB + k0] =
          *(const uint4*)&eprev[((size_t)blockIdx.x * MT + p) * CE + k0];
    }
    constexpr int QC = CMID / 8;
    for (int i = tid; i < MT * QC; i += 256) {
      int p = i / QC, c8 = (i - p * QC) * 8;
      int j = nnb[(size_t)bn0 * KNN + p];
      *(uint4*)&QY[p * QYP + c8] =
          *(const uint4*)&pq[((size_t)(b << 10) + j) * NPQ + CMID + c8];
    }
    if constexpr (K2 != CMID) {
      constexpr int PC = (K2 - CMID) / 8;
      for (int i = tid; i < MT * PC; i += 256) {
        int p = i / PC, c8 = CMID + (i - p * PC) * 8;
        uint4 z = {0, 0, 0, 0};
        *(uint4*)&QY[p * QYP + c8] = z;
      }
    }
    for (int i = tid; i < PTS * CMID; i += 256) {
      int pt = i / CMID, c = i - pt * CMID;
      pld[i] = bf2f(pq[(size_t)(bn0 + pt) * NPQ + c]) + b1v[c];
    }
  }
  __syncthreads();
  // ---- conv1 ----
  {
    constexpr int NT1 = CMID / 16;
    constexpr int J1 = MTL * NT1;
    constexpr int KS1 = CE / 32;
    for (int job = wv; job < J1; job += 4) {
      int mt = job / NT1, nt = job - mt * NT1;
      int row = mt * 16 + (lane & 15);
      int ncol = nt * 16 + (lane & 15);
      int kb = q * 8;
      f32x4 acc = {0.f, 0.f, 0.f, 0.f};
      const u16* ap = &Xs[row * XPB + kb];
      const u16* bp = &w1b[(size_t)ncol * CE + kb];
#pragma unroll
      for (int ks = 0; ks < KS1; ++ks) {
        short8 a = *(const short8*)(ap + ks * 32);
        short8 bb = *(const short8*)(bp + ks * 32);
        acc = __builtin_amdgcn_mfma_f32_16x16x32_bf16(a, bb, acc, 0, 0, 0);
      }
      int m0 = mt * 16 + q * 4;
      if constexpr (FIRST) {
        float bias = b1v[ncol];
#pragma unroll
        for (int r = 0; r < 4; ++r) {
          float yv = fmaxf(acc[r] + bias, 0.0f);
          QY[(m0 + r) * QYP + ncol] = f2bf(yv);
        }
      } else {
        int pt = m0 / KNN;
        float padd = pld[pt * CMID + ncol];
#pragma unroll
        for (int r = 0; r < 4; ++r) {
          int m = m0 + r;
          float qadd = bf2f(QY[m * QYP + ncol]);
          float yv = fmaxf(acc[r] + padd + qadd, 0.0f);
          QY[m * QYP + ncol] = f2bf(yv);
        }
      }
    }
  }
  __syncthreads();
  // ---- conv2 (+ m-sum); FUSE_N: also stage h2-half of Xn (dead Xs region) ----
  {
    if constexpr (FUSE_N) {
      // h2-part of Xn: 4 rows x 128 cols, bf16; issued early, hides under MFMAs
      for (int i = tid; i < 4 * 16; i += 256) {
        int p = i >> 4, kc = i & 15;
        int k0 = kc * 8;
        const float* src = &hprev[(size_t)(bn0 + p) * 128 + k0];
        float4 f0 = *(const float4*)src;
        float4 f1 = *(const float4*)(src + 4);
        ushort8 r;
        r[0] = f2bf(f0.x); r[1] = f2bf(f0.y); r[2] = f2bf(f0.z); r[3] = f2bf(f0.w);
        r[4] = f2bf(f1.x); r[5] = f2bf(f1.y); r[6] = f2bf(f1.z); r[7] = f2bf(f1.w);
        *(ushort8*)&Xn[p * XNP + k0] = r;
      }
      if (tid < 4) {
        ushort8 z = {0, 0, 0, 0, 0, 0, 0, 0};
        *(ushort8*)&Xn[tid * XNP + 320] = z;
      }
    }
    constexpr int NT2 = COUT / 16;
    constexpr int KS2 = K2 / 32;
    for (int nt = wv; nt < NT2; nt += 4) {
      int ncol = nt * 16 + (lane & 15);
      int kb = q * 8;
      short8 bfrag[KS2];
      const u16* bp = &w2b[(size_t)ncol * K2 + kb];
#pragma unroll
      for (int ks = 0; ks < KS2; ++ks)
        bfrag[ks] = *(const short8*)(bp + ks * 32);
      float bias = b2v[ncol];
      float s[PTS];
#pragma unroll
      for (int pt = 0; pt < PTS; ++pt) s[pt] = 0.0f;
#pragma unroll
      for (int mt = 0; mt < MTL; ++mt) {
        f32x4 acc = {0.f, 0.f, 0.f, 0.f};
        const u16* ap = &QY[(mt * 16 + (lane & 15)) * QYP + kb];
#pragma unroll
        for (int ks = 0; ks < KS2; ++ks) {
          short8 a = *(const short8*)(ap + ks * 32);
          acc = __builtin_amdgcn_mfma_f32_16x16x32_bf16(a, bfrag[ks], acc, 0, 0, 0);
        }
        int m0 = mt * 16 + q * 4;
        float part = 0.0f;
#pragma unroll
        for (int r = 0; r < 4; ++r) {
          float yv = fmaxf(acc[r] + bias, 0.0f);
          if (WRITE_E)
            eout[((size_t)blockIdx.x * MT + m0 + r) * COUT + ncol] = f2bf(yv);
          part += yv;
        }
        int ptA = (4 * mt) / 5;
        int ptB = (4 * mt + 3) / 5;
        int qb = 5 * ptB - 4 * mt;
#pragma unroll
        for (int pt2 = 0; pt2 < PTS; ++pt2) {
          if (pt2 == ptA && ptA == ptB) s[pt2] += part;
          else if (pt2 == ptA) s[pt2] += (q < qb) ? part : 0.0f;
          else if (pt2 == ptB) s[pt2] += (q < qb) ? 0.0f : part;
        }
      }
#pragma unroll
      for (int pt = 0; pt < PTS; ++pt) {
        float sv = s[pt];
        sv += __shfl_xor(sv, 16);
        sv += __shfl_xor(sv, 32);
        if (lane < 16) {
          if constexpr (FUSE_N)
            Xn[pt * XNP + 128 + nt * 16 + lane] = f2bf(sv);  // m -> Xn direct
          else
            mout[(size_t)(bn0 + pt) * COUT + nt * 16 + lane] = sv;
        }
      }
    }
  }
  // ---- fused node conv (block3): h3 = conv2n(relu(conv1n([h2|m3]))) ----
  if constexpr (FUSE_N) {
    __syncthreads();  // Xn complete
    // conv1n: [16(4 valid) x 320] @ wn1^T -> relu -> Y1n [16 x 96]
    for (int nt = wv; nt < 6; nt += 4) {
      int ncol = nt * 16 + (lane & 15);
      int kb = q * 8;
      f32x4 acc = {0.f, 0.f, 0.f, 0.f};
      const u16* ap = &Xn[(lane & 15) * XNP + kb];
      const u16* bp = &wn1b[(size_t)ncol * 320 + kb];
#pragma unroll
      for (int ks = 0; ks < 10; ++ks) {
        short8 a = *(const short8*)(ap + ks * 32);
        short8 bb = *(const short8*)(bp + ks * 32);
        acc = __builtin_amdgcn_mfma_f32_16x16x32_bf16(a, bb, acc, 0, 0, 0);
      }
      float bias = bn1v[ncol];
      int m0 = q * 4;
#pragma unroll
      for (int r = 0; r < 4; ++r)
        Y1n[(m0 + r) * Y1NP + ncol] = f2bf(fmaxf(acc[r] + bias, 0.0f));
    }
    __syncthreads();
    // conv2n: [16 x 96] @ wn2^T -> relu -> h3 (rows 0..3)
    for (int nt = wv; nt < 12; nt += 4) {
      int ncol = nt * 16 + (lane & 15);
      int kb = q * 8;
      f32x4 acc = {0.f, 0.f, 0.f, 0.f};
      const u16* ap = &Y1n[(lane & 15) * Y1NP + kb];
      const u16* bp = &wn2b[(size_t)ncol * 96 + kb];
#pragma unroll
      for (int ks = 0; ks < 3; ++ks) {
        short8 a = *(const short8*)(ap + ks * 32);
        short8 bb = *(const short8*)(bp + ks * 32);
        acc = __builtin_amdgcn_mfma_f32_16x16x32_bf16(a, bb, acc, 0, 0, 0);
      }
      float bias = bn2v[ncol];
      int m0 = q * 4;
#pragma unroll
      for (int r = 0; r < 4; ++r) {
        int m = m0 + r;
        if (m < 4)
          h3out[(size_t)(bn0 + m) * 192 + ncol] = fmaxf(acc[r] + bias, 0.0f);
      }
    }
  }
}

// ---- node conv: fp32 microtile GEMM + optional fused PQ MFMA phase ----
template <int TP, int CH, int CM, int CINP, int CMID, int COUT, int NPQ, bool FIRSTH>
__global__ __launch_bounds__(256) void node_conv(
    const float* __restrict__ h, const float* __restrict__ inputs,
    const float* __restrict__ mbuf, const float* __restrict__ w1p,
    const float* __restrict__ b1v, const float* __restrict__ w2,
    const float* __restrict__ b2v, float* __restrict__ hout,
    const u16* __restrict__ wpq, u16* __restrict__ pq) {
  constexpr int CIN = CH + CM;
  constexpr int XP = CINP + 4;
  constexpr int Y1P = CMID + 4;
  constexpr int PG = TP / 4;
  constexpr int HP = COUT + 8;
  __shared__ float Xs[TP * XP];
  __shared__ float Y1s[TP * Y1P];
  __shared__ u16 Hb[(NPQ > 0) ? TP * HP : 8];
  const int tid = threadIdx.x;
  const int bn0 = blockIdx.x * TP;
  if constexpr (FIRSTH) {
    for (int idx = tid; idx < TP * CIN; idx += 256) {
      int p = idx / CIN, c = idx - p * CIN;
      int bn = bn0 + p;
      int b = bn >> 10, n = bn & (NDIM - 1);
      Xs[p * XP + c] = (c < CH) ? inputs[(b * 3 + c) * NDIM + n]
                                : mbuf[(size_t)bn * CM + (c - CH)];
    }
    if constexpr (CINP > CIN) {
      constexpr int PAD = CINP - CIN;
      for (int idx = tid; idx < TP * PAD; idx += 256) {
        int p = idx / PAD, c = CIN + idx % PAD;
        Xs[p * XP + c] = 0.0f;
      }
    }
  } else {
    constexpr int C4 = CIN / 4;
    for (int idx = tid; idx < TP * C4; idx += 256) {
      int p = idx / C4, c = (idx - p * C4) * 4;
      int bn = bn0 + p;
      float4 v = (c < CH) ? *(const float4*)&h[(size_t)bn * CH + c]
                          : *(const float4*)&mbuf[(size_t)bn * CM + (c - CH)];
      *(float4*)&Xs[p * XP + c] = v;
    }
  }
  __syncthreads();
  {
    constexpr int NT1 = PG * (CMID / 4);
    for (int t = tid; t < NT1; t += 256) {
      int pg = t % PG, og = t / PG;
      float acc[4][4];
#pragma unroll
      for (int j = 0; j < 4; ++j) {
        float bj = b1v[og * 4 + j];
#pragma unroll
        for (int i = 0; i < 4; ++i) acc[i][j] = bj;
      }
      for (int cin = 0; cin < CINP; cin += 4) {
        float4 xr[4], wr[4];
#pragma unroll
        for (int i = 0; i < 4; ++i)
          xr[i] = *(const float4*)&Xs[(pg * 4 + i) * XP + cin];
#pragma unroll
        for (int j = 0; j < 4; ++j)
          wr[j] = *(const float4*)&w1p[(size_t)(og * 4 + j) * CINP + cin];
#pragma unroll
        for (int i = 0; i < 4; ++i)
#pragma unroll
          for (int j = 0; j < 4; ++j) {
            acc[i][j] += xr[i].x * wr[j].x;
            acc[i][j] += xr[i].y * wr[j].y;
            acc[i][j] += xr[i].z * wr[j].z;
            acc[i][j] += xr[i].w * wr[j].w;
          }
      }
#pragma unroll
      for (int i = 0; i < 4; ++i)
#pragma unroll
        for (int j = 0; j < 4; ++j)
          Y1s[(pg * 4 + i) * Y1P + og * 4 + j] = fmaxf(acc[i][j], 0.0f);
    }
  }
  __syncthreads();
  {
    constexpr int NT2 = PG * (COUT / 4);
    for (int t = tid; t < NT2; t += 256) {
      int pg = t % PG, og = t / PG;
      float acc[4][4];
#pragma unroll
      for (int j = 0; j < 4; ++j) {
        float bj = b2v[og * 4 + j];
#pragma unroll
        for (int i = 0; i < 4; ++i) acc[i][j] = bj;
      }
      for (int cin = 0; cin < CMID; cin += 4) {
        float4 xr[4], wr[4];
#pragma unroll
        for (int i = 0; i < 4; ++i)
          xr[i] = *(const float4*)&Y1s[(pg * 4 + i) * Y1P + cin];
#pragma unroll
        for (int j = 0; j < 4; ++j)
          wr[j] = *(const float4*)&w2[(size_t)(og * 4 + j) * CMID + cin];
#pragma unroll
        for (int i = 0; i < 4; ++i)
#pragma unroll
          for (int j = 0; j < 4; ++j) {
            acc[i][j] += xr[i].x * wr[j].x;
            acc[i][j] += xr[i].y * wr[j].y;
            acc[i][j] += xr[i].z * wr[j].z;
            acc[i][j] += xr[i].w * wr[j].w;
          }
      }
#pragma unroll
      for (int i = 0; i < 4; ++i) {
        int bn = bn0 + pg * 4 + i;
#pragma unroll
        for (int j = 0; j < 4; ++j) {
          float v = fmaxf(acc[i][j], 0.0f);
          hout[(size_t)bn * COUT + og * 4 + j] = v;
          if constexpr (NPQ > 0) Hb[(pg * 4 + i) * HP + og * 4 + j] = f2bf(v);
        }
      }
    }
  }
  if constexpr (NPQ > 0) {
    __syncthreads();
    const int lane = tid & 63;
    const int wv = tid >> 6;
    constexpr int NT = NPQ / 16;
    constexpr int JOBS = (TP / 16) * NT;
    constexpr int KS = COUT / 32;
    for (int job = wv; job < JOBS; job += 4) {
      int mt = job / NT, nt = job - mt * NT;
      int row = mt * 16 + (lane & 15);
      int ncol = nt * 16 + (lane & 15);
      int kb = (lane >> 4) * 8;
      f32x4 acc = {0.f, 0.f, 0.f, 0.f};
      const u16* ap = &Hb[row * HP + kb];
      const u16* bp = &wpq[(size_t)ncol * COUT + kb];
#pragma unroll
      for (int ks = 0; ks < KS; ++ks) {
        short8 a = *(const short8*)(ap + ks * 32);
        short8 bb = *(const short8*)(bp + ks * 32);
        acc = __builtin_amdgcn_mfma_f32_16x16x32_bf16(a, bb, acc, 0, 0, 0);
      }
      int m0 = mt * 16 + (lane >> 4) * 4;
#pragma unroll
      for (int r = 0; r < 4; ++r)
        pq[(size_t)(bn0 + m0 + r) * NPQ + ncol] = f2bf(acc[r]);
    }
  }
}

// ---------------- fusion conv (384->512) via MFMA + relu + global max pool ----------------
__global__ __launch_bounds__(256) void fuse_pool_mfma(
    const float* __restrict__ h1, const float* __restrict__ h2,
    const float* __restrict__ h3, const u16* __restrict__ fwb,
    const float* __restrict__ fb, int* __restrict__ pooled) {
  constexpr int CIN = 384, COUT = 512, TP = 32;
  constexpr int XPB = CIN + 8;
  __shared__ u16 Xs[TP * XPB];
  __shared__ int pmax[COUT];
  const int tid = threadIdx.x;
  const int lane = tid & 63;
  const int wv = tid >> 6;
  const int bn0 = blockIdx.x * TP;
  const int b = bn0 >> 10;
  for (int i = tid; i < COUT; i += 256) pmax[i] = 0;
  constexpr int KC = CIN / 8;
  for (int ch = tid; ch < TP * KC; ch += 256) {
    int p = ch / KC, kc = ch - p * KC;
    int k0 = kc * 8;
    int bn = bn0 + p;
    const float* src;
    if (k0 < 64) src = &h1[(size_t)bn * 64 + k0];
    else if (k0 < 192) src = &h2[(size_t)bn * 128 + (k0 - 64)];
    else src = &h3[(size_t)bn * 192 + (k0 - 192)];
    float4 f0 = *(const float4*)src;
    float4 f1 = *(const float4*)(src + 4);
    ushort8 r;
    r[0] = f2bf(f0.x); r[1] = f2bf(f0.y); r[2] = f2bf(f0.z); r[3] = f2bf(f0.w);
    r[4] = f2bf(f1.x); r[5] = f2bf(f1.y); r[6] = f2bf(f1.z); r[7] = f2bf(f1.w);
    *(ushort8*)&Xs[p * XPB + k0] = r;
  }
  __syncthreads();
  constexpr int NT = COUT / 16;
  constexpr int JOBS = (TP / 16) * NT;
  constexpr int KS = CIN / 32;
  for (int job = wv; job < JOBS; job += 4) {
    int mt = job / NT, nt = job - mt * NT;
    int row = mt * 16 + (lane & 15);
    int ncol = nt * 16 + (lane & 15);
    int kb = (lane >> 4) * 8;
    f32x4 acc = {0.f, 0.f, 0.f, 0.f};
    const u16* ap = &Xs[row * XPB + kb];
    const u16* bp = &fwb[(size_t)ncol * CIN + kb];
#pragma unroll
    for (int ks = 0; ks < KS; ++ks) {
      short8 a = *(const short8*)(ap + ks * 32);
      short8 bb = *(const short8*)(bp + ks * 32);
      acc = __builtin_amdgcn_mfma_f32_16x16x32_bf16(a, bb, acc, 0, 0, 0);
    }
    float bias = fb[ncol];
    float v = fmaxf(fmaxf(acc[0], acc[1]), fmaxf(acc[2], acc[3]));
    v = fmaxf(v + bias, 0.0f);
    v = fmaxf(v, __shfl_xor(v, 16));
    v = fmaxf(v, __shfl_xor(v, 32));
    if (lane < 16) atomicMax(&pmax[ncol], __float_as_int(v));
  }
  __syncthreads();
  for (int i = tid; i < COUT; i += 256)
    atomicMax(&pooled[b * COUT + i], pmax[i]);
}

// ---------------- prediction head (blocks 0..7) + inputs echo copy (blocks 8+) ----------------
__global__ __launch_bounds__(256) void head_kernel(
    const int* __restrict__ pooledi, const float* __restrict__ p1w,
    const float* __restrict__ p1b, const float* __restrict__ p2w,
    const float* __restrict__ p2b, const float* __restrict__ p3w,
    const float* __restrict__ p3b, const float* __restrict__ inputs,
    float* __restrict__ out) {
  const int tid = threadIdx.x;
  if (blockIdx.x >= BDIM) {
    int idx = (blockIdx.x - BDIM) * 256 + tid;
    if (idx < (BDIM * 3 * NDIM) / 4) {
      const float4* src = (const float4*)inputs;
      float4* dst = (float4*)(out + BDIM * 40);
      dst[idx] = src[idx];
    }
    return;
  }
  __shared__ float xs[512], y1[256], y2[128];
  const int b = blockIdx.x;
  for (int i = tid; i < 512; i += 256) xs[i] = __int_as_float(pooledi[b * 512 + i]);
  __syncthreads();
  {
    float acc = p1b[tid];
    for (int c = 0; c < 512; ++c) acc += xs[c] * p1w[tid * 512 + c];
    y1[tid] = fmaxf(acc, 0.0f);
  }
  __syncthreads();
  if (tid < 128) {
    float acc = p2b[tid];
    for (int c = 0; c < 256; ++c) acc += y1[c] * p2w[tid * 256 + c];
    y2[tid] = fmaxf(acc, 0.0f);
  }
  __syncthreads();
  if (tid < 40) {
    float acc = p3b[tid];
    for (int c = 0; c < 128; ++c) acc += y2[c] * p3w[tid * 128 + c];
    out[b * 40 + tid] = acc;
  }
}

extern "C" void kernel_launch(void* const* d_in, const int* in_sizes, int n_in,
                              void* d_out, int out_size, void* d_ws,
                              size_t ws_size, hipStream_t stream) {
  const float* inputs = (const float*)d_in[0];
  const float* he_w1 = (const float*)d_in[1];
  const float* he_b1 = (const float*)d_in[2];
  const float* he_w2 = (const float*)d_in[3];
  const float* he_b2 = (const float*)d_in[4];
  const float* hn_w1 = (const float*)d_in[5];
  const float* hn_b1 = (const float*)d_in[6];
  const float* hn_w2 = (const float*)d_in[7];
  const float* hn_b2 = (const float*)d_in[8];
  const float* b1e_w1 = (const float*)d_in[9];
  const float* b1e_b1 = (const float*)d_in[10];
  const float* b1e_w2 = (const float*)d_in[11];
  const float* b1e_b2 = (const float*)d_in[12];
  const float* b1n_w1 = (const float*)d_in[13];
  const float* b1n_b1 = (const float*)d_in[14];
  const float* b1n_w2 = (const float*)d_in[15];
  const float* b1n_b2 = (const float*)d_in[16];
  const float* b2e_w1 = (const float*)d_in[17];
  const float* b2e_b1 = (const float*)d_in[18];
  const float* b2e_w2 = (const float*)d_in[19];
  const float* b2e_b2 = (const float*)d_in[20];
  const float* b2n_w1 = (const float*)d_in[21];
  const float* b2n_b1 = (const float*)d_in[22];
  const float* b2n_w2 = (const float*)d_in[23];
  const float* b2n_b2 = (const float*)d_in[24];
  const float* f_w = (const float*)d_in[25];
  const float* f_b = (const float*)d_in[26];
  const float* p1_w = (const float*)d_in[27];
  const float* p1_b = (const float*)d_in[28];
  const float* p2_w = (const float*)d_in[29];
  const float* p2_b = (const float*)d_in[30];
  const float* p3_w = (const float*)d_in[31];
  const float* p3_b = (const float*)d_in[32];
  float* out = (float*)d_out;

  char* ws = (char*)d_ws;
  size_t off = 0;
  auto alloc = [&](size_t bytes) {
    void* p = ws + off;
    off += (bytes + 255) & ~(size_t)255;
    return p;
  };
  int* nn = (int*)alloc((size_t)BDIM * NDIM * KNN * 4);
  float* m1 = (float*)alloc((size_t)BDIM * NDIM * 64 * 4);
  float* h1 = (float*)alloc((size_t)BDIM * NDIM * 64 * 4);
  u16* e1 = (u16*)alloc((size_t)BDIM * NDIM * KNN * 64 * 2);   // bf16
  float* m2 = (float*)alloc((size_t)BDIM * NDIM * 128 * 4);
  float* h2 = (float*)alloc((size_t)BDIM * NDIM * 128 * 4);
  u16* e2 = (u16*)alloc((size_t)BDIM * NDIM * KNN * 128 * 2);  // bf16
  float* h3 = (float*)alloc((size_t)BDIM * NDIM * 192 * 4);
  u16* pq2 = (u16*)alloc((size_t)BDIM * NDIM * 96 * 2);        // bf16
  u16* pq3 = (u16*)alloc((size_t)BDIM * NDIM * 192 * 2);       // bf16
  int* pooled = (int*)alloc((size_t)BDIM * 512 * 4);
  u16* w1b3e = (u16*)alloc((size_t)96 * 128 * 2);
  u16* wpq3 = (u16*)alloc((size_t)192 * 128 * 2);
  u16* w2b3 = (u16*)alloc((size_t)192 * 96 * 2);
  u16* w1b2e = (u16*)alloc((size_t)48 * 64 * 2);
  u16* wpq2 = (u16*)alloc((size_t)96 * 64 * 2);
  u16* w2b2 = (u16*)alloc((size_t)128 * 64 * 2);
  float* w1p1 = (float*)alloc((size_t)32 * 68 * 4);
  u16* fwb = (u16*)alloc((size_t)512 * 384 * 2);
  u16* w1b1 = (u16*)alloc((size_t)32 * 32 * 2);
  u16* w2b1 = (u16*)alloc((size_t)64 * 32 * 2);
  u16* wn1b = (u16*)alloc((size_t)96 * 320 * 2);
  u16* wn2b = (u16*)alloc((size_t)192 * 96 * 2);

  knn_wcvt<<<BDIM * 256 + 768, 256, 0, stream>>>(
      inputs, nn, b2e_w1, b2e_w2, b1e_w1, b1e_w2, hn_w1, f_w, he_w1, he_w2,
      b2n_w1, b2n_w2, w1b3e, wpq3, w2b3, w1b2e, wpq2, w2b2, w1p1, fwb, w1b1,
      w2b1, wn1b, wn2b, pooled);

  edge_mfma<4, 32, 32, 64, true, true, false><<<BDIM * NDIM / 4, 256, 0, stream>>>(
      nullptr, inputs, nn, w1b1, he_b1, w2b1, he_b2, nullptr, e1, m1, nullptr,
      nullptr, nullptr, nullptr, nullptr, nullptr);
  node_conv<64, 3, 64, 68, 32, 64, 96, true><<<BDIM * NDIM / 64, 256, 0, stream>>>(
      nullptr, inputs, m1, w1p1, hn_b1, hn_w2, hn_b2, h1, wpq2, pq2);

  edge_mfma<4, 64, 48, 128, true, false, false><<<BDIM * NDIM / 4, 256, 0, stream>>>(
      e1, nullptr, nn, w1b2e, b1e_b1, w2b2, b1e_b2, pq2, e2, m2, nullptr,
      nullptr, nullptr, nullptr, nullptr, nullptr);
  node_conv<32, 64, 128, 192, 48, 128, 192, false><<<BDIM * NDIM / 32, 256, 0, stream>>>(
      h1, nullptr, m2, b1n_w1, b1n_b1, b1n_w2, b1n_b2, h2, wpq3, pq3);

  edge_mfma<4, 128, 96, 192, false, false, true><<<BDIM * NDIM / 4, 256, 0, stream>>>(
      e2, nullptr, nn, w1b3e, b2e_b1, w2b3, b2e_b2, pq3, nullptr, nullptr, h2,
      wn1b, b2n_b1, wn2b, b2n_b2, h3);

  fuse_pool_mfma<<<BDIM * NDIM / 32, 256, 0, stream>>>(h1, h2, h3, fwb, f_b,
                                                       pooled);
  head_kernel<<<BDIM + 24, 256, 0, stream>>>(pooled, p1_w, p1_b, p2_w, p2_b,
                                             p3_w, p3_b, inputs, out);
}

// Round 17
// 225.180 us; speedup vs baseline: 8.0259x; 1.0525x over previous
//
#include <hip/hip_runtime.h>

#define BDIM 8
#define NDIM 1024
#define KNN 20

typedef unsigned short u16;
typedef float f32x4 __attribute__((ext_vector_type(4)));
typedef short short8 __attribute__((ext_vector_type(8)));
typedef unsigned short ushort8 __attribute__((ext_vector_type(8)));

__device__ inline u16 f2bf(float f) {
  unsigned u = __float_as_uint(f);
  unsigned r = (u + 0x7fffu + ((u >> 16) & 1u)) >> 16;
  return (u16)r;
}
__device__ inline float bf2f(u16 v) {
  return __uint_as_float(((unsigned)v) << 16);
}

// ---- merged: KNN (blocks 0..2047, bit-exact) + weight prep (blocks 2048+) ----
__global__ __launch_bounds__(256) void knn_wcvt(
    const float* __restrict__ x, int* __restrict__ nn,
    const float* __restrict__ w1_3, const float* __restrict__ w2_3,
    const float* __restrict__ w1_2, const float* __restrict__ w2_2,
    const float* __restrict__ hn_w1, const float* __restrict__ f_w,
    const float* __restrict__ he_w1, const float* __restrict__ he_w2,
    const float* __restrict__ bn_w1, const float* __restrict__ bn_w2,
    u16* __restrict__ w1b3e, u16* __restrict__ wpq3, u16* __restrict__ w2b3,
    u16* __restrict__ w1b2e, u16* __restrict__ wpq2, u16* __restrict__ w2b2,
    float* __restrict__ w1p1, u16* __restrict__ fwb,
    u16* __restrict__ w1b1, u16* __restrict__ w2b1,
    u16* __restrict__ wn1b, u16* __restrict__ wn2b, int* __restrict__ pooled) {
  const int tid = threadIdx.x;
  if (blockIdx.x >= BDIM * 256) {
    const int idx = (blockIdx.x - BDIM * 256) * 256 + tid;
    if (idx < 512 * 384) fwb[idx] = f2bf(f_w[idx]);
    if (idx < 96 * 128) {
      int oc = idx >> 7, c = idx & 127;
      w1b3e[idx] = f2bf(w1_3[oc * 384 + c]);
    }
    if (idx < 192 * 128) {
      int n = idx >> 7, c = idx & 127;
      wpq3[idx] = f2bf(n < 96 ? w1_3[n * 384 + 128 + c]
                              : w1_3[(n - 96) * 384 + 256 + c]);
    }
    if (idx < 192 * 96) w2b3[idx] = f2bf(w2_3[idx]);
    if (idx < 48 * 64) {
      int oc = idx >> 6, c = idx & 63;
      w1b2e[idx] = f2bf(w1_2[oc * 192 + c]);
    }
    if (idx < 96 * 64) {
      int n = idx >> 6, c = idx & 63;
      wpq2[idx] = f2bf(n < 48 ? w1_2[n * 192 + 64 + c]
                              : w1_2[(n - 48) * 192 + 128 + c]);
    }
    if (idx < 128 * 64) {
      int oc = idx >> 6, i = idx & 63;
      w2b2[idx] = (i < 48) ? f2bf(w2_2[oc * 48 + i]) : (u16)0;
    }
    if (idx < 32 * 68) {
      int oc = idx / 68, c = idx - oc * 68;
      w1p1[idx] = (c < 67) ? hn_w1[oc * 67 + c] : 0.0f;
    }
    if (idx < 32 * 32) {
      int oc = idx >> 5, c = idx & 31;
      w1b1[idx] = (c < 12) ? f2bf(he_w1[oc * 12 + c]) : (u16)0;
    }
    if (idx < 64 * 32) w2b1[idx] = f2bf(he_w2[idx]);
    if (idx < 96 * 320) wn1b[idx] = f2bf(bn_w1[idx]);   // b2n_w1 [96][320]
    if (idx < 192 * 96) wn2b[idx] = f2bf(bn_w2[idx]);   // b2n_w2 [192][96]
    if (idx < BDIM * 512) pooled[idx] = 0;
    return;
  }
  {
#pragma clang fp contract(off)
    __shared__ float xs0[NDIM], xs1[NDIM], xs2[NDIM], sq[NDIM];
    const int lane = tid & 63;
    const int w = tid >> 6;
    const int b = blockIdx.x >> 8;
    const int n = ((blockIdx.x & 255) << 2) + w;
    for (int i = tid; i < NDIM; i += 256) {
      float a0 = x[(b * 3 + 0) * NDIM + i];
      float a1 = x[(b * 3 + 1) * NDIM + i];
      float a2 = x[(b * 3 + 2) * NDIM + i];
      xs0[i] = a0; xs1[i] = a1; xs2[i] = a2;
      sq[i] = (a0 * a0 + a1 * a1) + a2 * a2;
    }
    __syncthreads();
    const float xn0 = xs0[n], xn1 = xs1[n], xn2 = xs2[n], sqn = sq[n];
    float dl[16];
#pragma unroll
    for (int t = 0; t < 16; ++t) {
      int m = t * 64 + lane;
      float dot = (xn0 * xs0[m] + xn1 * xs1[m]) + xn2 * xs2[m];
      dl[t] = (sqn - 2.0f * dot) + sq[m];
    }
    int* nnrow = &nn[(b * NDIM + n) * KNN];
    for (int r = 0; r < KNN; ++r) {
      float bd = dl[0];
      int bt = 0;
#pragma unroll
      for (int t = 1; t < 16; ++t) {
        if (dl[t] < bd) { bd = dl[t]; bt = t; }
      }
      int bi = bt * 64 + lane;
#pragma unroll
      for (int off = 1; off < 64; off <<= 1) {
        float pd = __shfl_xor(bd, off);
        int pi = __shfl_xor(bi, off);
        if (pd < bd || (pd == bd && pi < bi)) { bd = pd; bi = pi; }
      }
      if (lane == 0) nnrow[r] = bi;
      if ((bi & 63) == lane) {
        int wt = bi >> 6;
#pragma unroll
        for (int t = 0; t < 16; ++t) {
          if (t == wt) dl[t] = 3.4e38f;
        }
      }
    }
  }
}

// ---- MFMA edge MP (lean v9): QY buffer aliasing, 2 barriers ----
template <int PTS, int CE, int CMID, int COUT, bool WRITE_E, bool FIRST>
__global__ __launch_bounds__(256) void edge_mfma(
    const u16* __restrict__ eprev, const float* __restrict__ finput,
    const int* __restrict__ nnb, const u16* __restrict__ w1b,
    const float* __restrict__ b1v, const u16* __restrict__ w2b,
    const float* __restrict__ b2v, const u16* __restrict__ pq,
    u16* __restrict__ eout, float* __restrict__ mout) {
  constexpr int K2 = (CMID + 31) & ~31;
  constexpr int NPQ = 2 * CMID;
  constexpr int MT = PTS * KNN;       // 80 edges
  constexpr int MTL = MT / 16;        // 5 M-tiles (exact)
  constexpr int XPB = CE + 8;
  constexpr int QYP = K2 + 8;         // unified Q / Y1 pitch
  __shared__ u16 Xs[MT * XPB];
  __shared__ u16 QY[MT * QYP];        // Q staged here, then overwritten by Y1
  __shared__ float pld[FIRST ? 8 : PTS * CMID];
  const int tid = threadIdx.x;
  const int lane = tid & 63;
  const int wv = tid >> 6;
  const int q = lane >> 4;
  const int bn0 = blockIdx.x * PTS;
  const int b = bn0 >> 10;
  // ---- bulk staging ----
  if constexpr (FIRST) {
    for (int idx = tid; idx < MT * (CE / 8); idx += 256) {
      int p = idx / (CE / 8), kc = idx - p * (CE / 8);
      int k0 = kc * 8;
      int bn = bn0 + p / KNN;
      int n = bn & (NDIM - 1);
      int j = nnb[(size_t)bn0 * KNN + p];
      ushort8 r;
#pragma unroll
      for (int t = 0; t < 8; ++t) {
        int c = k0 + t;
        float v = 0.0f;
        if (c < 3) v = finput[(b * 3 + c) * NDIM + n];
        else if (c < 6)
          v = finput[(b * 3 + c - 3) * NDIM + n] -
              finput[(b * 3 + c - 3) * NDIM + j];
        else if (c < 9) v = finput[(b * 3 + c - 6) * NDIM + n];
        else if (c < 12) v = finput[(b * 3 + c - 9) * NDIM + j];
        r[t] = f2bf(v);
      }
      *(ushort8*)&Xs[p * XPB + k0] = r;
    }
  } else {
    constexpr int KC = CE / 8;
    for (int ch = tid; ch < MT * KC; ch += 256) {
      int p = ch / KC, kc = ch - p * KC;
      int k0 = kc * 8;
      *(uint4*)&Xs[p * XPB + k0] =
          *(const uint4*)&eprev[((size_t)blockIdx.x * MT + p) * CE + k0];
    }
    constexpr int QC = CMID / 8;
    for (int i = tid; i < MT * QC; i += 256) {
      int p = i / QC, c8 = (i - p * QC) * 8;
      int j = nnb[(size_t)bn0 * KNN + p];
      *(uint4*)&QY[p * QYP + c8] =
          *(const uint4*)&pq[((size_t)(b << 10) + j) * NPQ + CMID + c8];
    }
    if constexpr (K2 != CMID) {
      constexpr int PC = (K2 - CMID) / 8;
      for (int i = tid; i < MT * PC; i += 256) {
        int p = i / PC, c8 = CMID + (i - p * PC) * 8;
        uint4 z = {0, 0, 0, 0};
        *(uint4*)&QY[p * QYP + c8] = z;
      }
    }
    for (int i = tid; i < PTS * CMID; i += 256) {
      int pt = i / CMID, c = i - pt * CMID;
      pld[i] = bf2f(pq[(size_t)(bn0 + pt) * NPQ + c]) + b1v[c];
    }
  }
  __syncthreads();
  // ---- conv1: Xs @ W1^T (+P+Q folded) -> relu -> QY (in-place over Q) ----
  {
    constexpr int NT1 = CMID / 16;
    constexpr int J1 = MTL * NT1;
    constexpr int KS1 = CE / 32;
    for (int job = wv; job < J1; job += 4) {
      int mt = job / NT1, nt = job - mt * NT1;
      int row = mt * 16 + (lane & 15);
      int ncol = nt * 16 + (lane & 15);
      int kb = q * 8;
      f32x4 acc = {0.f, 0.f, 0.f, 0.f};
      const u16* ap = &Xs[row * XPB + kb];
      const u16* bp = &w1b[(size_t)ncol * CE + kb];
#pragma unroll
      for (int ks = 0; ks < KS1; ++ks) {
        short8 a = *(const short8*)(ap + ks * 32);
        short8 bb = *(const short8*)(bp + ks * 32);
        acc = __builtin_amdgcn_mfma_f32_16x16x32_bf16(a, bb, acc, 0, 0, 0);
      }
      int m0 = mt * 16 + q * 4;
      if constexpr (FIRST) {
        float bias = b1v[ncol];
#pragma unroll
        for (int r = 0; r < 4; ++r) {
          float yv = fmaxf(acc[r] + bias, 0.0f);
          QY[(m0 + r) * QYP + ncol] = f2bf(yv);
        }
      } else {
        int pt = m0 / KNN;
        float padd = pld[pt * CMID + ncol];
#pragma unroll
        for (int r = 0; r < 4; ++r) {
          int m = m0 + r;
          float qadd = bf2f(QY[m * QYP + ncol]);
          float yv = fmaxf(acc[r] + padd + qadd, 0.0f);
          QY[m * QYP + ncol] = f2bf(yv);
        }
      }
    }
  }
  __syncthreads();
  // ---- conv2: fp32 m-sum, const-folded pt map ----
  {
    constexpr int NT2 = COUT / 16;
    constexpr int KS2 = K2 / 32;
    for (int nt = wv; nt < NT2; nt += 4) {
      int ncol = nt * 16 + (lane & 15);
      int kb = q * 8;
      short8 bfrag[KS2];
      const u16* bp = &w2b[(size_t)ncol * K2 + kb];
#pragma unroll
      for (int ks = 0; ks < KS2; ++ks)
        bfrag[ks] = *(const short8*)(bp + ks * 32);
      float bias = b2v[ncol];
      float s[PTS];
#pragma unroll
      for (int pt = 0; pt < PTS; ++pt) s[pt] = 0.0f;
#pragma unroll
      for (int mt = 0; mt < MTL; ++mt) {
        f32x4 acc = {0.f, 0.f, 0.f, 0.f};
        const u16* ap = &QY[(mt * 16 + (lane & 15)) * QYP + kb];
#pragma unroll
        for (int ks = 0; ks < KS2; ++ks) {
          short8 a = *(const short8*)(ap + ks * 32);
          acc = __builtin_amdgcn_mfma_f32_16x16x32_bf16(a, bfrag[ks], acc, 0, 0, 0);
        }
        int m0 = mt * 16 + q * 4;
        float part = 0.0f;
#pragma unroll
        for (int r = 0; r < 4; ++r) {
          float yv = fmaxf(acc[r] + bias, 0.0f);
          if (WRITE_E)
            eout[((size_t)blockIdx.x * MT + m0 + r) * COUT + ncol] = f2bf(yv);
          part += yv;
        }
        int ptA = (4 * mt) / 5;
        int ptB = (4 * mt + 3) / 5;
        int qb = 5 * ptB - 4 * mt;
#pragma unroll
        for (int pt2 = 0; pt2 < PTS; ++pt2) {
          if (pt2 == ptA && ptA == ptB) s[pt2] += part;
          else if (pt2 == ptA) s[pt2] += (q < qb) ? part : 0.0f;
          else if (pt2 == ptB) s[pt2] += (q < qb) ? 0.0f : part;
        }
      }
#pragma unroll
      for (int pt = 0; pt < PTS; ++pt) {
        float sv = s[pt];
        sv += __shfl_xor(sv, 16);
        sv += __shfl_xor(sv, 32);
        if (lane < 16)
          mout[(size_t)(bn0 + pt) * COUT + nt * 16 + lane] = sv;
      }
    }
  }
}

// ---- node conv: fp32 microtile GEMM + optional fused PQ MFMA phase ----
template <int TP, int CH, int CM, int CINP, int CMID, int COUT, int NPQ, bool FIRSTH>
__global__ __launch_bounds__(256) void node_conv(
    const float* __restrict__ h, const float* __restrict__ inputs,
    const float* __restrict__ mbuf, const float* __restrict__ w1p,
    const float* __restrict__ b1v, const float* __restrict__ w2,
    const float* __restrict__ b2v, float* __restrict__ hout,
    const u16* __restrict__ wpq, u16* __restrict__ pq) {
  constexpr int CIN = CH + CM;
  constexpr int XP = CINP + 4;
  constexpr int Y1P = CMID + 4;
  constexpr int PG = TP / 4;
  constexpr int HP = COUT + 8;
  __shared__ float Xs[TP * XP];
  __shared__ float Y1s[TP * Y1P];
  __shared__ u16 Hb[(NPQ > 0) ? TP * HP : 8];
  const int tid = threadIdx.x;
  const int bn0 = blockIdx.x * TP;
  if constexpr (FIRSTH) {
    for (int idx = tid; idx < TP * CIN; idx += 256) {
      int p = idx / CIN, c = idx - p * CIN;
      int bn = bn0 + p;
      int b = bn >> 10, n = bn & (NDIM - 1);
      Xs[p * XP + c] = (c < CH) ? inputs[(b * 3 + c) * NDIM + n]
                                : mbuf[(size_t)bn * CM + (c - CH)];
    }
    if constexpr (CINP > CIN) {
      constexpr int PAD = CINP - CIN;
      for (int idx = tid; idx < TP * PAD; idx += 256) {
        int p = idx / PAD, c = CIN + idx % PAD;
        Xs[p * XP + c] = 0.0f;
      }
    }
  } else {
    constexpr int C4 = CIN / 4;
    for (int idx = tid; idx < TP * C4; idx += 256) {
      int p = idx / C4, c = (idx - p * C4) * 4;
      int bn = bn0 + p;
      float4 v = (c < CH) ? *(const float4*)&h[(size_t)bn * CH + c]
                          : *(const float4*)&mbuf[(size_t)bn * CM + (c - CH)];
      *(float4*)&Xs[p * XP + c] = v;
    }
  }
  __syncthreads();
  {
    constexpr int NT1 = PG * (CMID / 4);
    for (int t = tid; t < NT1; t += 256) {
      int pg = t % PG, og = t / PG;
      float acc[4][4];
#pragma unroll
      for (int j = 0; j < 4; ++j) {
        float bj = b1v[og * 4 + j];
#pragma unroll
        for (int i = 0; i < 4; ++i) acc[i][j] = bj;
      }
      for (int cin = 0; cin < CINP; cin += 4) {
        float4 xr[4], wr[4];
#pragma unroll
        for (int i = 0; i < 4; ++i)
          xr[i] = *(const float4*)&Xs[(pg * 4 + i) * XP + cin];
#pragma unroll
        for (int j = 0; j < 4; ++j)
          wr[j] = *(const float4*)&w1p[(size_t)(og * 4 + j) * CINP + cin];
#pragma unroll
        for (int i = 0; i < 4; ++i)
#pragma unroll
          for (int j = 0; j < 4; ++j) {
            acc[i][j] += xr[i].x * wr[j].x;
            acc[i][j] += xr[i].y * wr[j].y;
            acc[i][j] += xr[i].z * wr[j].z;
            acc[i][j] += xr[i].w * wr[j].w;
          }
      }
#pragma unroll
      for (int i = 0; i < 4; ++i)
#pragma unroll
        for (int j = 0; j < 4; ++j)
          Y1s[(pg * 4 + i) * Y1P + og * 4 + j] = fmaxf(acc[i][j], 0.0f);
    }
  }
  __syncthreads();
  {
    constexpr int NT2 = PG * (COUT / 4);
    for (int t = tid; t < NT2; t += 256) {
      int pg = t % PG, og = t / PG;
      float acc[4][4];
#pragma unroll
      for (int j = 0; j < 4; ++j) {
        float bj = b2v[og * 4 + j];
#pragma unroll
        for (int i = 0; i < 4; ++i) acc[i][j] = bj;
      }
      for (int cin = 0; cin < CMID; cin += 4) {
        float4 xr[4], wr[4];
#pragma unroll
        for (int i = 0; i < 4; ++i)
          xr[i] = *(const float4*)&Y1s[(pg * 4 + i) * Y1P + cin];
#pragma unroll
        for (int j = 0; j < 4; ++j)
          wr[j] = *(const float4*)&w2[(size_t)(og * 4 + j) * CMID + cin];
#pragma unroll
        for (int i = 0; i < 4; ++i)
#pragma unroll
          for (int j = 0; j < 4; ++j) {
            acc[i][j] += xr[i].x * wr[j].x;
            acc[i][j] += xr[i].y * wr[j].y;
            acc[i][j] += xr[i].z * wr[j].z;
            acc[i][j] += xr[i].w * wr[j].w;
          }
      }
#pragma unroll
      for (int i = 0; i < 4; ++i) {
        int bn = bn0 + pg * 4 + i;
#pragma unroll
        for (int j = 0; j < 4; ++j) {
          float v = fmaxf(acc[i][j], 0.0f);
          hout[(size_t)bn * COUT + og * 4 + j] = v;
          if constexpr (NPQ > 0) Hb[(pg * 4 + i) * HP + og * 4 + j] = f2bf(v);
        }
      }
    }
  }
  if constexpr (NPQ > 0) {
    __syncthreads();
    const int lane = tid & 63;
    const int wv = tid >> 6;
    constexpr int NT = NPQ / 16;
    constexpr int JOBS = (TP / 16) * NT;
    constexpr int KS = COUT / 32;
    for (int job = wv; job < JOBS; job += 4) {
      int mt = job / NT, nt = job - mt * NT;
      int row = mt * 16 + (lane & 15);
      int ncol = nt * 16 + (lane & 15);
      int kb = (lane >> 4) * 8;
      f32x4 acc = {0.f, 0.f, 0.f, 0.f};
      const u16* ap = &Hb[row * HP + kb];
      const u16* bp = &wpq[(size_t)ncol * COUT + kb];
#pragma unroll
      for (int ks = 0; ks < KS; ++ks) {
        short8 a = *(const short8*)(ap + ks * 32);
        short8 bb = *(const short8*)(bp + ks * 32);
        acc = __builtin_amdgcn_mfma_f32_16x16x32_bf16(a, bb, acc, 0, 0, 0);
      }
      int m0 = mt * 16 + (lane >> 4) * 4;
#pragma unroll
      for (int r = 0; r < 4; ++r)
        pq[(size_t)(bn0 + m0 + r) * NPQ + ncol] = f2bf(acc[r]);
    }
  }
}

// ---- fuse_pool v2: fused node3 (h2,m3 -> h3 in LDS) + fusion conv + max pool ----
__global__ __launch_bounds__(256) void fuse_pool_mfma(
    const float* __restrict__ h1, const float* __restrict__ h2,
    const float* __restrict__ m3, const u16* __restrict__ wn1b,
    const float* __restrict__ bn1v, const u16* __restrict__ wn2b,
    const float* __restrict__ bn2v, const u16* __restrict__ fwb,
    const float* __restrict__ fb, int* __restrict__ pooled) {
  constexpr int TP = 32;
  constexpr int XNP = 328;   // node X pitch (320 + 8)
  constexpr int Y1NP = 104;  // node Y1 pitch (96 + 8)
  constexpr int XPB = 392;   // fusion X pitch (384 + 8)
  __shared__ __align__(16) char smem[TP * XPB * 2];  // 25088 B; Xn(20992) aliases
  u16* Xs = (u16*)smem;
  u16* Xn = (u16*)smem;
  __shared__ u16 Y1n[TP * Y1NP];
  __shared__ int pmax[512];
  const int tid = threadIdx.x;
  const int lane = tid & 63;
  const int wv = tid >> 6;
  const int q = lane >> 4;
  const int bn0 = blockIdx.x * TP;
  const int b = bn0 >> 10;
  for (int i = tid; i < 512; i += 256) pmax[i] = 0;
  // ---- phase 0: stage Xn = [h2(128) | m3(192) | 0-pad(8)] bf16 ----
  for (int i = tid; i < TP * 41; i += 256) {
    int p = i / 41, kc = i - p * 41;
    int k0 = kc * 8;
    ushort8 r;
    if (kc < 16) {
      const float* src = &h2[(size_t)(bn0 + p) * 128 + k0];
      float4 f0 = *(const float4*)src;
      float4 f1 = *(const float4*)(src + 4);
      r[0] = f2bf(f0.x); r[1] = f2bf(f0.y); r[2] = f2bf(f0.z); r[3] = f2bf(f0.w);
      r[4] = f2bf(f1.x); r[5] = f2bf(f1.y); r[6] = f2bf(f1.z); r[7] = f2bf(f1.w);
    } else if (kc < 40) {
      const float* src = &m3[(size_t)(bn0 + p) * 192 + (k0 - 128)];
      float4 f0 = *(const float4*)src;
      float4 f1 = *(const float4*)(src + 4);
      r[0] = f2bf(f0.x); r[1] = f2bf(f0.y); r[2] = f2bf(f0.z); r[3] = f2bf(f0.w);
      r[4] = f2bf(f1.x); r[5] = f2bf(f1.y); r[6] = f2bf(f1.z); r[7] = f2bf(f1.w);
    } else {
#pragma unroll
      for (int t = 0; t < 8; ++t) r[t] = 0;
    }
    *(ushort8*)&Xn[p * XNP + k0] = r;
  }
  __syncthreads();
  // ---- phase 1: conv1n [32x320] @ wn1^T -> relu -> Y1n [32x96] ----
  for (int job = wv; job < 12; job += 4) {
    int mt = job / 6, nt = job - mt * 6;
    int row = mt * 16 + (lane & 15);
    int ncol = nt * 16 + (lane & 15);
    int kb = q * 8;
    f32x4 acc = {0.f, 0.f, 0.f, 0.f};
    const u16* ap = &Xn[row * XNP + kb];
    const u16* bp = &wn1b[(size_t)ncol * 320 + kb];
#pragma unroll
    for (int ks = 0; ks < 10; ++ks) {
      short8 a = *(const short8*)(ap + ks * 32);
      short8 bb = *(const short8*)(bp + ks * 32);
      acc = __builtin_amdgcn_mfma_f32_16x16x32_bf16(a, bb, acc, 0, 0, 0);
    }
    float bias = bn1v[ncol];
    int m0 = mt * 16 + q * 4;
#pragma unroll
    for (int r = 0; r < 4; ++r)
      Y1n[(m0 + r) * Y1NP + ncol] = f2bf(fmaxf(acc[r] + bias, 0.0f));
  }
  __syncthreads();  // Xn dead; Xs (same memory) can now be written
  // ---- phase 2a: stage h1|h2 into Xs cols 0..191 ----
  for (int i = tid; i < TP * 24; i += 256) {
    int p = i / 24, kc = i - p * 24;
    int k0 = kc * 8;
    const float* src = (k0 < 64) ? &h1[(size_t)(bn0 + p) * 64 + k0]
                                 : &h2[(size_t)(bn0 + p) * 128 + (k0 - 64)];
    float4 f0 = *(const float4*)src;
    float4 f1 = *(const float4*)(src + 4);
    ushort8 r;
    r[0] = f2bf(f0.x); r[1] = f2bf(f0.y); r[2] = f2bf(f0.z); r[3] = f2bf(f0.w);
    r[4] = f2bf(f1.x); r[5] = f2bf(f1.y); r[6] = f2bf(f1.z); r[7] = f2bf(f1.w);
    *(ushort8*)&Xs[p * XPB + k0] = r;
  }
  if (tid < TP) {
    ushort8 z = {0, 0, 0, 0, 0, 0, 0, 0};
    *(ushort8*)&Xs[tid * XPB + 384] = z;
  }
  // ---- phase 2b: conv2n [32x96] @ wn2^T -> relu -> h3 -> Xs cols 192..383 ----
  for (int job = wv; job < 24; job += 4) {
    int mt = job / 12, nt = job - mt * 12;
    int row = mt * 16 + (lane & 15);
    int ncol = nt * 16 + (lane & 15);
    int kb = q * 8;
    f32x4 acc = {0.f, 0.f, 0.f, 0.f};
    const u16* ap = &Y1n[row * Y1NP + kb];
    const u16* bp = &wn2b[(size_t)ncol * 96 + kb];
#pragma unroll
    for (int ks = 0; ks < 3; ++ks) {
      short8 a = *(const short8*)(ap + ks * 32);
      short8 bb = *(const short8*)(bp + ks * 32);
      acc = __builtin_amdgcn_mfma_f32_16x16x32_bf16(a, bb, acc, 0, 0, 0);
    }
    float bias = bn2v[ncol];
    int m0 = mt * 16 + q * 4;
#pragma unroll
    for (int r = 0; r < 4; ++r)
      Xs[(m0 + r) * XPB + 192 + ncol] = f2bf(fmaxf(acc[r] + bias, 0.0f));
  }
  __syncthreads();
  // ---- phase 3: fusion conv [32x384] @ fwb^T + relu + max pool ----
  for (int job = wv; job < 64; job += 4) {
    int mt = job / 32, nt = job - mt * 32;
    int row = mt * 16 + (lane & 15);
    int ncol = nt * 16 + (lane & 15);
    int kb = q * 8;
    f32x4 acc = {0.f, 0.f, 0.f, 0.f};
    const u16* ap = &Xs[row * XPB + kb];
    const u16* bp = &fwb[(size_t)ncol * 384 + kb];
#pragma unroll
    for (int ks = 0; ks < 12; ++ks) {
      short8 a = *(const short8*)(ap + ks * 32);
      short8 bb = *(const short8*)(bp + ks * 32);
      acc = __builtin_amdgcn_mfma_f32_16x16x32_bf16(a, bb, acc, 0, 0, 0);
    }
    float bias = fb[ncol];
    float v = fmaxf(fmaxf(acc[0], acc[1]), fmaxf(acc[2], acc[3]));
    v = fmaxf(v + bias, 0.0f);
    v = fmaxf(v, __shfl_xor(v, 16));
    v = fmaxf(v, __shfl_xor(v, 32));
    if (lane < 16) atomicMax(&pmax[ncol], __float_as_int(v));
  }
  __syncthreads();
  for (int i = tid; i < 512; i += 256)
    atomicMax(&pooled[b * 512 + i], pmax[i]);
}

// ---------------- prediction head (blocks 0..7) + inputs echo copy (blocks 8+) ----------------
__global__ __launch_bounds__(256) void head_kernel(
    const int* __restrict__ pooledi, const float* __restrict__ p1w,
    const float* __restrict__ p1b, const float* __restrict__ p2w,
    const float* __restrict__ p2b, const float* __restrict__ p3w,
    const float* __restrict__ p3b, const float* __restrict__ inputs,
    float* __restrict__ out) {
  const int tid = threadIdx.x;
  if (blockIdx.x >= BDIM) {
    int idx = (blockIdx.x - BDIM) * 256 + tid;
    if (idx < (BDIM * 3 * NDIM) / 4) {
      const float4* src = (const float4*)inputs;
      float4* dst = (float4*)(out + BDIM * 40);
      dst[idx] = src[idx];
    }
    return;
  }
  __shared__ float xs[512], y1[256], y2[128];
  const int b = blockIdx.x;
  for (int i = tid; i < 512; i += 256) xs[i] = __int_as_float(pooledi[b * 512 + i]);
  __syncthreads();
  {
    float acc = p1b[tid];
    for (int c = 0; c < 512; ++c) acc += xs[c] * p1w[tid * 512 + c];
    y1[tid] = fmaxf(acc, 0.0f);
  }
  __syncthreads();
  if (tid < 128) {
    float acc = p2b[tid];
    for (int c = 0; c < 256; ++c) acc += y1[c] * p2w[tid * 256 + c];
    y2[tid] = fmaxf(acc, 0.0f);
  }
  __syncthreads();
  if (tid < 40) {
    float acc = p3b[tid];
    for (int c = 0; c < 128; ++c) acc += y2[c] * p3w[tid * 128 + c];
    out[b * 40 + tid] = acc;
  }
}

extern "C" void kernel_launch(void* const* d_in, const int* in_sizes, int n_in,
                              void* d_out, int out_size, void* d_ws,
                              size_t ws_size, hipStream_t stream) {
  const float* inputs = (const float*)d_in[0];
  const float* he_w1 = (const float*)d_in[1];
  const float* he_b1 = (const float*)d_in[2];
  const float* he_w2 = (const float*)d_in[3];
  const float* he_b2 = (const float*)d_in[4];
  const float* hn_w1 = (const float*)d_in[5];
  const float* hn_b1 = (const float*)d_in[6];
  const float* hn_w2 = (const float*)d_in[7];
  const float* hn_b2 = (const float*)d_in[8];
  const float* b1e_w1 = (const float*)d_in[9];
  const float* b1e_b1 = (const float*)d_in[10];
  const float* b1e_w2 = (const float*)d_in[11];
  const float* b1e_b2 = (const float*)d_in[12];
  const float* b1n_w1 = (const float*)d_in[13];
  const float* b1n_b1 = (const float*)d_in[14];
  const float* b1n_w2 = (const float*)d_in[15];
  const float* b1n_b2 = (const float*)d_in[16];
  const float* b2e_w1 = (const float*)d_in[17];
  const float* b2e_b1 = (const float*)d_in[18];
  const float* b2e_w2 = (const float*)d_in[19];
  const float* b2e_b2 = (const float*)d_in[20];
  const float* b2n_w1 = (const float*)d_in[21];
  const float* b2n_b1 = (const float*)d_in[22];
  const float* b2n_w2 = (const float*)d_in[23];
  const float* b2n_b2 = (const float*)d_in[24];
  const float* f_w = (const float*)d_in[25];
  const float* f_b = (const float*)d_in[26];
  const float* p1_w = (const float*)d_in[27];
  const float* p1_b = (const float*)d_in[28];
  const float* p2_w = (const float*)d_in[29];
  const float* p2_b = (const float*)d_in[30];
  const float* p3_w = (const float*)d_in[31];
  const float* p3_b = (const float*)d_in[32];
  float* out = (float*)d_out;

  char* ws = (char*)d_ws;
  size_t off = 0;
  auto alloc = [&](size_t bytes) {
    void* p = ws + off;
    off += (bytes + 255) & ~(size_t)255;
    return p;
  };
  int* nn = (int*)alloc((size_t)BDIM * NDIM * KNN * 4);
  float* m1 = (float*)alloc((size_t)BDIM * NDIM * 64 * 4);
  float* h1 = (float*)alloc((size_t)BDIM * NDIM * 64 * 4);
  u16* e1 = (u16*)alloc((size_t)BDIM * NDIM * KNN * 64 * 2);   // bf16
  float* m2 = (float*)alloc((size_t)BDIM * NDIM * 128 * 4);
  float* h2 = (float*)alloc((size_t)BDIM * NDIM * 128 * 4);
  u16* e2 = (u16*)alloc((size_t)BDIM * NDIM * KNN * 128 * 2);  // bf16
  float* m3 = (float*)alloc((size_t)BDIM * NDIM * 192 * 4);
  u16* pq2 = (u16*)alloc((size_t)BDIM * NDIM * 96 * 2);        // bf16
  u16* pq3 = (u16*)alloc((size_t)BDIM * NDIM * 192 * 2);       // bf16
  int* pooled = (int*)alloc((size_t)BDIM * 512 * 4);
  u16* w1b3e = (u16*)alloc((size_t)96 * 128 * 2);
  u16* wpq3 = (u16*)alloc((size_t)192 * 128 * 2);
  u16* w2b3 = (u16*)alloc((size_t)192 * 96 * 2);
  u16* w1b2e = (u16*)alloc((size_t)48 * 64 * 2);
  u16* wpq2 = (u16*)alloc((size_t)96 * 64 * 2);
  u16* w2b2 = (u16*)alloc((size_t)128 * 64 * 2);
  float* w1p1 = (float*)alloc((size_t)32 * 68 * 4);
  u16* fwb = (u16*)alloc((size_t)512 * 384 * 2);
  u16* w1b1 = (u16*)alloc((size_t)32 * 32 * 2);
  u16* w2b1 = (u16*)alloc((size_t)64 * 32 * 2);
  u16* wn1b = (u16*)alloc((size_t)96 * 320 * 2);
  u16* wn2b = (u16*)alloc((size_t)192 * 96 * 2);

  knn_wcvt<<<BDIM * 256 + 768, 256, 0, stream>>>(
      inputs, nn, b2e_w1, b2e_w2, b1e_w1, b1e_w2, hn_w1, f_w, he_w1, he_w2,
      b2n_w1, b2n_w2, w1b3e, wpq3, w2b3, w1b2e, wpq2, w2b2, w1p1, fwb, w1b1,
      w2b1, wn1b, wn2b, pooled);

  edge_mfma<4, 32, 32, 64, true, true><<<BDIM * NDIM / 4, 256, 0, stream>>>(
      nullptr, inputs, nn, w1b1, he_b1, w2b1, he_b2, nullptr, e1, m1);
  node_conv<64, 3, 64, 68, 32, 64, 96, true><<<BDIM * NDIM / 64, 256, 0, stream>>>(
      nullptr, inputs, m1, w1p1, hn_b1, hn_w2, hn_b2, h1, wpq2, pq2);

  edge_mfma<4, 64, 48, 128, true, false><<<BDIM * NDIM / 4, 256, 0, stream>>>(
      e1, nullptr, nn, w1b2e, b1e_b1, w2b2, b1e_b2, pq2, e2, m2);
  node_conv<32, 64, 128, 192, 48, 128, 192, false><<<BDIM * NDIM / 32, 256, 0, stream>>>(
      h1, nullptr, m2, b1n_w1, b1n_b1, b1n_w2, b1n_b2, h2, wpq3, pq3);

  edge_mfma<4, 128, 96, 192, false, false><<<BDIM * NDIM / 4, 256, 0, stream>>>(
      e2, nullptr, nn, w1b3e, b2e_b1, w2b3, b2e_b2, pq3, nullptr, m3);

  fuse_pool_mfma<<<BDIM * NDIM / 32, 256, 0, stream>>>(
      h1, h2, m3, wn1b, b2n_b1, wn2b, b2n_b2, fwb, f_b, pooled);
  head_kernel<<<BDIM + 24, 256, 0, stream>>>(pooled, p1_w, p1_b, p2_w, p2_b,
                                             p3_w, p3_b, inputs, out);
}